// Round 1
// baseline (2365.252 us; speedup 1.0000x reference)
//
#include <hip/hip_runtime.h>
#include <hip/hip_bf16.h>
#include <math.h>

#define CCH 320
#define NHEADS 8
#define DH 40
#define HW 4096
#define FFI 1280

// ---------------------------------------------------------------------------
// GroupNorm: x (C=320, HW=4096) -> y transposed (HW, C), 32 groups of 10 ch.
// One block per group; group = 10*4096 contiguous floats.
__global__ __launch_bounds__(256) void gn_kernel(const float* __restrict__ X,
                                                 const float* __restrict__ w,
                                                 const float* __restrict__ b,
                                                 float* __restrict__ Y) {
    __shared__ float s1[256], s2[256];
    const int g = blockIdx.x, tid = threadIdx.x;
    const float* xg = X + g * 40960;
    float s = 0.f, sq = 0.f;
    for (int i = tid; i < 40960; i += 256) { float v = xg[i]; s += v; sq += v * v; }
    s1[tid] = s; s2[tid] = sq; __syncthreads();
    for (int off = 128; off > 0; off >>= 1) {
        if (tid < off) { s1[tid] += s1[tid + off]; s2[tid] += s2[tid + off]; }
        __syncthreads();
    }
    const float mean = s1[0] * (1.f / 40960.f);
    const float var  = s2[0] * (1.f / 40960.f) - mean * mean;
    const float rstd = rsqrtf(var + 1e-6f);
    for (int i = tid; i < 40960; i += 256) {
        int c  = g * 10 + (i >> 12);
        int hw = i & 4095;
        Y[hw * CCH + c] = (xg[i] - mean) * rstd * w[c] + b[c];
    }
}

// ---------------------------------------------------------------------------
// LayerNorm over last dim (320). One wave per row, 4 rows per block.
__global__ __launch_bounds__(256) void ln_kernel(const float* __restrict__ X,
                                                 const float* __restrict__ w,
                                                 const float* __restrict__ b,
                                                 float* __restrict__ Y) {
    const int row  = blockIdx.x * 4 + (threadIdx.x >> 6);
    const int lane = threadIdx.x & 63;
    const float* xr = X + row * CCH;
    float v[5];
    float s = 0.f, sq = 0.f;
#pragma unroll
    for (int i = 0; i < 5; ++i) { v[i] = xr[lane + 64 * i]; s += v[i]; sq += v[i] * v[i]; }
#pragma unroll
    for (int off = 32; off > 0; off >>= 1) {
        s  += __shfl_xor(s, off, 64);
        sq += __shfl_xor(sq, off, 64);
    }
    const float mean = s * (1.f / 320.f);
    const float var  = sq * (1.f / 320.f) - mean * mean;
    const float rstd = rsqrtf(var + 1e-5f);
    float* yr = Y + row * CCH;
#pragma unroll
    for (int i = 0; i < 5; ++i) {
        int c = lane + 64 * i;
        yr[c] = (v[i] - mean) * rstd * w[c] + b[c];
    }
}

// ---------------------------------------------------------------------------
// Generic fp32 GEMM: C[m,n] = sum_k A[m,k]*B[k,n] (+bias[n]) (+res[m,n]).
// Block tile 64x64, BK=16, 256 threads, 4x4 microtile. N = gridDim.x*64 exact;
// M guarded (needed for M=77 context GEMMs); K multiple of 16.
__global__ __launch_bounds__(256) void gemm_kernel(
    const float* __restrict__ A, int lda,
    const float* __restrict__ B, int ldb,
    const float* __restrict__ bias,
    const float* __restrict__ res,
    float* __restrict__ C, int ldc,
    int M, int K) {
    __shared__ __align__(16) float As[16][68];   // [k][m]
    __shared__ __align__(16) float Bs[16][68];   // [k][n]
    const int tid = threadIdx.x;
    const int tx = tid & 15, ty = tid >> 4;
    const int bn = blockIdx.x, bm = blockIdx.y;
    float acc[4][4] = {};
    for (int k0 = 0; k0 < K; k0 += 16) {
#pragma unroll
        for (int i = 0; i < 4; ++i) {
            int idx = tid + i * 256;
            int r = idx >> 4, c = idx & 15;
            int gm = bm * 64 + r;
            As[c][r] = (gm < M) ? A[gm * lda + k0 + c] : 0.f;
        }
#pragma unroll
        for (int i = 0; i < 4; ++i) {
            int idx = tid + i * 256;
            int r = idx >> 6, c = idx & 63;
            Bs[r][c] = B[(k0 + r) * ldb + bn * 64 + c];
        }
        __syncthreads();
#pragma unroll
        for (int kk = 0; kk < 16; ++kk) {
            float4 a4 = *(const float4*)&As[kk][ty * 4];
            float4 b4 = *(const float4*)&Bs[kk][tx * 4];
            float av[4] = {a4.x, a4.y, a4.z, a4.w};
            float bv[4] = {b4.x, b4.y, b4.z, b4.w};
#pragma unroll
            for (int i = 0; i < 4; ++i)
#pragma unroll
                for (int j = 0; j < 4; ++j) acc[i][j] += av[i] * bv[j];
        }
        __syncthreads();
    }
#pragma unroll
    for (int i = 0; i < 4; ++i) {
        int gm = bm * 64 + ty * 4 + i;
        if (gm >= M) continue;
#pragma unroll
        for (int j = 0; j < 4; ++j) {
            int gn = bn * 64 + tx * 4 + j;
            float v = acc[i][j];
            if (bias) v += bias[gn];
            if (res)  v += res[gm * ldc + gn];
            C[gm * ldc + gn] = v;
        }
    }
}

// ---------------------------------------------------------------------------
// Flash-style attention. Q,K,V are (rows, 320) with head mapping
// channel = d*NHEADS + h (input) ; output channel = h*DH + d.
// Block = (64 queries, one head). 256 threads: tq = tid>>2 (query),
// tk = tid&3 (key-quarter, keys j = tk + 4*jj). Per-thread online softmax,
// 4-thread combine at the end. Lk arbitrary (masked tail).
__global__ __launch_bounds__(256) void attn_kernel(
    const float* __restrict__ Q, const float* __restrict__ K,
    const float* __restrict__ V, float* __restrict__ O, int Lk) {
    __shared__ __align__(16) float Ks[64][44];
    __shared__ __align__(16) float Vs[64][44];
    __shared__ float red_m[64][4];
    __shared__ float red_l[64][4];

    const int tid = threadIdx.x;
    const int tq = tid >> 2;
    const int tk = tid & 3;
    const int h  = blockIdx.y;
    const int q0 = blockIdx.x * 64;
    const float scale = 0.15811388300841897f;  // 40^-0.5

    const int qrow = q0 + tq;
    float qr[DH];
#pragma unroll
    for (int d = 0; d < DH; ++d) qr[d] = Q[qrow * CCH + d * NHEADS + h] * scale;

    float m = -1e30f, l = 0.f;
    float acc[DH];
#pragma unroll
    for (int d = 0; d < DH; ++d) acc[d] = 0.f;

    const int nt = (Lk + 63) >> 6;
    for (int kt = 0; kt < nt; ++kt) {
        __syncthreads();
        for (int idx = tid; idx < 64 * DH; idx += 256) {
            int j = idx / DH, d = idx - j * DH;
            int gk = kt * 64 + j;
            float kv = 0.f, vv = 0.f;
            if (gk < Lk) {
                kv = K[gk * CCH + d * NHEADS + h];
                vv = V[gk * CCH + d * NHEADS + h];
            }
            Ks[j][d] = kv;
            Vs[j][d] = vv;
        }
        __syncthreads();

        float s[16];
        float tmax = -1e30f;
#pragma unroll
        for (int jj = 0; jj < 16; ++jj) {
            int j = tk + 4 * jj;
            float a = 0.f;
            const float4* kr = (const float4*)&Ks[j][0];
#pragma unroll
            for (int dq = 0; dq < 10; ++dq) {
                float4 kv = kr[dq];
                a += qr[dq * 4 + 0] * kv.x + qr[dq * 4 + 1] * kv.y +
                     qr[dq * 4 + 2] * kv.z + qr[dq * 4 + 3] * kv.w;
            }
            bool valid = (kt * 64 + j) < Lk;
            s[jj] = valid ? a : -1e30f;
            tmax = fmaxf(tmax, s[jj]);
        }
        float mn = fmaxf(m, tmax);
        float r = __expf(m - mn);
        l *= r;
#pragma unroll
        for (int d = 0; d < DH; ++d) acc[d] *= r;
#pragma unroll
        for (int jj = 0; jj < 16; ++jj) {
            int j = tk + 4 * jj;
            float p = (s[jj] > -1e29f) ? __expf(s[jj] - mn) : 0.f;
            l += p;
            const float4* vr = (const float4*)&Vs[j][0];
#pragma unroll
            for (int dq = 0; dq < 10; ++dq) {
                float4 vv = vr[dq];
                acc[dq * 4 + 0] += p * vv.x;
                acc[dq * 4 + 1] += p * vv.y;
                acc[dq * 4 + 2] += p * vv.z;
                acc[dq * 4 + 3] += p * vv.w;
            }
        }
        m = mn;
    }

    red_m[tq][tk] = m;
    red_l[tq][tk] = l;
    __syncthreads();
    const float M2 = fmaxf(fmaxf(red_m[tq][0], red_m[tq][1]),
                           fmaxf(red_m[tq][2], red_m[tq][3]));
    float Ltot = 0.f;
#pragma unroll
    for (int r2 = 0; r2 < 4; ++r2) Ltot += red_l[tq][r2] * __expf(red_m[tq][r2] - M2);
    const float sc = __expf(m - M2);
    float* obuf = &Ks[0][0];  // reuse Ks as (64 x 44) output scratch
    for (int r2 = 0; r2 < 4; ++r2) {
        if (tk == r2) {
            if (r2 == 0) {
#pragma unroll
                for (int d = 0; d < DH; ++d) obuf[tq * 44 + d] = acc[d] * sc;
            } else {
#pragma unroll
                for (int d = 0; d < DH; ++d) obuf[tq * 44 + d] += acc[d] * sc;
            }
        }
        __syncthreads();
    }
    const float inv = 1.f / Ltot;
#pragma unroll
    for (int dd = 0; dd < 10; ++dd) {
        int d = tk * 10 + dd;
        O[qrow * CCH + h * DH + d] = obuf[tq * 44 + d] * inv;
    }
}

// ---------------------------------------------------------------------------
// GEGLU (exact): in-place on P (4096 x 2560, row stride 2560):
// P[r, j] = P[r, j] * gelu(P[r, 1280 + j]),  j < 1280.
__global__ void glu_kernel(float* __restrict__ P) {
    int idx = blockIdx.x * 256 + threadIdx.x;  // < 4096*1280 exact
    int row = idx / FFI;
    int j = idx - row * FFI;
    float a = P[row * (2 * FFI) + j];
    float x = P[row * (2 * FFI) + FFI + j];
    float g = 0.5f * x * (1.f + erff(x * 0.70710678118654752f));
    P[row * (2 * FFI) + j] = a * g;
}

// ---------------------------------------------------------------------------
// Final: out (C, HW) = y (HW, C) transposed + x (C, HW). b_out already in y.
__global__ void final_kernel(const float* __restrict__ Yv,
                             const float* __restrict__ X,
                             float* __restrict__ Out) {
    int idx = blockIdx.x * 256 + threadIdx.x;  // < 320*4096 exact
    int o = idx >> 12, hw = idx & 4095;
    Out[idx] = Yv[hw * CCH + o] + X[idx];
}

// ---------------------------------------------------------------------------
extern "C" void kernel_launch(void* const* d_in, const int* in_sizes, int n_in,
                              void* d_out, int out_size, void* d_ws, size_t ws_size,
                              hipStream_t stream) {
    const float* x     = (const float*)d_in[0];
    const float* ctx   = (const float*)d_in[1];
    const float* gn_w  = (const float*)d_in[2];
    const float* gn_b  = (const float*)d_in[3];
    const float* w_in  = (const float*)d_in[4];
    const float* b_in  = (const float*)d_in[5];
    const float* ln1_w = (const float*)d_in[6];
    const float* ln1_b = (const float*)d_in[7];
    const float* wq1   = (const float*)d_in[8];
    const float* wk1   = (const float*)d_in[9];
    const float* wv1   = (const float*)d_in[10];
    const float* wo1   = (const float*)d_in[11];
    const float* bo1   = (const float*)d_in[12];
    const float* ln2_w = (const float*)d_in[13];
    const float* ln2_b = (const float*)d_in[14];
    const float* wq2   = (const float*)d_in[15];
    const float* wk2   = (const float*)d_in[16];
    const float* wv2   = (const float*)d_in[17];
    const float* wo2   = (const float*)d_in[18];
    const float* bo2   = (const float*)d_in[19];
    const float* ln3_w = (const float*)d_in[20];
    const float* ln3_b = (const float*)d_in[21];
    const float* wff1  = (const float*)d_in[22];
    const float* bff1  = (const float*)d_in[23];
    const float* wff2  = (const float*)d_in[24];
    const float* bff2  = (const float*)d_in[25];
    const float* w_out = (const float*)d_in[26];
    const float* b_out = (const float*)d_in[27];
    float* out = (float*)d_out;

    const int NT = HW * CCH;  // 1,310,720 floats
    float* ws = (float*)d_ws;
    float* t_ = ws;            // residual stream (HW, C)
    float* a_ = t_ + NT;       // normed activations (HW, C)
    float* q_ = a_ + NT;
    float* k_ = q_ + NT;
    float* v_ = k_ + NT;
    float* o_ = v_ + NT;       // attn out / final y
    float* p_ = o_ + NT;       // FF inner (HW, 2560)

    // 1) GroupNorm -> a_ (transposed to (HW,C))
    gn_kernel<<<32, 256, 0, stream>>>(x, gn_w, gn_b, a_);
    // 2) proj_in: t = a_ @ w_in + b_in
    gemm_kernel<<<dim3(5, 64), 256, 0, stream>>>(a_, CCH, w_in, CCH, b_in, nullptr, t_, CCH, HW, CCH);
    // 3) ln1 -> a_
    ln_kernel<<<1024, 256, 0, stream>>>(t_, ln1_w, ln1_b, a_);
    // 4) q = a_ @ wq1 ; k = q @ wk1 ; v = q @ wv1  (reference: k,v from q!)
    gemm_kernel<<<dim3(5, 64), 256, 0, stream>>>(a_, CCH, wq1, CCH, nullptr, nullptr, q_, CCH, HW, CCH);
    gemm_kernel<<<dim3(5, 64), 256, 0, stream>>>(q_, CCH, wk1, CCH, nullptr, nullptr, k_, CCH, HW, CCH);
    gemm_kernel<<<dim3(5, 64), 256, 0, stream>>>(q_, CCH, wv1, CCH, nullptr, nullptr, v_, CCH, HW, CCH);
    // 5) self-attention
    attn_kernel<<<dim3(64, NHEADS), 256, 0, stream>>>(q_, k_, v_, o_, HW);
    // 6) t += o @ wo1 + bo1
    gemm_kernel<<<dim3(5, 64), 256, 0, stream>>>(o_, CCH, wo1, CCH, bo1, t_, t_, CCH, HW, CCH);
    // 7) ln2 -> a_
    ln_kernel<<<1024, 256, 0, stream>>>(t_, ln2_w, ln2_b, a_);
    // 8) cross-attn projections: q from a_, k/v from context (77 x 768)
    gemm_kernel<<<dim3(5, 64), 256, 0, stream>>>(a_, CCH, wq2, CCH, nullptr, nullptr, q_, CCH, HW, CCH);
    gemm_kernel<<<dim3(5, 2), 256, 0, stream>>>(ctx, 768, wk2, CCH, nullptr, nullptr, k_, CCH, 77, 768);
    gemm_kernel<<<dim3(5, 2), 256, 0, stream>>>(ctx, 768, wv2, CCH, nullptr, nullptr, v_, CCH, 77, 768);
    // 9) cross-attention (Lk = 77)
    attn_kernel<<<dim3(64, NHEADS), 256, 0, stream>>>(q_, k_, v_, o_, 77);
    // 10) t += o @ wo2 + bo2
    gemm_kernel<<<dim3(5, 64), 256, 0, stream>>>(o_, CCH, wo2, CCH, bo2, t_, t_, CCH, HW, CCH);
    // 11) ln3 -> a_
    ln_kernel<<<1024, 256, 0, stream>>>(t_, ln3_w, ln3_b, a_);
    // 12) p = a_ @ wff1 + bff1  (HW x 2560)
    gemm_kernel<<<dim3(40, 64), 256, 0, stream>>>(a_, CCH, wff1, 2 * FFI, bff1, nullptr, p_, 2 * FFI, HW, CCH);
    // 13) GEGLU in-place on first half of p
    glu_kernel<<<20480, 256, 0, stream>>>(p_);
    // 14) t += g @ wff2 + bff2   (A = p_ with lda 2560, K = 1280)
    gemm_kernel<<<dim3(5, 64), 256, 0, stream>>>(p_, 2 * FFI, wff2, CCH, bff2, t_, t_, CCH, HW, FFI);
    // 15) y = t @ w_out + b_out -> o_
    gemm_kernel<<<dim3(5, 64), 256, 0, stream>>>(t_, CCH, w_out, CCH, b_out, nullptr, o_, CCH, HW, CCH);
    // 16) out = y^T + x
    final_kernel<<<5120, 256, 0, stream>>>(o_, x, out);
}

// Round 2
// 1120.757 us; speedup vs baseline: 2.1104x; 2.1104x over previous
//
#include <hip/hip_runtime.h>
#include <hip/hip_bf16.h>
#include <math.h>

#define CCH 320
#define NHEADS 8
#define DH 40
#define HW 4096
#define FFI 1280

typedef __bf16 bf16x8 __attribute__((ext_vector_type(8)));
typedef unsigned short u16x8 __attribute__((ext_vector_type(8)));
typedef float f32x4 __attribute__((ext_vector_type(4)));

__device__ inline unsigned short f2bf(float f) {
    __hip_bfloat16 h = __float2bfloat16(f);
    return __builtin_bit_cast(unsigned short, h);
}
__device__ inline bf16x8 ldfrag(const unsigned short* p) {
    u16x8 raw = *reinterpret_cast<const u16x8*>(p);
    return __builtin_bit_cast(bf16x8, raw);
}

// ---------------------------------------------------------------------------
// GroupNorm: x (C=320, HW=4096) -> y transposed (HW, C), 32 groups of 10 ch.
__global__ __launch_bounds__(256) void gn_kernel(const float* __restrict__ X,
                                                 const float* __restrict__ w,
                                                 const float* __restrict__ b,
                                                 float* __restrict__ Y) {
    __shared__ float s1[256], s2[256];
    const int g = blockIdx.x, tid = threadIdx.x;
    const float* xg = X + g * 40960;
    float s = 0.f, sq = 0.f;
    for (int i = tid; i < 40960; i += 256) { float v = xg[i]; s += v; sq += v * v; }
    s1[tid] = s; s2[tid] = sq; __syncthreads();
    for (int off = 128; off > 0; off >>= 1) {
        if (tid < off) { s1[tid] += s1[tid + off]; s2[tid] += s2[tid + off]; }
        __syncthreads();
    }
    const float mean = s1[0] * (1.f / 40960.f);
    const float var  = s2[0] * (1.f / 40960.f) - mean * mean;
    const float rstd = rsqrtf(var + 1e-6f);
    for (int i = tid; i < 40960; i += 256) {
        int c  = g * 10 + (i >> 12);
        int hw = i & 4095;
        Y[hw * CCH + c] = (xg[i] - mean) * rstd * w[c] + b[c];
    }
}

// ---------------------------------------------------------------------------
// LayerNorm over last dim (320). One wave per row, 4 rows per block.
__global__ __launch_bounds__(256) void ln_kernel(const float* __restrict__ X,
                                                 const float* __restrict__ w,
                                                 const float* __restrict__ b,
                                                 float* __restrict__ Y) {
    const int row  = blockIdx.x * 4 + (threadIdx.x >> 6);
    const int lane = threadIdx.x & 63;
    const float* xr = X + row * CCH;
    float v[5];
    float s = 0.f, sq = 0.f;
#pragma unroll
    for (int i = 0; i < 5; ++i) { v[i] = xr[lane + 64 * i]; s += v[i]; sq += v[i] * v[i]; }
#pragma unroll
    for (int off = 32; off > 0; off >>= 1) {
        s  += __shfl_xor(s, off, 64);
        sq += __shfl_xor(sq, off, 64);
    }
    const float mean = s * (1.f / 320.f);
    const float var  = sq * (1.f / 320.f) - mean * mean;
    const float rstd = rsqrtf(var + 1e-5f);
    float* yr = Y + row * CCH;
#pragma unroll
    for (int i = 0; i < 5; ++i) {
        int c = lane + 64 * i;
        yr[c] = (v[i] - mean) * rstd * w[c] + b[c];
    }
}

// ---------------------------------------------------------------------------
// Generic fp32 GEMM: C[m,n] = sum_k A[m,k]*B[k,n] (+bias[n]) (+res[m,n]).
__global__ __launch_bounds__(256) void gemm_kernel(
    const float* __restrict__ A, int lda,
    const float* __restrict__ B, int ldb,
    const float* __restrict__ bias,
    const float* __restrict__ res,
    float* __restrict__ C, int ldc,
    int M, int K) {
    __shared__ __align__(16) float As[16][68];
    __shared__ __align__(16) float Bs[16][68];
    const int tid = threadIdx.x;
    const int tx = tid & 15, ty = tid >> 4;
    const int bn = blockIdx.x, bm = blockIdx.y;
    float acc[4][4] = {};
    for (int k0 = 0; k0 < K; k0 += 16) {
#pragma unroll
        for (int i = 0; i < 4; ++i) {
            int idx = tid + i * 256;
            int r = idx >> 4, c = idx & 15;
            int gm = bm * 64 + r;
            As[c][r] = (gm < M) ? A[gm * lda + k0 + c] : 0.f;
        }
#pragma unroll
        for (int i = 0; i < 4; ++i) {
            int idx = tid + i * 256;
            int r = idx >> 6, c = idx & 63;
            Bs[r][c] = B[(k0 + r) * ldb + bn * 64 + c];
        }
        __syncthreads();
#pragma unroll
        for (int kk = 0; kk < 16; ++kk) {
            float4 a4 = *(const float4*)&As[kk][ty * 4];
            float4 b4 = *(const float4*)&Bs[kk][tx * 4];
            float av[4] = {a4.x, a4.y, a4.z, a4.w};
            float bv[4] = {b4.x, b4.y, b4.z, b4.w};
#pragma unroll
            for (int i = 0; i < 4; ++i)
#pragma unroll
                for (int j = 0; j < 4; ++j) acc[i][j] += av[i] * bv[j];
        }
        __syncthreads();
    }
#pragma unroll
    for (int i = 0; i < 4; ++i) {
        int gm = bm * 64 + ty * 4 + i;
        if (gm >= M) continue;
#pragma unroll
        for (int j = 0; j < 4; ++j) {
            int gn = bn * 64 + tx * 4 + j;
            float v = acc[i][j];
            if (bias) v += bias[gn];
            if (res)  v += res[gm * ldc + gn];
            C[gm * ldc + gn] = v;
        }
    }
}

// ---------------------------------------------------------------------------
// Pack q/k (rows,320) fp32 -> [8][Rp][64] bf16, head channel = d*8+h,
// dims padded 40->64 with zeros, rows padded to Rp with zeros. Optional scale.
__global__ void pack_qk(const float* __restrict__ S, unsigned short* __restrict__ D,
                        int rows, int Rp, float scale) {
    int idx = blockIdx.x * 256 + threadIdx.x;  // total = 8*Rp*64 (grid exact)
    int d = idx & 63;
    int r = (idx >> 6) % Rp;
    int h = idx / (Rp * 64);
    float v = 0.f;
    if (r < rows && d < 40) v = S[r * CCH + d * 8 + h] * scale;
    D[idx] = f2bf(v);
}

// Pack v (rows,320) fp32 -> transposed [8][48][Rp] bf16 (dim-major).
__global__ void pack_vt(const float* __restrict__ S, unsigned short* __restrict__ D,
                        int rows, int Rp) {
    int idx = blockIdx.x * 256 + threadIdx.x;  // total = 8*48*Rp (grid exact)
    int r = idx % Rp;
    int d = (idx / Rp) % 48;
    int h = idx / (48 * Rp);
    float v = 0.f;
    if (r < rows && d < 40) v = S[r * CCH + d * 8 + h];
    D[idx] = f2bf(v);
}

// ---------------------------------------------------------------------------
// MFMA flash attention. Qp [8][4096][64] bf16 (pre-scaled), Kp [8][Lkp][64],
// Vt [8][48][Lkp]. O (4096,320) fp32, out channel = h*40+d.
// Block: 256 thr = 4 independent waves, each wave owns 16 queries.
// Per 64-key tile: 8 QK^T mfmas -> online softmax (C-layout, shfl over 16-lane
// col group) -> P via per-wave LDS (stride 72 bf16, 16B-aligned reads) -> 6 PV
// mfmas. No __syncthreads anywhere.
__global__ __launch_bounds__(256) void attn_mfma(
    const unsigned short* __restrict__ Qp,
    const unsigned short* __restrict__ Kp,
    const unsigned short* __restrict__ Vt,
    float* __restrict__ O, int Lk, int Lkp) {
    __shared__ unsigned short Pb[4][16 * 72];
    const int tid  = threadIdx.x;
    const int wave = tid >> 6, lane = tid & 63;
    const int quad = lane >> 4, c = lane & 15;
    const int h  = blockIdx.y;
    const int q0 = blockIdx.x * 64 + wave * 16;

    const unsigned short* qbase = Qp + (((h << 12) + q0 + c) << 6) + quad * 8;
    const bf16x8 aQ0 = ldfrag(qbase);
    const bf16x8 aQ1 = ldfrag(qbase + 32);

    f32x4 oacc0 = {0.f, 0.f, 0.f, 0.f}, oacc1 = oacc0, oacc2 = oacc0;
    float m_r[4] = {-1e30f, -1e30f, -1e30f, -1e30f};
    float l_r[4] = {0.f, 0.f, 0.f, 0.f};
    unsigned short* Pw = &Pb[wave][0];

    const int ntiles = Lkp >> 6;
    for (int kt = 0; kt < ntiles; ++kt) {
        const int kb = kt * 64;
        // ---- S = Q K^T (16 x 64) ----
        const unsigned short* kbase = Kp + ((size_t)(h * Lkp + kb + c) << 6) + quad * 8;
        f32x4 s[4];
#pragma unroll
        for (int nt = 0; nt < 4; ++nt) {
            bf16x8 k0 = ldfrag(kbase + nt * 1024);
            bf16x8 k1 = ldfrag(kbase + nt * 1024 + 32);
            f32x4 z = {0.f, 0.f, 0.f, 0.f};
            z = __builtin_amdgcn_mfma_f32_16x16x32_bf16(aQ0, k0, z, 0, 0, 0);
            z = __builtin_amdgcn_mfma_f32_16x16x32_bf16(aQ1, k1, z, 0, 0, 0);
            s[nt] = z;
        }
        // mask invalid keys (cross-attn tail)
#pragma unroll
        for (int nt = 0; nt < 4; ++nt)
            if (kb + nt * 16 + c >= Lk) { s[nt][0] = s[nt][1] = s[nt][2] = s[nt][3] = -1e30f; }
        // ---- online softmax (rows = quad*4+reg, cols across 16 lanes) ----
        float mn[4], alpha[4];
#pragma unroll
        for (int r = 0; r < 4; ++r) {
            float mx = fmaxf(fmaxf(s[0][r], s[1][r]), fmaxf(s[2][r], s[3][r]));
            mx = fmaxf(mx, __shfl_xor(mx, 1, 64));
            mx = fmaxf(mx, __shfl_xor(mx, 2, 64));
            mx = fmaxf(mx, __shfl_xor(mx, 4, 64));
            mx = fmaxf(mx, __shfl_xor(mx, 8, 64));
            mn[r] = fmaxf(m_r[r], mx);
            alpha[r] = __expf(m_r[r] - mn[r]);
            m_r[r] = mn[r];
        }
        // V frags early (independent of LDS)
        bf16x8 vf[3][2];
#pragma unroll
        for (int nt = 0; nt < 3; ++nt) {
            const unsigned short* vb = Vt + (size_t)(h * 48 + nt * 16 + c) * Lkp + kb + quad * 8;
            vf[nt][0] = ldfrag(vb);
            vf[nt][1] = ldfrag(vb + 32);
        }
        // p = exp(s - mn); write P to per-wave LDS (row = quad*4+r)
        asm volatile("s_waitcnt lgkmcnt(0)" ::: "memory");  // prev tile's P reads done
#pragma unroll
        for (int nt = 0; nt < 4; ++nt) {
#pragma unroll
            for (int r = 0; r < 4; ++r) {
                float p = __expf(s[nt][r] - mn[r]);
                s[nt][r] = p;
                Pw[(quad * 4 + r) * 72 + nt * 16 + c] = f2bf(p);
            }
        }
#pragma unroll
        for (int r = 0; r < 4; ++r) {
            float ps = s[0][r] + s[1][r] + s[2][r] + s[3][r];
            ps += __shfl_xor(ps, 1, 64);
            ps += __shfl_xor(ps, 2, 64);
            ps += __shfl_xor(ps, 4, 64);
            ps += __shfl_xor(ps, 8, 64);
            l_r[r] = l_r[r] * alpha[r] + ps;
        }
#pragma unroll
        for (int r = 0; r < 4; ++r) {
            oacc0[r] *= alpha[r]; oacc1[r] *= alpha[r]; oacc2[r] *= alpha[r];
        }
        // read P as A-frags (row = c), then PV
        asm volatile("s_waitcnt lgkmcnt(0)" ::: "memory");  // P writes visible
        bf16x8 pA0 = ldfrag(Pw + c * 72 + quad * 8);
        bf16x8 pA1 = ldfrag(Pw + c * 72 + quad * 8 + 32);
        oacc0 = __builtin_amdgcn_mfma_f32_16x16x32_bf16(pA0, vf[0][0], oacc0, 0, 0, 0);
        oacc0 = __builtin_amdgcn_mfma_f32_16x16x32_bf16(pA1, vf[0][1], oacc0, 0, 0, 0);
        oacc1 = __builtin_amdgcn_mfma_f32_16x16x32_bf16(pA0, vf[1][0], oacc1, 0, 0, 0);
        oacc1 = __builtin_amdgcn_mfma_f32_16x16x32_bf16(pA1, vf[1][1], oacc1, 0, 0, 0);
        oacc2 = __builtin_amdgcn_mfma_f32_16x16x32_bf16(pA0, vf[2][0], oacc2, 0, 0, 0);
        oacc2 = __builtin_amdgcn_mfma_f32_16x16x32_bf16(pA1, vf[2][1], oacc2, 0, 0, 0);
    }
    // ---- epilogue: O[row][h*40 + col] = oacc/l ----
#pragma unroll
    for (int r = 0; r < 4; ++r) {
        float inv = 1.f / l_r[r];
        int row = q0 + quad * 4 + r;
        float* ob = O + (size_t)row * CCH + h * DH;
        ob[c]      = oacc0[r] * inv;
        ob[16 + c] = oacc1[r] * inv;
        if (c < 8) ob[32 + c] = oacc2[r] * inv;
    }
}

// ---------------------------------------------------------------------------
// GEGLU (exact): in-place on P (4096 x 2560).
__global__ void glu_kernel(float* __restrict__ P) {
    int idx = blockIdx.x * 256 + threadIdx.x;
    int row = idx / FFI;
    int j = idx - row * FFI;
    float a = P[row * (2 * FFI) + j];
    float x = P[row * (2 * FFI) + FFI + j];
    float g = 0.5f * x * (1.f + erff(x * 0.70710678118654752f));
    P[row * (2 * FFI) + j] = a * g;
}

// ---------------------------------------------------------------------------
__global__ void final_kernel(const float* __restrict__ Yv,
                             const float* __restrict__ X,
                             float* __restrict__ Out) {
    int idx = blockIdx.x * 256 + threadIdx.x;
    int o = idx >> 12, hw = idx & 4095;
    Out[idx] = Yv[hw * CCH + o] + X[idx];
}

// ---------------------------------------------------------------------------
extern "C" void kernel_launch(void* const* d_in, const int* in_sizes, int n_in,
                              void* d_out, int out_size, void* d_ws, size_t ws_size,
                              hipStream_t stream) {
    const float* x     = (const float*)d_in[0];
    const float* ctx   = (const float*)d_in[1];
    const float* gn_w  = (const float*)d_in[2];
    const float* gn_b  = (const float*)d_in[3];
    const float* w_in  = (const float*)d_in[4];
    const float* b_in  = (const float*)d_in[5];
    const float* ln1_w = (const float*)d_in[6];
    const float* ln1_b = (const float*)d_in[7];
    const float* wq1   = (const float*)d_in[8];
    const float* wk1   = (const float*)d_in[9];
    const float* wv1   = (const float*)d_in[10];
    const float* wo1   = (const float*)d_in[11];
    const float* bo1   = (const float*)d_in[12];
    const float* ln2_w = (const float*)d_in[13];
    const float* ln2_b = (const float*)d_in[14];
    const float* wq2   = (const float*)d_in[15];
    const float* wk2   = (const float*)d_in[16];
    const float* wv2   = (const float*)d_in[17];
    const float* wo2   = (const float*)d_in[18];
    const float* bo2   = (const float*)d_in[19];
    const float* ln3_w = (const float*)d_in[20];
    const float* ln3_b = (const float*)d_in[21];
    const float* wff1  = (const float*)d_in[22];
    const float* bff1  = (const float*)d_in[23];
    const float* wff2  = (const float*)d_in[24];
    const float* bff2  = (const float*)d_in[25];
    const float* w_out = (const float*)d_in[26];
    const float* b_out = (const float*)d_in[27];
    float* out = (float*)d_out;

    const int NT = HW * CCH;
    float* ws = (float*)d_ws;
    float* t_ = ws;
    float* a_ = t_ + NT;
    float* q_ = a_ + NT;
    float* k_ = q_ + NT;
    float* v_ = k_ + NT;
    float* o_ = v_ + NT;
    float* p_ = o_ + NT;  // FF inner (HW x 2560); doubles as bf16 pack arena pre-FF

    // bf16 pack buffers live inside p_ (dead until the FF GEMM)
    unsigned short* Qp = (unsigned short*)p_;          // 8*4096*64
    unsigned short* Kp = Qp + 8 * 4096 * 64;           // 8*4096*64
    unsigned short* Vt = Kp + 8 * 4096 * 64;           // 8*48*4096
    unsigned short* Kc = Vt + 8 * 48 * 4096;           // 8*128*64
    unsigned short* Vc = Kc + 8 * 128 * 64;            // 8*48*128

    const float scale = 0.15811388300841897f;  // 40^-0.5

    // 1) GroupNorm -> a_
    gn_kernel<<<32, 256, 0, stream>>>(x, gn_w, gn_b, a_);
    // 2) proj_in
    gemm_kernel<<<dim3(5, 64), 256, 0, stream>>>(a_, CCH, w_in, CCH, b_in, nullptr, t_, CCH, HW, CCH);
    // 3) ln1
    ln_kernel<<<1024, 256, 0, stream>>>(t_, ln1_w, ln1_b, a_);
    // 4) q = a_ @ wq1 ; k = q @ wk1 ; v = q @ wv1
    gemm_kernel<<<dim3(5, 64), 256, 0, stream>>>(a_, CCH, wq1, CCH, nullptr, nullptr, q_, CCH, HW, CCH);
    gemm_kernel<<<dim3(5, 64), 256, 0, stream>>>(q_, CCH, wk1, CCH, nullptr, nullptr, k_, CCH, HW, CCH);
    gemm_kernel<<<dim3(5, 64), 256, 0, stream>>>(q_, CCH, wv1, CCH, nullptr, nullptr, v_, CCH, HW, CCH);
    // 5) pack + self-attention (MFMA)
    pack_qk<<<8192, 256, 0, stream>>>(q_, Qp, HW, HW, scale);
    pack_qk<<<8192, 256, 0, stream>>>(k_, Kp, HW, HW, 1.f);
    pack_vt<<<6144, 256, 0, stream>>>(v_, Vt, HW, HW);
    attn_mfma<<<dim3(64, NHEADS), 256, 0, stream>>>(Qp, Kp, Vt, o_, HW, HW);
    // 6) t += o @ wo1 + bo1
    gemm_kernel<<<dim3(5, 64), 256, 0, stream>>>(o_, CCH, wo1, CCH, bo1, t_, t_, CCH, HW, CCH);
    // 7) ln2
    ln_kernel<<<1024, 256, 0, stream>>>(t_, ln2_w, ln2_b, a_);
    // 8) cross projections
    gemm_kernel<<<dim3(5, 64), 256, 0, stream>>>(a_, CCH, wq2, CCH, nullptr, nullptr, q_, CCH, HW, CCH);
    gemm_kernel<<<dim3(5, 2), 256, 0, stream>>>(ctx, 768, wk2, CCH, nullptr, nullptr, k_, CCH, 77, 768);
    gemm_kernel<<<dim3(5, 2), 256, 0, stream>>>(ctx, 768, wv2, CCH, nullptr, nullptr, v_, CCH, 77, 768);
    // 9) pack + cross-attention (Lk=77, padded to 128)
    pack_qk<<<8192, 256, 0, stream>>>(q_, Qp, HW, HW, scale);
    pack_qk<<<256, 256, 0, stream>>>(k_, Kc, 77, 128, 1.f);
    pack_vt<<<192, 256, 0, stream>>>(v_, Vc, 77, 128);
    attn_mfma<<<dim3(64, NHEADS), 256, 0, stream>>>(Qp, Kc, Vc, o_, 77, 128);
    // 10) t += o @ wo2 + bo2
    gemm_kernel<<<dim3(5, 64), 256, 0, stream>>>(o_, CCH, wo2, CCH, bo2, t_, t_, CCH, HW, CCH);
    // 11) ln3
    ln_kernel<<<1024, 256, 0, stream>>>(t_, ln3_w, ln3_b, a_);
    // 12) p = a_ @ wff1 + bff1
    gemm_kernel<<<dim3(40, 64), 256, 0, stream>>>(a_, CCH, wff1, 2 * FFI, bff1, nullptr, p_, 2 * FFI, HW, CCH);
    // 13) GEGLU
    glu_kernel<<<20480, 256, 0, stream>>>(p_);
    // 14) t += g @ wff2 + bff2
    gemm_kernel<<<dim3(5, 64), 256, 0, stream>>>(p_, 2 * FFI, wff2, CCH, bff2, t_, t_, CCH, HW, FFI);
    // 15) y = t @ w_out + b_out
    gemm_kernel<<<dim3(5, 64), 256, 0, stream>>>(t_, CCH, w_out, CCH, b_out, nullptr, o_, CCH, HW, CCH);
    // 16) out = y^T + x
    final_kernel<<<5120, 256, 0, stream>>>(o_, x, out);
}

// Round 3
// 841.666 us; speedup vs baseline: 2.8102x; 1.3316x over previous
//
#include <hip/hip_runtime.h>
#include <hip/hip_bf16.h>
#include <math.h>

#define CCH 320
#define NHEADS 8
#define DH 40
#define HW 4096
#define FFI 1280

typedef __bf16 bf16x8 __attribute__((ext_vector_type(8)));
typedef unsigned short u16x8 __attribute__((ext_vector_type(8)));
typedef float f32x4 __attribute__((ext_vector_type(4)));

__device__ inline unsigned short f2bf(float f) {
    __hip_bfloat16 h = __float2bfloat16(f);
    return __builtin_bit_cast(unsigned short, h);
}
__device__ inline float bf2f(unsigned short u) {
    return __builtin_bit_cast(float, ((unsigned)u) << 16);
}
__device__ inline bf16x8 ldfrag(const unsigned short* p) {
    u16x8 raw = *reinterpret_cast<const u16x8*>(p);
    return __builtin_bit_cast(bf16x8, raw);
}

// ---------------------------------------------------------------------------
// Convert + transpose all weights to bf16 B^T (N x K) layouts, one kernel.
// Arena layout (ushort offsets):
//   0: w_inT  102400: wq1T  204800: wk1T  307200: wv1T  409600: wo1T
//   512000: wq2T  614400: wo2T  716800: w_outT
//   819200: wff1T (2560x320)   1638400: wff2T (320x1280)   total 2048000
__global__ __launch_bounds__(256) void prep_w(
    const float* __restrict__ w_in, const float* __restrict__ wq1,
    const float* __restrict__ wk1, const float* __restrict__ wv1,
    const float* __restrict__ wo1, const float* __restrict__ wq2,
    const float* __restrict__ wo2, const float* __restrict__ w_out,
    const float* __restrict__ wff1, const float* __restrict__ wff2,
    unsigned short* __restrict__ Wt) {
    int idx = blockIdx.x * 256 + threadIdx.x;  // < 2048000 exact
    float v;
    if (idx < 819200) {
        int m = idx / 102400;
        int j = idx - m * 102400;
        int n = j / 320, k = j - n * 320;
        const float* src = (m == 0) ? w_in : (m == 1) ? wq1 : (m == 2) ? wk1 :
                           (m == 3) ? wv1 : (m == 4) ? wo1 : (m == 5) ? wq2 :
                           (m == 6) ? wo2 : w_out;
        v = src[k * 320 + n];
    } else if (idx < 1638400) {
        int j = idx - 819200;
        int n = j / 320, k = j - n * 320;
        v = wff1[k * 2560 + n];
    } else {
        int j = idx - 1638400;
        int n = j / 1280, k = j - n * 1280;
        v = wff2[k * 320 + n];
    }
    Wt[idx] = f2bf(v);
}

// ---------------------------------------------------------------------------
// GroupNorm: x (C=320, HW=4096) -> bf16 transposed (HW, C).
__global__ __launch_bounds__(256) void gn_kernel(const float* __restrict__ X,
                                                 const float* __restrict__ w,
                                                 const float* __restrict__ b,
                                                 unsigned short* __restrict__ Y) {
    __shared__ float s1[256], s2[256];
    const int g = blockIdx.x, tid = threadIdx.x;
    const float* xg = X + g * 40960;
    float s = 0.f, sq = 0.f;
    for (int i = tid; i < 40960; i += 256) { float v = xg[i]; s += v; sq += v * v; }
    s1[tid] = s; s2[tid] = sq; __syncthreads();
    for (int off = 128; off > 0; off >>= 1) {
        if (tid < off) { s1[tid] += s1[tid + off]; s2[tid] += s2[tid + off]; }
        __syncthreads();
    }
    const float mean = s1[0] * (1.f / 40960.f);
    const float var  = s2[0] * (1.f / 40960.f) - mean * mean;
    const float rstd = rsqrtf(var + 1e-6f);
    for (int i = tid; i < 40960; i += 256) {
        int c  = g * 10 + (i >> 12);
        int hw = i & 4095;
        Y[hw * CCH + c] = f2bf((xg[i] - mean) * rstd * w[c] + b[c]);
    }
}

// ---------------------------------------------------------------------------
// LayerNorm over last dim (320), fp32 in -> bf16 out. One wave per row.
__global__ __launch_bounds__(256) void ln_kernel(const float* __restrict__ X,
                                                 const float* __restrict__ w,
                                                 const float* __restrict__ b,
                                                 unsigned short* __restrict__ Y) {
    const int row  = blockIdx.x * 4 + (threadIdx.x >> 6);
    const int lane = threadIdx.x & 63;
    const float* xr = X + row * CCH;
    float v[5];
    float s = 0.f, sq = 0.f;
#pragma unroll
    for (int i = 0; i < 5; ++i) { v[i] = xr[lane + 64 * i]; s += v[i]; sq += v[i] * v[i]; }
#pragma unroll
    for (int off = 32; off > 0; off >>= 1) {
        s  += __shfl_xor(s, off, 64);
        sq += __shfl_xor(sq, off, 64);
    }
    const float mean = s * (1.f / 320.f);
    const float var  = sq * (1.f / 320.f) - mean * mean;
    const float rstd = rsqrtf(var + 1e-5f);
    unsigned short* yr = Y + row * CCH;
#pragma unroll
    for (int i = 0; i < 5; ++i) {
        int c = lane + 64 * i;
        yr[c] = f2bf((v[i] - mean) * rstd * w[c] + b[c]);
    }
}

// ---------------------------------------------------------------------------
// bf16 MFMA GEMM, direct-from-global (operands L2-resident).
// A: M x K bf16 row-major. Bt: N x K bf16 (pre-transposed). Grid (N/64, M/64),
// 256 threads = 4 waves; wave w owns 16-col strip n0 = bx*64+w*16, rows m0..+63
// as 4 16x16 mfma tiles. BK=64 (two chained mfma_16x16x32).
// Epilogue modes:
//  0: fp32 out = acc + bias (+res fp32)
//  1: bf16 out = acc + bias
//  2: QK-pack:  col n -> h=n&7, d=n>>3; out[((h*4096)+row)*64 + d] = bf16(acc*scale)
//  3: VT-pack:  out[(h*48+d)*4096 + row] = bf16(acc)
//  4: bf16 out = acc + bias + res(fp32)
__global__ __launch_bounds__(256) void gemm_mfma(
    const unsigned short* __restrict__ A,
    const unsigned short* __restrict__ Bt,
    const float* __restrict__ bias,
    const float* __restrict__ res,
    void* __restrict__ Cout,
    int N, int K, int mode, float scale) {
    const int tid  = threadIdx.x;
    const int wave = tid >> 6, lane = tid & 63;
    const int quad = lane >> 4, c = lane & 15;
    const int m0 = blockIdx.y * 64;
    const int n0 = blockIdx.x * 64 + wave * 16;

    f32x4 acc[4];
#pragma unroll
    for (int i = 0; i < 4; ++i) acc[i] = (f32x4){0.f, 0.f, 0.f, 0.f};

    const unsigned short* bp = Bt + (size_t)(n0 + c) * K + quad * 8;
    const unsigned short* ap = A + (size_t)(m0 + c) * K + quad * 8;
    for (int k0 = 0; k0 < K; k0 += 64) {
        bf16x8 b0 = ldfrag(bp + k0);
        bf16x8 b1 = ldfrag(bp + k0 + 32);
#pragma unroll
        for (int mt = 0; mt < 4; ++mt) {
            bf16x8 a0 = ldfrag(ap + (size_t)mt * 16 * K + k0);
            bf16x8 a1 = ldfrag(ap + (size_t)mt * 16 * K + k0 + 32);
            acc[mt] = __builtin_amdgcn_mfma_f32_16x16x32_bf16(a0, b0, acc[mt], 0, 0, 0);
            acc[mt] = __builtin_amdgcn_mfma_f32_16x16x32_bf16(a1, b1, acc[mt], 0, 0, 0);
        }
    }

    const int col = n0 + c;
    const float bval = bias ? bias[col] : 0.f;
#pragma unroll
    for (int mt = 0; mt < 4; ++mt) {
#pragma unroll
        for (int r = 0; r < 4; ++r) {
            const int row = m0 + mt * 16 + quad * 4 + r;
            float v = acc[mt][r];
            if (mode == 0) {
                v += bval;
                if (res) v += res[(size_t)row * N + col];
                ((float*)Cout)[(size_t)row * N + col] = v;
            } else if (mode == 1) {
                ((unsigned short*)Cout)[(size_t)row * N + col] = f2bf(v + bval);
            } else if (mode == 2) {
                int h = col & 7, d = col >> 3;
                ((unsigned short*)Cout)[(((size_t)h << 12) + row) * 64 + d] = f2bf(v * scale);
            } else if (mode == 3) {
                int h = col & 7, d = col >> 3;
                ((unsigned short*)Cout)[(((size_t)(h * 48 + d)) << 12) + row] = f2bf(v);
            } else {
                ((unsigned short*)Cout)[(size_t)row * N + col] =
                    f2bf(v + bval + res[(size_t)row * N + col]);
            }
        }
    }
}

// ---------------------------------------------------------------------------
// Generic fp32 GEMM (kept for the tiny 77-row context projections).
__global__ __launch_bounds__(256) void gemm_kernel(
    const float* __restrict__ A, int lda,
    const float* __restrict__ B, int ldb,
    const float* __restrict__ bias,
    const float* __restrict__ res,
    float* __restrict__ C, int ldc,
    int M, int K) {
    __shared__ __align__(16) float As[16][68];
    __shared__ __align__(16) float Bs[16][68];
    const int tid = threadIdx.x;
    const int tx = tid & 15, ty = tid >> 4;
    const int bn = blockIdx.x, bm = blockIdx.y;
    float acc[4][4] = {};
    for (int k0 = 0; k0 < K; k0 += 16) {
#pragma unroll
        for (int i = 0; i < 4; ++i) {
            int idx = tid + i * 256;
            int r = idx >> 4, c = idx & 15;
            int gm = bm * 64 + r;
            As[c][r] = (gm < M) ? A[gm * lda + k0 + c] : 0.f;
        }
#pragma unroll
        for (int i = 0; i < 4; ++i) {
            int idx = tid + i * 256;
            int r = idx >> 6, c = idx & 63;
            Bs[r][c] = B[(k0 + r) * ldb + bn * 64 + c];
        }
        __syncthreads();
#pragma unroll
        for (int kk = 0; kk < 16; ++kk) {
            float4 a4 = *(const float4*)&As[kk][ty * 4];
            float4 b4 = *(const float4*)&Bs[kk][tx * 4];
            float av[4] = {a4.x, a4.y, a4.z, a4.w};
            float bv[4] = {b4.x, b4.y, b4.z, b4.w};
#pragma unroll
            for (int i = 0; i < 4; ++i)
#pragma unroll
                for (int j = 0; j < 4; ++j) acc[i][j] += av[i] * bv[j];
        }
        __syncthreads();
    }
#pragma unroll
    for (int i = 0; i < 4; ++i) {
        int gm = bm * 64 + ty * 4 + i;
        if (gm >= M) continue;
#pragma unroll
        for (int j = 0; j < 4; ++j) {
            int gn = bn * 64 + tx * 4 + j;
            float v = acc[i][j];
            if (bias) v += bias[gn];
            if (res)  v += res[gm * ldc + gn];
            C[gm * ldc + gn] = v;
        }
    }
}

// ---------------------------------------------------------------------------
// Pack bf16 q (rows=4096, 320) -> [8][4096][64], channel = d*8+h, scaled.
__global__ void pack_qk_bf(const unsigned short* __restrict__ S,
                           unsigned short* __restrict__ D, float scale) {
    int idx = blockIdx.x * 256 + threadIdx.x;  // 8*4096*64, grid 8192
    int d = idx & 63;
    int r = (idx >> 6) & 4095;
    int h = idx >> 18;
    float v = 0.f;
    if (d < 40) v = bf2f(S[r * CCH + d * 8 + h]) * scale;
    D[idx] = f2bf(v);
}

// fp32 packs for the small context K/V.
__global__ void pack_qk(const float* __restrict__ S, unsigned short* __restrict__ D,
                        int rows, int Rp, float scale) {
    int idx = blockIdx.x * 256 + threadIdx.x;
    int d = idx & 63;
    int r = (idx >> 6) % Rp;
    int h = idx / (Rp * 64);
    float v = 0.f;
    if (r < rows && d < 40) v = S[r * CCH + d * 8 + h] * scale;
    D[idx] = f2bf(v);
}
__global__ void pack_vt(const float* __restrict__ S, unsigned short* __restrict__ D,
                        int rows, int Rp) {
    int idx = blockIdx.x * 256 + threadIdx.x;
    int r = idx % Rp;
    int d = (idx / Rp) % 48;
    int h = idx / (48 * Rp);
    float v = 0.f;
    if (r < rows && d < 40) v = S[r * CCH + d * 8 + h];
    D[idx] = f2bf(v);
}

// ---------------------------------------------------------------------------
// MFMA flash attention (as round 1), output now bf16 (HW,320), ch = h*40+d.
__global__ __launch_bounds__(256) void attn_mfma(
    const unsigned short* __restrict__ Qp,
    const unsigned short* __restrict__ Kp,
    const unsigned short* __restrict__ Vt,
    unsigned short* __restrict__ O, int Lk, int Lkp) {
    __shared__ unsigned short Pb[4][16 * 72];
    const int tid  = threadIdx.x;
    const int wave = tid >> 6, lane = tid & 63;
    const int quad = lane >> 4, c = lane & 15;
    const int h  = blockIdx.y;
    const int q0 = blockIdx.x * 64 + wave * 16;

    const unsigned short* qbase = Qp + (((h << 12) + q0 + c) << 6) + quad * 8;
    const bf16x8 aQ0 = ldfrag(qbase);
    const bf16x8 aQ1 = ldfrag(qbase + 32);

    f32x4 oacc0 = {0.f, 0.f, 0.f, 0.f}, oacc1 = oacc0, oacc2 = oacc0;
    float m_r[4] = {-1e30f, -1e30f, -1e30f, -1e30f};
    float l_r[4] = {0.f, 0.f, 0.f, 0.f};
    unsigned short* Pw = &Pb[wave][0];

    const int ntiles = Lkp >> 6;
    for (int kt = 0; kt < ntiles; ++kt) {
        const int kb = kt * 64;
        const unsigned short* kbase = Kp + ((size_t)(h * Lkp + kb + c) << 6) + quad * 8;
        f32x4 s[4];
#pragma unroll
        for (int nt = 0; nt < 4; ++nt) {
            bf16x8 k0 = ldfrag(kbase + nt * 1024);
            bf16x8 k1 = ldfrag(kbase + nt * 1024 + 32);
            f32x4 z = {0.f, 0.f, 0.f, 0.f};
            z = __builtin_amdgcn_mfma_f32_16x16x32_bf16(aQ0, k0, z, 0, 0, 0);
            z = __builtin_amdgcn_mfma_f32_16x16x32_bf16(aQ1, k1, z, 0, 0, 0);
            s[nt] = z;
        }
#pragma unroll
        for (int nt = 0; nt < 4; ++nt)
            if (kb + nt * 16 + c >= Lk) { s[nt][0] = s[nt][1] = s[nt][2] = s[nt][3] = -1e30f; }
        float mn[4], alpha[4];
#pragma unroll
        for (int r = 0; r < 4; ++r) {
            float mx = fmaxf(fmaxf(s[0][r], s[1][r]), fmaxf(s[2][r], s[3][r]));
            mx = fmaxf(mx, __shfl_xor(mx, 1, 64));
            mx = fmaxf(mx, __shfl_xor(mx, 2, 64));
            mx = fmaxf(mx, __shfl_xor(mx, 4, 64));
            mx = fmaxf(mx, __shfl_xor(mx, 8, 64));
            mn[r] = fmaxf(m_r[r], mx);
            alpha[r] = __expf(m_r[r] - mn[r]);
            m_r[r] = mn[r];
        }
        bf16x8 vf[3][2];
#pragma unroll
        for (int nt = 0; nt < 3; ++nt) {
            const unsigned short* vb = Vt + (size_t)(h * 48 + nt * 16 + c) * Lkp + kb + quad * 8;
            vf[nt][0] = ldfrag(vb);
            vf[nt][1] = ldfrag(vb + 32);
        }
        asm volatile("s_waitcnt lgkmcnt(0)" ::: "memory");
#pragma unroll
        for (int nt = 0; nt < 4; ++nt) {
#pragma unroll
            for (int r = 0; r < 4; ++r) {
                float p = __expf(s[nt][r] - mn[r]);
                s[nt][r] = p;
                Pw[(quad * 4 + r) * 72 + nt * 16 + c] = f2bf(p);
            }
        }
#pragma unroll
        for (int r = 0; r < 4; ++r) {
            float ps = s[0][r] + s[1][r] + s[2][r] + s[3][r];
            ps += __shfl_xor(ps, 1, 64);
            ps += __shfl_xor(ps, 2, 64);
            ps += __shfl_xor(ps, 4, 64);
            ps += __shfl_xor(ps, 8, 64);
            l_r[r] = l_r[r] * alpha[r] + ps;
        }
#pragma unroll
        for (int r = 0; r < 4; ++r) {
            oacc0[r] *= alpha[r]; oacc1[r] *= alpha[r]; oacc2[r] *= alpha[r];
        }
        asm volatile("s_waitcnt lgkmcnt(0)" ::: "memory");
        bf16x8 pA0 = ldfrag(Pw + c * 72 + quad * 8);
        bf16x8 pA1 = ldfrag(Pw + c * 72 + quad * 8 + 32);
        oacc0 = __builtin_amdgcn_mfma_f32_16x16x32_bf16(pA0, vf[0][0], oacc0, 0, 0, 0);
        oacc0 = __builtin_amdgcn_mfma_f32_16x16x32_bf16(pA1, vf[0][1], oacc0, 0, 0, 0);
        oacc1 = __builtin_amdgcn_mfma_f32_16x16x32_bf16(pA0, vf[1][0], oacc1, 0, 0, 0);
        oacc1 = __builtin_amdgcn_mfma_f32_16x16x32_bf16(pA1, vf[1][1], oacc1, 0, 0, 0);
        oacc2 = __builtin_amdgcn_mfma_f32_16x16x32_bf16(pA0, vf[2][0], oacc2, 0, 0, 0);
        oacc2 = __builtin_amdgcn_mfma_f32_16x16x32_bf16(pA1, vf[2][1], oacc2, 0, 0, 0);
    }
#pragma unroll
    for (int r = 0; r < 4; ++r) {
        float inv = 1.f / l_r[r];
        int row = q0 + quad * 4 + r;
        unsigned short* ob = O + (size_t)row * CCH + h * DH;
        ob[c]      = f2bf(oacc0[r] * inv);
        ob[16 + c] = f2bf(oacc1[r] * inv);
        if (c < 8) ob[32 + c] = f2bf(oacc2[r] * inv);
    }
}

// ---------------------------------------------------------------------------
// GEGLU (exact), bf16 in (4096 x 2560) -> bf16 out (4096 x 1280).
__global__ void glu_kernel(const unsigned short* __restrict__ P,
                           unsigned short* __restrict__ G) {
    int idx = blockIdx.x * 256 + threadIdx.x;  // < 4096*1280 exact
    int row = idx / FFI;
    int j = idx - row * FFI;
    float a = bf2f(P[row * (2 * FFI) + j]);
    float x = bf2f(P[row * (2 * FFI) + FFI + j]);
    float g = 0.5f * x * (1.f + erff(x * 0.70710678118654752f));
    G[idx] = f2bf(a * g);
}

// ---------------------------------------------------------------------------
__global__ void final_kernel(const float* __restrict__ Yv,
                             const float* __restrict__ X,
                             float* __restrict__ Out) {
    int idx = blockIdx.x * 256 + threadIdx.x;
    int o = idx >> 12, hw = idx & 4095;
    Out[idx] = Yv[hw * CCH + o] + X[idx];
}

// ---------------------------------------------------------------------------
extern "C" void kernel_launch(void* const* d_in, const int* in_sizes, int n_in,
                              void* d_out, int out_size, void* d_ws, size_t ws_size,
                              hipStream_t stream) {
    const float* x     = (const float*)d_in[0];
    const float* ctx   = (const float*)d_in[1];
    const float* gn_w  = (const float*)d_in[2];
    const float* gn_b  = (const float*)d_in[3];
    const float* w_in  = (const float*)d_in[4];
    const float* b_in  = (const float*)d_in[5];
    const float* ln1_w = (const float*)d_in[6];
    const float* ln1_b = (const float*)d_in[7];
    const float* wq1   = (const float*)d_in[8];
    const float* wk1   = (const float*)d_in[9];
    const float* wv1   = (const float*)d_in[10];
    const float* wo1   = (const float*)d_in[11];
    const float* bo1   = (const float*)d_in[12];
    const float* ln2_w = (const float*)d_in[13];
    const float* ln2_b = (const float*)d_in[14];
    const float* wq2   = (const float*)d_in[15];
    const float* wk2   = (const float*)d_in[16];
    const float* wv2   = (const float*)d_in[17];
    const float* wo2   = (const float*)d_in[18];
    const float* bo2   = (const float*)d_in[19];
    const float* ln3_w = (const float*)d_in[20];
    const float* ln3_b = (const float*)d_in[21];
    const float* wff1  = (const float*)d_in[22];
    const float* bff1  = (const float*)d_in[23];
    const float* wff2  = (const float*)d_in[24];
    const float* bff2  = (const float*)d_in[25];
    const float* w_out = (const float*)d_in[26];
    const float* b_out = (const float*)d_in[27];
    float* out = (float*)d_out;

    const int NT = HW * CCH;  // 1,310,720
    float* ws = (float*)d_ws;
    float* t_  = ws;               // fp32 residual (HW, C)
    float* y_  = t_ + NT;          // fp32 final proj
    float* kc_ = y_ + NT;          // fp32 ctx K (77x320)
    float* vc_ = kc_ + 32768;
    unsigned short* u = (unsigned short*)(vc_ + 32768);
    unsigned short* a_bf = u;                  u += NT;
    unsigned short* q_bf = u;                  u += NT;
    unsigned short* o_bf = u;                  u += NT;
    unsigned short* t_bf = u;                  u += NT;
    unsigned short* p_bf = u;                  u += HW * 2 * FFI;   // 10.49M
    unsigned short* g_bf = u;                  u += HW * FFI;       // 5.24M
    unsigned short* Qp   = u;                  u += 8 * 4096 * 64;
    unsigned short* Kp   = u;                  u += 8 * 4096 * 64;
    unsigned short* Vt   = u;                  u += 8 * 48 * 4096;
    unsigned short* Kc   = u;                  u += 8 * 128 * 64;
    unsigned short* Vc   = u;                  u += 8 * 48 * 128;
    unsigned short* Wt   = u;                  u += 2048000;

    const unsigned short* w_inT  = Wt;
    const unsigned short* wq1T   = Wt + 102400;
    const unsigned short* wk1T   = Wt + 204800;
    const unsigned short* wv1T   = Wt + 307200;
    const unsigned short* wo1T   = Wt + 409600;
    const unsigned short* wq2T   = Wt + 512000;
    const unsigned short* wo2T   = Wt + 614400;
    const unsigned short* w_outT = Wt + 716800;
    const unsigned short* wff1T  = Wt + 819200;
    const unsigned short* wff2T  = Wt + 1638400;

    const float scale = 0.15811388300841897f;  // 40^-0.5

    // weight prep + zero the GEMM-written pack buffers' pad regions
    prep_w<<<8000, 256, 0, stream>>>(w_in, wq1, wk1, wv1, wo1, wq2, wo2, w_out,
                                     wff1, wff2, Wt);
    hipMemsetAsync(Kp, 0, (size_t)(8 * 4096 * 64 + 8 * 48 * 4096) * 2, stream);

    // 1) GroupNorm -> a_bf
    gn_kernel<<<32, 256, 0, stream>>>(x, gn_w, gn_b, a_bf);
    // 2) proj_in: t = a @ w_in + b_in (fp32)
    gemm_mfma<<<dim3(5, 64), 256, 0, stream>>>(a_bf, w_inT, b_in, nullptr, t_, CCH, CCH, 0, 1.f);
    // 3) ln1 -> a_bf
    ln_kernel<<<1024, 256, 0, stream>>>(t_, ln1_w, ln1_b, a_bf);
    // 4) q (bf16 row-major), then k/v straight into attention pack layouts
    gemm_mfma<<<dim3(5, 64), 256, 0, stream>>>(a_bf, wq1T, nullptr, nullptr, q_bf, CCH, CCH, 1, 1.f);
    pack_qk_bf<<<8192, 256, 0, stream>>>(q_bf, Qp, scale);
    gemm_mfma<<<dim3(5, 64), 256, 0, stream>>>(q_bf, wk1T, nullptr, nullptr, Kp, CCH, CCH, 2, 1.f);
    gemm_mfma<<<dim3(5, 64), 256, 0, stream>>>(q_bf, wv1T, nullptr, nullptr, Vt, CCH, CCH, 3, 1.f);
    // 5) self-attention -> o_bf
    attn_mfma<<<dim3(64, NHEADS), 256, 0, stream>>>(Qp, Kp, Vt, o_bf, HW, HW);
    // 6) t += o @ wo1 + bo1
    gemm_mfma<<<dim3(5, 64), 256, 0, stream>>>(o_bf, wo1T, bo1, t_, t_, CCH, CCH, 0, 1.f);
    // 7) ln2 -> a_bf
    ln_kernel<<<1024, 256, 0, stream>>>(t_, ln2_w, ln2_b, a_bf);
    // 8) cross q straight into Qp (scaled); ctx K/V via fp32 path
    gemm_mfma<<<dim3(5, 64), 256, 0, stream>>>(a_bf, wq2T, nullptr, nullptr, Qp, CCH, CCH, 2, scale);
    gemm_kernel<<<dim3(5, 2), 256, 0, stream>>>(ctx, 768, wk2, CCH, nullptr, nullptr, kc_, CCH, 77, 768);
    gemm_kernel<<<dim3(5, 2), 256, 0, stream>>>(ctx, 768, wv2, CCH, nullptr, nullptr, vc_, CCH, 77, 768);
    pack_qk<<<256, 256, 0, stream>>>(kc_, Kc, 77, 128, 1.f);
    pack_vt<<<192, 256, 0, stream>>>(vc_, Vc, 77, 128);
    // 9) cross-attention -> o_bf
    attn_mfma<<<dim3(64, NHEADS), 256, 0, stream>>>(Qp, Kc, Vc, o_bf, 77, 128);
    // 10) t += o @ wo2 + bo2
    gemm_mfma<<<dim3(5, 64), 256, 0, stream>>>(o_bf, wo2T, bo2, t_, t_, CCH, CCH, 0, 1.f);
    // 11) ln3 -> a_bf
    ln_kernel<<<1024, 256, 0, stream>>>(t_, ln3_w, ln3_b, a_bf);
    // 12) p = a @ wff1 + bff1 (bf16, N=2560)
    gemm_mfma<<<dim3(40, 64), 256, 0, stream>>>(a_bf, wff1T, bff1, nullptr, p_bf, 2 * FFI, CCH, 1, 1.f);
    // 13) GEGLU -> g_bf
    glu_kernel<<<20480, 256, 0, stream>>>(p_bf, g_bf);
    // 14) t_bf = bf16(t + g @ wff2 + bff2)  (K=1280)
    gemm_mfma<<<dim3(5, 64), 256, 0, stream>>>(g_bf, wff2T, bff2, t_, t_bf, CCH, FFI, 4, 1.f);
    // 15) y = t_bf @ w_out + b_out (fp32)
    gemm_mfma<<<dim3(5, 64), 256, 0, stream>>>(t_bf, w_outT, b_out, nullptr, y_, CCH, CCH, 0, 1.f);
    // 16) out = y^T + x
    final_kernel<<<5120, 256, 0, stream>>>(y_, x, out);
}

// Round 4
// 712.660 us; speedup vs baseline: 3.3189x; 1.1810x over previous
//
#include <hip/hip_runtime.h>
#include <hip/hip_bf16.h>
#include <math.h>

#define CCH 320
#define NHEADS 8
#define DH 40
#define HW 4096
#define FFI 1280

typedef __bf16 bf16x8 __attribute__((ext_vector_type(8)));
typedef unsigned short u16x8 __attribute__((ext_vector_type(8)));
typedef float f32x4 __attribute__((ext_vector_type(4)));

__device__ inline unsigned short f2bf(float f) {
    __hip_bfloat16 h = __float2bfloat16(f);
    return __builtin_bit_cast(unsigned short, h);
}
__device__ inline float bf2f(unsigned short u) {
    return __builtin_bit_cast(float, ((unsigned)u) << 16);
}
__device__ inline bf16x8 ldfrag(const unsigned short* p) {
    u16x8 raw = *reinterpret_cast<const u16x8*>(p);
    return __builtin_bit_cast(bf16x8, raw);
}

// ---------------------------------------------------------------------------
// Weights -> bf16 B^T (N x K). wff1T is GLU-interleaved: row n of wff1T is
// source col (n>>1) + (n&1)*1280, so a 64-col GEMM tile holds (a,gate) pairs
// in adjacent columns.
// Offsets (ushort): 0 w_inT | 102400 wq1T | 204800 wk1T | 307200 wv1T |
// 409600 wo1T | 512000 wq2T | 614400 wo2T | 716800 w_outT |
// 819200 wff1T(2560x320) | 1638400 wff2T(320x1280) | total 2048000
__global__ __launch_bounds__(256) void prep_w(
    const float* __restrict__ w_in, const float* __restrict__ wq1,
    const float* __restrict__ wk1, const float* __restrict__ wv1,
    const float* __restrict__ wo1, const float* __restrict__ wq2,
    const float* __restrict__ wo2, const float* __restrict__ w_out,
    const float* __restrict__ wff1, const float* __restrict__ wff2,
    unsigned short* __restrict__ Wt) {
    int idx = blockIdx.x * 256 + threadIdx.x;  // < 2048000 exact
    float v;
    if (idx < 819200) {
        int m = idx / 102400;
        int j = idx - m * 102400;
        int n = j / 320, k = j - n * 320;
        const float* src = (m == 0) ? w_in : (m == 1) ? wq1 : (m == 2) ? wk1 :
                           (m == 3) ? wv1 : (m == 4) ? wo1 : (m == 5) ? wq2 :
                           (m == 6) ? wo2 : w_out;
        v = src[k * 320 + n];
    } else if (idx < 1638400) {
        int j = idx - 819200;
        int n = j / 320, k = j - n * 320;
        int nsrc = (n >> 1) + (n & 1) * FFI;  // GLU interleave
        v = wff1[k * 2560 + nsrc];
    } else {
        int j = idx - 1638400;
        int n = j / 1280, k = j - n * 1280;
        v = wff2[k * 320 + n];
    }
    Wt[idx] = f2bf(v);
}

// ---------------------------------------------------------------------------
// GroupNorm stats: 8 blocks per group (32 groups), partial (sum,sumsq).
__global__ __launch_bounds__(256) void gn_stats(const float* __restrict__ X,
                                                float2* __restrict__ part) {
    __shared__ float s1[256], s2[256];
    const int b = blockIdx.x, tid = threadIdx.x;
    const float* xg = X + b * 5120;  // group g = b>>3, chunk = b&7
    float s = 0.f, sq = 0.f;
#pragma unroll
    for (int i = 0; i < 20; ++i) { float v = xg[tid + i * 256]; s += v; sq += v * v; }
    s1[tid] = s; s2[tid] = sq; __syncthreads();
    for (int off = 128; off > 0; off >>= 1) {
        if (tid < off) { s1[tid] += s1[tid + off]; s2[tid] += s2[tid + off]; }
        __syncthreads();
    }
    if (tid == 0) part[b] = make_float2(s1[0], s2[0]);
}

// GroupNorm apply + transpose: X (C,HW) fp32 -> Y (HW,C) bf16, LDS 64x64 tile.
__global__ __launch_bounds__(256) void gn_apply(const float* __restrict__ X,
                                                const float2* __restrict__ part,
                                                const float* __restrict__ w,
                                                const float* __restrict__ b,
                                                unsigned short* __restrict__ Y) {
    __shared__ float tile[64][65];
    __shared__ float gm[32], gr[32];
    const int tid = threadIdx.x;
    const int hw0 = blockIdx.x * 64, c0 = blockIdx.y * 64;
    if (tid < 32) {
        float s = 0.f, sq = 0.f;
#pragma unroll
        for (int i = 0; i < 8; ++i) { float2 p = part[tid * 8 + i]; s += p.x; sq += p.y; }
        float mean = s * (1.f / 40960.f);
        float var  = sq * (1.f / 40960.f) - mean * mean;
        gm[tid] = mean; gr[tid] = rsqrtf(var + 1e-6f);
    }
#pragma unroll
    for (int i = 0; i < 16; ++i) {
        int idx = tid + i * 256;
        int r = idx >> 6, col = idx & 63;
        tile[r][col] = X[(size_t)(c0 + r) * HW + hw0 + col];
    }
    __syncthreads();
#pragma unroll
    for (int i = 0; i < 16; ++i) {
        int idx = tid + i * 256;
        int hwl = idx >> 6, cl = idx & 63;
        int c = c0 + cl, g = c / 10;
        float v = (tile[cl][hwl] - gm[g]) * gr[g] * w[c] + b[c];
        Y[(size_t)(hw0 + hwl) * CCH + c] = f2bf(v);
    }
}

// ---------------------------------------------------------------------------
// LayerNorm over last dim (320), fp32 in -> bf16 out. One wave per row.
__global__ __launch_bounds__(256) void ln_kernel(const float* __restrict__ X,
                                                 const float* __restrict__ w,
                                                 const float* __restrict__ b,
                                                 unsigned short* __restrict__ Y) {
    const int row  = blockIdx.x * 4 + (threadIdx.x >> 6);
    const int lane = threadIdx.x & 63;
    const float* xr = X + row * CCH;
    float v[5];
    float s = 0.f, sq = 0.f;
#pragma unroll
    for (int i = 0; i < 5; ++i) { v[i] = xr[lane + 64 * i]; s += v[i]; sq += v[i] * v[i]; }
#pragma unroll
    for (int off = 32; off > 0; off >>= 1) {
        s  += __shfl_xor(s, off, 64);
        sq += __shfl_xor(sq, off, 64);
    }
    const float mean = s * (1.f / 320.f);
    const float var  = sq * (1.f / 320.f) - mean * mean;
    const float rstd = rsqrtf(var + 1e-5f);
    unsigned short* yr = Y + row * CCH;
#pragma unroll
    for (int i = 0; i < 5; ++i) {
        int c = lane + 64 * i;
        yr[c] = f2bf((v[i] - mean) * rstd * w[c] + b[c]);
    }
}

// ---------------------------------------------------------------------------
// bf16 MFMA GEMM, direct-from-global. A: MxK bf16 rm. Bt: NxK bf16.
// Grid (N/64, M/64), 4 waves, wave = 16 cols x 64 rows (4 mfma tiles), BK=64.
// Modes:
//  0: fp32 out = acc + bias (+res fp32)
//  1: bf16 out = acc + bias
//  2: QK-pack (h=col&7,d=col>>3): Cout[((h<<12)+row)*64+d] = bf16(acc*scale)
//  3: VT-pack: Cout[((h*48+d)<<12)+row] = bf16(acc)
//  4: bf16 out = acc + bias + res(fp32)
//  5: GLU (interleaved cols): pair (even=a, odd=gate) via shfl_xor 1;
//     even lanes store Cout[row*1280 + col/2] = bf16(a * gelu(gate));
//     bias indexed bff1[(col>>1) + (col&1)*1280]
//  6: dual: Cout[row*N+col] = bf16(acc) AND Cout2 QK-pack with scale
__global__ __launch_bounds__(256) void gemm_mfma(
    const unsigned short* __restrict__ A,
    const unsigned short* __restrict__ Bt,
    const float* __restrict__ bias,
    const float* __restrict__ res,
    void* __restrict__ Cout, void* __restrict__ Cout2,
    int N, int K, int mode, float scale) {
    const int tid  = threadIdx.x;
    const int wave = tid >> 6, lane = tid & 63;
    const int quad = lane >> 4, c = lane & 15;
    const int m0 = blockIdx.y * 64;
    const int n0 = blockIdx.x * 64 + wave * 16;

    f32x4 acc[4];
#pragma unroll
    for (int i = 0; i < 4; ++i) acc[i] = (f32x4){0.f, 0.f, 0.f, 0.f};

    const unsigned short* bp = Bt + (size_t)(n0 + c) * K + quad * 8;
    const unsigned short* ap = A + (size_t)(m0 + c) * K + quad * 8;
    for (int k0 = 0; k0 < K; k0 += 64) {
        bf16x8 b0 = ldfrag(bp + k0);
        bf16x8 b1 = ldfrag(bp + k0 + 32);
#pragma unroll
        for (int mt = 0; mt < 4; ++mt) {
            bf16x8 a0 = ldfrag(ap + (size_t)mt * 16 * K + k0);
            bf16x8 a1 = ldfrag(ap + (size_t)mt * 16 * K + k0 + 32);
            acc[mt] = __builtin_amdgcn_mfma_f32_16x16x32_bf16(a0, b0, acc[mt], 0, 0, 0);
            acc[mt] = __builtin_amdgcn_mfma_f32_16x16x32_bf16(a1, b1, acc[mt], 0, 0, 0);
        }
    }

    const int col = n0 + c;
    float bval = 0.f;
    if (bias) bval = (mode == 5) ? bias[(col >> 1) + (col & 1) * FFI] : bias[col];
#pragma unroll
    for (int mt = 0; mt < 4; ++mt) {
#pragma unroll
        for (int r = 0; r < 4; ++r) {
            const int row = m0 + mt * 16 + quad * 4 + r;
            float v = acc[mt][r];
            if (mode == 0) {
                v += bval;
                if (res) v += res[(size_t)row * N + col];
                ((float*)Cout)[(size_t)row * N + col] = v;
            } else if (mode == 1) {
                ((unsigned short*)Cout)[(size_t)row * N + col] = f2bf(v + bval);
            } else if (mode == 2) {
                int h = col & 7, d = col >> 3;
                ((unsigned short*)Cout)[(((size_t)h << 12) + row) * 64 + d] = f2bf(v * scale);
            } else if (mode == 3) {
                int h = col & 7, d = col >> 3;
                ((unsigned short*)Cout)[(((size_t)(h * 48 + d)) << 12) + row] = f2bf(v);
            } else if (mode == 4) {
                ((unsigned short*)Cout)[(size_t)row * N + col] =
                    f2bf(v + bval + res[(size_t)row * N + col]);
            } else if (mode == 5) {
                v += bval;
                float other = __shfl_xor(v, 1, 64);
                if ((c & 1) == 0) {
                    float g = 0.5f * other * (1.f + erff(other * 0.70710678118654752f));
                    ((unsigned short*)Cout)[(size_t)row * FFI + (col >> 1)] = f2bf(v * g);
                }
            } else {  // 6
                ((unsigned short*)Cout)[(size_t)row * N + col] = f2bf(v);
                int h = col & 7, d = col >> 3;
                ((unsigned short*)Cout2)[(((size_t)h << 12) + row) * 64 + d] = f2bf(v * scale);
            }
        }
    }
}

// ---------------------------------------------------------------------------
// Context K/V: one kernel computes kc = ctx@wk2 -> Kc packed [h][128][64] and
// vc = ctx@wv2 -> Vc packed [h*48+d][128], rows >=77 zeroed. Grid (5,2,2).
__global__ __launch_bounds__(256) void ctx_kv(
    const float* __restrict__ ctx, const float* __restrict__ wk2,
    const float* __restrict__ wv2, unsigned short* __restrict__ Kc,
    unsigned short* __restrict__ Vc) {
    __shared__ __align__(16) float As[16][68];
    __shared__ __align__(16) float Bs[16][68];
    const int tid = threadIdx.x;
    const int tx = tid & 15, ty = tid >> 4;
    const int bn = blockIdx.x, bm = blockIdx.y;
    const float* B = (blockIdx.z == 0) ? wk2 : wv2;
    float acc[4][4] = {};
    for (int k0 = 0; k0 < 768; k0 += 16) {
#pragma unroll
        for (int i = 0; i < 4; ++i) {
            int idx = tid + i * 256;
            int r = idx >> 4, cc = idx & 15;
            int gm = bm * 64 + r;
            As[cc][r] = (gm < 77) ? ctx[gm * 768 + k0 + cc] : 0.f;
        }
#pragma unroll
        for (int i = 0; i < 4; ++i) {
            int idx = tid + i * 256;
            int r = idx >> 6, cc = idx & 63;
            Bs[r][cc] = B[(k0 + r) * CCH + bn * 64 + cc];
        }
        __syncthreads();
#pragma unroll
        for (int kk = 0; kk < 16; ++kk) {
            float4 a4 = *(const float4*)&As[kk][ty * 4];
            float4 b4 = *(const float4*)&Bs[kk][tx * 4];
            float av[4] = {a4.x, a4.y, a4.z, a4.w};
            float bv[4] = {b4.x, b4.y, b4.z, b4.w};
#pragma unroll
            for (int i = 0; i < 4; ++i)
#pragma unroll
                for (int j = 0; j < 4; ++j) acc[i][j] += av[i] * bv[j];
        }
        __syncthreads();
    }
#pragma unroll
    for (int i = 0; i < 4; ++i) {
        int row = bm * 64 + ty * 4 + i;
#pragma unroll
        for (int j = 0; j < 4; ++j) {
            int col = bn * 64 + tx * 4 + j;
            int h = col & 7, d = col >> 3;
            float v = (row < 77) ? acc[i][j] : 0.f;
            if (blockIdx.z == 0)
                Kc[(((size_t)h << 7) + row) * 64 + d] = f2bf(v);
            else
                Vc[(size_t)(h * 48 + d) * 128 + row] = f2bf(v);
        }
    }
}

// ---------------------------------------------------------------------------
// Split-K MFMA flash attention, static-max softmax (scores bounded ~1; Q is
// pre-scaled by scale*log2e so p = exp2(s)). Grid (64, 8, S); 4 waves/block,
// wave = 16 queries x segment of keys. Unnormalized partials:
// pO[((seg*8+h)<<12)+row)*40+col] fp32, pL[((seg*8+h)<<12)+row].
__global__ __launch_bounds__(256) void attn2(
    const unsigned short* __restrict__ Qp,
    const unsigned short* __restrict__ Kp,
    const unsigned short* __restrict__ Vt,
    float* __restrict__ pO, float* __restrict__ pL,
    int Lk, int Lkp, int tilesPerSeg) {
    __shared__ unsigned short Pb[4][16 * 72];
    const int tid  = threadIdx.x;
    const int wave = tid >> 6, lane = tid & 63;
    const int quad = lane >> 4, c = lane & 15;
    const int h   = blockIdx.y;
    const int seg = blockIdx.z;
    const int q0  = blockIdx.x * 64 + wave * 16;

    const unsigned short* qbase = Qp + (((h << 12) + q0 + c) << 6) + quad * 8;
    const bf16x8 aQ0 = ldfrag(qbase);
    const bf16x8 aQ1 = ldfrag(qbase + 32);

    f32x4 oacc0 = {0.f, 0.f, 0.f, 0.f}, oacc1 = oacc0, oacc2 = oacc0;
    f32x4 lacc = {0.f, 0.f, 0.f, 0.f};
    unsigned short* Pw = &Pb[wave][0];

    const int kt0 = seg * tilesPerSeg;
    for (int t = 0; t < tilesPerSeg; ++t) {
        const int kb = (kt0 + t) * 64;
        const unsigned short* kbase = Kp + ((size_t)(h * Lkp + kb + c) << 6) + quad * 8;
        f32x4 s[4];
#pragma unroll
        for (int nt = 0; nt < 4; ++nt) {
            bf16x8 k0 = ldfrag(kbase + nt * 1024);
            bf16x8 k1 = ldfrag(kbase + nt * 1024 + 32);
            f32x4 z = {0.f, 0.f, 0.f, 0.f};
            z = __builtin_amdgcn_mfma_f32_16x16x32_bf16(aQ0, k0, z, 0, 0, 0);
            z = __builtin_amdgcn_mfma_f32_16x16x32_bf16(aQ1, k1, z, 0, 0, 0);
            s[nt] = z;
        }
        if (kb + 64 > Lk) {
#pragma unroll
            for (int nt = 0; nt < 4; ++nt)
                if (kb + nt * 16 + c >= Lk)
                    { s[nt][0] = s[nt][1] = s[nt][2] = s[nt][3] = -30000.f; }
        }
        // V fragments (independent of LDS)
        bf16x8 vf[3][2];
#pragma unroll
        for (int nt = 0; nt < 3; ++nt) {
            const unsigned short* vb = Vt + (size_t)(h * 48 + nt * 16 + c) * Lkp + kb + quad * 8;
            vf[nt][0] = ldfrag(vb);
            vf[nt][1] = ldfrag(vb + 32);
        }
        asm volatile("s_waitcnt lgkmcnt(0)" ::: "memory");  // prior P reads done
#pragma unroll
        for (int nt = 0; nt < 4; ++nt) {
#pragma unroll
            for (int r = 0; r < 4; ++r) {
                float p = exp2f(s[nt][r]);
                lacc[r] += p;
                Pw[(quad * 4 + r) * 72 + nt * 16 + c] = f2bf(p);
            }
        }
        asm volatile("s_waitcnt lgkmcnt(0)" ::: "memory");  // P writes visible
        bf16x8 pA0 = ldfrag(Pw + c * 72 + quad * 8);
        bf16x8 pA1 = ldfrag(Pw + c * 72 + quad * 8 + 32);
        oacc0 = __builtin_amdgcn_mfma_f32_16x16x32_bf16(pA0, vf[0][0], oacc0, 0, 0, 0);
        oacc0 = __builtin_amdgcn_mfma_f32_16x16x32_bf16(pA1, vf[0][1], oacc0, 0, 0, 0);
        oacc1 = __builtin_amdgcn_mfma_f32_16x16x32_bf16(pA0, vf[1][0], oacc1, 0, 0, 0);
        oacc1 = __builtin_amdgcn_mfma_f32_16x16x32_bf16(pA1, vf[1][1], oacc1, 0, 0, 0);
        oacc2 = __builtin_amdgcn_mfma_f32_16x16x32_bf16(pA0, vf[2][0], oacc2, 0, 0, 0);
        oacc2 = __builtin_amdgcn_mfma_f32_16x16x32_bf16(pA1, vf[2][1], oacc2, 0, 0, 0);
    }
    // row-sum of l across the 16-lane col group
#pragma unroll
    for (int r = 0; r < 4; ++r) {
        float ps = lacc[r];
        ps += __shfl_xor(ps, 1, 64);
        ps += __shfl_xor(ps, 2, 64);
        ps += __shfl_xor(ps, 4, 64);
        ps += __shfl_xor(ps, 8, 64);
        lacc[r] = ps;
    }
    const size_t base = ((size_t)(seg * 8 + h)) << 12;
#pragma unroll
    for (int r = 0; r < 4; ++r) {
        int row = q0 + quad * 4 + r;
        float* ob = pO + (base + row) * 40;
        ob[c]      = oacc0[r];
        ob[16 + c] = oacc1[r];
        if (c < 8) ob[32 + c] = oacc2[r];
        if (c == 0) pL[base + row] = lacc[r];
    }
}

// Combine partials across S segments -> bf16 O (HW,320), col = h*40+d.
__global__ __launch_bounds__(256) void attn_combine(
    const float* __restrict__ pO, const float* __restrict__ pL,
    unsigned short* __restrict__ O, int S) {
    int idx = blockIdx.x * 256 + threadIdx.x;  // < 8*4096*40, grid 5120
    int h = idx / (HW * 40);
    int rem = idx - h * (HW * 40);
    int row = rem / 40, d = rem - row * 40;
    float num = 0.f, den = 0.f;
    for (int s = 0; s < S; ++s) {
        size_t base = ((size_t)(s * 8 + h)) << 12;
        num += pO[(base + row) * 40 + d];
        den += pL[base + row];
    }
    O[(size_t)row * CCH + h * DH + d] = f2bf(num / den);
}

// ---------------------------------------------------------------------------
__global__ void final_kernel(const float* __restrict__ Yv,
                             const float* __restrict__ X,
                             float* __restrict__ Out) {
    int idx = blockIdx.x * 256 + threadIdx.x;
    int o = idx >> 12, hw = idx & 4095;
    Out[idx] = Yv[hw * CCH + o] + X[idx];
}

// ---------------------------------------------------------------------------
extern "C" void kernel_launch(void* const* d_in, const int* in_sizes, int n_in,
                              void* d_out, int out_size, void* d_ws, size_t ws_size,
                              hipStream_t stream) {
    const float* x     = (const float*)d_in[0];
    const float* ctx   = (const float*)d_in[1];
    const float* gn_w  = (const float*)d_in[2];
    const float* gn_b  = (const float*)d_in[3];
    const float* w_in  = (const float*)d_in[4];
    const float* b_in  = (const float*)d_in[5];
    const float* ln1_w = (const float*)d_in[6];
    const float* ln1_b = (const float*)d_in[7];
    const float* wq1   = (const float*)d_in[8];
    const float* wk1   = (const float*)d_in[9];
    const float* wv1   = (const float*)d_in[10];
    const float* wo1   = (const float*)d_in[11];
    const float* bo1   = (const float*)d_in[12];
    const float* ln2_w = (const float*)d_in[13];
    const float* ln2_b = (const float*)d_in[14];
    const float* wq2   = (const float*)d_in[15];
    const float* wk2   = (const float*)d_in[16];
    const float* wv2   = (const float*)d_in[17];
    const float* wo2   = (const float*)d_in[18];
    const float* bo2   = (const float*)d_in[19];
    const float* ln3_w = (const float*)d_in[20];
    const float* ln3_b = (const float*)d_in[21];
    const float* wff1  = (const float*)d_in[22];
    const float* bff1  = (const float*)d_in[23];
    const float* wff2  = (const float*)d_in[24];
    const float* bff2  = (const float*)d_in[25];
    const float* w_out = (const float*)d_in[26];
    const float* b_out = (const float*)d_in[27];
    float* out = (float*)d_out;

    const int NT = HW * CCH;  // 1,310,720
    float* ws = (float*)d_ws;
    float* t_   = ws;                 // fp32 residual (HW,C)
    float* y_   = t_ + NT;            // fp32 final proj
    float* pO   = y_ + NT;            // attn partial O: 4*8*4096*40
    float* pL   = pO + 4 * 8 * 4096 * 40;  // 4*8*4096
    float2* gnp = (float2*)(pL + 4 * 8 * 4096);  // 256 float2
    unsigned short* u = (unsigned short*)(gnp + 256);
    unsigned short* a_bf = u;                  u += NT;
    unsigned short* q_bf = u;                  u += NT;
    unsigned short* o_bf = u;                  u += NT;
    unsigned short* t_bf = u;                  u += NT;
    unsigned short* g_bf = u;                  u += HW * FFI;
    unsigned short* Qp   = u;                  u += 8 * 4096 * 64;
    unsigned short* Kp   = u;                  u += 8 * 4096 * 64;
    unsigned short* Vt   = u;                  u += 8 * 48 * 4096;
    unsigned short* Kc   = u;                  u += 8 * 128 * 64;
    unsigned short* Vc   = u;                  u += 8 * 48 * 128;
    unsigned short* Wt   = u;                  u += 2048000;

    const unsigned short* w_inT  = Wt;
    const unsigned short* wq1T   = Wt + 102400;
    const unsigned short* wk1T   = Wt + 204800;
    const unsigned short* wv1T   = Wt + 307200;
    const unsigned short* wo1T   = Wt + 409600;
    const unsigned short* wq2T   = Wt + 512000;
    const unsigned short* wo2T   = Wt + 614400;
    const unsigned short* w_outT = Wt + 716800;
    const unsigned short* wff1T  = Wt + 819200;
    const unsigned short* wff2T  = Wt + 1638400;

    // fold softmax scale and log2(e) into Q so attention uses exp2 directly
    const float qscale = 0.15811388300841897f * 1.4426950408889634f;

    prep_w<<<8000, 256, 0, stream>>>(w_in, wq1, wk1, wv1, wo1, wq2, wo2, w_out,
                                     wff1, wff2, Wt);
    // zero pads of Qp,Kp,Vt,Kc,Vc (contiguous)
    hipMemsetAsync(Qp, 0,
                   (size_t)(8 * 4096 * 64 * 2 + 8 * 48 * 4096 + 8 * 128 * 64 + 8 * 48 * 128) * 2,
                   stream);

    // 1) GroupNorm -> a_bf (HW,C)
    gn_stats<<<256, 256, 0, stream>>>(x, gnp);
    gn_apply<<<dim3(64, 5), 256, 0, stream>>>(x, gnp, gn_w, gn_b, a_bf);
    // 2) proj_in: t = a @ w_in + b_in (fp32)
    gemm_mfma<<<dim3(5, 64), 256, 0, stream>>>(a_bf, w_inT, b_in, nullptr, t_, nullptr, CCH, CCH, 0, 1.f);
    // 3) ln1 -> a_bf
    ln_kernel<<<1024, 256, 0, stream>>>(t_, ln1_w, ln1_b, a_bf);
    // 4) q (dual: row-major + Qp scaled), k -> Kp, v -> Vt
    gemm_mfma<<<dim3(5, 64), 256, 0, stream>>>(a_bf, wq1T, nullptr, nullptr, q_bf, Qp, CCH, CCH, 6, qscale);
    gemm_mfma<<<dim3(5, 64), 256, 0, stream>>>(q_bf, wk1T, nullptr, nullptr, Kp, nullptr, CCH, CCH, 2, 1.f);
    gemm_mfma<<<dim3(5, 64), 256, 0, stream>>>(q_bf, wv1T, nullptr, nullptr, Vt, nullptr, CCH, CCH, 3, 1.f);
    // 5) self-attention: 4 key-segments of 1024, then combine
    attn2<<<dim3(64, NHEADS, 4), 256, 0, stream>>>(Qp, Kp, Vt, pO, pL, HW, HW, 16);
    attn_combine<<<5120, 256, 0, stream>>>(pO, pL, o_bf, 4);
    // 6) t += o @ wo1 + bo1
    gemm_mfma<<<dim3(5, 64), 256, 0, stream>>>(o_bf, wo1T, bo1, t_, t_, nullptr, CCH, CCH, 0, 1.f);
    // 7) ln2 -> a_bf
    ln_kernel<<<1024, 256, 0, stream>>>(t_, ln2_w, ln2_b, a_bf);
    // 8) cross q -> Qp; ctx K/V packed directly
    gemm_mfma<<<dim3(5, 64), 256, 0, stream>>>(a_bf, wq2T, nullptr, nullptr, Qp, nullptr, CCH, CCH, 2, qscale);
    ctx_kv<<<dim3(5, 2, 2), 256, 0, stream>>>(ctx, wk2, wv2, Kc, Vc);
    // 9) cross-attention (Lk=77, 1 segment of 2 tiles)
    attn2<<<dim3(64, NHEADS, 1), 256, 0, stream>>>(Qp, Kc, Vc, pO, pL, 77, 128, 2);
    attn_combine<<<5120, 256, 0, stream>>>(pO, pL, o_bf, 1);
    // 10) t += o @ wo2 + bo2
    gemm_mfma<<<dim3(5, 64), 256, 0, stream>>>(o_bf, wo2T, bo2, t_, t_, nullptr, CCH, CCH, 0, 1.f);
    // 11) ln3 -> a_bf
    ln_kernel<<<1024, 256, 0, stream>>>(t_, ln3_w, ln3_b, a_bf);
    // 12+13) FF1 with fused GEGLU (interleaved wff1T) -> g_bf
    gemm_mfma<<<dim3(40, 64), 256, 0, stream>>>(a_bf, wff1T, bff1, nullptr, g_bf, nullptr, 2 * FFI, CCH, 5, 1.f);
    // 14) t_bf = bf16(t + g @ wff2 + bff2)
    gemm_mfma<<<dim3(5, 64), 256, 0, stream>>>(g_bf, wff2T, bff2, t_, t_bf, nullptr, CCH, FFI, 4, 1.f);
    // 15) y = t_bf @ w_out + b_out (fp32)
    gemm_mfma<<<dim3(5, 64), 256, 0, stream>>>(t_bf, w_outT, b_out, nullptr, y_, nullptr, CCH, CCH, 0, 1.f);
    // 16) out = y^T + x
    final_kernel<<<5120, 256, 0, stream>>>(y_, x, out);
}

// Round 5
// 688.978 us; speedup vs baseline: 3.4330x; 1.0344x over previous
//
#include <hip/hip_runtime.h>
#include <hip/hip_bf16.h>
#include <math.h>

#define CCH 320
#define NHEADS 8
#define DH 40
#define HW 4096
#define FFI 1280

typedef __bf16 bf16x8 __attribute__((ext_vector_type(8)));
typedef unsigned short u16x8 __attribute__((ext_vector_type(8)));
typedef float f32x4 __attribute__((ext_vector_type(4)));
typedef unsigned int u32x4 __attribute__((ext_vector_type(4)));

__device__ inline unsigned short f2bf(float f) {
    __hip_bfloat16 h = __float2bfloat16(f);
    return __builtin_bit_cast(unsigned short, h);
}
__device__ inline float bf2f(unsigned short u) {
    return __builtin_bit_cast(float, ((unsigned)u) << 16);
}
__device__ inline bf16x8 ldfrag(const unsigned short* p) {
    u16x8 raw = *reinterpret_cast<const u16x8*>(p);
    return __builtin_bit_cast(bf16x8, raw);
}

// ---------------------------------------------------------------------------
// Weights -> bf16 B^T (N x K). wff1T GLU-interleaved (row n <- col (n>>1)+(n&1)*1280).
__global__ __launch_bounds__(256) void prep_w(
    const float* __restrict__ w_in, const float* __restrict__ wq1,
    const float* __restrict__ wk1, const float* __restrict__ wv1,
    const float* __restrict__ wo1, const float* __restrict__ wq2,
    const float* __restrict__ wo2, const float* __restrict__ w_out,
    const float* __restrict__ wff1, const float* __restrict__ wff2,
    unsigned short* __restrict__ Wt) {
    int idx = blockIdx.x * 256 + threadIdx.x;  // < 2048000 exact
    float v;
    if (idx < 819200) {
        int m = idx / 102400;
        int j = idx - m * 102400;
        int n = j / 320, k = j - n * 320;
        const float* src = (m == 0) ? w_in : (m == 1) ? wq1 : (m == 2) ? wk1 :
                           (m == 3) ? wv1 : (m == 4) ? wo1 : (m == 5) ? wq2 :
                           (m == 6) ? wo2 : w_out;
        v = src[k * 320 + n];
    } else if (idx < 1638400) {
        int j = idx - 819200;
        int n = j / 320, k = j - n * 320;
        int nsrc = (n >> 1) + (n & 1) * FFI;
        v = wff1[k * 2560 + nsrc];
    } else {
        int j = idx - 1638400;
        int n = j / 1280, k = j - n * 1280;
        v = wff2[k * 320 + n];
    }
    Wt[idx] = f2bf(v);
}

// ---------------------------------------------------------------------------
__global__ __launch_bounds__(256) void gn_stats(const float* __restrict__ X,
                                                float2* __restrict__ part) {
    __shared__ float s1[256], s2[256];
    const int b = blockIdx.x, tid = threadIdx.x;
    const float* xg = X + b * 5120;
    float s = 0.f, sq = 0.f;
#pragma unroll
    for (int i = 0; i < 20; ++i) { float v = xg[tid + i * 256]; s += v; sq += v * v; }
    s1[tid] = s; s2[tid] = sq; __syncthreads();
    for (int off = 128; off > 0; off >>= 1) {
        if (tid < off) { s1[tid] += s1[tid + off]; s2[tid] += s2[tid + off]; }
        __syncthreads();
    }
    if (tid == 0) part[b] = make_float2(s1[0], s2[0]);
}

__global__ __launch_bounds__(256) void gn_apply(const float* __restrict__ X,
                                                const float2* __restrict__ part,
                                                const float* __restrict__ w,
                                                const float* __restrict__ b,
                                                unsigned short* __restrict__ Y) {
    __shared__ float tile[64][65];
    __shared__ float gm[32], gr[32];
    const int tid = threadIdx.x;
    const int hw0 = blockIdx.x * 64, c0 = blockIdx.y * 64;
    if (tid < 32) {
        float s = 0.f, sq = 0.f;
#pragma unroll
        for (int i = 0; i < 8; ++i) { float2 p = part[tid * 8 + i]; s += p.x; sq += p.y; }
        float mean = s * (1.f / 40960.f);
        float var  = sq * (1.f / 40960.f) - mean * mean;
        gm[tid] = mean; gr[tid] = rsqrtf(var + 1e-6f);
    }
#pragma unroll
    for (int i = 0; i < 16; ++i) {
        int idx = tid + i * 256;
        int r = idx >> 6, col = idx & 63;
        tile[r][col] = X[(size_t)(c0 + r) * HW + hw0 + col];
    }
    __syncthreads();
#pragma unroll
    for (int i = 0; i < 16; ++i) {
        int idx = tid + i * 256;
        int hwl = idx >> 6, cl = idx & 63;
        int c = c0 + cl, g = c / 10;
        float v = (tile[cl][hwl] - gm[g]) * gr[g] * w[c] + b[c];
        Y[(size_t)(hw0 + hwl) * CCH + c] = f2bf(v);
    }
}

// ---------------------------------------------------------------------------
__global__ __launch_bounds__(256) void ln_kernel(const float* __restrict__ X,
                                                 const float* __restrict__ w,
                                                 const float* __restrict__ b,
                                                 unsigned short* __restrict__ Y) {
    const int row  = blockIdx.x * 4 + (threadIdx.x >> 6);
    const int lane = threadIdx.x & 63;
    const float* xr = X + row * CCH;
    float v[5];
    float s = 0.f, sq = 0.f;
#pragma unroll
    for (int i = 0; i < 5; ++i) { v[i] = xr[lane + 64 * i]; s += v[i]; sq += v[i] * v[i]; }
#pragma unroll
    for (int off = 32; off > 0; off >>= 1) {
        s  += __shfl_xor(s, off, 64);
        sq += __shfl_xor(sq, off, 64);
    }
    const float mean = s * (1.f / 320.f);
    const float var  = sq * (1.f / 320.f) - mean * mean;
    const float rstd = rsqrtf(var + 1e-5f);
    unsigned short* yr = Y + row * CCH;
#pragma unroll
    for (int i = 0; i < 5; ++i) {
        int c = lane + 64 * i;
        yr[c] = f2bf((v[i] - mean) * rstd * w[c] + b[c]);
    }
}

// ---------------------------------------------------------------------------
// bf16 MFMA GEMM, direct-from-global. Wave = 16 cols x (MT*16) rows, BK=64.
// Grid (N/64, M/(MT*16)). Modes as before.
template <int MT>
__global__ __launch_bounds__(256) void gemm_mfma(
    const unsigned short* __restrict__ A,
    const unsigned short* __restrict__ Bt,
    const float* __restrict__ bias,
    const float* __restrict__ res,
    void* __restrict__ Cout, void* __restrict__ Cout2,
    int N, int K, int mode, float scale) {
    const int tid  = threadIdx.x;
    const int wave = tid >> 6, lane = tid & 63;
    const int quad = lane >> 4, c = lane & 15;
    const int m0 = blockIdx.y * (MT * 16);
    const int n0 = blockIdx.x * 64 + wave * 16;

    f32x4 acc[MT];
#pragma unroll
    for (int i = 0; i < MT; ++i) acc[i] = (f32x4){0.f, 0.f, 0.f, 0.f};

    const unsigned short* bp = Bt + (size_t)(n0 + c) * K + quad * 8;
    const unsigned short* ap = A + (size_t)(m0 + c) * K + quad * 8;
    for (int k0 = 0; k0 < K; k0 += 64) {
        bf16x8 b0 = ldfrag(bp + k0);
        bf16x8 b1 = ldfrag(bp + k0 + 32);
#pragma unroll
        for (int mt = 0; mt < MT; ++mt) {
            bf16x8 a0 = ldfrag(ap + (size_t)mt * 16 * K + k0);
            bf16x8 a1 = ldfrag(ap + (size_t)mt * 16 * K + k0 + 32);
            acc[mt] = __builtin_amdgcn_mfma_f32_16x16x32_bf16(a0, b0, acc[mt], 0, 0, 0);
            acc[mt] = __builtin_amdgcn_mfma_f32_16x16x32_bf16(a1, b1, acc[mt], 0, 0, 0);
        }
    }

    const int col = n0 + c;
    float bval = 0.f;
    if (bias) bval = (mode == 5) ? bias[(col >> 1) + (col & 1) * FFI] : bias[col];
#pragma unroll
    for (int mt = 0; mt < MT; ++mt) {
#pragma unroll
        for (int r = 0; r < 4; ++r) {
            const int row = m0 + mt * 16 + quad * 4 + r;
            float v = acc[mt][r];
            if (mode == 0) {
                v += bval;
                if (res) v += res[(size_t)row * N + col];
                ((float*)Cout)[(size_t)row * N + col] = v;
            } else if (mode == 1) {
                ((unsigned short*)Cout)[(size_t)row * N + col] = f2bf(v + bval);
            } else if (mode == 2) {
                int h = col & 7, d = col >> 3;
                ((unsigned short*)Cout)[(((size_t)h << 12) + row) * 64 + d] = f2bf(v * scale);
            } else if (mode == 3) {
                int h = col & 7, d = col >> 3;
                ((unsigned short*)Cout)[(((size_t)(h * 48 + d)) << 12) + row] = f2bf(v);
            } else if (mode == 4) {
                ((unsigned short*)Cout)[(size_t)row * N + col] =
                    f2bf(v + bval + res[(size_t)row * N + col]);
            } else if (mode == 5) {
                v += bval;
                float other = __shfl_xor(v, 1, 64);
                if ((c & 1) == 0) {
                    float g = 0.5f * other * (1.f + erff(other * 0.70710678118654752f));
                    ((unsigned short*)Cout)[(size_t)row * FFI + (col >> 1)] = f2bf(v * g);
                }
            } else {  // 6
                ((unsigned short*)Cout)[(size_t)row * N + col] = f2bf(v);
                int h = col & 7, d = col >> 3;
                ((unsigned short*)Cout2)[(((size_t)h << 12) + row) * 64 + d] = f2bf(v * scale);
            }
        }
    }
}

// ---------------------------------------------------------------------------
// Context K/V (77 rows) -> packed Kc [h][128][64], Vc [h*48+d][128].
__global__ __launch_bounds__(256) void ctx_kv(
    const float* __restrict__ ctx, const float* __restrict__ wk2,
    const float* __restrict__ wv2, unsigned short* __restrict__ Kc,
    unsigned short* __restrict__ Vc) {
    __shared__ __align__(16) float As[16][68];
    __shared__ __align__(16) float Bs[16][68];
    const int tid = threadIdx.x;
    const int tx = tid & 15, ty = tid >> 4;
    const int bn = blockIdx.x, bm = blockIdx.y;
    const float* B = (blockIdx.z == 0) ? wk2 : wv2;
    float acc[4][4] = {};
    for (int k0 = 0; k0 < 768; k0 += 16) {
#pragma unroll
        for (int i = 0; i < 4; ++i) {
            int idx = tid + i * 256;
            int r = idx >> 4, cc = idx & 15;
            int gm = bm * 64 + r;
            As[cc][r] = (gm < 77) ? ctx[gm * 768 + k0 + cc] : 0.f;
        }
#pragma unroll
        for (int i = 0; i < 4; ++i) {
            int idx = tid + i * 256;
            int r = idx >> 6, cc = idx & 63;
            Bs[r][cc] = B[(k0 + r) * CCH + bn * 64 + cc];
        }
        __syncthreads();
#pragma unroll
        for (int kk = 0; kk < 16; ++kk) {
            float4 a4 = *(const float4*)&As[kk][ty * 4];
            float4 b4 = *(const float4*)&Bs[kk][tx * 4];
            float av[4] = {a4.x, a4.y, a4.z, a4.w};
            float bv[4] = {b4.x, b4.y, b4.z, b4.w};
#pragma unroll
            for (int i = 0; i < 4; ++i)
#pragma unroll
                for (int j = 0; j < 4; ++j) acc[i][j] += av[i] * bv[j];
        }
        __syncthreads();
    }
#pragma unroll
    for (int i = 0; i < 4; ++i) {
        int row = bm * 64 + ty * 4 + i;
#pragma unroll
        for (int j = 0; j < 4; ++j) {
            int col = bn * 64 + tx * 4 + j;
            int h = col & 7, d = col >> 3;
            float v = (row < 77) ? acc[i][j] : 0.f;
            if (blockIdx.z == 0)
                Kc[(((size_t)h << 7) + row) * 64 + d] = f2bf(v);
            else
                Vc[(size_t)(h * 48 + d) * 128 + row] = f2bf(v);
        }
    }
}

// ---------------------------------------------------------------------------
// LDS-free MFMA flash attention (static-max, split-K). Computes transposed:
//  S^T = mfma(A=K, B=Q)  -> C-layout row=key(quad*4+r), col=query(c)
//  P^T C-layout -> B-layout via 8 packs + 16 ds_bpermute + 8 cndmask
//  O^T = mfma(A=V^T, B=P^T) -> C-layout row=dim, col=query -> float4 stores.
// No __shared__, no barriers -> compiler pipelines loads across tiles.
__global__ __launch_bounds__(256) void attn3(
    const unsigned short* __restrict__ Qp,
    const unsigned short* __restrict__ Kp,
    const unsigned short* __restrict__ Vt,
    float* __restrict__ pO, float* __restrict__ pL,
    int Lk, int Lkp, int tilesPerSeg) {
    const int tid  = threadIdx.x;
    const int wave = tid >> 6, lane = tid & 63;
    const int quad = lane >> 4, c = lane & 15;
    const int h   = blockIdx.y;
    const int seg = blockIdx.z;
    const int q0  = blockIdx.x * 64 + wave * 16;

    // Q as B-operand: lane c = query, k = quad*8+j (+32 for second half)
    const unsigned short* qbase = Qp + ((((size_t)h << 12) + q0 + c) << 6) + quad * 8;
    const bf16x8 bQ0 = ldfrag(qbase);
    const bf16x8 bQ1 = ldfrag(qbase + 32);

    f32x4 oacc0 = {0.f, 0.f, 0.f, 0.f}, oacc1 = oacc0, oacc2 = oacc0;
    float lacc = 0.f;
    // bpermute source-lane patterns (bytes): qs = 2*quad[0] + d[1]
    const int idx0 = ((((quad & 1) * 2 + 0) * 16 + c) << 2);
    const int idx1 = ((((quad & 1) * 2 + 1) * 16 + c) << 2);
    const bool hiQuad = (quad >> 1) != 0;

    const int kt0 = seg * tilesPerSeg;
    for (int t = 0; t < tilesPerSeg; ++t) {
        const int kb = (kt0 + t) * 64;
        // ---- S^T = K·Q^T : 4 key-blocks of 16 ----
        const unsigned short* kbase = Kp + (((size_t)h * Lkp + kb + c) << 6) + quad * 8;
        f32x4 s[4];
#pragma unroll
        for (int blk = 0; blk < 4; ++blk) {
            bf16x8 k0 = ldfrag(kbase + blk * 1024);
            bf16x8 k1 = ldfrag(kbase + blk * 1024 + 32);
            f32x4 z = {0.f, 0.f, 0.f, 0.f};
            z = __builtin_amdgcn_mfma_f32_16x16x32_bf16(k0, bQ0, z, 0, 0, 0);
            z = __builtin_amdgcn_mfma_f32_16x16x32_bf16(k1, bQ1, z, 0, 0, 0);
            s[blk] = z;
        }
        // mask invalid keys (rows): key = kb + blk*16 + quad*4 + r
        if (kb + 64 > Lk) {
#pragma unroll
            for (int blk = 0; blk < 4; ++blk)
#pragma unroll
                for (int r = 0; r < 4; ++r)
                    s[blk][r] = (kb + blk * 16 + quad * 4 + r >= Lk) ? -30000.f : s[blk][r];
        }
        // ---- V^T A-frags ----
        bf16x8 vf[3][2];
#pragma unroll
        for (int blk = 0; blk < 3; ++blk) {
            const unsigned short* vb = Vt + (size_t)(h * 48 + blk * 16 + c) * Lkp + kb + quad * 8;
            vf[blk][0] = ldfrag(vb);
            vf[blk][1] = ldfrag(vb + 32);
        }
        // ---- p = exp2(s); pack row-pairs; accumulate l ----
        unsigned pk[4][2];
#pragma unroll
        for (int blk = 0; blk < 4; ++blk) {
            float p0 = exp2f(s[blk][0]);
            float p1 = exp2f(s[blk][1]);
            float p2 = exp2f(s[blk][2]);
            float p3 = exp2f(s[blk][3]);
            lacc += (p0 + p1) + (p2 + p3);
            pk[blk][0] = (unsigned)f2bf(p0) | ((unsigned)f2bf(p1) << 16);
            pk[blk][1] = (unsigned)f2bf(p2) | ((unsigned)f2bf(p3) << 16);
        }
        // ---- C-layout -> B-layout register permutation ----
        // B dword d of mfma m = keys (32m + 8*quad + 2d, +1)
        //   = pk[2m + quad[1]][d&1] pulled from lane (2*quad[0] + d[1])*16 + c
        u32x4 Bw[2];
#pragma unroll
        for (int m = 0; m < 2; ++m) {
            int lo, hi;
            lo = __builtin_amdgcn_ds_bpermute(idx0, (int)pk[2 * m][0]);
            hi = __builtin_amdgcn_ds_bpermute(idx0, (int)pk[2 * m + 1][0]);
            Bw[m][0] = (unsigned)(hiQuad ? hi : lo);
            lo = __builtin_amdgcn_ds_bpermute(idx0, (int)pk[2 * m][1]);
            hi = __builtin_amdgcn_ds_bpermute(idx0, (int)pk[2 * m + 1][1]);
            Bw[m][1] = (unsigned)(hiQuad ? hi : lo);
            lo = __builtin_amdgcn_ds_bpermute(idx1, (int)pk[2 * m][0]);
            hi = __builtin_amdgcn_ds_bpermute(idx1, (int)pk[2 * m + 1][0]);
            Bw[m][2] = (unsigned)(hiQuad ? hi : lo);
            lo = __builtin_amdgcn_ds_bpermute(idx1, (int)pk[2 * m][1]);
            hi = __builtin_amdgcn_ds_bpermute(idx1, (int)pk[2 * m + 1][1]);
            Bw[m][3] = (unsigned)(hiQuad ? hi : lo);
        }
        bf16x8 P0 = __builtin_bit_cast(bf16x8, Bw[0]);
        bf16x8 P1 = __builtin_bit_cast(bf16x8, Bw[1]);
        // ---- O^T += V^T · P^T ----
        oacc0 = __builtin_amdgcn_mfma_f32_16x16x32_bf16(vf[0][0], P0, oacc0, 0, 0, 0);
        oacc0 = __builtin_amdgcn_mfma_f32_16x16x32_bf16(vf[0][1], P1, oacc0, 0, 0, 0);
        oacc1 = __builtin_amdgcn_mfma_f32_16x16x32_bf16(vf[1][0], P0, oacc1, 0, 0, 0);
        oacc1 = __builtin_amdgcn_mfma_f32_16x16x32_bf16(vf[1][1], P1, oacc1, 0, 0, 0);
        oacc2 = __builtin_amdgcn_mfma_f32_16x16x32_bf16(vf[2][0], P0, oacc2, 0, 0, 0);
        oacc2 = __builtin_amdgcn_mfma_f32_16x16x32_bf16(vf[2][1], P1, oacc2, 0, 0, 0);
    }
    // l: sum over quads (keys were distributed across quads)
    lacc += __shfl_xor(lacc, 16, 64);
    lacc += __shfl_xor(lacc, 32, 64);
    // partials: row = q0 + c (query), dims contiguous per lane
    const size_t base = ((size_t)(seg * 8 + h)) << 12;
    float* ob = pO + (base + q0 + c) * 40;
    *(float4*)(ob + quad * 4)      = make_float4(oacc0[0], oacc0[1], oacc0[2], oacc0[3]);
    *(float4*)(ob + 16 + quad * 4) = make_float4(oacc1[0], oacc1[1], oacc1[2], oacc1[3]);
    if (quad < 2)
        *(float4*)(ob + 32 + quad * 4) = make_float4(oacc2[0], oacc2[1], oacc2[2], oacc2[3]);
    if (quad == 0) pL[base + q0 + c] = lacc;
}

// Combine partials across S segments -> bf16 O (HW,320), col = h*40+d.
__global__ __launch_bounds__(256) void attn_combine(
    const float* __restrict__ pO, const float* __restrict__ pL,
    unsigned short* __restrict__ O, int S) {
    int idx = blockIdx.x * 256 + threadIdx.x;  // < 8*4096*40, grid 5120
    int h = idx / (HW * 40);
    int rem = idx - h * (HW * 40);
    int row = rem / 40, d = rem - row * 40;
    float num = 0.f, den = 0.f;
    for (int s = 0; s < S; ++s) {
        size_t base = ((size_t)(s * 8 + h)) << 12;
        num += pO[(base + row) * 40 + d];
        den += pL[base + row];
    }
    O[(size_t)row * CCH + h * DH + d] = f2bf(num / den);
}

// ---------------------------------------------------------------------------
__global__ void final_kernel(const float* __restrict__ Yv,
                             const float* __restrict__ X,
                             float* __restrict__ Out) {
    int idx = blockIdx.x * 256 + threadIdx.x;
    int o = idx >> 12, hw = idx & 4095;
    Out[idx] = Yv[hw * CCH + o] + X[idx];
}

// ---------------------------------------------------------------------------
extern "C" void kernel_launch(void* const* d_in, const int* in_sizes, int n_in,
                              void* d_out, int out_size, void* d_ws, size_t ws_size,
                              hipStream_t stream) {
    const float* x     = (const float*)d_in[0];
    const float* ctx   = (const float*)d_in[1];
    const float* gn_w  = (const float*)d_in[2];
    const float* gn_b  = (const float*)d_in[3];
    const float* w_in  = (const float*)d_in[4];
    const float* b_in  = (const float*)d_in[5];
    const float* ln1_w = (const float*)d_in[6];
    const float* ln1_b = (const float*)d_in[7];
    const float* wq1   = (const float*)d_in[8];
    const float* wk1   = (const float*)d_in[9];
    const float* wv1   = (const float*)d_in[10];
    const float* wo1   = (const float*)d_in[11];
    const float* bo1   = (const float*)d_in[12];
    const float* ln2_w = (const float*)d_in[13];
    const float* ln2_b = (const float*)d_in[14];
    const float* wq2   = (const float*)d_in[15];
    const float* wk2   = (const float*)d_in[16];
    const float* wv2   = (const float*)d_in[17];
    const float* wo2   = (const float*)d_in[18];
    const float* bo2   = (const float*)d_in[19];
    const float* ln3_w = (const float*)d_in[20];
    const float* ln3_b = (const float*)d_in[21];
    const float* wff1  = (const float*)d_in[22];
    const float* bff1  = (const float*)d_in[23];
    const float* wff2  = (const float*)d_in[24];
    const float* bff2  = (const float*)d_in[25];
    const float* w_out = (const float*)d_in[26];
    const float* b_out = (const float*)d_in[27];
    float* out = (float*)d_out;

    const int NT = HW * CCH;  // 1,310,720
    float* ws = (float*)d_ws;
    float* t_   = ws;                 // fp32 residual (HW,C)
    float* y_   = t_ + NT;            // fp32 final proj
    float* pO   = y_ + NT;            // attn partial O: 4*8*4096*40
    float* pL   = pO + 4 * 8 * 4096 * 40;  // 4*8*4096
    float2* gnp = (float2*)(pL + 4 * 8 * 4096);  // 256 float2
    unsigned short* u = (unsigned short*)(gnp + 256);
    unsigned short* a_bf = u;                  u += NT;
    unsigned short* q_bf = u;                  u += NT;
    unsigned short* o_bf = u;                  u += NT;
    unsigned short* t_bf = u;                  u += NT;
    unsigned short* g_bf = u;                  u += HW * FFI;
    unsigned short* Qp   = u;                  u += 8 * 4096 * 64;
    unsigned short* Kp   = u;                  u += 8 * 4096 * 64;
    unsigned short* Vt   = u;                  u += 8 * 48 * 4096;
    unsigned short* Kc   = u;                  u += 8 * 128 * 64;
    unsigned short* Vc   = u;                  u += 8 * 48 * 128;
    unsigned short* Wt   = u;                  u += 2048000;

    const unsigned short* w_inT  = Wt;
    const unsigned short* wq1T   = Wt + 102400;
    const unsigned short* wk1T   = Wt + 204800;
    const unsigned short* wv1T   = Wt + 307200;
    const unsigned short* wo1T   = Wt + 409600;
    const unsigned short* wq2T   = Wt + 512000;
    const unsigned short* wo2T   = Wt + 614400;
    const unsigned short* w_outT = Wt + 716800;
    const unsigned short* wff1T  = Wt + 819200;
    const unsigned short* wff2T  = Wt + 1638400;

    const float qscale = 0.15811388300841897f * 1.4426950408889634f;  // 40^-.5 * log2e

    prep_w<<<8000, 256, 0, stream>>>(w_in, wq1, wk1, wv1, wo1, wq2, wo2, w_out,
                                     wff1, wff2, Wt);
    hipMemsetAsync(Qp, 0,
                   (size_t)(8 * 4096 * 64 * 2 + 8 * 48 * 4096 + 8 * 128 * 64 + 8 * 48 * 128) * 2,
                   stream);

    // 1) GroupNorm -> a_bf (HW,C)
    gn_stats<<<256, 256, 0, stream>>>(x, gnp);
    gn_apply<<<dim3(64, 5), 256, 0, stream>>>(x, gnp, gn_w, gn_b, a_bf);
    // 2) proj_in: t = a @ w_in + b_in (fp32)
    gemm_mfma<2><<<dim3(5, 128), 256, 0, stream>>>(a_bf, w_inT, b_in, nullptr, t_, nullptr, CCH, CCH, 0, 1.f);
    // 3) ln1 -> a_bf
    ln_kernel<<<1024, 256, 0, stream>>>(t_, ln1_w, ln1_b, a_bf);
    // 4) q (dual: row-major + Qp scaled), k -> Kp, v -> Vt
    gemm_mfma<2><<<dim3(5, 128), 256, 0, stream>>>(a_bf, wq1T, nullptr, nullptr, q_bf, Qp, CCH, CCH, 6, qscale);
    gemm_mfma<2><<<dim3(5, 128), 256, 0, stream>>>(q_bf, wk1T, nullptr, nullptr, Kp, nullptr, CCH, CCH, 2, 1.f);
    gemm_mfma<2><<<dim3(5, 128), 256, 0, stream>>>(q_bf, wv1T, nullptr, nullptr, Vt, nullptr, CCH, CCH, 3, 1.f);
    // 5) self-attention: 4 key-segments of 1024, then combine
    attn3<<<dim3(64, NHEADS, 4), 256, 0, stream>>>(Qp, Kp, Vt, pO, pL, HW, HW, 16);
    attn_combine<<<5120, 256, 0, stream>>>(pO, pL, o_bf, 4);
    // 6) t += o @ wo1 + bo1
    gemm_mfma<2><<<dim3(5, 128), 256, 0, stream>>>(o_bf, wo1T, bo1, t_, t_, nullptr, CCH, CCH, 0, 1.f);
    // 7) ln2 -> a_bf
    ln_kernel<<<1024, 256, 0, stream>>>(t_, ln2_w, ln2_b, a_bf);
    // 8) cross q -> Qp; ctx K/V packed directly
    gemm_mfma<2><<<dim3(5, 128), 256, 0, stream>>>(a_bf, wq2T, nullptr, nullptr, Qp, nullptr, CCH, CCH, 2, qscale);
    ctx_kv<<<dim3(5, 2, 2), 256, 0, stream>>>(ctx, wk2, wv2, Kc, Vc);
    // 9) cross-attention (Lk=77, 1 segment of 2 tiles)
    attn3<<<dim3(64, NHEADS, 1), 256, 0, stream>>>(Qp, Kc, Vc, pO, pL, 77, 128, 2);
    attn_combine<<<5120, 256, 0, stream>>>(pO, pL, o_bf, 1);
    // 10) t += o @ wo2 + bo2
    gemm_mfma<2><<<dim3(5, 128), 256, 0, stream>>>(o_bf, wo2T, bo2, t_, t_, nullptr, CCH, CCH, 0, 1.f);
    // 11) ln3 -> a_bf
    ln_kernel<<<1024, 256, 0, stream>>>(t_, ln3_w, ln3_b, a_bf);
    // 12+13) FF1 with fused GEGLU -> g_bf
    gemm_mfma<4><<<dim3(40, 64), 256, 0, stream>>>(a_bf, wff1T, bff1, nullptr, g_bf, nullptr, 2 * FFI, CCH, 5, 1.f);
    // 14) t_bf = bf16(t + g @ wff2 + bff2)
    gemm_mfma<2><<<dim3(5, 128), 256, 0, stream>>>(g_bf, wff2T, bff2, t_, t_bf, nullptr, CCH, FFI, 4, 1.f);
    // 15) y = t_bf @ w_out + b_out (fp32)
    gemm_mfma<2><<<dim3(5, 128), 256, 0, stream>>>(t_bf, w_outT, b_out, nullptr, y_, nullptr, CCH, CCH, 0, 1.f);
    // 16) out = y^T + x
    final_kernel<<<5120, 256, 0, stream>>>(y_, x, out);
}

// Round 6
// 688.538 us; speedup vs baseline: 3.4352x; 1.0006x over previous
//
#include <hip/hip_runtime.h>
#include <hip/hip_bf16.h>
#include <math.h>

#define CCH 320
#define NHEADS 8
#define DH 40
#define HW 4096
#define FFI 1280

typedef __bf16 bf16x8 __attribute__((ext_vector_type(8)));
typedef unsigned short u16x8 __attribute__((ext_vector_type(8)));
typedef float f32x4 __attribute__((ext_vector_type(4)));
typedef unsigned int u32x4 __attribute__((ext_vector_type(4)));

__device__ inline unsigned short f2bf(float f) {
    __hip_bfloat16 h = __float2bfloat16(f);
    return __builtin_bit_cast(unsigned short, h);
}
__device__ inline float bf2f(unsigned short u) {
    return __builtin_bit_cast(float, ((unsigned)u) << 16);
}
__device__ inline bf16x8 ldfrag(const unsigned short* p) {
    u16x8 raw = *reinterpret_cast<const u16x8*>(p);
    return __builtin_bit_cast(bf16x8, raw);
}

// ---------------------------------------------------------------------------
// Weights -> bf16 B^T (N x K). wff1T GLU-interleaved (row n <- col (n>>1)+(n&1)*1280).
__global__ __launch_bounds__(256) void prep_w(
    const float* __restrict__ w_in, const float* __restrict__ wq1,
    const float* __restrict__ wk1, const float* __restrict__ wv1,
    const float* __restrict__ wo1, const float* __restrict__ wq2,
    const float* __restrict__ wo2, const float* __restrict__ w_out,
    const float* __restrict__ wff1, const float* __restrict__ wff2,
    unsigned short* __restrict__ Wt) {
    int idx = blockIdx.x * 256 + threadIdx.x;  // < 2048000 exact
    float v;
    if (idx < 819200) {
        int m = idx / 102400;
        int j = idx - m * 102400;
        int n = j / 320, k = j - n * 320;
        const float* src = (m == 0) ? w_in : (m == 1) ? wq1 : (m == 2) ? wk1 :
                           (m == 3) ? wv1 : (m == 4) ? wo1 : (m == 5) ? wq2 :
                           (m == 6) ? wo2 : w_out;
        v = src[k * 320 + n];
    } else if (idx < 1638400) {
        int j = idx - 819200;
        int n = j / 320, k = j - n * 320;
        int nsrc = (n >> 1) + (n & 1) * FFI;
        v = wff1[k * 2560 + nsrc];
    } else {
        int j = idx - 1638400;
        int n = j / 1280, k = j - n * 1280;
        v = wff2[k * 320 + n];
    }
    Wt[idx] = f2bf(v);
}

// ---------------------------------------------------------------------------
__global__ __launch_bounds__(256) void gn_stats(const float* __restrict__ X,
                                                float2* __restrict__ part) {
    __shared__ float s1[256], s2[256];
    const int b = blockIdx.x, tid = threadIdx.x;
    const float* xg = X + b * 5120;
    float s = 0.f, sq = 0.f;
#pragma unroll
    for (int i = 0; i < 20; ++i) { float v = xg[tid + i * 256]; s += v; sq += v * v; }
    s1[tid] = s; s2[tid] = sq; __syncthreads();
    for (int off = 128; off > 0; off >>= 1) {
        if (tid < off) { s1[tid] += s1[tid + off]; s2[tid] += s2[tid + off]; }
        __syncthreads();
    }
    if (tid == 0) part[b] = make_float2(s1[0], s2[0]);
}

__global__ __launch_bounds__(256) void gn_apply(const float* __restrict__ X,
                                                const float2* __restrict__ part,
                                                const float* __restrict__ w,
                                                const float* __restrict__ b,
                                                unsigned short* __restrict__ Y) {
    __shared__ float tile[64][65];
    __shared__ float gm[32], gr[32];
    const int tid = threadIdx.x;
    const int hw0 = blockIdx.x * 64, c0 = blockIdx.y * 64;
    if (tid < 32) {
        float s = 0.f, sq = 0.f;
#pragma unroll
        for (int i = 0; i < 8; ++i) { float2 p = part[tid * 8 + i]; s += p.x; sq += p.y; }
        float mean = s * (1.f / 40960.f);
        float var  = sq * (1.f / 40960.f) - mean * mean;
        gm[tid] = mean; gr[tid] = rsqrtf(var + 1e-6f);
    }
#pragma unroll
    for (int i = 0; i < 16; ++i) {
        int idx = tid + i * 256;
        int r = idx >> 6, col = idx & 63;
        tile[r][col] = X[(size_t)(c0 + r) * HW + hw0 + col];
    }
    __syncthreads();
#pragma unroll
    for (int i = 0; i < 16; ++i) {
        int idx = tid + i * 256;
        int hwl = idx >> 6, cl = idx & 63;
        int c = c0 + cl, g = c / 10;
        float v = (tile[cl][hwl] - gm[g]) * gr[g] * w[c] + b[c];
        Y[(size_t)(hw0 + hwl) * CCH + c] = f2bf(v);
    }
}

// ---------------------------------------------------------------------------
__global__ __launch_bounds__(256) void ln_kernel(const float* __restrict__ X,
                                                 const float* __restrict__ w,
                                                 const float* __restrict__ b,
                                                 unsigned short* __restrict__ Y) {
    const int row  = blockIdx.x * 4 + (threadIdx.x >> 6);
    const int lane = threadIdx.x & 63;
    const float* xr = X + row * CCH;
    float v[5];
    float s = 0.f, sq = 0.f;
#pragma unroll
    for (int i = 0; i < 5; ++i) { v[i] = xr[lane + 64 * i]; s += v[i]; sq += v[i] * v[i]; }
#pragma unroll
    for (int off = 32; off > 0; off >>= 1) {
        s  += __shfl_xor(s, off, 64);
        sq += __shfl_xor(sq, off, 64);
    }
    const float mean = s * (1.f / 320.f);
    const float var  = sq * (1.f / 320.f) - mean * mean;
    const float rstd = rsqrtf(var + 1e-5f);
    unsigned short* yr = Y + row * CCH;
#pragma unroll
    for (int i = 0; i < 5; ++i) {
        int c = lane + 64 * i;
        yr[c] = f2bf((v[i] - mean) * rstd * w[c] + b[c]);
    }
}

// ---------------------------------------------------------------------------
// bf16 MFMA GEMM, direct-from-global. Wave = 16 cols x (MT*16) rows, BK=64.
template <int MT>
__global__ __launch_bounds__(256) void gemm_mfma(
    const unsigned short* __restrict__ A,
    const unsigned short* __restrict__ Bt,
    const float* __restrict__ bias,
    const float* __restrict__ res,
    void* __restrict__ Cout, void* __restrict__ Cout2,
    int N, int K, int mode, float scale) {
    const int tid  = threadIdx.x;
    const int wave = tid >> 6, lane = tid & 63;
    const int quad = lane >> 4, c = lane & 15;
    const int m0 = blockIdx.y * (MT * 16);
    const int n0 = blockIdx.x * 64 + wave * 16;

    f32x4 acc[MT];
#pragma unroll
    for (int i = 0; i < MT; ++i) acc[i] = (f32x4){0.f, 0.f, 0.f, 0.f};

    const unsigned short* bp = Bt + (size_t)(n0 + c) * K + quad * 8;
    const unsigned short* ap = A + (size_t)(m0 + c) * K + quad * 8;
    for (int k0 = 0; k0 < K; k0 += 64) {
        bf16x8 b0 = ldfrag(bp + k0);
        bf16x8 b1 = ldfrag(bp + k0 + 32);
#pragma unroll
        for (int mt = 0; mt < MT; ++mt) {
            bf16x8 a0 = ldfrag(ap + (size_t)mt * 16 * K + k0);
            bf16x8 a1 = ldfrag(ap + (size_t)mt * 16 * K + k0 + 32);
            acc[mt] = __builtin_amdgcn_mfma_f32_16x16x32_bf16(a0, b0, acc[mt], 0, 0, 0);
            acc[mt] = __builtin_amdgcn_mfma_f32_16x16x32_bf16(a1, b1, acc[mt], 0, 0, 0);
        }
    }

    const int col = n0 + c;
    float bval = 0.f;
    if (bias) bval = (mode == 5) ? bias[(col >> 1) + (col & 1) * FFI] : bias[col];
#pragma unroll
    for (int mt = 0; mt < MT; ++mt) {
#pragma unroll
        for (int r = 0; r < 4; ++r) {
            const int row = m0 + mt * 16 + quad * 4 + r;
            float v = acc[mt][r];
            if (mode == 0) {
                v += bval;
                if (res) v += res[(size_t)row * N + col];
                ((float*)Cout)[(size_t)row * N + col] = v;
            } else if (mode == 1) {
                ((unsigned short*)Cout)[(size_t)row * N + col] = f2bf(v + bval);
            } else if (mode == 2) {
                int h = col & 7, d = col >> 3;
                ((unsigned short*)Cout)[(((size_t)h << 12) + row) * 64 + d] = f2bf(v * scale);
            } else if (mode == 3) {
                int h = col & 7, d = col >> 3;
                ((unsigned short*)Cout)[(((size_t)(h * 48 + d)) << 12) + row] = f2bf(v);
            } else if (mode == 4) {
                ((unsigned short*)Cout)[(size_t)row * N + col] =
                    f2bf(v + bval + res[(size_t)row * N + col]);
            } else if (mode == 5) {
                v += bval;
                float other = __shfl_xor(v, 1, 64);
                if ((c & 1) == 0) {
                    float g = 0.5f * other * (1.f + erff(other * 0.70710678118654752f));
                    ((unsigned short*)Cout)[(size_t)row * FFI + (col >> 1)] = f2bf(v * g);
                }
            } else {  // 6
                ((unsigned short*)Cout)[(size_t)row * N + col] = f2bf(v);
                int h = col & 7, d = col >> 3;
                ((unsigned short*)Cout2)[(((size_t)h << 12) + row) * 64 + d] = f2bf(v * scale);
            }
        }
    }
}

// ---------------------------------------------------------------------------
// Context K/V (77 rows) -> packed Kc [h][128][64], Vc [h*48+d][128].
__global__ __launch_bounds__(256) void ctx_kv(
    const float* __restrict__ ctx, const float* __restrict__ wk2,
    const float* __restrict__ wv2, unsigned short* __restrict__ Kc,
    unsigned short* __restrict__ Vc) {
    __shared__ __align__(16) float As[16][68];
    __shared__ __align__(16) float Bs[16][68];
    const int tid = threadIdx.x;
    const int tx = tid & 15, ty = tid >> 4;
    const int bn = blockIdx.x, bm = blockIdx.y;
    const float* B = (blockIdx.z == 0) ? wk2 : wv2;
    float acc[4][4] = {};
    for (int k0 = 0; k0 < 768; k0 += 16) {
#pragma unroll
        for (int i = 0; i < 4; ++i) {
            int idx = tid + i * 256;
            int r = idx >> 4, cc = idx & 15;
            int gm = bm * 64 + r;
            As[cc][r] = (gm < 77) ? ctx[gm * 768 + k0 + cc] : 0.f;
        }
#pragma unroll
        for (int i = 0; i < 4; ++i) {
            int idx = tid + i * 256;
            int r = idx >> 6, cc = idx & 63;
            Bs[r][cc] = B[(k0 + r) * CCH + bn * 64 + cc];
        }
        __syncthreads();
#pragma unroll
        for (int kk = 0; kk < 16; ++kk) {
            float4 a4 = *(const float4*)&As[kk][ty * 4];
            float4 b4 = *(const float4*)&Bs[kk][tx * 4];
            float av[4] = {a4.x, a4.y, a4.z, a4.w};
            float bv[4] = {b4.x, b4.y, b4.z, b4.w};
#pragma unroll
            for (int i = 0; i < 4; ++i)
#pragma unroll
                for (int j = 0; j < 4; ++j) acc[i][j] += av[i] * bv[j];
        }
        __syncthreads();
    }
#pragma unroll
    for (int i = 0; i < 4; ++i) {
        int row = bm * 64 + ty * 4 + i;
#pragma unroll
        for (int j = 0; j < 4; ++j) {
            int col = bn * 64 + tx * 4 + j;
            int h = col & 7, d = col >> 3;
            float v = (row < 77) ? acc[i][j] : 0.f;
            if (blockIdx.z == 0)
                Kc[(((size_t)h << 7) + row) * 64 + d] = f2bf(v);
            else
                Vc[(size_t)(h * 48 + d) * 128 + row] = f2bf(v);
        }
    }
}

// ---------------------------------------------------------------------------
// LDS-free MFMA flash attention, compile-time-unrolled K-loop (TILES) and
// compile-time masking (MASK) so the scheduler can software-pipeline next-tile
// global loads over the current tile's softmax/permute/PV chain.
// Math identical to round-5 attn3.
template <int TILES, bool MASK>
__global__ __launch_bounds__(256) void attn4(
    const unsigned short* __restrict__ Qp,
    const unsigned short* __restrict__ Kp,
    const unsigned short* __restrict__ Vt,
    float* __restrict__ pO, float* __restrict__ pL,
    int Lk, int Lkp) {
    const int tid  = threadIdx.x;
    const int wave = tid >> 6, lane = tid & 63;
    const int quad = lane >> 4, c = lane & 15;
    const int h   = blockIdx.y;
    const int seg = blockIdx.z;
    const int q0  = blockIdx.x * 64 + wave * 16;

    const unsigned short* qbase = Qp + ((((size_t)h << 12) + q0 + c) << 6) + quad * 8;
    const bf16x8 bQ0 = ldfrag(qbase);
    const bf16x8 bQ1 = ldfrag(qbase + 32);

    f32x4 oacc0 = {0.f, 0.f, 0.f, 0.f}, oacc1 = oacc0, oacc2 = oacc0;
    float lacc = 0.f;
    const int idx0 = ((((quad & 1) * 2 + 0) * 16 + c) << 2);
    const int idx1 = ((((quad & 1) * 2 + 1) * 16 + c) << 2);
    const bool hiQuad = (quad >> 1) != 0;

    const int kt0 = seg * TILES;
    // base pointers: K row (h*Lkp + kt0*64 + c), V row (h*48 + c), col kt0*64
    const unsigned short* kseg = Kp + (((size_t)h * Lkp + kt0 * 64 + c) << 6) + quad * 8;
    const unsigned short* vseg = Vt + (size_t)(h * 48 + c) * Lkp + kt0 * 64 + quad * 8;

#pragma unroll
    for (int t = 0; t < TILES; ++t) {
        const int kb = t * 64;  // within segment
        // ---- S^T = K·Q^T ----
        f32x4 s[4];
#pragma unroll
        for (int blk = 0; blk < 4; ++blk) {
            bf16x8 k0 = ldfrag(kseg + (size_t)(kb + blk * 16) * 64);
            bf16x8 k1 = ldfrag(kseg + (size_t)(kb + blk * 16) * 64 + 32);
            f32x4 z = {0.f, 0.f, 0.f, 0.f};
            z = __builtin_amdgcn_mfma_f32_16x16x32_bf16(k0, bQ0, z, 0, 0, 0);
            z = __builtin_amdgcn_mfma_f32_16x16x32_bf16(k1, bQ1, z, 0, 0, 0);
            s[blk] = z;
        }
        if (MASK) {
            const int abs_kb = (kt0) * 64 + kb;
#pragma unroll
            for (int blk = 0; blk < 4; ++blk)
#pragma unroll
                for (int r = 0; r < 4; ++r)
                    s[blk][r] = (abs_kb + blk * 16 + quad * 4 + r >= Lk) ? -30000.f : s[blk][r];
        }
        // ---- V^T A-frags ----
        bf16x8 vf[3][2];
#pragma unroll
        for (int blk = 0; blk < 3; ++blk) {
            const unsigned short* vb = vseg + (size_t)(blk * 16) * Lkp + kb;
            vf[blk][0] = ldfrag(vb);
            vf[blk][1] = ldfrag(vb + 32);
        }
        // ---- p = exp2(s); pack; accumulate l ----
        unsigned pk[4][2];
#pragma unroll
        for (int blk = 0; blk < 4; ++blk) {
            float p0 = exp2f(s[blk][0]);
            float p1 = exp2f(s[blk][1]);
            float p2 = exp2f(s[blk][2]);
            float p3 = exp2f(s[blk][3]);
            lacc += (p0 + p1) + (p2 + p3);
            pk[blk][0] = (unsigned)f2bf(p0) | ((unsigned)f2bf(p1) << 16);
            pk[blk][1] = (unsigned)f2bf(p2) | ((unsigned)f2bf(p3) << 16);
        }
        // ---- C-layout -> B-layout register permutation ----
        u32x4 Bw[2];
#pragma unroll
        for (int m = 0; m < 2; ++m) {
            int lo, hi;
            lo = __builtin_amdgcn_ds_bpermute(idx0, (int)pk[2 * m][0]);
            hi = __builtin_amdgcn_ds_bpermute(idx0, (int)pk[2 * m + 1][0]);
            Bw[m][0] = (unsigned)(hiQuad ? hi : lo);
            lo = __builtin_amdgcn_ds_bpermute(idx0, (int)pk[2 * m][1]);
            hi = __builtin_amdgcn_ds_bpermute(idx0, (int)pk[2 * m + 1][1]);
            Bw[m][1] = (unsigned)(hiQuad ? hi : lo);
            lo = __builtin_amdgcn_ds_bpermute(idx1, (int)pk[2 * m][0]);
            hi = __builtin_amdgcn_ds_bpermute(idx1, (int)pk[2 * m + 1][0]);
            Bw[m][2] = (unsigned)(hiQuad ? hi : lo);
            lo = __builtin_amdgcn_ds_bpermute(idx1, (int)pk[2 * m][1]);
            hi = __builtin_amdgcn_ds_bpermute(idx1, (int)pk[2 * m + 1][1]);
            Bw[m][3] = (unsigned)(hiQuad ? hi : lo);
        }
        bf16x8 P0 = __builtin_bit_cast(bf16x8, Bw[0]);
        bf16x8 P1 = __builtin_bit_cast(bf16x8, Bw[1]);
        // ---- O^T += V^T · P^T ----
        oacc0 = __builtin_amdgcn_mfma_f32_16x16x32_bf16(vf[0][0], P0, oacc0, 0, 0, 0);
        oacc0 = __builtin_amdgcn_mfma_f32_16x16x32_bf16(vf[0][1], P1, oacc0, 0, 0, 0);
        oacc1 = __builtin_amdgcn_mfma_f32_16x16x32_bf16(vf[1][0], P0, oacc1, 0, 0, 0);
        oacc1 = __builtin_amdgcn_mfma_f32_16x16x32_bf16(vf[1][1], P1, oacc1, 0, 0, 0);
        oacc2 = __builtin_amdgcn_mfma_f32_16x16x32_bf16(vf[2][0], P0, oacc2, 0, 0, 0);
        oacc2 = __builtin_amdgcn_mfma_f32_16x16x32_bf16(vf[2][1], P1, oacc2, 0, 0, 0);
    }
    // l: sum over quads
    lacc += __shfl_xor(lacc, 16, 64);
    lacc += __shfl_xor(lacc, 32, 64);
    const size_t base = ((size_t)(seg * 8 + h)) << 12;
    float* ob = pO + (base + q0 + c) * 40;
    *(float4*)(ob + quad * 4)      = make_float4(oacc0[0], oacc0[1], oacc0[2], oacc0[3]);
    *(float4*)(ob + 16 + quad * 4) = make_float4(oacc1[0], oacc1[1], oacc1[2], oacc1[3]);
    if (quad < 2)
        *(float4*)(ob + 32 + quad * 4) = make_float4(oacc2[0], oacc2[1], oacc2[2], oacc2[3]);
    if (quad == 0) pL[base + q0 + c] = lacc;
}

// Combine partials across S segments -> bf16 O (HW,320), col = h*40+d.
__global__ __launch_bounds__(256) void attn_combine(
    const float* __restrict__ pO, const float* __restrict__ pL,
    unsigned short* __restrict__ O, int S) {
    int idx = blockIdx.x * 256 + threadIdx.x;  // < 8*4096*40, grid 5120
    int h = idx / (HW * 40);
    int rem = idx - h * (HW * 40);
    int row = rem / 40, d = rem - row * 40;
    float num = 0.f, den = 0.f;
    for (int s = 0; s < S; ++s) {
        size_t base = ((size_t)(s * 8 + h)) << 12;
        num += pO[(base + row) * 40 + d];
        den += pL[base + row];
    }
    O[(size_t)row * CCH + h * DH + d] = f2bf(num / den);
}

// ---------------------------------------------------------------------------
__global__ void final_kernel(const float* __restrict__ Yv,
                             const float* __restrict__ X,
                             float* __restrict__ Out) {
    int idx = blockIdx.x * 256 + threadIdx.x;
    int o = idx >> 12, hw = idx & 4095;
    Out[idx] = Yv[hw * CCH + o] + X[idx];
}

// ---------------------------------------------------------------------------
extern "C" void kernel_launch(void* const* d_in, const int* in_sizes, int n_in,
                              void* d_out, int out_size, void* d_ws, size_t ws_size,
                              hipStream_t stream) {
    const float* x     = (const float*)d_in[0];
    const float* ctx   = (const float*)d_in[1];
    const float* gn_w  = (const float*)d_in[2];
    const float* gn_b  = (const float*)d_in[3];
    const float* w_in  = (const float*)d_in[4];
    const float* b_in  = (const float*)d_in[5];
    const float* ln1_w = (const float*)d_in[6];
    const float* ln1_b = (const float*)d_in[7];
    const float* wq1   = (const float*)d_in[8];
    const float* wk1   = (const float*)d_in[9];
    const float* wv1   = (const float*)d_in[10];
    const float* wo1   = (const float*)d_in[11];
    const float* bo1   = (const float*)d_in[12];
    const float* ln2_w = (const float*)d_in[13];
    const float* ln2_b = (const float*)d_in[14];
    const float* wq2   = (const float*)d_in[15];
    const float* wk2   = (const float*)d_in[16];
    const float* wv2   = (const float*)d_in[17];
    const float* wo2   = (const float*)d_in[18];
    const float* bo2   = (const float*)d_in[19];
    const float* ln3_w = (const float*)d_in[20];
    const float* ln3_b = (const float*)d_in[21];
    const float* wff1  = (const float*)d_in[22];
    const float* bff1  = (const float*)d_in[23];
    const float* wff2  = (const float*)d_in[24];
    const float* bff2  = (const float*)d_in[25];
    const float* w_out = (const float*)d_in[26];
    const float* b_out = (const float*)d_in[27];
    float* out = (float*)d_out;

    const int NT = HW * CCH;  // 1,310,720
    float* ws = (float*)d_ws;
    float* t_   = ws;                 // fp32 residual (HW,C)
    float* y_   = t_ + NT;            // fp32 final proj
    float* pO   = y_ + NT;            // attn partial O: 4*8*4096*40
    float* pL   = pO + 4 * 8 * 4096 * 40;  // 4*8*4096
    float2* gnp = (float2*)(pL + 4 * 8 * 4096);  // 256 float2
    unsigned short* u = (unsigned short*)(gnp + 256);
    unsigned short* a_bf = u;                  u += NT;
    unsigned short* q_bf = u;                  u += NT;
    unsigned short* o_bf = u;                  u += NT;
    unsigned short* t_bf = u;                  u += NT;
    unsigned short* g_bf = u;                  u += HW * FFI;
    unsigned short* Qp   = u;                  u += 8 * 4096 * 64;
    unsigned short* Kp   = u;                  u += 8 * 4096 * 64;
    unsigned short* Vt   = u;                  u += 8 * 48 * 4096;
    unsigned short* Kc   = u;                  u += 8 * 128 * 64;
    unsigned short* Vc   = u;                  u += 8 * 48 * 128;
    unsigned short* Wt   = u;                  u += 2048000;

    const unsigned short* w_inT  = Wt;
    const unsigned short* wq1T   = Wt + 102400;
    const unsigned short* wk1T   = Wt + 204800;
    const unsigned short* wv1T   = Wt + 307200;
    const unsigned short* wo1T   = Wt + 409600;
    const unsigned short* wq2T   = Wt + 512000;
    const unsigned short* wo2T   = Wt + 614400;
    const unsigned short* w_outT = Wt + 716800;
    const unsigned short* wff1T  = Wt + 819200;
    const unsigned short* wff2T  = Wt + 1638400;

    const float qscale = 0.15811388300841897f * 1.4426950408889634f;  // 40^-.5 * log2e

    prep_w<<<8000, 256, 0, stream>>>(w_in, wq1, wk1, wv1, wo1, wq2, wo2, w_out,
                                     wff1, wff2, Wt);
    hipMemsetAsync(Qp, 0,
                   (size_t)(8 * 4096 * 64 * 2 + 8 * 48 * 4096 + 8 * 128 * 64 + 8 * 48 * 128) * 2,
                   stream);

    // 1) GroupNorm -> a_bf (HW,C)
    gn_stats<<<256, 256, 0, stream>>>(x, gnp);
    gn_apply<<<dim3(64, 5), 256, 0, stream>>>(x, gnp, gn_w, gn_b, a_bf);
    // 2) proj_in: t = a @ w_in + b_in (fp32)
    gemm_mfma<2><<<dim3(5, 128), 256, 0, stream>>>(a_bf, w_inT, b_in, nullptr, t_, nullptr, CCH, CCH, 0, 1.f);
    // 3) ln1 -> a_bf
    ln_kernel<<<1024, 256, 0, stream>>>(t_, ln1_w, ln1_b, a_bf);
    // 4) q (dual: row-major + Qp scaled), k -> Kp, v -> Vt
    gemm_mfma<2><<<dim3(5, 128), 256, 0, stream>>>(a_bf, wq1T, nullptr, nullptr, q_bf, Qp, CCH, CCH, 6, qscale);
    gemm_mfma<2><<<dim3(5, 128), 256, 0, stream>>>(q_bf, wk1T, nullptr, nullptr, Kp, nullptr, CCH, CCH, 2, 1.f);
    gemm_mfma<2><<<dim3(5, 128), 256, 0, stream>>>(q_bf, wv1T, nullptr, nullptr, Vt, nullptr, CCH, CCH, 3, 1.f);
    // 5) self-attention: 4 key-segments of 1024 (16 tiles, fully unrolled)
    attn4<16, false><<<dim3(64, NHEADS, 4), 256, 0, stream>>>(Qp, Kp, Vt, pO, pL, HW, HW);
    attn_combine<<<5120, 256, 0, stream>>>(pO, pL, o_bf, 4);
    // 6) t += o @ wo1 + bo1
    gemm_mfma<2><<<dim3(5, 128), 256, 0, stream>>>(o_bf, wo1T, bo1, t_, t_, nullptr, CCH, CCH, 0, 1.f);
    // 7) ln2 -> a_bf
    ln_kernel<<<1024, 256, 0, stream>>>(t_, ln2_w, ln2_b, a_bf);
    // 8) cross q -> Qp; ctx K/V packed directly
    gemm_mfma<2><<<dim3(5, 128), 256, 0, stream>>>(a_bf, wq2T, nullptr, nullptr, Qp, nullptr, CCH, CCH, 2, qscale);
    ctx_kv<<<dim3(5, 2, 2), 256, 0, stream>>>(ctx, wk2, wv2, Kc, Vc);
    // 9) cross-attention (Lk=77, 1 segment of 2 tiles, masked)
    attn4<2, true><<<dim3(64, NHEADS, 1), 256, 0, stream>>>(Qp, Kc, Vc, pO, pL, 77, 128);
    attn_combine<<<5120, 256, 0, stream>>>(pO, pL, o_bf, 1);
    // 10) t += o @ wo2 + bo2
    gemm_mfma<2><<<dim3(5, 128), 256, 0, stream>>>(o_bf, wo2T, bo2, t_, t_, nullptr, CCH, CCH, 0, 1.f);
    // 11) ln3 -> a_bf
    ln_kernel<<<1024, 256, 0, stream>>>(t_, ln3_w, ln3_b, a_bf);
    // 12+13) FF1 with fused GEGLU -> g_bf
    gemm_mfma<4><<<dim3(40, 64), 256, 0, stream>>>(a_bf, wff1T, bff1, nullptr, g_bf, nullptr, 2 * FFI, CCH, 5, 1.f);
    // 14) t_bf = bf16(t + g @ wff2 + bff2)
    gemm_mfma<2><<<dim3(5, 128), 256, 0, stream>>>(g_bf, wff2T, bff2, t_, t_bf, nullptr, CCH, FFI, 4, 1.f);
    // 15) y = t_bf @ w_out + b_out (fp32)
    gemm_mfma<2><<<dim3(5, 128), 256, 0, stream>>>(t_bf, w_outT, b_out, nullptr, y_, nullptr, CCH, CCH, 0, 1.f);
    // 16) out = y^T + x
    final_kernel<<<5120, 256, 0, stream>>>(y_, x, out);
}

// Round 7
// 680.887 us; speedup vs baseline: 3.4738x; 1.0112x over previous
//
#include <hip/hip_runtime.h>
#include <hip/hip_bf16.h>
#include <math.h>

#define CCH 320
#define NHEADS 8
#define DH 40
#define HW 4096
#define FFI 1280

typedef __bf16 bf16x8 __attribute__((ext_vector_type(8)));
typedef unsigned short u16x8 __attribute__((ext_vector_type(8)));
typedef float f32x4 __attribute__((ext_vector_type(4)));
typedef unsigned int u32x4 __attribute__((ext_vector_type(4)));

__device__ inline unsigned short f2bf(float f) {
    __hip_bfloat16 h = __float2bfloat16(f);
    return __builtin_bit_cast(unsigned short, h);
}
__device__ inline float bf2f(unsigned short u) {
    return __builtin_bit_cast(float, ((unsigned)u) << 16);
}
__device__ inline bf16x8 ldfrag(const unsigned short* p) {
    u16x8 raw = *reinterpret_cast<const u16x8*>(p);
    return __builtin_bit_cast(bf16x8, raw);
}

// ---------------------------------------------------------------------------
// Weights -> bf16 B^T (N x K). wff1T GLU-interleaved (row n <- col (n>>1)+(n&1)*1280).
__global__ __launch_bounds__(256) void prep_w(
    const float* __restrict__ w_in, const float* __restrict__ wq1,
    const float* __restrict__ wk1, const float* __restrict__ wv1,
    const float* __restrict__ wo1, const float* __restrict__ wq2,
    const float* __restrict__ wo2, const float* __restrict__ w_out,
    const float* __restrict__ wff1, const float* __restrict__ wff2,
    unsigned short* __restrict__ Wt) {
    int idx = blockIdx.x * 256 + threadIdx.x;  // < 2048000 exact
    float v;
    if (idx < 819200) {
        int m = idx / 102400;
        int j = idx - m * 102400;
        int n = j / 320, k = j - n * 320;
        const float* src = (m == 0) ? w_in : (m == 1) ? wq1 : (m == 2) ? wk1 :
                           (m == 3) ? wv1 : (m == 4) ? wo1 : (m == 5) ? wq2 :
                           (m == 6) ? wo2 : w_out;
        v = src[k * 320 + n];
    } else if (idx < 1638400) {
        int j = idx - 819200;
        int n = j / 320, k = j - n * 320;
        int nsrc = (n >> 1) + (n & 1) * FFI;
        v = wff1[k * 2560 + nsrc];
    } else {
        int j = idx - 1638400;
        int n = j / 1280, k = j - n * 1280;
        v = wff2[k * 320 + n];
    }
    Wt[idx] = f2bf(v);
}

// ---------------------------------------------------------------------------
__global__ __launch_bounds__(256) void gn_stats(const float* __restrict__ X,
                                                float2* __restrict__ part) {
    __shared__ float s1[256], s2[256];
    const int b = blockIdx.x, tid = threadIdx.x;
    const float* xg = X + b * 5120;
    float s = 0.f, sq = 0.f;
#pragma unroll
    for (int i = 0; i < 20; ++i) { float v = xg[tid + i * 256]; s += v; sq += v * v; }
    s1[tid] = s; s2[tid] = sq; __syncthreads();
    for (int off = 128; off > 0; off >>= 1) {
        if (tid < off) { s1[tid] += s1[tid + off]; s2[tid] += s2[tid + off]; }
        __syncthreads();
    }
    if (tid == 0) part[b] = make_float2(s1[0], s2[0]);
}

__global__ __launch_bounds__(256) void gn_apply(const float* __restrict__ X,
                                                const float2* __restrict__ part,
                                                const float* __restrict__ w,
                                                const float* __restrict__ b,
                                                unsigned short* __restrict__ Y) {
    __shared__ float tile[64][65];
    __shared__ float gm[32], gr[32];
    const int tid = threadIdx.x;
    const int hw0 = blockIdx.x * 64, c0 = blockIdx.y * 64;
    if (tid < 32) {
        float s = 0.f, sq = 0.f;
#pragma unroll
        for (int i = 0; i < 8; ++i) { float2 p = part[tid * 8 + i]; s += p.x; sq += p.y; }
        float mean = s * (1.f / 40960.f);
        float var  = sq * (1.f / 40960.f) - mean * mean;
        gm[tid] = mean; gr[tid] = rsqrtf(var + 1e-6f);
    }
#pragma unroll
    for (int i = 0; i < 16; ++i) {
        int idx = tid + i * 256;
        int r = idx >> 6, col = idx & 63;
        tile[r][col] = X[(size_t)(c0 + r) * HW + hw0 + col];
    }
    __syncthreads();
#pragma unroll
    for (int i = 0; i < 16; ++i) {
        int idx = tid + i * 256;
        int hwl = idx >> 6, cl = idx & 63;
        int c = c0 + cl, g = c / 10;
        float v = (tile[cl][hwl] - gm[g]) * gr[g] * w[c] + b[c];
        Y[(size_t)(hw0 + hwl) * CCH + c] = f2bf(v);
    }
}

// ---------------------------------------------------------------------------
__global__ __launch_bounds__(256) void ln_kernel(const float* __restrict__ X,
                                                 const float* __restrict__ w,
                                                 const float* __restrict__ b,
                                                 unsigned short* __restrict__ Y) {
    const int row  = blockIdx.x * 4 + (threadIdx.x >> 6);
    const int lane = threadIdx.x & 63;
    const float* xr = X + row * CCH;
    float v[5];
    float s = 0.f, sq = 0.f;
#pragma unroll
    for (int i = 0; i < 5; ++i) { v[i] = xr[lane + 64 * i]; s += v[i]; sq += v[i] * v[i]; }
#pragma unroll
    for (int off = 32; off > 0; off >>= 1) {
        s  += __shfl_xor(s, off, 64);
        sq += __shfl_xor(sq, off, 64);
    }
    const float mean = s * (1.f / 320.f);
    const float var  = sq * (1.f / 320.f) - mean * mean;
    const float rstd = rsqrtf(var + 1e-5f);
    unsigned short* yr = Y + row * CCH;
#pragma unroll
    for (int i = 0; i < 5; ++i) {
        int c = lane + 64 * i;
        yr[c] = f2bf((v[i] - mean) * rstd * w[c] + b[c]);
    }
}

// ---------------------------------------------------------------------------
// bf16 MFMA GEMM, direct-from-global, compile-time K, software-pipelined
// (next BK=64 slab's loads issued before current slab's MFMAs consume theirs).
template <int MT, int K>
__global__ __launch_bounds__(256) void gemm_mfma(
    const unsigned short* __restrict__ A,
    const unsigned short* __restrict__ Bt,
    const float* __restrict__ bias,
    const float* __restrict__ res,
    void* __restrict__ Cout, void* __restrict__ Cout2,
    int N, int mode, float scale) {
    const int tid  = threadIdx.x;
    const int wave = tid >> 6, lane = tid & 63;
    const int quad = lane >> 4, c = lane & 15;
    const int m0 = blockIdx.y * (MT * 16);
    const int n0 = blockIdx.x * 64 + wave * 16;

    f32x4 acc[MT];
#pragma unroll
    for (int i = 0; i < MT; ++i) acc[i] = (f32x4){0.f, 0.f, 0.f, 0.f};

    const unsigned short* bp = Bt + (size_t)(n0 + c) * K + quad * 8;
    const unsigned short* ap = A + (size_t)(m0 + c) * K + quad * 8;

    constexpr int NK = K / 64;
    bf16x8 b0 = ldfrag(bp), b1 = ldfrag(bp + 32);
    bf16x8 a0[MT], a1[MT];
#pragma unroll
    for (int mt = 0; mt < MT; ++mt) {
        a0[mt] = ldfrag(ap + (size_t)mt * 16 * K);
        a1[mt] = ldfrag(ap + (size_t)mt * 16 * K + 32);
    }
#pragma unroll
    for (int kk = 0; kk < NK; ++kk) {
        bf16x8 nb0, nb1, na0[MT], na1[MT];
        if (kk + 1 < NK) {
            const int k0 = (kk + 1) * 64;
            nb0 = ldfrag(bp + k0);
            nb1 = ldfrag(bp + k0 + 32);
#pragma unroll
            for (int mt = 0; mt < MT; ++mt) {
                na0[mt] = ldfrag(ap + (size_t)mt * 16 * K + k0);
                na1[mt] = ldfrag(ap + (size_t)mt * 16 * K + k0 + 32);
            }
        }
#pragma unroll
        for (int mt = 0; mt < MT; ++mt) {
            acc[mt] = __builtin_amdgcn_mfma_f32_16x16x32_bf16(a0[mt], b0, acc[mt], 0, 0, 0);
            acc[mt] = __builtin_amdgcn_mfma_f32_16x16x32_bf16(a1[mt], b1, acc[mt], 0, 0, 0);
        }
        if (kk + 1 < NK) {
            b0 = nb0; b1 = nb1;
#pragma unroll
            for (int mt = 0; mt < MT; ++mt) { a0[mt] = na0[mt]; a1[mt] = na1[mt]; }
        }
    }

    const int col = n0 + c;
    float bval = 0.f;
    if (bias) bval = (mode == 5) ? bias[(col >> 1) + (col & 1) * FFI] : bias[col];
#pragma unroll
    for (int mt = 0; mt < MT; ++mt) {
#pragma unroll
        for (int r = 0; r < 4; ++r) {
            const int row = m0 + mt * 16 + quad * 4 + r;
            float v = acc[mt][r];
            if (mode == 0) {
                v += bval;
                if (res) v += res[(size_t)row * N + col];
                ((float*)Cout)[(size_t)row * N + col] = v;
            } else if (mode == 1) {
                ((unsigned short*)Cout)[(size_t)row * N + col] = f2bf(v + bval);
            } else if (mode == 2) {
                int h = col & 7, d = col >> 3;
                ((unsigned short*)Cout)[(((size_t)h << 12) + row) * 64 + d] = f2bf(v * scale);
            } else if (mode == 3) {
                int h = col & 7, d = col >> 3;
                ((unsigned short*)Cout)[(((size_t)(h * 48 + d)) << 12) + row] = f2bf(v);
            } else if (mode == 4) {
                ((unsigned short*)Cout)[(size_t)row * N + col] =
                    f2bf(v + bval + res[(size_t)row * N + col]);
            } else if (mode == 5) {
                v += bval;
                float other = __shfl_xor(v, 1, 64);
                if ((c & 1) == 0) {
                    float g = 0.5f * other * (1.f + erff(other * 0.70710678118654752f));
                    ((unsigned short*)Cout)[(size_t)row * FFI + (col >> 1)] = f2bf(v * g);
                }
            } else {  // 6
                ((unsigned short*)Cout)[(size_t)row * N + col] = f2bf(v);
                int h = col & 7, d = col >> 3;
                ((unsigned short*)Cout2)[(((size_t)h << 12) + row) * 64 + d] = f2bf(v * scale);
            }
        }
    }
}

// ---------------------------------------------------------------------------
// Context K/V (77 rows) -> packed Kc [h][128][64], Vc [h*48+d][128].
__global__ __launch_bounds__(256) void ctx_kv(
    const float* __restrict__ ctx, const float* __restrict__ wk2,
    const float* __restrict__ wv2, unsigned short* __restrict__ Kc,
    unsigned short* __restrict__ Vc) {
    __shared__ __align__(16) float As[16][68];
    __shared__ __align__(16) float Bs[16][68];
    const int tid = threadIdx.x;
    const int tx = tid & 15, ty = tid >> 4;
    const int bn = blockIdx.x, bm = blockIdx.y;
    const float* B = (blockIdx.z == 0) ? wk2 : wv2;
    float acc[4][4] = {};
    for (int k0 = 0; k0 < 768; k0 += 16) {
#pragma unroll
        for (int i = 0; i < 4; ++i) {
            int idx = tid + i * 256;
            int r = idx >> 4, cc = idx & 15;
            int gm = bm * 64 + r;
            As[cc][r] = (gm < 77) ? ctx[gm * 768 + k0 + cc] : 0.f;
        }
#pragma unroll
        for (int i = 0; i < 4; ++i) {
            int idx = tid + i * 256;
            int r = idx >> 6, cc = idx & 63;
            Bs[r][cc] = B[(k0 + r) * CCH + bn * 64 + cc];
        }
        __syncthreads();
#pragma unroll
        for (int kk = 0; kk < 16; ++kk) {
            float4 a4 = *(const float4*)&As[kk][ty * 4];
            float4 b4 = *(const float4*)&Bs[kk][tx * 4];
            float av[4] = {a4.x, a4.y, a4.z, a4.w};
            float bv[4] = {b4.x, b4.y, b4.z, b4.w};
#pragma unroll
            for (int i = 0; i < 4; ++i)
#pragma unroll
                for (int j = 0; j < 4; ++j) acc[i][j] += av[i] * bv[j];
        }
        __syncthreads();
    }
#pragma unroll
    for (int i = 0; i < 4; ++i) {
        int row = bm * 64 + ty * 4 + i;
#pragma unroll
        for (int j = 0; j < 4; ++j) {
            int col = bn * 64 + tx * 4 + j;
            int h = col & 7, d = col >> 3;
            float v = (row < 77) ? acc[i][j] : 0.f;
            if (blockIdx.z == 0)
                Kc[(((size_t)h << 7) + row) * 64 + d] = f2bf(v);
            else
                Vc[(size_t)(h * 48 + d) * 128 + row] = f2bf(v);
        }
    }
}

// ---------------------------------------------------------------------------
// LDS-free MFMA flash attention with explicit one-tile register lookahead:
// next tile's 14 global loads are issued before current tile's compute
// consumes its fragments, so waits become partial vmcnt(N), not full drains.
template <int TILES, bool MASK>
__global__ __launch_bounds__(256) void attn5(
    const unsigned short* __restrict__ Qp,
    const unsigned short* __restrict__ Kp,
    const unsigned short* __restrict__ Vt,
    float* __restrict__ pO, float* __restrict__ pL,
    int Lk, int Lkp) {
    const int tid  = threadIdx.x;
    const int wave = tid >> 6, lane = tid & 63;
    const int quad = lane >> 4, c = lane & 15;
    const int h   = blockIdx.y;
    const int seg = blockIdx.z;
    const int q0  = blockIdx.x * 64 + wave * 16;

    const unsigned short* qbase = Qp + ((((size_t)h << 12) + q0 + c) << 6) + quad * 8;
    const bf16x8 bQ0 = ldfrag(qbase);
    const bf16x8 bQ1 = ldfrag(qbase + 32);

    f32x4 oacc0 = {0.f, 0.f, 0.f, 0.f}, oacc1 = oacc0, oacc2 = oacc0;
    float lacc = 0.f;
    const int idx0 = ((((quad & 1) * 2 + 0) * 16 + c) << 2);
    const int idx1 = ((((quad & 1) * 2 + 1) * 16 + c) << 2);
    const bool hiQuad = (quad >> 1) != 0;

    const int kt0 = seg * TILES;
    const unsigned short* kseg = Kp + (((size_t)h * Lkp + kt0 * 64 + c) << 6) + quad * 8;
    const unsigned short* vseg = Vt + (size_t)(h * 48 + c) * Lkp + kt0 * 64 + quad * 8;

    // prologue: tile 0 fragments
    bf16x8 kf[4][2], vf[3][2];
#pragma unroll
    for (int blk = 0; blk < 4; ++blk) {
        kf[blk][0] = ldfrag(kseg + (size_t)(blk * 16) * 64);
        kf[blk][1] = ldfrag(kseg + (size_t)(blk * 16) * 64 + 32);
    }
#pragma unroll
    for (int blk = 0; blk < 3; ++blk) {
        vf[blk][0] = ldfrag(vseg + (size_t)(blk * 16) * Lkp);
        vf[blk][1] = ldfrag(vseg + (size_t)(blk * 16) * Lkp + 32);
    }

#pragma unroll
    for (int t = 0; t < TILES; ++t) {
        // ---- prefetch tile t+1 (in flight during this tile's compute) ----
        bf16x8 nk[4][2], nv[3][2];
        if (t + 1 < TILES) {
            const int kb = (t + 1) * 64;
#pragma unroll
            for (int blk = 0; blk < 4; ++blk) {
                nk[blk][0] = ldfrag(kseg + (size_t)(kb + blk * 16) * 64);
                nk[blk][1] = ldfrag(kseg + (size_t)(kb + blk * 16) * 64 + 32);
            }
#pragma unroll
            for (int blk = 0; blk < 3; ++blk) {
                nv[blk][0] = ldfrag(vseg + (size_t)(blk * 16) * Lkp + kb);
                nv[blk][1] = ldfrag(vseg + (size_t)(blk * 16) * Lkp + kb + 32);
            }
        }
        // ---- S^T = K·Q^T ----
        f32x4 s[4];
#pragma unroll
        for (int blk = 0; blk < 4; ++blk) {
            f32x4 z = {0.f, 0.f, 0.f, 0.f};
            z = __builtin_amdgcn_mfma_f32_16x16x32_bf16(kf[blk][0], bQ0, z, 0, 0, 0);
            z = __builtin_amdgcn_mfma_f32_16x16x32_bf16(kf[blk][1], bQ1, z, 0, 0, 0);
            s[blk] = z;
        }
        if (MASK) {
            const int abs_kb = kt0 * 64 + t * 64;
#pragma unroll
            for (int blk = 0; blk < 4; ++blk)
#pragma unroll
                for (int r = 0; r < 4; ++r)
                    s[blk][r] = (abs_kb + blk * 16 + quad * 4 + r >= Lk) ? -30000.f : s[blk][r];
        }
        // ---- p = exp2(s); pack; accumulate l ----
        unsigned pk[4][2];
#pragma unroll
        for (int blk = 0; blk < 4; ++blk) {
            float p0 = exp2f(s[blk][0]);
            float p1 = exp2f(s[blk][1]);
            float p2 = exp2f(s[blk][2]);
            float p3 = exp2f(s[blk][3]);
            lacc += (p0 + p1) + (p2 + p3);
            pk[blk][0] = (unsigned)f2bf(p0) | ((unsigned)f2bf(p1) << 16);
            pk[blk][1] = (unsigned)f2bf(p2) | ((unsigned)f2bf(p3) << 16);
        }
        // ---- C-layout -> B-layout register permutation ----
        u32x4 Bw[2];
#pragma unroll
        for (int m = 0; m < 2; ++m) {
            int lo, hi;
            lo = __builtin_amdgcn_ds_bpermute(idx0, (int)pk[2 * m][0]);
            hi = __builtin_amdgcn_ds_bpermute(idx0, (int)pk[2 * m + 1][0]);
            Bw[m][0] = (unsigned)(hiQuad ? hi : lo);
            lo = __builtin_amdgcn_ds_bpermute(idx0, (int)pk[2 * m][1]);
            hi = __builtin_amdgcn_ds_bpermute(idx0, (int)pk[2 * m + 1][1]);
            Bw[m][1] = (unsigned)(hiQuad ? hi : lo);
            lo = __builtin_amdgcn_ds_bpermute(idx1, (int)pk[2 * m][0]);
            hi = __builtin_amdgcn_ds_bpermute(idx1, (int)pk[2 * m + 1][0]);
            Bw[m][2] = (unsigned)(hiQuad ? hi : lo);
            lo = __builtin_amdgcn_ds_bpermute(idx1, (int)pk[2 * m][1]);
            hi = __builtin_amdgcn_ds_bpermute(idx1, (int)pk[2 * m + 1][1]);
            Bw[m][3] = (unsigned)(hiQuad ? hi : lo);
        }
        bf16x8 P0 = __builtin_bit_cast(bf16x8, Bw[0]);
        bf16x8 P1 = __builtin_bit_cast(bf16x8, Bw[1]);
        // ---- O^T += V^T · P^T ----
        oacc0 = __builtin_amdgcn_mfma_f32_16x16x32_bf16(vf[0][0], P0, oacc0, 0, 0, 0);
        oacc0 = __builtin_amdgcn_mfma_f32_16x16x32_bf16(vf[0][1], P1, oacc0, 0, 0, 0);
        oacc1 = __builtin_amdgcn_mfma_f32_16x16x32_bf16(vf[1][0], P0, oacc1, 0, 0, 0);
        oacc1 = __builtin_amdgcn_mfma_f32_16x16x32_bf16(vf[1][1], P1, oacc1, 0, 0, 0);
        oacc2 = __builtin_amdgcn_mfma_f32_16x16x32_bf16(vf[2][0], P0, oacc2, 0, 0, 0);
        oacc2 = __builtin_amdgcn_mfma_f32_16x16x32_bf16(vf[2][1], P1, oacc2, 0, 0, 0);
        // ---- rotate ----
        if (t + 1 < TILES) {
#pragma unroll
            for (int blk = 0; blk < 4; ++blk) { kf[blk][0] = nk[blk][0]; kf[blk][1] = nk[blk][1]; }
#pragma unroll
            for (int blk = 0; blk < 3; ++blk) { vf[blk][0] = nv[blk][0]; vf[blk][1] = nv[blk][1]; }
        }
    }
    // l: sum over quads
    lacc += __shfl_xor(lacc, 16, 64);
    lacc += __shfl_xor(lacc, 32, 64);
    const size_t base = ((size_t)(seg * 8 + h)) << 12;
    float* ob = pO + (base + q0 + c) * 40;
    *(float4*)(ob + quad * 4)      = make_float4(oacc0[0], oacc0[1], oacc0[2], oacc0[3]);
    *(float4*)(ob + 16 + quad * 4) = make_float4(oacc1[0], oacc1[1], oacc1[2], oacc1[3]);
    if (quad < 2)
        *(float4*)(ob + 32 + quad * 4) = make_float4(oacc2[0], oacc2[1], oacc2[2], oacc2[3]);
    if (quad == 0) pL[base + q0 + c] = lacc;
}

// Combine partials across S segments -> bf16 O (HW,320), col = h*40+d.
__global__ __launch_bounds__(256) void attn_combine(
    const float* __restrict__ pO, const float* __restrict__ pL,
    unsigned short* __restrict__ O, int S) {
    int idx = blockIdx.x * 256 + threadIdx.x;  // < 8*4096*40, grid 5120
    int h = idx / (HW * 40);
    int rem = idx - h * (HW * 40);
    int row = rem / 40, d = rem - row * 40;
    float num = 0.f, den = 0.f;
    for (int s = 0; s < S; ++s) {
        size_t base = ((size_t)(s * 8 + h)) << 12;
        num += pO[(base + row) * 40 + d];
        den += pL[base + row];
    }
    O[(size_t)row * CCH + h * DH + d] = f2bf(num / den);
}

// ---------------------------------------------------------------------------
__global__ void final_kernel(const float* __restrict__ Yv,
                             const float* __restrict__ X,
                             float* __restrict__ Out) {
    int idx = blockIdx.x * 256 + threadIdx.x;
    int o = idx >> 12, hw = idx & 4095;
    Out[idx] = Yv[hw * CCH + o] + X[idx];
}

// ---------------------------------------------------------------------------
extern "C" void kernel_launch(void* const* d_in, const int* in_sizes, int n_in,
                              void* d_out, int out_size, void* d_ws, size_t ws_size,
                              hipStream_t stream) {
    const float* x     = (const float*)d_in[0];
    const float* ctx   = (const float*)d_in[1];
    const float* gn_w  = (const float*)d_in[2];
    const float* gn_b  = (const float*)d_in[3];
    const float* w_in  = (const float*)d_in[4];
    const float* b_in  = (const float*)d_in[5];
    const float* ln1_w = (const float*)d_in[6];
    const float* ln1_b = (const float*)d_in[7];
    const float* wq1   = (const float*)d_in[8];
    const float* wk1   = (const float*)d_in[9];
    const float* wv1   = (const float*)d_in[10];
    const float* wo1   = (const float*)d_in[11];
    const float* bo1   = (const float*)d_in[12];
    const float* ln2_w = (const float*)d_in[13];
    const float* ln2_b = (const float*)d_in[14];
    const float* wq2   = (const float*)d_in[15];
    const float* wk2   = (const float*)d_in[16];
    const float* wv2   = (const float*)d_in[17];
    const float* wo2   = (const float*)d_in[18];
    const float* bo2   = (const float*)d_in[19];
    const float* ln3_w = (const float*)d_in[20];
    const float* ln3_b = (const float*)d_in[21];
    const float* wff1  = (const float*)d_in[22];
    const float* bff1  = (const float*)d_in[23];
    const float* wff2  = (const float*)d_in[24];
    const float* bff2  = (const float*)d_in[25];
    const float* w_out = (const float*)d_in[26];
    const float* b_out = (const float*)d_in[27];
    float* out = (float*)d_out;

    const int NT = HW * CCH;  // 1,310,720
    float* ws = (float*)d_ws;
    float* t_   = ws;                 // fp32 residual (HW,C)
    float* y_   = t_ + NT;            // fp32 final proj
    float* pO   = y_ + NT;            // attn partial O: 4*8*4096*40
    float* pL   = pO + 4 * 8 * 4096 * 40;  // 4*8*4096
    float2* gnp = (float2*)(pL + 4 * 8 * 4096);  // 256 float2
    unsigned short* u = (unsigned short*)(gnp + 256);
    unsigned short* a_bf = u;                  u += NT;
    unsigned short* q_bf = u;                  u += NT;
    unsigned short* o_bf = u;                  u += NT;
    unsigned short* t_bf = u;                  u += NT;
    unsigned short* g_bf = u;                  u += HW * FFI;
    unsigned short* Qp   = u;                  u += 8 * 4096 * 64;
    unsigned short* Kp   = u;                  u += 8 * 4096 * 64;
    unsigned short* Vt   = u;                  u += 8 * 48 * 4096;
    unsigned short* Kc   = u;                  u += 8 * 128 * 64;
    unsigned short* Vc   = u;                  u += 8 * 48 * 128;
    unsigned short* Wt   = u;                  u += 2048000;

    const unsigned short* w_inT  = Wt;
    const unsigned short* wq1T   = Wt + 102400;
    const unsigned short* wk1T   = Wt + 204800;
    const unsigned short* wv1T   = Wt + 307200;
    const unsigned short* wo1T   = Wt + 409600;
    const unsigned short* wq2T   = Wt + 512000;
    const unsigned short* wo2T   = Wt + 614400;
    const unsigned short* w_outT = Wt + 716800;
    const unsigned short* wff1T  = Wt + 819200;
    const unsigned short* wff2T  = Wt + 1638400;

    const float qscale = 0.15811388300841897f * 1.4426950408889634f;  // 40^-.5 * log2e

    prep_w<<<8000, 256, 0, stream>>>(w_in, wq1, wk1, wv1, wo1, wq2, wo2, w_out,
                                     wff1, wff2, Wt);
    hipMemsetAsync(Qp, 0,
                   (size_t)(8 * 4096 * 64 * 2 + 8 * 48 * 4096 + 8 * 128 * 64 + 8 * 48 * 128) * 2,
                   stream);

    // 1) GroupNorm -> a_bf (HW,C)
    gn_stats<<<256, 256, 0, stream>>>(x, gnp);
    gn_apply<<<dim3(64, 5), 256, 0, stream>>>(x, gnp, gn_w, gn_b, a_bf);
    // 2) proj_in: t = a @ w_in + b_in (fp32)
    gemm_mfma<2, 320><<<dim3(5, 128), 256, 0, stream>>>(a_bf, w_inT, b_in, nullptr, t_, nullptr, CCH, 0, 1.f);
    // 3) ln1 -> a_bf
    ln_kernel<<<1024, 256, 0, stream>>>(t_, ln1_w, ln1_b, a_bf);
    // 4) q (dual: row-major + Qp scaled), k -> Kp, v -> Vt
    gemm_mfma<2, 320><<<dim3(5, 128), 256, 0, stream>>>(a_bf, wq1T, nullptr, nullptr, q_bf, Qp, CCH, 6, qscale);
    gemm_mfma<2, 320><<<dim3(5, 128), 256, 0, stream>>>(q_bf, wk1T, nullptr, nullptr, Kp, nullptr, CCH, 2, 1.f);
    gemm_mfma<2, 320><<<dim3(5, 128), 256, 0, stream>>>(q_bf, wv1T, nullptr, nullptr, Vt, nullptr, CCH, 3, 1.f);
    // 5) self-attention: 4 key-segments of 1024, register-pipelined
    attn5<16, false><<<dim3(64, NHEADS, 4), 256, 0, stream>>>(Qp, Kp, Vt, pO, pL, HW, HW);
    attn_combine<<<5120, 256, 0, stream>>>(pO, pL, o_bf, 4);
    // 6) t += o @ wo1 + bo1
    gemm_mfma<2, 320><<<dim3(5, 128), 256, 0, stream>>>(o_bf, wo1T, bo1, t_, t_, nullptr, CCH, 0, 1.f);
    // 7) ln2 -> a_bf
    ln_kernel<<<1024, 256, 0, stream>>>(t_, ln2_w, ln2_b, a_bf);
    // 8) cross q -> Qp; ctx K/V packed directly
    gemm_mfma<2, 320><<<dim3(5, 128), 256, 0, stream>>>(a_bf, wq2T, nullptr, nullptr, Qp, nullptr, CCH, 2, qscale);
    ctx_kv<<<dim3(5, 2, 2), 256, 0, stream>>>(ctx, wk2, wv2, Kc, Vc);
    // 9) cross-attention (Lk=77, 1 segment of 2 tiles, masked)
    attn5<2, true><<<dim3(64, NHEADS, 1), 256, 0, stream>>>(Qp, Kc, Vc, pO, pL, 77, 128);
    attn_combine<<<5120, 256, 0, stream>>>(pO, pL, o_bf, 1);
    // 10) t += o @ wo2 + bo2
    gemm_mfma<2, 320><<<dim3(5, 128), 256, 0, stream>>>(o_bf, wo2T, bo2, t_, t_, nullptr, CCH, 0, 1.f);
    // 11) ln3 -> a_bf
    ln_kernel<<<1024, 256, 0, stream>>>(t_, ln3_w, ln3_b, a_bf);
    // 12+13) FF1 with fused GEGLU -> g_bf
    gemm_mfma<4, 320><<<dim3(40, 64), 256, 0, stream>>>(a_bf, wff1T, bff1, nullptr, g_bf, nullptr, 2 * FFI, 5, 1.f);
    // 14) t_bf = bf16(t + g @ wff2 + bff2)
    gemm_mfma<2, 1280><<<dim3(5, 128), 256, 0, stream>>>(g_bf, wff2T, bff2, t_, t_bf, nullptr, CCH, 4, 1.f);
    // 15) y = t_bf @ w_out + b_out (fp32)
    gemm_mfma<2, 320><<<dim3(5, 128), 256, 0, stream>>>(t_bf, w_outT, b_out, nullptr, y_, nullptr, CCH, 0, 1.f);
    // 16) out = y^T + x
    final_kernel<<<5120, 256, 0, stream>>>(y_, x, out);
}

// Round 8
// 629.397 us; speedup vs baseline: 3.7580x; 1.0818x over previous
//
#include <hip/hip_runtime.h>
#include <hip/hip_bf16.h>
#include <math.h>

#define CCH 320
#define NHEADS 8
#define DH 40
#define HW 4096
#define FFI 1280

typedef __bf16 bf16x8 __attribute__((ext_vector_type(8)));
typedef unsigned short u16x8 __attribute__((ext_vector_type(8)));
typedef float f32x4 __attribute__((ext_vector_type(4)));
typedef unsigned int u32x4 __attribute__((ext_vector_type(4)));

__device__ inline unsigned short f2bf(float f) {
    __hip_bfloat16 h = __float2bfloat16(f);
    return __builtin_bit_cast(unsigned short, h);
}
__device__ inline float bf2f(unsigned short u) {
    return __builtin_bit_cast(float, ((unsigned)u) << 16);
}
__device__ inline bf16x8 ldfrag(const unsigned short* p) {
    u16x8 raw = *reinterpret_cast<const u16x8*>(p);
    return __builtin_bit_cast(bf16x8, raw);
}

// ---------------------------------------------------------------------------
// Weights -> bf16 B^T (N x K). wff1T GLU-interleaved (row n <- col (n>>1)+(n&1)*1280).
__global__ __launch_bounds__(256) void prep_w(
    const float* __restrict__ w_in, const float* __restrict__ wq1,
    const float* __restrict__ wk1, const float* __restrict__ wv1,
    const float* __restrict__ wo1, const float* __restrict__ wq2,
    const float* __restrict__ wo2, const float* __restrict__ w_out,
    const float* __restrict__ wff1, const float* __restrict__ wff2,
    unsigned short* __restrict__ Wt) {
    int idx = blockIdx.x * 256 + threadIdx.x;  // < 2048000 exact
    float v;
    if (idx < 819200) {
        int m = idx / 102400;
        int j = idx - m * 102400;
        int n = j / 320, k = j - n * 320;
        const float* src = (m == 0) ? w_in : (m == 1) ? wq1 : (m == 2) ? wk1 :
                           (m == 3) ? wv1 : (m == 4) ? wo1 : (m == 5) ? wq2 :
                           (m == 6) ? wo2 : w_out;
        v = src[k * 320 + n];
    } else if (idx < 1638400) {
        int j = idx - 819200;
        int n = j / 320, k = j - n * 320;
        int nsrc = (n >> 1) + (n & 1) * FFI;
        v = wff1[k * 2560 + nsrc];
    } else {
        int j = idx - 1638400;
        int n = j / 1280, k = j - n * 1280;
        v = wff2[k * 320 + n];
    }
    Wt[idx] = f2bf(v);
}

// ---------------------------------------------------------------------------
__global__ __launch_bounds__(256) void gn_stats(const float* __restrict__ X,
                                                float2* __restrict__ part) {
    __shared__ float s1[256], s2[256];
    const int b = blockIdx.x, tid = threadIdx.x;
    const float* xg = X + b * 5120;
    float s = 0.f, sq = 0.f;
#pragma unroll
    for (int i = 0; i < 20; ++i) { float v = xg[tid + i * 256]; s += v; sq += v * v; }
    s1[tid] = s; s2[tid] = sq; __syncthreads();
    for (int off = 128; off > 0; off >>= 1) {
        if (tid < off) { s1[tid] += s1[tid + off]; s2[tid] += s2[tid + off]; }
        __syncthreads();
    }
    if (tid == 0) part[b] = make_float2(s1[0], s2[0]);
}

__global__ __launch_bounds__(256) void gn_apply(const float* __restrict__ X,
                                                const float2* __restrict__ part,
                                                const float* __restrict__ w,
                                                const float* __restrict__ b,
                                                unsigned short* __restrict__ Y) {
    __shared__ float tile[64][65];
    __shared__ float gm[32], gr[32];
    const int tid = threadIdx.x;
    const int hw0 = blockIdx.x * 64, c0 = blockIdx.y * 64;
    if (tid < 32) {
        float s = 0.f, sq = 0.f;
#pragma unroll
        for (int i = 0; i < 8; ++i) { float2 p = part[tid * 8 + i]; s += p.x; sq += p.y; }
        float mean = s * (1.f / 40960.f);
        float var  = sq * (1.f / 40960.f) - mean * mean;
        gm[tid] = mean; gr[tid] = rsqrtf(var + 1e-6f);
    }
#pragma unroll
    for (int i = 0; i < 16; ++i) {
        int idx = tid + i * 256;
        int r = idx >> 6, col = idx & 63;
        tile[r][col] = X[(size_t)(c0 + r) * HW + hw0 + col];
    }
    __syncthreads();
#pragma unroll
    for (int i = 0; i < 16; ++i) {
        int idx = tid + i * 256;
        int hwl = idx >> 6, cl = idx & 63;
        int c = c0 + cl, g = c / 10;
        float v = (tile[cl][hwl] - gm[g]) * gr[g] * w[c] + b[c];
        Y[(size_t)(hw0 + hwl) * CCH + c] = f2bf(v);
    }
}

// ---------------------------------------------------------------------------
__global__ __launch_bounds__(256) void ln_kernel(const float* __restrict__ X,
                                                 const float* __restrict__ w,
                                                 const float* __restrict__ b,
                                                 unsigned short* __restrict__ Y) {
    const int row  = blockIdx.x * 4 + (threadIdx.x >> 6);
    const int lane = threadIdx.x & 63;
    const float* xr = X + row * CCH;
    float v[5];
    float s = 0.f, sq = 0.f;
#pragma unroll
    for (int i = 0; i < 5; ++i) { v[i] = xr[lane + 64 * i]; s += v[i]; sq += v[i] * v[i]; }
#pragma unroll
    for (int off = 32; off > 0; off >>= 1) {
        s  += __shfl_xor(s, off, 64);
        sq += __shfl_xor(sq, off, 64);
    }
    const float mean = s * (1.f / 320.f);
    const float var  = sq * (1.f / 320.f) - mean * mean;
    const float rstd = rsqrtf(var + 1e-5f);
    unsigned short* yr = Y + row * CCH;
#pragma unroll
    for (int i = 0; i < 5; ++i) {
        int c = lane + 64 * i;
        yr[c] = f2bf((v[i] - mean) * rstd * w[c] + b[c]);
    }
}

// ---------------------------------------------------------------------------
// bf16 MFMA GEMM, direct-from-global, compile-time K (as round 7).
template <int MT, int K>
__global__ __launch_bounds__(256) void gemm_mfma(
    const unsigned short* __restrict__ A,
    const unsigned short* __restrict__ Bt,
    const float* __restrict__ bias,
    const float* __restrict__ res,
    void* __restrict__ Cout, void* __restrict__ Cout2,
    int N, int mode, float scale) {
    const int tid  = threadIdx.x;
    const int wave = tid >> 6, lane = tid & 63;
    const int quad = lane >> 4, c = lane & 15;
    const int m0 = blockIdx.y * (MT * 16);
    const int n0 = blockIdx.x * 64 + wave * 16;

    f32x4 acc[MT];
#pragma unroll
    for (int i = 0; i < MT; ++i) acc[i] = (f32x4){0.f, 0.f, 0.f, 0.f};

    const unsigned short* bp = Bt + (size_t)(n0 + c) * K + quad * 8;
    const unsigned short* ap = A + (size_t)(m0 + c) * K + quad * 8;

    constexpr int NK = K / 64;
    bf16x8 b0 = ldfrag(bp), b1 = ldfrag(bp + 32);
    bf16x8 a0[MT], a1[MT];
#pragma unroll
    for (int mt = 0; mt < MT; ++mt) {
        a0[mt] = ldfrag(ap + (size_t)mt * 16 * K);
        a1[mt] = ldfrag(ap + (size_t)mt * 16 * K + 32);
    }
#pragma unroll
    for (int kk = 0; kk < NK; ++kk) {
        bf16x8 nb0, nb1, na0[MT], na1[MT];
        if (kk + 1 < NK) {
            const int k0 = (kk + 1) * 64;
            nb0 = ldfrag(bp + k0);
            nb1 = ldfrag(bp + k0 + 32);
#pragma unroll
            for (int mt = 0; mt < MT; ++mt) {
                na0[mt] = ldfrag(ap + (size_t)mt * 16 * K + k0);
                na1[mt] = ldfrag(ap + (size_t)mt * 16 * K + k0 + 32);
            }
        }
#pragma unroll
        for (int mt = 0; mt < MT; ++mt) {
            acc[mt] = __builtin_amdgcn_mfma_f32_16x16x32_bf16(a0[mt], b0, acc[mt], 0, 0, 0);
            acc[mt] = __builtin_amdgcn_mfma_f32_16x16x32_bf16(a1[mt], b1, acc[mt], 0, 0, 0);
        }
        if (kk + 1 < NK) {
            b0 = nb0; b1 = nb1;
#pragma unroll
            for (int mt = 0; mt < MT; ++mt) { a0[mt] = na0[mt]; a1[mt] = na1[mt]; }
        }
    }

    const int col = n0 + c;
    float bval = 0.f;
    if (bias) bval = (mode == 5) ? bias[(col >> 1) + (col & 1) * FFI] : bias[col];
#pragma unroll
    for (int mt = 0; mt < MT; ++mt) {
#pragma unroll
        for (int r = 0; r < 4; ++r) {
            const int row = m0 + mt * 16 + quad * 4 + r;
            float v = acc[mt][r];
            if (mode == 0) {
                v += bval;
                if (res) v += res[(size_t)row * N + col];
                ((float*)Cout)[(size_t)row * N + col] = v;
            } else if (mode == 1) {
                ((unsigned short*)Cout)[(size_t)row * N + col] = f2bf(v + bval);
            } else if (mode == 2) {
                int h = col & 7, d = col >> 3;
                ((unsigned short*)Cout)[(((size_t)h << 12) + row) * 64 + d] = f2bf(v * scale);
            } else if (mode == 3) {
                int h = col & 7, d = col >> 3;
                ((unsigned short*)Cout)[(((size_t)(h * 48 + d)) << 12) + row] = f2bf(v);
            } else if (mode == 4) {
                ((unsigned short*)Cout)[(size_t)row * N + col] =
                    f2bf(v + bval + res[(size_t)row * N + col]);
            } else if (mode == 5) {
                v += bval;
                float other = __shfl_xor(v, 1, 64);
                if ((c & 1) == 0) {
                    float g = 0.5f * other * (1.f + erff(other * 0.70710678118654752f));
                    ((unsigned short*)Cout)[(size_t)row * FFI + (col >> 1)] = f2bf(v * g);
                }
            } else {  // 6
                ((unsigned short*)Cout)[(size_t)row * N + col] = f2bf(v);
                int h = col & 7, d = col >> 3;
                ((unsigned short*)Cout2)[(((size_t)h << 12) + row) * 64 + d] = f2bf(v * scale);
            }
        }
    }
}

// ---------------------------------------------------------------------------
// Context K/V (77 rows) -> packed Kc [h][128][64], Vc [h*48+d][128].
__global__ __launch_bounds__(256) void ctx_kv(
    const float* __restrict__ ctx, const float* __restrict__ wk2,
    const float* __restrict__ wv2, unsigned short* __restrict__ Kc,
    unsigned short* __restrict__ Vc) {
    __shared__ __align__(16) float As[16][68];
    __shared__ __align__(16) float Bs[16][68];
    const int tid = threadIdx.x;
    const int tx = tid & 15, ty = tid >> 4;
    const int bn = blockIdx.x, bm = blockIdx.y;
    const float* B = (blockIdx.z == 0) ? wk2 : wv2;
    float acc[4][4] = {};
    for (int k0 = 0; k0 < 768; k0 += 16) {
#pragma unroll
        for (int i = 0; i < 4; ++i) {
            int idx = tid + i * 256;
            int r = idx >> 4, cc = idx & 15;
            int gm = bm * 64 + r;
            As[cc][r] = (gm < 77) ? ctx[gm * 768 + k0 + cc] : 0.f;
        }
#pragma unroll
        for (int i = 0; i < 4; ++i) {
            int idx = tid + i * 256;
            int r = idx >> 6, cc = idx & 63;
            Bs[r][cc] = B[(k0 + r) * CCH + bn * 64 + cc];
        }
        __syncthreads();
#pragma unroll
        for (int kk = 0; kk < 16; ++kk) {
            float4 a4 = *(const float4*)&As[kk][ty * 4];
            float4 b4 = *(const float4*)&Bs[kk][tx * 4];
            float av[4] = {a4.x, a4.y, a4.z, a4.w};
            float bv[4] = {b4.x, b4.y, b4.z, b4.w};
#pragma unroll
            for (int i = 0; i < 4; ++i)
#pragma unroll
                for (int j = 0; j < 4; ++j) acc[i][j] += av[i] * bv[j];
        }
        __syncthreads();
    }
#pragma unroll
    for (int i = 0; i < 4; ++i) {
        int row = bm * 64 + ty * 4 + i;
#pragma unroll
        for (int j = 0; j < 4; ++j) {
            int col = bn * 64 + tx * 4 + j;
            int h = col & 7, d = col >> 3;
            float v = (row < 77) ? acc[i][j] : 0.f;
            if (blockIdx.z == 0)
                Kc[(((size_t)h << 7) + row) * 64 + d] = f2bf(v);
            else
                Vc[(size_t)(h * 48 + d) * 128 + row] = f2bf(v);
        }
    }
}

// ---------------------------------------------------------------------------
// LDS-staged MFMA flash attention (m97-style double buffer).
// Block = 64 queries x 1 head x 1 segment; the 4 waves SHARE K/V tiles via
// LDS (4x fewer global loads). Per tile: [issue global loads for t+1] ->
// [compute t from LDS] -> [ds_write t+1] -> barrier. The ds_write+barrier
// pins the loads a full tile early - the compiler cannot sink them.
// 16B groups XOR-swizzled by (row&7) on write AND read: 2 lanes/bank (free).
// Math identical to attn5 (S^T via K*Q^T, exp2 static-max, bpermute, V^T*P^T).
template <int TILES, bool MASK>
__global__ __launch_bounds__(256) void attn6(
    const unsigned short* __restrict__ Qp,
    const unsigned short* __restrict__ Kp,
    const unsigned short* __restrict__ Vt,
    float* __restrict__ pO, float* __restrict__ pL,
    int Lk, int Lkp) {
    __shared__ __align__(16) unsigned short Kb[2][64 * 64];  // [key][dim-groups swizzled]
    __shared__ __align__(16) unsigned short Vb[2][48 * 64];  // [dim][key-groups swizzled]
    const int tid  = threadIdx.x;
    const int wave = tid >> 6, lane = tid & 63;
    const int quad = lane >> 4, c = lane & 15;
    const int h   = blockIdx.y;
    const int seg = blockIdx.z;
    const int q0  = blockIdx.x * 64 + wave * 16;

    // Q as B-operand, direct from global (one-time)
    const unsigned short* qbase = Qp + ((((size_t)h << 12) + q0 + c) << 6) + quad * 8;
    const bf16x8 bQ0 = ldfrag(qbase);
    const bf16x8 bQ1 = ldfrag(qbase + 32);

    f32x4 oacc0 = {0.f, 0.f, 0.f, 0.f}, oacc1 = oacc0, oacc2 = oacc0;
    float lacc = 0.f;
    const int idx0 = ((((quad & 1) * 2 + 0) * 16 + c) << 2);
    const int idx1 = ((((quad & 1) * 2 + 1) * 16 + c) << 2);
    const bool hiQuad = (quad >> 1) != 0;

    const int kt0 = seg * TILES;
    const unsigned short* kglob = Kp + (((size_t)h * Lkp + kt0 * 64) << 6);
    const unsigned short* vglob = Vt + ((size_t)h * 48) * Lkp + kt0 * 64;

    // staging: 14 slabs of 8 rows x 128B; slabs 0..7 = K keys, 8..13 = V dims.
    // wave w handles slabs w, w+4, w+8, w+12(<14).
    const int r0 = lane >> 3;   // row within slab
    const int g  = lane & 7;    // 16B group
    // swizzled LDS element offsets (constant per lane per slab)
    int ldsoff[4];
    const unsigned short* gptr0[4];
#pragma unroll
    for (int i = 0; i < 4; ++i) {
        int s = wave + 4 * i;
        if (s < 8) {
            int row = s * 8 + r0;
            ldsoff[i] = row * 64 + (g ^ (row & 7)) * 8;           // into Kb
            gptr0[i]  = kglob + (size_t)row * 64 + g * 8;
        } else if (s < 14) {
            int d = (s - 8) * 8 + r0;
            ldsoff[i] = d * 64 + (g ^ (d & 7)) * 8;               // into Vb
            gptr0[i]  = vglob + (size_t)d * Lkp + g * 8;
        } else {
            ldsoff[i] = 0; gptr0[i] = nullptr;
        }
    }
    const bool isK[4] = {(wave + 0) < 8, (wave + 4) < 8, (wave + 8) < 8, (wave + 12) < 8};
    const bool act[4] = {true, true, true, (wave + 12) < 14};

    // prologue: stage tile 0 into buffer 0
    {
        u16x8 st[4];
#pragma unroll
        for (int i = 0; i < 4; ++i)
            if (act[i]) st[i] = *(const u16x8*)(gptr0[i]);
#pragma unroll
        for (int i = 0; i < 4; ++i)
            if (act[i]) {
                unsigned short* lp = isK[i] ? &Kb[0][ldsoff[i]] : &Vb[0][ldsoff[i]];
                *(u16x8*)lp = st[i];
            }
    }
    __syncthreads();

#pragma unroll
    for (int t = 0; t < TILES; ++t) {
        const int b = t & 1;
        // ---- issue global loads for tile t+1 (K stride 64 elem/key row,
        //      V stride = 64 keys within row) ----
        u16x8 st[4];
        if (t + 1 < TILES) {
            const int kb = (t + 1) * 64;
#pragma unroll
            for (int i = 0; i < 4; ++i)
                if (act[i]) {
                    const unsigned short* gp =
                        isK[i] ? (gptr0[i] + (size_t)kb * 64) : (gptr0[i] + kb);
                    st[i] = *(const u16x8*)gp;
                }
        }
        // ---- compute tile t from LDS[b] ----
        const unsigned short* Kl = &Kb[b][0];
        const unsigned short* Vl = &Vb[b][0];
        const int sw0 = (quad ^ (c & 7)) * 8;        // frag0 group offset
        const int sw1 = ((quad + 4) ^ (c & 7)) * 8;  // frag1 group offset
        f32x4 s[4];
#pragma unroll
        for (int blk = 0; blk < 4; ++blk) {
            const int row = (blk * 16 + c) * 64;
            bf16x8 k0 = ldfrag(Kl + row + sw0);
            bf16x8 k1 = ldfrag(Kl + row + sw1);
            f32x4 z = {0.f, 0.f, 0.f, 0.f};
            z = __builtin_amdgcn_mfma_f32_16x16x32_bf16(k0, bQ0, z, 0, 0, 0);
            z = __builtin_amdgcn_mfma_f32_16x16x32_bf16(k1, bQ1, z, 0, 0, 0);
            s[blk] = z;
        }
        if (MASK) {
            const int abs_kb = kt0 * 64 + t * 64;
#pragma unroll
            for (int blk = 0; blk < 4; ++blk)
#pragma unroll
                for (int r = 0; r < 4; ++r)
                    s[blk][r] = (abs_kb + blk * 16 + quad * 4 + r >= Lk) ? -30000.f : s[blk][r];
        }
        bf16x8 vf[3][2];
#pragma unroll
        for (int blk = 0; blk < 3; ++blk) {
            const int row = (blk * 16 + c) * 64;
            vf[blk][0] = ldfrag(Vl + row + sw0);
            vf[blk][1] = ldfrag(Vl + row + sw1);
        }
        unsigned pk[4][2];
#pragma unroll
        for (int blk = 0; blk < 4; ++blk) {
            float p0 = exp2f(s[blk][0]);
            float p1 = exp2f(s[blk][1]);
            float p2 = exp2f(s[blk][2]);
            float p3 = exp2f(s[blk][3]);
            lacc += (p0 + p1) + (p2 + p3);
            pk[blk][0] = (unsigned)f2bf(p0) | ((unsigned)f2bf(p1) << 16);
            pk[blk][1] = (unsigned)f2bf(p2) | ((unsigned)f2bf(p3) << 16);
        }
        u32x4 Bw[2];
#pragma unroll
        for (int m = 0; m < 2; ++m) {
            int lo, hi;
            lo = __builtin_amdgcn_ds_bpermute(idx0, (int)pk[2 * m][0]);
            hi = __builtin_amdgcn_ds_bpermute(idx0, (int)pk[2 * m + 1][0]);
            Bw[m][0] = (unsigned)(hiQuad ? hi : lo);
            lo = __builtin_amdgcn_ds_bpermute(idx0, (int)pk[2 * m][1]);
            hi = __builtin_amdgcn_ds_bpermute(idx0, (int)pk[2 * m + 1][1]);
            Bw[m][1] = (unsigned)(hiQuad ? hi : lo);
            lo = __builtin_amdgcn_ds_bpermute(idx1, (int)pk[2 * m][0]);
            hi = __builtin_amdgcn_ds_bpermute(idx1, (int)pk[2 * m + 1][0]);
            Bw[m][2] = (unsigned)(hiQuad ? hi : lo);
            lo = __builtin_amdgcn_ds_bpermute(idx1, (int)pk[2 * m][1]);
            hi = __builtin_amdgcn_ds_bpermute(idx1, (int)pk[2 * m + 1][1]);
            Bw[m][3] = (unsigned)(hiQuad ? hi : lo);
        }
        bf16x8 P0 = __builtin_bit_cast(bf16x8, Bw[0]);
        bf16x8 P1 = __builtin_bit_cast(bf16x8, Bw[1]);
        oacc0 = __builtin_amdgcn_mfma_f32_16x16x32_bf16(vf[0][0], P0, oacc0, 0, 0, 0);
        oacc0 = __builtin_amdgcn_mfma_f32_16x16x32_bf16(vf[0][1], P1, oacc0, 0, 0, 0);
        oacc1 = __builtin_amdgcn_mfma_f32_16x16x32_bf16(vf[1][0], P0, oacc1, 0, 0, 0);
        oacc1 = __builtin_amdgcn_mfma_f32_16x16x32_bf16(vf[1][1], P1, oacc1, 0, 0, 0);
        oacc2 = __builtin_amdgcn_mfma_f32_16x16x32_bf16(vf[2][0], P0, oacc2, 0, 0, 0);
        oacc2 = __builtin_amdgcn_mfma_f32_16x16x32_bf16(vf[2][1], P1, oacc2, 0, 0, 0);
        // ---- commit staged tile t+1 to the other buffer, then barrier ----
        if (t + 1 < TILES) {
            const int nb = b ^ 1;
#pragma unroll
            for (int i = 0; i < 4; ++i)
                if (act[i]) {
                    unsigned short* lp = isK[i] ? &Kb[nb][ldsoff[i]] : &Vb[nb][ldsoff[i]];
                    *(u16x8*)lp = st[i];
                }
        }
        __syncthreads();
    }
    // l: sum over quads
    lacc += __shfl_xor(lacc, 16, 64);
    lacc += __shfl_xor(lacc, 32, 64);
    const size_t base = ((size_t)(seg * 8 + h)) << 12;
    float* ob = pO + (base + q0 + c) * 40;
    *(float4*)(ob + quad * 4)      = make_float4(oacc0[0], oacc0[1], oacc0[2], oacc0[3]);
    *(float4*)(ob + 16 + quad * 4) = make_float4(oacc1[0], oacc1[1], oacc1[2], oacc1[3]);
    if (quad < 2)
        *(float4*)(ob + 32 + quad * 4) = make_float4(oacc2[0], oacc2[1], oacc2[2], oacc2[3]);
    if (quad == 0) pL[base + q0 + c] = lacc;
}

// Combine partials across S segments -> bf16 O (HW,320), col = h*40+d.
__global__ __launch_bounds__(256) void attn_combine(
    const float* __restrict__ pO, const float* __restrict__ pL,
    unsigned short* __restrict__ O, int S) {
    int idx = blockIdx.x * 256 + threadIdx.x;  // < 8*4096*40, grid 5120
    int h = idx / (HW * 40);
    int rem = idx - h * (HW * 40);
    int row = rem / 40, d = rem - row * 40;
    float num = 0.f, den = 0.f;
    for (int s = 0; s < S; ++s) {
        size_t base = ((size_t)(s * 8 + h)) << 12;
        num += pO[(base + row) * 40 + d];
        den += pL[base + row];
    }
    O[(size_t)row * CCH + h * DH + d] = f2bf(num / den);
}

// ---------------------------------------------------------------------------
__global__ void final_kernel(const float* __restrict__ Yv,
                             const float* __restrict__ X,
                             float* __restrict__ Out) {
    int idx = blockIdx.x * 256 + threadIdx.x;
    int o = idx >> 12, hw = idx & 4095;
    Out[idx] = Yv[hw * CCH + o] + X[idx];
}

// ---------------------------------------------------------------------------
extern "C" void kernel_launch(void* const* d_in, const int* in_sizes, int n_in,
                              void* d_out, int out_size, void* d_ws, size_t ws_size,
                              hipStream_t stream) {
    const float* x     = (const float*)d_in[0];
    const float* ctx   = (const float*)d_in[1];
    const float* gn_w  = (const float*)d_in[2];
    const float* gn_b  = (const float*)d_in[3];
    const float* w_in  = (const float*)d_in[4];
    const float* b_in  = (const float*)d_in[5];
    const float* ln1_w = (const float*)d_in[6];
    const float* ln1_b = (const float*)d_in[7];
    const float* wq1   = (const float*)d_in[8];
    const float* wk1   = (const float*)d_in[9];
    const float* wv1   = (const float*)d_in[10];
    const float* wo1   = (const float*)d_in[11];
    const float* bo1   = (const float*)d_in[12];
    const float* ln2_w = (const float*)d_in[13];
    const float* ln2_b = (const float*)d_in[14];
    const float* wq2   = (const float*)d_in[15];
    const float* wk2   = (const float*)d_in[16];
    const float* wv2   = (const float*)d_in[17];
    const float* wo2   = (const float*)d_in[18];
    const float* bo2   = (const float*)d_in[19];
    const float* ln3_w = (const float*)d_in[20];
    const float* ln3_b = (const float*)d_in[21];
    const float* wff1  = (const float*)d_in[22];
    const float* bff1  = (const float*)d_in[23];
    const float* wff2  = (const float*)d_in[24];
    const float* bff2  = (const float*)d_in[25];
    const float* w_out = (const float*)d_in[26];
    const float* b_out = (const float*)d_in[27];
    float* out = (float*)d_out;

    const int NT = HW * CCH;  // 1,310,720
    float* ws = (float*)d_ws;
    float* t_   = ws;                 // fp32 residual (HW,C)
    float* y_   = t_ + NT;            // fp32 final proj
    float* pO   = y_ + NT;            // attn partial O: 4*8*4096*40
    float* pL   = pO + 4 * 8 * 4096 * 40;  // 4*8*4096
    float2* gnp = (float2*)(pL + 4 * 8 * 4096);  // 256 float2
    unsigned short* u = (unsigned short*)(gnp + 256);
    unsigned short* a_bf = u;                  u += NT;
    unsigned short* q_bf = u;                  u += NT;
    unsigned short* o_bf = u;                  u += NT;
    unsigned short* t_bf = u;                  u += NT;
    unsigned short* g_bf = u;                  u += HW * FFI;
    unsigned short* Qp   = u;                  u += 8 * 4096 * 64;
    unsigned short* Kp   = u;                  u += 8 * 4096 * 64;
    unsigned short* Vt   = u;                  u += 8 * 48 * 4096;
    unsigned short* Kc   = u;                  u += 8 * 128 * 64;
    unsigned short* Vc   = u;                  u += 8 * 48 * 128;
    unsigned short* Wt   = u;                  u += 2048000;

    const unsigned short* w_inT  = Wt;
    const unsigned short* wq1T   = Wt + 102400;
    const unsigned short* wk1T   = Wt + 204800;
    const unsigned short* wv1T   = Wt + 307200;
    const unsigned short* wo1T   = Wt + 409600;
    const unsigned short* wq2T   = Wt + 512000;
    const unsigned short* wo2T   = Wt + 614400;
    const unsigned short* w_outT = Wt + 716800;
    const unsigned short* wff1T  = Wt + 819200;
    const unsigned short* wff2T  = Wt + 1638400;

    const float qscale = 0.15811388300841897f * 1.4426950408889634f;  // 40^-.5 * log2e

    prep_w<<<8000, 256, 0, stream>>>(w_in, wq1, wk1, wv1, wo1, wq2, wo2, w_out,
                                     wff1, wff2, Wt);
    hipMemsetAsync(Qp, 0,
                   (size_t)(8 * 4096 * 64 * 2 + 8 * 48 * 4096 + 8 * 128 * 64 + 8 * 48 * 128) * 2,
                   stream);

    // 1) GroupNorm -> a_bf (HW,C)
    gn_stats<<<256, 256, 0, stream>>>(x, gnp);
    gn_apply<<<dim3(64, 5), 256, 0, stream>>>(x, gnp, gn_w, gn_b, a_bf);
    // 2) proj_in: t = a @ w_in + b_in (fp32)
    gemm_mfma<2, 320><<<dim3(5, 128), 256, 0, stream>>>(a_bf, w_inT, b_in, nullptr, t_, nullptr, CCH, 0, 1.f);
    // 3) ln1 -> a_bf
    ln_kernel<<<1024, 256, 0, stream>>>(t_, ln1_w, ln1_b, a_bf);
    // 4) q (dual: row-major + Qp scaled), k -> Kp, v -> Vt
    gemm_mfma<2, 320><<<dim3(5, 128), 256, 0, stream>>>(a_bf, wq1T, nullptr, nullptr, q_bf, Qp, CCH, 6, qscale);
    gemm_mfma<2, 320><<<dim3(5, 128), 256, 0, stream>>>(q_bf, wk1T, nullptr, nullptr, Kp, nullptr, CCH, 2, 1.f);
    gemm_mfma<2, 320><<<dim3(5, 128), 256, 0, stream>>>(q_bf, wv1T, nullptr, nullptr, Vt, nullptr, CCH, 3, 1.f);
    // 5) self-attention: 4 key-segments of 1024, LDS-staged double buffer
    attn6<16, false><<<dim3(64, NHEADS, 4), 256, 0, stream>>>(Qp, Kp, Vt, pO, pL, HW, HW);
    attn_combine<<<5120, 256, 0, stream>>>(pO, pL, o_bf, 4);
    // 6) t += o @ wo1 + bo1
    gemm_mfma<2, 320><<<dim3(5, 128), 256, 0, stream>>>(o_bf, wo1T, bo1, t_, t_, nullptr, CCH, 0, 1.f);
    // 7) ln2 -> a_bf
    ln_kernel<<<1024, 256, 0, stream>>>(t_, ln2_w, ln2_b, a_bf);
    // 8) cross q -> Qp; ctx K/V packed directly
    gemm_mfma<2, 320><<<dim3(5, 128), 256, 0, stream>>>(a_bf, wq2T, nullptr, nullptr, Qp, nullptr, CCH, 2, qscale);
    ctx_kv<<<dim3(5, 2, 2), 256, 0, stream>>>(ctx, wk2, wv2, Kc, Vc);
    // 9) cross-attention (Lk=77, 1 segment of 2 tiles, masked)
    attn6<2, true><<<dim3(64, NHEADS, 1), 256, 0, stream>>>(Qp, Kc, Vc, pO, pL, 77, 128);
    attn_combine<<<5120, 256, 0, stream>>>(pO, pL, o_bf, 1);
    // 10) t += o @ wo2 + bo2
    gemm_mfma<2, 320><<<dim3(5, 128), 256, 0, stream>>>(o_bf, wo2T, bo2, t_, t_, nullptr, CCH, 0, 1.f);
    // 11) ln3 -> a_bf
    ln_kernel<<<1024, 256, 0, stream>>>(t_, ln3_w, ln3_b, a_bf);
    // 12+13) FF1 with fused GEGLU -> g_bf
    gemm_mfma<4, 320><<<dim3(40, 64), 256, 0, stream>>>(a_bf, wff1T, bff1, nullptr, g_bf, nullptr, 2 * FFI, 5, 1.f);
    // 14) t_bf = bf16(t + g @ wff2 + bff2)
    gemm_mfma<2, 1280><<<dim3(5, 128), 256, 0, stream>>>(g_bf, wff2T, bff2, t_, t_bf, nullptr, CCH, 4, 1.f);
    // 15) y = t_bf @ w_out + b_out (fp32)
    gemm_mfma<2, 320><<<dim3(5, 128), 256, 0, stream>>>(t_bf, w_outT, b_out, nullptr, y_, nullptr, CCH, 0, 1.f);
    // 16) out = y^T + x
    final_kernel<<<5120, 256, 0, stream>>>(y_, x, out);
}

// Round 9
// 596.166 us; speedup vs baseline: 3.9674x; 1.0557x over previous
//
#include <hip/hip_runtime.h>
#include <hip/hip_bf16.h>
#include <math.h>

#define CCH 320
#define NHEADS 8
#define DH 40
#define HW 4096
#define FFI 1280

typedef __bf16 bf16x8 __attribute__((ext_vector_type(8)));
typedef unsigned short u16x8 __attribute__((ext_vector_type(8)));
typedef float f32x4 __attribute__((ext_vector_type(4)));
typedef unsigned int u32x4 __attribute__((ext_vector_type(4)));

__device__ inline unsigned short f2bf(float f) {
    __hip_bfloat16 h = __float2bfloat16(f);
    return __builtin_bit_cast(unsigned short, h);
}
__device__ inline float bf2f(unsigned short u) {
    return __builtin_bit_cast(float, ((unsigned)u) << 16);
}
__device__ inline bf16x8 ldfrag(const unsigned short* p) {
    u16x8 raw = *reinterpret_cast<const u16x8*>(p);
    return __builtin_bit_cast(bf16x8, raw);
}

// ---------------------------------------------------------------------------
// Weights -> bf16 B^T (N x K). wff1T GLU-interleaved (row n <- col (n>>1)+(n&1)*1280).
__global__ __launch_bounds__(256) void prep_w(
    const float* __restrict__ w_in, const float* __restrict__ wq1,
    const float* __restrict__ wk1, const float* __restrict__ wv1,
    const float* __restrict__ wo1, const float* __restrict__ wq2,
    const float* __restrict__ wo2, const float* __restrict__ w_out,
    const float* __restrict__ wff1, const float* __restrict__ wff2,
    unsigned short* __restrict__ Wt) {
    int idx = blockIdx.x * 256 + threadIdx.x;  // < 2048000 exact
    float v;
    if (idx < 819200) {
        int m = idx / 102400;
        int j = idx - m * 102400;
        int n = j / 320, k = j - n * 320;
        const float* src = (m == 0) ? w_in : (m == 1) ? wq1 : (m == 2) ? wk1 :
                           (m == 3) ? wv1 : (m == 4) ? wo1 : (m == 5) ? wq2 :
                           (m == 6) ? wo2 : w_out;
        v = src[k * 320 + n];
    } else if (idx < 1638400) {
        int j = idx - 819200;
        int n = j / 320, k = j - n * 320;
        int nsrc = (n >> 1) + (n & 1) * FFI;
        v = wff1[k * 2560 + nsrc];
    } else {
        int j = idx - 1638400;
        int n = j / 1280, k = j - n * 1280;
        v = wff2[k * 320 + n];
    }
    Wt[idx] = f2bf(v);
}

// ---------------------------------------------------------------------------
__global__ __launch_bounds__(256) void gn_stats(const float* __restrict__ X,
                                                float2* __restrict__ part) {
    __shared__ float s1[256], s2[256];
    const int b = blockIdx.x, tid = threadIdx.x;
    const float* xg = X + b * 5120;
    float s = 0.f, sq = 0.f;
#pragma unroll
    for (int i = 0; i < 20; ++i) { float v = xg[tid + i * 256]; s += v; sq += v * v; }
    s1[tid] = s; s2[tid] = sq; __syncthreads();
    for (int off = 128; off > 0; off >>= 1) {
        if (tid < off) { s1[tid] += s1[tid + off]; s2[tid] += s2[tid + off]; }
        __syncthreads();
    }
    if (tid == 0) part[b] = make_float2(s1[0], s2[0]);
}

__global__ __launch_bounds__(256) void gn_apply(const float* __restrict__ X,
                                                const float2* __restrict__ part,
                                                const float* __restrict__ w,
                                                const float* __restrict__ b,
                                                unsigned short* __restrict__ Y) {
    __shared__ float tile[64][65];
    __shared__ float gm[32], gr[32];
    const int tid = threadIdx.x;
    const int hw0 = blockIdx.x * 64, c0 = blockIdx.y * 64;
    if (tid < 32) {
        float s = 0.f, sq = 0.f;
#pragma unroll
        for (int i = 0; i < 8; ++i) { float2 p = part[tid * 8 + i]; s += p.x; sq += p.y; }
        float mean = s * (1.f / 40960.f);
        float var  = sq * (1.f / 40960.f) - mean * mean;
        gm[tid] = mean; gr[tid] = rsqrtf(var + 1e-6f);
    }
#pragma unroll
    for (int i = 0; i < 16; ++i) {
        int idx = tid + i * 256;
        int r = idx >> 6, col = idx & 63;
        tile[r][col] = X[(size_t)(c0 + r) * HW + hw0 + col];
    }
    __syncthreads();
#pragma unroll
    for (int i = 0; i < 16; ++i) {
        int idx = tid + i * 256;
        int hwl = idx >> 6, cl = idx & 63;
        int c = c0 + cl, g = c / 10;
        float v = (tile[cl][hwl] - gm[g]) * gr[g] * w[c] + b[c];
        Y[(size_t)(hw0 + hwl) * CCH + c] = f2bf(v);
    }
}

// ---------------------------------------------------------------------------
__global__ __launch_bounds__(256) void ln_kernel(const float* __restrict__ X,
                                                 const float* __restrict__ w,
                                                 const float* __restrict__ b,
                                                 unsigned short* __restrict__ Y) {
    const int row  = blockIdx.x * 4 + (threadIdx.x >> 6);
    const int lane = threadIdx.x & 63;
    const float* xr = X + row * CCH;
    float v[5];
    float s = 0.f, sq = 0.f;
#pragma unroll
    for (int i = 0; i < 5; ++i) { v[i] = xr[lane + 64 * i]; s += v[i]; sq += v[i] * v[i]; }
#pragma unroll
    for (int off = 32; off > 0; off >>= 1) {
        s  += __shfl_xor(s, off, 64);
        sq += __shfl_xor(sq, off, 64);
    }
    const float mean = s * (1.f / 320.f);
    const float var  = sq * (1.f / 320.f) - mean * mean;
    const float rstd = rsqrtf(var + 1e-5f);
    unsigned short* yr = Y + row * CCH;
#pragma unroll
    for (int i = 0; i < 5; ++i) {
        int c = lane + 64 * i;
        yr[c] = f2bf((v[i] - mean) * rstd * w[c] + b[c]);
    }
}

// ---------------------------------------------------------------------------
// Bulk-LDS-staged bf16 MFMA GEMM. Per block: stage the ENTIRE A-slab
// (MT*16 x 320) and B-tile (64 x 320) into LDS with two contiguous memcpys
// (one latency exposure, deep MLP), one barrier, then the whole MFMA loop
// runs from LDS with zero global dependency. K > 320 loops staged chunks.
// LDS rows padded +8 elems -> ds_read_b128 at the 8-cyc conflict-free floor.
// Modes: 0 fp32+bias(+res) | 1 bf16+bias | 2 QK-pack*scale | 3 VT-pack |
//        4 bf16+bias+res | 5 GLU-interleaved | 6 dual bf16 + QK-pack
template <int MT, int K>
__global__ __launch_bounds__(256) void gemm3(
    const unsigned short* __restrict__ A,
    const unsigned short* __restrict__ Bt,
    const float* __restrict__ bias,
    const float* __restrict__ res,
    void* __restrict__ Cout, void* __restrict__ Cout2,
    int N, int mode, float scale) {
    constexpr int KB = 320;       // staged K-chunk
    constexpr int KP = KB + 8;    // padded LDS row stride (bank-spread)
    constexpr int NCH = K / KB;
    __shared__ __align__(16) unsigned short As[MT * 16 * KP];
    __shared__ __align__(16) unsigned short Bs[64 * KP];

    const int tid  = threadIdx.x;
    const int wave = tid >> 6, lane = tid & 63;
    const int quad = lane >> 4, c = lane & 15;
    const int m0 = blockIdx.y * (MT * 16);
    const int bn = blockIdx.x;

    f32x4 acc[MT];
#pragma unroll
    for (int i = 0; i < MT; ++i) acc[i] = (f32x4){0.f, 0.f, 0.f, 0.f};

    const unsigned short* aslab = A + (size_t)m0 * K;
    const unsigned short* bslab = Bt + (size_t)(bn * 64) * K;

    for (int ch = 0; ch < NCH; ++ch) {
        const int kb = ch * KB;
        if (ch > 0) __syncthreads();
        // ---- stage A-slab chunk ----
        constexpr int CHA = MT * 16 * KB / 8;  // 16B chunks
#pragma unroll
        for (int j = tid; j < CHA; j += 256) {
            int row = j / (KB / 8), off = j - row * (KB / 8);
            *(u16x8*)&As[row * KP + off * 8] =
                *(const u16x8*)(aslab + (size_t)row * K + kb + off * 8);
        }
        // ---- stage B-tile chunk ----
        constexpr int CHB = 64 * KB / 8;
#pragma unroll
        for (int j = tid; j < CHB; j += 256) {
            int row = j / (KB / 8), off = j - row * (KB / 8);
            *(u16x8*)&Bs[row * KP + off * 8] =
                *(const u16x8*)(bslab + (size_t)row * K + kb + off * 8);
        }
        __syncthreads();
        // ---- compute from LDS ----
#pragma unroll
        for (int k0 = 0; k0 < KB; k0 += 64) {
            bf16x8 b0 = ldfrag(&Bs[(wave * 16 + c) * KP + k0 + quad * 8]);
            bf16x8 b1 = ldfrag(&Bs[(wave * 16 + c) * KP + k0 + quad * 8 + 32]);
#pragma unroll
            for (int mt = 0; mt < MT; ++mt) {
                bf16x8 a0 = ldfrag(&As[(mt * 16 + c) * KP + k0 + quad * 8]);
                bf16x8 a1 = ldfrag(&As[(mt * 16 + c) * KP + k0 + quad * 8 + 32]);
                acc[mt] = __builtin_amdgcn_mfma_f32_16x16x32_bf16(a0, b0, acc[mt], 0, 0, 0);
                acc[mt] = __builtin_amdgcn_mfma_f32_16x16x32_bf16(a1, b1, acc[mt], 0, 0, 0);
            }
        }
    }

    const int col = bn * 64 + wave * 16 + c;
    float bval = 0.f;
    if (bias) bval = (mode == 5) ? bias[(col >> 1) + (col & 1) * FFI] : bias[col];
#pragma unroll
    for (int mt = 0; mt < MT; ++mt) {
#pragma unroll
        for (int r = 0; r < 4; ++r) {
            const int row = m0 + mt * 16 + quad * 4 + r;
            float v = acc[mt][r];
            if (mode == 0) {
                v += bval;
                if (res) v += res[(size_t)row * N + col];
                ((float*)Cout)[(size_t)row * N + col] = v;
            } else if (mode == 1) {
                ((unsigned short*)Cout)[(size_t)row * N + col] = f2bf(v + bval);
            } else if (mode == 2) {
                int h = col & 7, d = col >> 3;
                ((unsigned short*)Cout)[(((size_t)h << 12) + row) * 64 + d] = f2bf(v * scale);
            } else if (mode == 3) {
                int h = col & 7, d = col >> 3;
                ((unsigned short*)Cout)[(((size_t)(h * 48 + d)) << 12) + row] = f2bf(v);
            } else if (mode == 4) {
                ((unsigned short*)Cout)[(size_t)row * N + col] =
                    f2bf(v + bval + res[(size_t)row * N + col]);
            } else if (mode == 5) {
                v += bval;
                float other = __shfl_xor(v, 1, 64);
                if ((c & 1) == 0) {
                    float g = 0.5f * other * (1.f + erff(other * 0.70710678118654752f));
                    ((unsigned short*)Cout)[(size_t)row * FFI + (col >> 1)] = f2bf(v * g);
                }
            } else {  // 6
                ((unsigned short*)Cout)[(size_t)row * N + col] = f2bf(v);
                int h = col & 7, d = col >> 3;
                ((unsigned short*)Cout2)[(((size_t)h << 12) + row) * 64 + d] = f2bf(v * scale);
            }
        }
    }
}

// ---------------------------------------------------------------------------
// Context K/V (77 rows) -> packed Kc [h][128][64], Vc [h*48+d][128].
__global__ __launch_bounds__(256) void ctx_kv(
    const float* __restrict__ ctx, const float* __restrict__ wk2,
    const float* __restrict__ wv2, unsigned short* __restrict__ Kc,
    unsigned short* __restrict__ Vc) {
    __shared__ __align__(16) float As[16][68];
    __shared__ __align__(16) float Bs[16][68];
    const int tid = threadIdx.x;
    const int tx = tid & 15, ty = tid >> 4;
    const int bn = blockIdx.x, bm = blockIdx.y;
    const float* B = (blockIdx.z == 0) ? wk2 : wv2;
    float acc[4][4] = {};
    for (int k0 = 0; k0 < 768; k0 += 16) {
#pragma unroll
        for (int i = 0; i < 4; ++i) {
            int idx = tid + i * 256;
            int r = idx >> 4, cc = idx & 15;
            int gm = bm * 64 + r;
            As[cc][r] = (gm < 77) ? ctx[gm * 768 + k0 + cc] : 0.f;
        }
#pragma unroll
        for (int i = 0; i < 4; ++i) {
            int idx = tid + i * 256;
            int r = idx >> 6, cc = idx & 63;
            Bs[r][cc] = B[(k0 + r) * CCH + bn * 64 + cc];
        }
        __syncthreads();
#pragma unroll
        for (int kk = 0; kk < 16; ++kk) {
            float4 a4 = *(const float4*)&As[kk][ty * 4];
            float4 b4 = *(const float4*)&Bs[kk][tx * 4];
            float av[4] = {a4.x, a4.y, a4.z, a4.w};
            float bv[4] = {b4.x, b4.y, b4.z, b4.w};
#pragma unroll
            for (int i = 0; i < 4; ++i)
#pragma unroll
                for (int j = 0; j < 4; ++j) acc[i][j] += av[i] * bv[j];
        }
        __syncthreads();
    }
#pragma unroll
    for (int i = 0; i < 4; ++i) {
        int row = bm * 64 + ty * 4 + i;
#pragma unroll
        for (int j = 0; j < 4; ++j) {
            int col = bn * 64 + tx * 4 + j;
            int h = col & 7, d = col >> 3;
            float v = (row < 77) ? acc[i][j] : 0.f;
            if (blockIdx.z == 0)
                Kc[(((size_t)h << 7) + row) * 64 + d] = f2bf(v);
            else
                Vc[(size_t)(h * 48 + d) * 128 + row] = f2bf(v);
        }
    }
}

// ---------------------------------------------------------------------------
// LDS-staged MFMA flash attention (round-8 version, unchanged).
template <int TILES, bool MASK>
__global__ __launch_bounds__(256) void attn6(
    const unsigned short* __restrict__ Qp,
    const unsigned short* __restrict__ Kp,
    const unsigned short* __restrict__ Vt,
    float* __restrict__ pO, float* __restrict__ pL,
    int Lk, int Lkp) {
    __shared__ __align__(16) unsigned short Kb[2][64 * 64];
    __shared__ __align__(16) unsigned short Vb[2][48 * 64];
    const int tid  = threadIdx.x;
    const int wave = tid >> 6, lane = tid & 63;
    const int quad = lane >> 4, c = lane & 15;
    const int h   = blockIdx.y;
    const int seg = blockIdx.z;
    const int q0  = blockIdx.x * 64 + wave * 16;

    const unsigned short* qbase = Qp + ((((size_t)h << 12) + q0 + c) << 6) + quad * 8;
    const bf16x8 bQ0 = ldfrag(qbase);
    const bf16x8 bQ1 = ldfrag(qbase + 32);

    f32x4 oacc0 = {0.f, 0.f, 0.f, 0.f}, oacc1 = oacc0, oacc2 = oacc0;
    float lacc = 0.f;
    const int idx0 = ((((quad & 1) * 2 + 0) * 16 + c) << 2);
    const int idx1 = ((((quad & 1) * 2 + 1) * 16 + c) << 2);
    const bool hiQuad = (quad >> 1) != 0;

    const int kt0 = seg * TILES;
    const unsigned short* kglob = Kp + (((size_t)h * Lkp + kt0 * 64) << 6);
    const unsigned short* vglob = Vt + ((size_t)h * 48) * Lkp + kt0 * 64;

    const int r0 = lane >> 3;
    const int g  = lane & 7;
    int ldsoff[4];
    const unsigned short* gptr0[4];
#pragma unroll
    for (int i = 0; i < 4; ++i) {
        int s = wave + 4 * i;
        if (s < 8) {
            int row = s * 8 + r0;
            ldsoff[i] = row * 64 + (g ^ (row & 7)) * 8;
            gptr0[i]  = kglob + (size_t)row * 64 + g * 8;
        } else if (s < 14) {
            int d = (s - 8) * 8 + r0;
            ldsoff[i] = d * 64 + (g ^ (d & 7)) * 8;
            gptr0[i]  = vglob + (size_t)d * Lkp + g * 8;
        } else {
            ldsoff[i] = 0; gptr0[i] = nullptr;
        }
    }
    const bool isK[4] = {(wave + 0) < 8, (wave + 4) < 8, (wave + 8) < 8, (wave + 12) < 8};
    const bool act[4] = {true, true, true, (wave + 12) < 14};

    {
        u16x8 st[4];
#pragma unroll
        for (int i = 0; i < 4; ++i)
            if (act[i]) st[i] = *(const u16x8*)(gptr0[i]);
#pragma unroll
        for (int i = 0; i < 4; ++i)
            if (act[i]) {
                unsigned short* lp = isK[i] ? &Kb[0][ldsoff[i]] : &Vb[0][ldsoff[i]];
                *(u16x8*)lp = st[i];
            }
    }
    __syncthreads();

#pragma unroll
    for (int t = 0; t < TILES; ++t) {
        const int b = t & 1;
        u16x8 st[4];
        if (t + 1 < TILES) {
            const int kb = (t + 1) * 64;
#pragma unroll
            for (int i = 0; i < 4; ++i)
                if (act[i]) {
                    const unsigned short* gp =
                        isK[i] ? (gptr0[i] + (size_t)kb * 64) : (gptr0[i] + kb);
                    st[i] = *(const u16x8*)gp;
                }
        }
        const unsigned short* Kl = &Kb[b][0];
        const unsigned short* Vl = &Vb[b][0];
        const int sw0 = (quad ^ (c & 7)) * 8;
        const int sw1 = ((quad + 4) ^ (c & 7)) * 8;
        f32x4 s[4];
#pragma unroll
        for (int blk = 0; blk < 4; ++blk) {
            const int row = (blk * 16 + c) * 64;
            bf16x8 k0 = ldfrag(Kl + row + sw0);
            bf16x8 k1 = ldfrag(Kl + row + sw1);
            f32x4 z = {0.f, 0.f, 0.f, 0.f};
            z = __builtin_amdgcn_mfma_f32_16x16x32_bf16(k0, bQ0, z, 0, 0, 0);
            z = __builtin_amdgcn_mfma_f32_16x16x32_bf16(k1, bQ1, z, 0, 0, 0);
            s[blk] = z;
        }
        if (MASK) {
            const int abs_kb = kt0 * 64 + t * 64;
#pragma unroll
            for (int blk = 0; blk < 4; ++blk)
#pragma unroll
                for (int r = 0; r < 4; ++r)
                    s[blk][r] = (abs_kb + blk * 16 + quad * 4 + r >= Lk) ? -30000.f : s[blk][r];
        }
        bf16x8 vf[3][2];
#pragma unroll
        for (int blk = 0; blk < 3; ++blk) {
            const int row = (blk * 16 + c) * 64;
            vf[blk][0] = ldfrag(Vl + row + sw0);
            vf[blk][1] = ldfrag(Vl + row + sw1);
        }
        unsigned pk[4][2];
#pragma unroll
        for (int blk = 0; blk < 4; ++blk) {
            float p0 = exp2f(s[blk][0]);
            float p1 = exp2f(s[blk][1]);
            float p2 = exp2f(s[blk][2]);
            float p3 = exp2f(s[blk][3]);
            lacc += (p0 + p1) + (p2 + p3);
            pk[blk][0] = (unsigned)f2bf(p0) | ((unsigned)f2bf(p1) << 16);
            pk[blk][1] = (unsigned)f2bf(p2) | ((unsigned)f2bf(p3) << 16);
        }
        u32x4 Bw[2];
#pragma unroll
        for (int m = 0; m < 2; ++m) {
            int lo, hi;
            lo = __builtin_amdgcn_ds_bpermute(idx0, (int)pk[2 * m][0]);
            hi = __builtin_amdgcn_ds_bpermute(idx0, (int)pk[2 * m + 1][0]);
            Bw[m][0] = (unsigned)(hiQuad ? hi : lo);
            lo = __builtin_amdgcn_ds_bpermute(idx0, (int)pk[2 * m][1]);
            hi = __builtin_amdgcn_ds_bpermute(idx0, (int)pk[2 * m + 1][1]);
            Bw[m][1] = (unsigned)(hiQuad ? hi : lo);
            lo = __builtin_amdgcn_ds_bpermute(idx1, (int)pk[2 * m][0]);
            hi = __builtin_amdgcn_ds_bpermute(idx1, (int)pk[2 * m + 1][0]);
            Bw[m][2] = (unsigned)(hiQuad ? hi : lo);
            lo = __builtin_amdgcn_ds_bpermute(idx1, (int)pk[2 * m][1]);
            hi = __builtin_amdgcn_ds_bpermute(idx1, (int)pk[2 * m + 1][1]);
            Bw[m][3] = (unsigned)(hiQuad ? hi : lo);
        }
        bf16x8 P0 = __builtin_bit_cast(bf16x8, Bw[0]);
        bf16x8 P1 = __builtin_bit_cast(bf16x8, Bw[1]);
        oacc0 = __builtin_amdgcn_mfma_f32_16x16x32_bf16(vf[0][0], P0, oacc0, 0, 0, 0);
        oacc0 = __builtin_amdgcn_mfma_f32_16x16x32_bf16(vf[0][1], P1, oacc0, 0, 0, 0);
        oacc1 = __builtin_amdgcn_mfma_f32_16x16x32_bf16(vf[1][0], P0, oacc1, 0, 0, 0);
        oacc1 = __builtin_amdgcn_mfma_f32_16x16x32_bf16(vf[1][1], P1, oacc1, 0, 0, 0);
        oacc2 = __builtin_amdgcn_mfma_f32_16x16x32_bf16(vf[2][0], P0, oacc2, 0, 0, 0);
        oacc2 = __builtin_amdgcn_mfma_f32_16x16x32_bf16(vf[2][1], P1, oacc2, 0, 0, 0);
        if (t + 1 < TILES) {
            const int nb = b ^ 1;
#pragma unroll
            for (int i = 0; i < 4; ++i)
                if (act[i]) {
                    unsigned short* lp = isK[i] ? &Kb[nb][ldsoff[i]] : &Vb[nb][ldsoff[i]];
                    *(u16x8*)lp = st[i];
                }
        }
        __syncthreads();
    }
    lacc += __shfl_xor(lacc, 16, 64);
    lacc += __shfl_xor(lacc, 32, 64);
    const size_t base = ((size_t)(seg * 8 + h)) << 12;
    float* ob = pO + (base + q0 + c) * 40;
    *(float4*)(ob + quad * 4)      = make_float4(oacc0[0], oacc0[1], oacc0[2], oacc0[3]);
    *(float4*)(ob + 16 + quad * 4) = make_float4(oacc1[0], oacc1[1], oacc1[2], oacc1[3]);
    if (quad < 2)
        *(float4*)(ob + 32 + quad * 4) = make_float4(oacc2[0], oacc2[1], oacc2[2], oacc2[3]);
    if (quad == 0) pL[base + q0 + c] = lacc;
}

// Combine partials across S segments -> bf16 O (HW,320), col = h*40+d.
__global__ __launch_bounds__(256) void attn_combine(
    const float* __restrict__ pO, const float* __restrict__ pL,
    unsigned short* __restrict__ O, int S) {
    int idx = blockIdx.x * 256 + threadIdx.x;  // < 8*4096*40, grid 5120
    int h = idx / (HW * 40);
    int rem = idx - h * (HW * 40);
    int row = rem / 40, d = rem - row * 40;
    float num = 0.f, den = 0.f;
    for (int s = 0; s < S; ++s) {
        size_t base = ((size_t)(s * 8 + h)) << 12;
        num += pO[(base + row) * 40 + d];
        den += pL[base + row];
    }
    O[(size_t)row * CCH + h * DH + d] = f2bf(num / den);
}

// ---------------------------------------------------------------------------
__global__ void final_kernel(const float* __restrict__ Yv,
                             const float* __restrict__ X,
                             float* __restrict__ Out) {
    int idx = blockIdx.x * 256 + threadIdx.x;
    int o = idx >> 12, hw = idx & 4095;
    Out[idx] = Yv[hw * CCH + o] + X[idx];
}

// ---------------------------------------------------------------------------
extern "C" void kernel_launch(void* const* d_in, const int* in_sizes, int n_in,
                              void* d_out, int out_size, void* d_ws, size_t ws_size,
                              hipStream_t stream) {
    const float* x     = (const float*)d_in[0];
    const float* ctx   = (const float*)d_in[1];
    const float* gn_w  = (const float*)d_in[2];
    const float* gn_b  = (const float*)d_in[3];
    const float* w_in  = (const float*)d_in[4];
    const float* b_in  = (const float*)d_in[5];
    const float* ln1_w = (const float*)d_in[6];
    const float* ln1_b = (const float*)d_in[7];
    const float* wq1   = (const float*)d_in[8];
    const float* wk1   = (const float*)d_in[9];
    const float* wv1   = (const float*)d_in[10];
    const float* wo1   = (const float*)d_in[11];
    const float* bo1   = (const float*)d_in[12];
    const float* ln2_w = (const float*)d_in[13];
    const float* ln2_b = (const float*)d_in[14];
    const float* wq2   = (const float*)d_in[15];
    const float* wk2   = (const float*)d_in[16];
    const float* wv2   = (const float*)d_in[17];
    const float* wo2   = (const float*)d_in[18];
    const float* bo2   = (const float*)d_in[19];
    const float* ln3_w = (const float*)d_in[20];
    const float* ln3_b = (const float*)d_in[21];
    const float* wff1  = (const float*)d_in[22];
    const float* bff1  = (const float*)d_in[23];
    const float* wff2  = (const float*)d_in[24];
    const float* bff2  = (const float*)d_in[25];
    const float* w_out = (const float*)d_in[26];
    const float* b_out = (const float*)d_in[27];
    float* out = (float*)d_out;

    const int NT = HW * CCH;  // 1,310,720
    float* ws = (float*)d_ws;
    float* t_   = ws;                 // fp32 residual (HW,C)
    float* y_   = t_ + NT;            // fp32 final proj
    float* pO   = y_ + NT;            // attn partial O: 4*8*4096*40
    float* pL   = pO + 4 * 8 * 4096 * 40;  // 4*8*4096
    float2* gnp = (float2*)(pL + 4 * 8 * 4096);  // 256 float2
    unsigned short* u = (unsigned short*)(gnp + 256);
    unsigned short* a_bf = u;                  u += NT;
    unsigned short* q_bf = u;                  u += NT;
    unsigned short* o_bf = u;                  u += NT;
    unsigned short* t_bf = u;                  u += NT;
    unsigned short* g_bf = u;                  u += HW * FFI;
    unsigned short* Qp   = u;                  u += 8 * 4096 * 64;
    unsigned short* Kp   = u;                  u += 8 * 4096 * 64;
    unsigned short* Vt   = u;                  u += 8 * 48 * 4096;
    unsigned short* Kc   = u;                  u += 8 * 128 * 64;
    unsigned short* Vc   = u;                  u += 8 * 48 * 128;
    unsigned short* Wt   = u;                  u += 2048000;

    const unsigned short* w_inT  = Wt;
    const unsigned short* wq1T   = Wt + 102400;
    const unsigned short* wk1T   = Wt + 204800;
    const unsigned short* wv1T   = Wt + 307200;
    const unsigned short* wo1T   = Wt + 409600;
    const unsigned short* wq2T   = Wt + 512000;
    const unsigned short* wo2T   = Wt + 614400;
    const unsigned short* w_outT = Wt + 716800;
    const unsigned short* wff1T  = Wt + 819200;
    const unsigned short* wff2T  = Wt + 1638400;

    const float qscale = 0.15811388300841897f * 1.4426950408889634f;  // 40^-.5 * log2e

    prep_w<<<8000, 256, 0, stream>>>(w_in, wq1, wk1, wv1, wo1, wq2, wo2, w_out,
                                     wff1, wff2, Wt);
    hipMemsetAsync(Qp, 0,
                   (size_t)(8 * 4096 * 64 * 2 + 8 * 48 * 4096 + 8 * 128 * 64 + 8 * 48 * 128) * 2,
                   stream);

    // 1) GroupNorm -> a_bf (HW,C)
    gn_stats<<<256, 256, 0, stream>>>(x, gnp);
    gn_apply<<<dim3(64, 5), 256, 0, stream>>>(x, gnp, gn_w, gn_b, a_bf);
    // 2) proj_in: t = a @ w_in + b_in (fp32)
    gemm3<2, 320><<<dim3(5, 128), 256, 0, stream>>>(a_bf, w_inT, b_in, nullptr, t_, nullptr, CCH, 0, 1.f);
    // 3) ln1 -> a_bf
    ln_kernel<<<1024, 256, 0, stream>>>(t_, ln1_w, ln1_b, a_bf);
    // 4) q (dual: row-major + Qp scaled), k -> Kp, v -> Vt
    gemm3<2, 320><<<dim3(5, 128), 256, 0, stream>>>(a_bf, wq1T, nullptr, nullptr, q_bf, Qp, CCH, 6, qscale);
    gemm3<2, 320><<<dim3(5, 128), 256, 0, stream>>>(q_bf, wk1T, nullptr, nullptr, Kp, nullptr, CCH, 2, 1.f);
    gemm3<2, 320><<<dim3(5, 128), 256, 0, stream>>>(q_bf, wv1T, nullptr, nullptr, Vt, nullptr, CCH, 3, 1.f);
    // 5) self-attention: 4 key-segments of 1024, LDS-staged double buffer
    attn6<16, false><<<dim3(64, NHEADS, 4), 256, 0, stream>>>(Qp, Kp, Vt, pO, pL, HW, HW);
    attn_combine<<<5120, 256, 0, stream>>>(pO, pL, o_bf, 4);
    // 6) t += o @ wo1 + bo1
    gemm3<2, 320><<<dim3(5, 128), 256, 0, stream>>>(o_bf, wo1T, bo1, t_, t_, nullptr, CCH, 0, 1.f);
    // 7) ln2 -> a_bf
    ln_kernel<<<1024, 256, 0, stream>>>(t_, ln2_w, ln2_b, a_bf);
    // 8) cross q -> Qp; ctx K/V packed directly
    gemm3<2, 320><<<dim3(5, 128), 256, 0, stream>>>(a_bf, wq2T, nullptr, nullptr, Qp, nullptr, CCH, 2, qscale);
    ctx_kv<<<dim3(5, 2, 2), 256, 0, stream>>>(ctx, wk2, wv2, Kc, Vc);
    // 9) cross-attention (Lk=77, 1 segment of 2 tiles, masked)
    attn6<2, true><<<dim3(64, NHEADS, 1), 256, 0, stream>>>(Qp, Kc, Vc, pO, pL, 77, 128);
    attn_combine<<<5120, 256, 0, stream>>>(pO, pL, o_bf, 1);
    // 10) t += o @ wo2 + bo2
    gemm3<2, 320><<<dim3(5, 128), 256, 0, stream>>>(o_bf, wo2T, bo2, t_, t_, nullptr, CCH, 0, 1.f);
    // 11) ln3 -> a_bf
    ln_kernel<<<1024, 256, 0, stream>>>(t_, ln3_w, ln3_b, a_bf);
    // 12+13) FF1 with fused GEGLU -> g_bf
    gemm3<2, 320><<<dim3(40, 128), 256, 0, stream>>>(a_bf, wff1T, bff1, nullptr, g_bf, nullptr, 2 * FFI, 5, 1.f);
    // 14) t_bf = bf16(t + g @ wff2 + bff2)  (K=1280: 4 staged chunks)
    gemm3<2, 1280><<<dim3(5, 128), 256, 0, stream>>>(g_bf, wff2T, bff2, t_, t_bf, nullptr, CCH, 4, 1.f);
    // 15) y = t_bf @ w_out + b_out (fp32)
    gemm3<2, 320><<<dim3(5, 128), 256, 0, stream>>>(t_bf, w_outT, b_out, nullptr, y_, nullptr, CCH, 0, 1.f);
    // 16) out = y^T + x
    final_kernel<<<5120, 256, 0, stream>>>(y_, x, out);
}

// Round 10
// 456.476 us; speedup vs baseline: 5.1815x; 1.3060x over previous
//
#include <hip/hip_runtime.h>
#include <hip/hip_bf16.h>
#include <math.h>

#define CCH 320
#define NHEADS 8
#define DH 40
#define HW 4096
#define FFI 1280

typedef __bf16 bf16x8 __attribute__((ext_vector_type(8)));
typedef unsigned short u16x8 __attribute__((ext_vector_type(8)));
typedef float f32x4 __attribute__((ext_vector_type(4)));
typedef unsigned int u32x4 __attribute__((ext_vector_type(4)));

__device__ inline unsigned short f2bf(float f) {
    __hip_bfloat16 h = __float2bfloat16(f);
    return __builtin_bit_cast(unsigned short, h);
}
__device__ inline float bf2f(unsigned short u) {
    return __builtin_bit_cast(float, ((unsigned)u) << 16);
}
__device__ inline bf16x8 ldfrag(const unsigned short* p) {
    u16x8 raw = *reinterpret_cast<const u16x8*>(p);
    return __builtin_bit_cast(bf16x8, raw);
}

// ---------------------------------------------------------------------------
// Coalesced weight transpose via LDS 64x65 tiles (old prep_w was stride-1280B
// uncoalesced). 500 tiles: 8 squares (25 each), wff2 (100), wff1-GLU (200).
__global__ __launch_bounds__(256) void prep_w2(
    const float* __restrict__ w_in, const float* __restrict__ wq1,
    const float* __restrict__ wk1, const float* __restrict__ wv1,
    const float* __restrict__ wo1, const float* __restrict__ wq2,
    const float* __restrict__ wo2, const float* __restrict__ w_out,
    const float* __restrict__ wff1, const float* __restrict__ wff2,
    unsigned short* __restrict__ Wt) {
    __shared__ float tile[64][65];
    const int b = blockIdx.x, tid = threadIdx.x;
    const float* src;
    int K, stride, dstoff, k0, n0;
    bool glu = false;
    if (b < 200) {
        int m = b / 25, t = b % 25;
        k0 = (t / 5) * 64; n0 = (t % 5) * 64;
        K = 320; stride = 320; dstoff = m * 102400;
        src = (m == 0) ? w_in : (m == 1) ? wq1 : (m == 2) ? wk1 :
              (m == 3) ? wv1 : (m == 4) ? wo1 : (m == 5) ? wq2 :
              (m == 6) ? wo2 : w_out;
    } else if (b < 300) {
        int t = b - 200;
        k0 = (t / 5) * 64; n0 = (t % 5) * 64;
        K = 1280; stride = 320; dstoff = 1638400; src = wff2;
    } else {
        int t = b - 300;
        k0 = (t / 40) * 64; n0 = (t % 40) * 64;
        K = 320; stride = 2560; dstoff = 819200; src = wff1; glu = true;
    }
#pragma unroll
    for (int i = 0; i < 16; ++i) {
        int idx = tid + i * 256;
        int r = idx >> 6, cn = idx & 63;
        int scol = glu ? ((n0 >> 1) + (cn >> 1) + (cn & 1) * FFI) : (n0 + cn);
        tile[r][cn] = src[(size_t)(k0 + r) * stride + scol];
    }
    __syncthreads();
#pragma unroll
    for (int i = 0; i < 16; ++i) {
        int idx = tid + i * 256;
        int cl = idx >> 6, cr = idx & 63;
        Wt[dstoff + (size_t)(n0 + cl) * K + k0 + cr] = f2bf(tile[cr][cl]);
    }
}

// ---------------------------------------------------------------------------
__global__ __launch_bounds__(256) void gn_stats(const float* __restrict__ X,
                                                float2* __restrict__ part) {
    __shared__ float s1[256], s2[256];
    const int b = blockIdx.x, tid = threadIdx.x;
    const float* xg = X + b * 5120;
    float s = 0.f, sq = 0.f;
#pragma unroll
    for (int i = 0; i < 20; ++i) { float v = xg[tid + i * 256]; s += v; sq += v * v; }
    s1[tid] = s; s2[tid] = sq; __syncthreads();
    for (int off = 128; off > 0; off >>= 1) {
        if (tid < off) { s1[tid] += s1[tid + off]; s2[tid] += s2[tid + off]; }
        __syncthreads();
    }
    if (tid == 0) part[b] = make_float2(s1[0], s2[0]);
}

__global__ __launch_bounds__(256) void gn_apply(const float* __restrict__ X,
                                                const float2* __restrict__ part,
                                                const float* __restrict__ w,
                                                const float* __restrict__ b,
                                                unsigned short* __restrict__ Y) {
    __shared__ float tile[64][65];
    __shared__ float gm[32], gr[32];
    const int tid = threadIdx.x;
    const int hw0 = blockIdx.x * 64, c0 = blockIdx.y * 64;
    if (tid < 32) {
        float s = 0.f, sq = 0.f;
#pragma unroll
        for (int i = 0; i < 8; ++i) { float2 p = part[tid * 8 + i]; s += p.x; sq += p.y; }
        float mean = s * (1.f / 40960.f);
        float var  = sq * (1.f / 40960.f) - mean * mean;
        gm[tid] = mean; gr[tid] = rsqrtf(var + 1e-6f);
    }
#pragma unroll
    for (int i = 0; i < 16; ++i) {
        int idx = tid + i * 256;
        int r = idx >> 6, col = idx & 63;
        tile[r][col] = X[(size_t)(c0 + r) * HW + hw0 + col];
    }
    __syncthreads();
#pragma unroll
    for (int i = 0; i < 16; ++i) {
        int idx = tid + i * 256;
        int hwl = idx >> 6, cl = idx & 63;
        int c = c0 + cl, g = c / 10;
        float v = (tile[cl][hwl] - gm[g]) * gr[g] * w[c] + b[c];
        Y[(size_t)(hw0 + hwl) * CCH + c] = f2bf(v);
    }
}

// ---------------------------------------------------------------------------
__global__ __launch_bounds__(256) void ln_kernel(const float* __restrict__ X,
                                                 const float* __restrict__ w,
                                                 const float* __restrict__ b,
                                                 unsigned short* __restrict__ Y) {
    const int row  = blockIdx.x * 4 + (threadIdx.x >> 6);
    const int lane = threadIdx.x & 63;
    const float* xr = X + row * CCH;
    float v[5];
    float s = 0.f, sq = 0.f;
#pragma unroll
    for (int i = 0; i < 5; ++i) { v[i] = xr[lane + 64 * i]; s += v[i]; sq += v[i] * v[i]; }
#pragma unroll
    for (int off = 32; off > 0; off >>= 1) {
        s  += __shfl_xor(s, off, 64);
        sq += __shfl_xor(sq, off, 64);
    }
    const float mean = s * (1.f / 320.f);
    const float var  = sq * (1.f / 320.f) - mean * mean;
    const float rstd = rsqrtf(var + 1e-5f);
    unsigned short* yr = Y + row * CCH;
#pragma unroll
    for (int i = 0; i < 5; ++i) {
        int c = lane + 64 * i;
        yr[c] = f2bf((v[i] - mean) * rstd * w[c] + b[c]);
    }
}

// ---------------------------------------------------------------------------
// gemm4: attn6's proven double-buffer structure applied to GEMM.
// KB=64 chunks; per chunk: [load regs ch+1] -> [compute ch from LDS] ->
// [ds_write ch+1] -> barrier. XOR-swizzled 16B groups (2-way banks, free).
// Wave = 16 cols x 32 rows (MT=2). 24 KB LDS -> high blocks/CU.
// Modes: 0 fp32+bias(+res) | 2 QK-pack*scale | 4 bf16+bias+res |
//        5 GLU-interleaved | 6 dual bf16+QK-pack | 7 kv-merged (N=640)
template <int MT, int K>
__global__ __launch_bounds__(256) void gemm4(
    const unsigned short* __restrict__ A,
    const unsigned short* __restrict__ Bt,
    const float* __restrict__ bias,
    const float* __restrict__ res,
    void* __restrict__ Cout, void* __restrict__ Cout2,
    int N, int mode, float scale) {
    constexpr int NCH = K / 64;
    __shared__ __align__(16) unsigned short Ab[2][MT * 16 * 64];
    __shared__ __align__(16) unsigned short Bb[2][64 * 64];
    const int tid  = threadIdx.x;
    const int wave = tid >> 6, lane = tid & 63;
    const int quad = lane >> 4, c = lane & 15;
    const int m0 = blockIdx.y * (MT * 16);
    const int bn = blockIdx.x;

    f32x4 acc[MT];
#pragma unroll
    for (int i = 0; i < MT; ++i) acc[i] = (f32x4){0.f, 0.f, 0.f, 0.f};

    const unsigned short* aslab = A + (size_t)m0 * K;
    const unsigned short* bslab = Bt + (size_t)(bn * 64) * K;

    constexpr int ITA = MT * 16 * 8 / 256;  // A 16B-groups per thread
    // staging indices (constant per thread)
    int arow[ITA], aoff[ITA];
#pragma unroll
    for (int i = 0; i < ITA; ++i) {
        int idx = tid + i * 256;
        arow[i] = idx >> 3;
        int g = idx & 7;
        aoff[i] = arow[i] * 64 + ((g ^ (arow[i] & 7)) * 8);
    }
    int brow[2], boff[2];
#pragma unroll
    for (int i = 0; i < 2; ++i) {
        int idx = tid + i * 256;
        brow[i] = idx >> 3;
        int g = idx & 7;
        boff[i] = brow[i] * 64 + ((g ^ (brow[i] & 7)) * 8);
    }
    const int ag = (tid & 7) * 8;  // global k-offset of this thread's group

    // prologue: stage chunk 0
    {
        u16x8 ra[ITA], rb[2];
#pragma unroll
        for (int i = 0; i < ITA; ++i)
            ra[i] = *(const u16x8*)(aslab + (size_t)arow[i] * K + ag);
#pragma unroll
        for (int i = 0; i < 2; ++i)
            rb[i] = *(const u16x8*)(bslab + (size_t)brow[i] * K + ag);
#pragma unroll
        for (int i = 0; i < ITA; ++i) *(u16x8*)&Ab[0][aoff[i]] = ra[i];
#pragma unroll
        for (int i = 0; i < 2; ++i) *(u16x8*)&Bb[0][boff[i]] = rb[i];
    }
    __syncthreads();

    const int swz0 = (quad ^ (c & 7)) * 8;
    const int swz1 = ((quad + 4) ^ (c & 7)) * 8;
#pragma unroll
    for (int ch = 0; ch < NCH; ++ch) {
        const int buf = ch & 1;
        u16x8 ra[ITA], rb[2];
        if (ch + 1 < NCH) {
            const int kb = (ch + 1) * 64;
#pragma unroll
            for (int i = 0; i < ITA; ++i)
                ra[i] = *(const u16x8*)(aslab + (size_t)arow[i] * K + kb + ag);
#pragma unroll
            for (int i = 0; i < 2; ++i)
                rb[i] = *(const u16x8*)(bslab + (size_t)brow[i] * K + kb + ag);
        }
        // compute chunk ch from LDS
        bf16x8 b0 = ldfrag(&Bb[buf][(wave * 16 + c) * 64 + swz0]);
        bf16x8 b1 = ldfrag(&Bb[buf][(wave * 16 + c) * 64 + swz1]);
#pragma unroll
        for (int mt = 0; mt < MT; ++mt) {
            bf16x8 a0 = ldfrag(&Ab[buf][(mt * 16 + c) * 64 + swz0]);
            bf16x8 a1 = ldfrag(&Ab[buf][(mt * 16 + c) * 64 + swz1]);
            acc[mt] = __builtin_amdgcn_mfma_f32_16x16x32_bf16(a0, b0, acc[mt], 0, 0, 0);
            acc[mt] = __builtin_amdgcn_mfma_f32_16x16x32_bf16(a1, b1, acc[mt], 0, 0, 0);
        }
        if (ch + 1 < NCH) {
            const int nb = buf ^ 1;
#pragma unroll
            for (int i = 0; i < ITA; ++i) *(u16x8*)&Ab[nb][aoff[i]] = ra[i];
#pragma unroll
            for (int i = 0; i < 2; ++i) *(u16x8*)&Bb[nb][boff[i]] = rb[i];
        }
        __syncthreads();
    }

    const int col = bn * 64 + wave * 16 + c;
    float bval = 0.f;
    if (bias) bval = (mode == 5) ? bias[(col >> 1) + (col & 1) * FFI] : bias[col];
#pragma unroll
    for (int mt = 0; mt < MT; ++mt) {
#pragma unroll
        for (int r = 0; r < 4; ++r) {
            const int row = m0 + mt * 16 + quad * 4 + r;
            float v = acc[mt][r];
            if (mode == 0) {
                v += bval;
                if (res) v += res[(size_t)row * N + col];
                ((float*)Cout)[(size_t)row * N + col] = v;
            } else if (mode == 2) {
                int h = col & 7, d = col >> 3;
                ((unsigned short*)Cout)[(((size_t)h << 12) + row) * 64 + d] = f2bf(v * scale);
            } else if (mode == 4) {
                ((unsigned short*)Cout)[(size_t)row * N + col] =
                    f2bf(v + bval + res[(size_t)row * N + col]);
            } else if (mode == 5) {
                v += bval;
                float other = __shfl_xor(v, 1, 64);
                if ((c & 1) == 0) {
                    float g = 0.5f * other * (1.f + erff(other * 0.70710678118654752f));
                    ((unsigned short*)Cout)[(size_t)row * FFI + (col >> 1)] = f2bf(v * g);
                }
            } else if (mode == 6) {
                ((unsigned short*)Cout)[(size_t)row * N + col] = f2bf(v);
                int h = col & 7, d = col >> 3;
                ((unsigned short*)Cout2)[(((size_t)h << 12) + row) * 64 + d] = f2bf(v * scale);
            } else {  // 7: kv-merged — col<320 -> K pack, col>=320 -> V^T pack
                if (col < 320) {
                    int h = col & 7, d = col >> 3;
                    ((unsigned short*)Cout)[(((size_t)h << 12) + row) * 64 + d] = f2bf(v);
                } else {
                    int c2 = col - 320;
                    int h = c2 & 7, d = c2 >> 3;
                    ((unsigned short*)Cout2)[(((size_t)(h * 48 + d)) << 12) + row] = f2bf(v);
                }
            }
        }
    }
}

// ---------------------------------------------------------------------------
// Context K/V (77 rows) -> packed Kc [h][128][64], Vc [h*48+d][128].
__global__ __launch_bounds__(256) void ctx_kv(
    const float* __restrict__ ctx, const float* __restrict__ wk2,
    const float* __restrict__ wv2, unsigned short* __restrict__ Kc,
    unsigned short* __restrict__ Vc) {
    __shared__ __align__(16) float As[16][68];
    __shared__ __align__(16) float Bs[16][68];
    const int tid = threadIdx.x;
    const int tx = tid & 15, ty = tid >> 4;
    const int bn = blockIdx.x, bm = blockIdx.y;
    const float* B = (blockIdx.z == 0) ? wk2 : wv2;
    float acc[4][4] = {};
    for (int k0 = 0; k0 < 768; k0 += 16) {
#pragma unroll
        for (int i = 0; i < 4; ++i) {
            int idx = tid + i * 256;
            int r = idx >> 4, cc = idx & 15;
            int gm = bm * 64 + r;
            As[cc][r] = (gm < 77) ? ctx[gm * 768 + k0 + cc] : 0.f;
        }
#pragma unroll
        for (int i = 0; i < 4; ++i) {
            int idx = tid + i * 256;
            int r = idx >> 6, cc = idx & 63;
            Bs[r][cc] = B[(k0 + r) * CCH + bn * 64 + cc];
        }
        __syncthreads();
#pragma unroll
        for (int kk = 0; kk < 16; ++kk) {
            float4 a4 = *(const float4*)&As[kk][ty * 4];
            float4 b4 = *(const float4*)&Bs[kk][tx * 4];
            float av[4] = {a4.x, a4.y, a4.z, a4.w};
            float bv[4] = {b4.x, b4.y, b4.z, b4.w};
#pragma unroll
            for (int i = 0; i < 4; ++i)
#pragma unroll
                for (int j = 0; j < 4; ++j) acc[i][j] += av[i] * bv[j];
        }
        __syncthreads();
    }
#pragma unroll
    for (int i = 0; i < 4; ++i) {
        int row = bm * 64 + ty * 4 + i;
#pragma unroll
        for (int j = 0; j < 4; ++j) {
            int col = bn * 64 + tx * 4 + j;
            int h = col & 7, d = col >> 3;
            float v = (row < 77) ? acc[i][j] : 0.f;
            if (blockIdx.z == 0)
                Kc[(((size_t)h << 7) + row) * 64 + d] = f2bf(v);
            else
                Vc[(size_t)(h * 48 + d) * 128 + row] = f2bf(v);
        }
    }
}

// ---------------------------------------------------------------------------
// LDS-staged MFMA flash attention (round-8 core). 1-D grid with head-major
// XCD swizzle: h = id&7 pins each head's K/V working set to one XCD's L2.
template <int TILES, bool MASK>
__global__ __launch_bounds__(256) void attn6(
    const unsigned short* __restrict__ Qp,
    const unsigned short* __restrict__ Kp,
    const unsigned short* __restrict__ Vt,
    float* __restrict__ pO, float* __restrict__ pL,
    int Lk, int Lkp) {
    __shared__ __align__(16) unsigned short Kb[2][64 * 64];
    __shared__ __align__(16) unsigned short Vb[2][48 * 64];
    const int tid  = threadIdx.x;
    const int wave = tid >> 6, lane = tid & 63;
    const int quad = lane >> 4, c = lane & 15;
    const int id  = blockIdx.x;
    const int h   = id & 7;
    const int qt  = (id >> 3) & 63;
    const int seg = id >> 9;
    const int q0  = qt * 64 + wave * 16;

    const unsigned short* qbase = Qp + ((((size_t)h << 12) + q0 + c) << 6) + quad * 8;
    const bf16x8 bQ0 = ldfrag(qbase);
    const bf16x8 bQ1 = ldfrag(qbase + 32);

    f32x4 oacc0 = {0.f, 0.f, 0.f, 0.f}, oacc1 = oacc0, oacc2 = oacc0;
    float lacc = 0.f;
    const int idx0 = ((((quad & 1) * 2 + 0) * 16 + c) << 2);
    const int idx1 = ((((quad & 1) * 2 + 1) * 16 + c) << 2);
    const bool hiQuad = (quad >> 1) != 0;

    const int kt0 = seg * TILES;
    const unsigned short* kglob = Kp + (((size_t)h * Lkp + kt0 * 64) << 6);
    const unsigned short* vglob = Vt + ((size_t)h * 48) * Lkp + kt0 * 64;

    const int r0 = lane >> 3;
    const int g  = lane & 7;
    int ldsoff[4];
    const unsigned short* gptr0[4];
#pragma unroll
    for (int i = 0; i < 4; ++i) {
        int s = wave + 4 * i;
        if (s < 8) {
            int row = s * 8 + r0;
            ldsoff[i] = row * 64 + (g ^ (row & 7)) * 8;
            gptr0[i]  = kglob + (size_t)row * 64 + g * 8;
        } else if (s < 14) {
            int d = (s - 8) * 8 + r0;
            ldsoff[i] = d * 64 + (g ^ (d & 7)) * 8;
            gptr0[i]  = vglob + (size_t)d * Lkp + g * 8;
        } else {
            ldsoff[i] = 0; gptr0[i] = nullptr;
        }
    }
    const bool isK[4] = {(wave + 0) < 8, (wave + 4) < 8, (wave + 8) < 8, (wave + 12) < 8};
    const bool act[4] = {true, true, true, (wave + 12) < 14};

    {
        u16x8 st[4];
#pragma unroll
        for (int i = 0; i < 4; ++i)
            if (act[i]) st[i] = *(const u16x8*)(gptr0[i]);
#pragma unroll
        for (int i = 0; i < 4; ++i)
            if (act[i]) {
                unsigned short* lp = isK[i] ? &Kb[0][ldsoff[i]] : &Vb[0][ldsoff[i]];
                *(u16x8*)lp = st[i];
            }
    }
    __syncthreads();

#pragma unroll
    for (int t = 0; t < TILES; ++t) {
        const int b = t & 1;
        u16x8 st[4];
        if (t + 1 < TILES) {
            const int kb = (t + 1) * 64;
#pragma unroll
            for (int i = 0; i < 4; ++i)
                if (act[i]) {
                    const unsigned short* gp =
                        isK[i] ? (gptr0[i] + (size_t)kb * 64) : (gptr0[i] + kb);
                    st[i] = *(const u16x8*)gp;
                }
        }
        const unsigned short* Kl = &Kb[b][0];
        const unsigned short* Vl = &Vb[b][0];
        const int sw0 = (quad ^ (c & 7)) * 8;
        const int sw1 = ((quad + 4) ^ (c & 7)) * 8;
        f32x4 s[4];
#pragma unroll
        for (int blk = 0; blk < 4; ++blk) {
            const int row = (blk * 16 + c) * 64;
            bf16x8 k0 = ldfrag(Kl + row + sw0);
            bf16x8 k1 = ldfrag(Kl + row + sw1);
            f32x4 z = {0.f, 0.f, 0.f, 0.f};
            z = __builtin_amdgcn_mfma_f32_16x16x32_bf16(k0, bQ0, z, 0, 0, 0);
            z = __builtin_amdgcn_mfma_f32_16x16x32_bf16(k1, bQ1, z, 0, 0, 0);
            s[blk] = z;
        }
        if (MASK) {
            const int abs_kb = kt0 * 64 + t * 64;
#pragma unroll
            for (int blk = 0; blk < 4; ++blk)
#pragma unroll
                for (int r = 0; r < 4; ++r)
                    s[blk][r] = (abs_kb + blk * 16 + quad * 4 + r >= Lk) ? -30000.f : s[blk][r];
        }
        bf16x8 vf[3][2];
#pragma unroll
        for (int blk = 0; blk < 3; ++blk) {
            const int row = (blk * 16 + c) * 64;
            vf[blk][0] = ldfrag(Vl + row + sw0);
            vf[blk][1] = ldfrag(Vl + row + sw1);
        }
        unsigned pk[4][2];
#pragma unroll
        for (int blk = 0; blk < 4; ++blk) {
            float p0 = exp2f(s[blk][0]);
            float p1 = exp2f(s[blk][1]);
            float p2 = exp2f(s[blk][2]);
            float p3 = exp2f(s[blk][3]);
            lacc += (p0 + p1) + (p2 + p3);
            pk[blk][0] = (unsigned)f2bf(p0) | ((unsigned)f2bf(p1) << 16);
            pk[blk][1] = (unsigned)f2bf(p2) | ((unsigned)f2bf(p3) << 16);
        }
        u32x4 Bw[2];
#pragma unroll
        for (int m = 0; m < 2; ++m) {
            int lo, hi;
            lo = __builtin_amdgcn_ds_bpermute(idx0, (int)pk[2 * m][0]);
            hi = __builtin_amdgcn_ds_bpermute(idx0, (int)pk[2 * m + 1][0]);
            Bw[m][0] = (unsigned)(hiQuad ? hi : lo);
            lo = __builtin_amdgcn_ds_bpermute(idx0, (int)pk[2 * m][1]);
            hi = __builtin_amdgcn_ds_bpermute(idx0, (int)pk[2 * m + 1][1]);
            Bw[m][1] = (unsigned)(hiQuad ? hi : lo);
            lo = __builtin_amdgcn_ds_bpermute(idx1, (int)pk[2 * m][0]);
            hi = __builtin_amdgcn_ds_bpermute(idx1, (int)pk[2 * m + 1][0]);
            Bw[m][2] = (unsigned)(hiQuad ? hi : lo);
            lo = __builtin_amdgcn_ds_bpermute(idx1, (int)pk[2 * m][1]);
            hi = __builtin_amdgcn_ds_bpermute(idx1, (int)pk[2 * m + 1][1]);
            Bw[m][3] = (unsigned)(hiQuad ? hi : lo);
        }
        bf16x8 P0 = __builtin_bit_cast(bf16x8, Bw[0]);
        bf16x8 P1 = __builtin_bit_cast(bf16x8, Bw[1]);
        oacc0 = __builtin_amdgcn_mfma_f32_16x16x32_bf16(vf[0][0], P0, oacc0, 0, 0, 0);
        oacc0 = __builtin_amdgcn_mfma_f32_16x16x32_bf16(vf[0][1], P1, oacc0, 0, 0, 0);
        oacc1 = __builtin_amdgcn_mfma_f32_16x16x32_bf16(vf[1][0], P0, oacc1, 0, 0, 0);
        oacc1 = __builtin_amdgcn_mfma_f32_16x16x32_bf16(vf[1][1], P1, oacc1, 0, 0, 0);
        oacc2 = __builtin_amdgcn_mfma_f32_16x16x32_bf16(vf[2][0], P0, oacc2, 0, 0, 0);
        oacc2 = __builtin_amdgcn_mfma_f32_16x16x32_bf16(vf[2][1], P1, oacc2, 0, 0, 0);
        if (t + 1 < TILES) {
            const int nb = b ^ 1;
#pragma unroll
            for (int i = 0; i < 4; ++i)
                if (act[i]) {
                    unsigned short* lp = isK[i] ? &Kb[nb][ldsoff[i]] : &Vb[nb][ldsoff[i]];
                    *(u16x8*)lp = st[i];
                }
        }
        __syncthreads();
    }
    lacc += __shfl_xor(lacc, 16, 64);
    lacc += __shfl_xor(lacc, 32, 64);
    const size_t base = ((size_t)(seg * 8 + h)) << 12;
    float* ob = pO + (base + q0 + c) * 40;
    *(float4*)(ob + quad * 4)      = make_float4(oacc0[0], oacc0[1], oacc0[2], oacc0[3]);
    *(float4*)(ob + 16 + quad * 4) = make_float4(oacc1[0], oacc1[1], oacc1[2], oacc1[3]);
    if (quad < 2)
        *(float4*)(ob + 32 + quad * 4) = make_float4(oacc2[0], oacc2[1], oacc2[2], oacc2[3]);
    if (quad == 0) pL[base + q0 + c] = lacc;
}

// Combine partials across S segments -> bf16 O (HW,320), col = h*40+d.
__global__ __launch_bounds__(256) void attn_combine(
    const float* __restrict__ pO, const float* __restrict__ pL,
    unsigned short* __restrict__ O, int S) {
    int idx = blockIdx.x * 256 + threadIdx.x;  // < 8*4096*40, grid 5120
    int h = idx / (HW * 40);
    int rem = idx - h * (HW * 40);
    int row = rem / 40, d = rem - row * 40;
    float num = 0.f, den = 0.f;
    for (int s = 0; s < S; ++s) {
        size_t base = ((size_t)(s * 8 + h)) << 12;
        num += pO[(base + row) * 40 + d];
        den += pL[base + row];
    }
    O[(size_t)row * CCH + h * DH + d] = f2bf(num / den);
}

// ---------------------------------------------------------------------------
__global__ void final_kernel(const float* __restrict__ Yv,
                             const float* __restrict__ X,
                             float* __restrict__ Out) {
    int idx = blockIdx.x * 256 + threadIdx.x;
    int o = idx >> 12, hw = idx & 4095;
    Out[idx] = Yv[hw * CCH + o] + X[idx];
}

// ---------------------------------------------------------------------------
extern "C" void kernel_launch(void* const* d_in, const int* in_sizes, int n_in,
                              void* d_out, int out_size, void* d_ws, size_t ws_size,
                              hipStream_t stream) {
    const float* x     = (const float*)d_in[0];
    const float* ctx   = (const float*)d_in[1];
    const float* gn_w  = (const float*)d_in[2];
    const float* gn_b  = (const float*)d_in[3];
    const float* w_in  = (const float*)d_in[4];
    const float* b_in  = (const float*)d_in[5];
    const float* ln1_w = (const float*)d_in[6];
    const float* ln1_b = (const float*)d_in[7];
    const float* wq1   = (const float*)d_in[8];
    const float* wk1   = (const float*)d_in[9];
    const float* wv1   = (const float*)d_in[10];
    const float* wo1   = (const float*)d_in[11];
    const float* bo1   = (const float*)d_in[12];
    const float* ln2_w = (const float*)d_in[13];
    const float* ln2_b = (const float*)d_in[14];
    const float* wq2   = (const float*)d_in[15];
    const float* wk2   = (const float*)d_in[16];
    const float* wv2   = (const float*)d_in[17];
    const float* wo2   = (const float*)d_in[18];
    const float* bo2   = (const float*)d_in[19];
    const float* ln3_w = (const float*)d_in[20];
    const float* ln3_b = (const float*)d_in[21];
    const float* wff1  = (const float*)d_in[22];
    const float* bff1  = (const float*)d_in[23];
    const float* wff2  = (const float*)d_in[24];
    const float* bff2  = (const float*)d_in[25];
    const float* w_out = (const float*)d_in[26];
    const float* b_out = (const float*)d_in[27];
    float* out = (float*)d_out;

    const int NT = HW * CCH;  // 1,310,720
    float* ws = (float*)d_ws;
    float* t_   = ws;                 // fp32 residual (HW,C)
    float* y_   = t_ + NT;            // fp32 final proj
    float* pO   = y_ + NT;            // attn partial O: 4*8*4096*40
    float* pL   = pO + 4 * 8 * 4096 * 40;  // 4*8*4096
    float2* gnp = (float2*)(pL + 4 * 8 * 4096);  // 256 float2
    unsigned short* u = (unsigned short*)(gnp + 256);
    unsigned short* a_bf = u;                  u += NT;
    unsigned short* q_bf = u;                  u += NT;
    unsigned short* o_bf = u;                  u += NT;
    unsigned short* t_bf = u;                  u += NT;
    unsigned short* g_bf = u;                  u += HW * FFI;
    unsigned short* Qp   = u;                  u += 8 * 4096 * 64;
    unsigned short* Kp   = u;                  u += 8 * 4096 * 64;
    unsigned short* Vt   = u;                  u += 8 * 48 * 4096;
    unsigned short* Kc   = u;                  u += 8 * 128 * 64;
    unsigned short* Vc   = u;                  u += 8 * 48 * 128;
    unsigned short* Wt   = u;                  u += 2048000;

    const unsigned short* w_inT  = Wt;
    const unsigned short* wq1T   = Wt + 102400;
    const unsigned short* wk1T   = Wt + 204800;  // wv1T contiguous at +307200
    const unsigned short* wo1T   = Wt + 409600;
    const unsigned short* wq2T   = Wt + 512000;
    const unsigned short* wo2T   = Wt + 614400;
    const unsigned short* w_outT = Wt + 716800;
    const unsigned short* wff1T  = Wt + 819200;
    const unsigned short* wff2T  = Wt + 1638400;

    const float qscale = 0.15811388300841897f * 1.4426950408889634f;  // 40^-.5 * log2e

    prep_w2<<<500, 256, 0, stream>>>(w_in, wq1, wk1, wv1, wo1, wq2, wo2, w_out,
                                     wff1, wff2, Wt);
    hipMemsetAsync(Qp, 0,
                   (size_t)(8 * 4096 * 64 * 2 + 8 * 48 * 4096 + 8 * 128 * 64 + 8 * 48 * 128) * 2,
                   stream);

    // 1) GroupNorm -> a_bf (HW,C)
    gn_stats<<<256, 256, 0, stream>>>(x, gnp);
    gn_apply<<<dim3(64, 5), 256, 0, stream>>>(x, gnp, gn_w, gn_b, a_bf);
    // 2) proj_in: t = a @ w_in + b_in (fp32)
    gemm4<2, 320><<<dim3(5, 128), 256, 0, stream>>>(a_bf, w_inT, b_in, nullptr, t_, nullptr, CCH, 0, 1.f);
    // 3) ln1 -> a_bf
    ln_kernel<<<1024, 256, 0, stream>>>(t_, ln1_w, ln1_b, a_bf);
    // 4) q (dual: row-major + Qp scaled); k&v in ONE N=640 dispatch
    gemm4<2, 320><<<dim3(5, 128), 256, 0, stream>>>(a_bf, wq1T, nullptr, nullptr, q_bf, Qp, CCH, 6, qscale);
    gemm4<2, 320><<<dim3(10, 128), 256, 0, stream>>>(q_bf, wk1T, nullptr, nullptr, Kp, Vt, 640, 7, 1.f);
    // 5) self-attention: 4 segs, head-major XCD swizzle (1-D grid)
    attn6<16, false><<<2048, 256, 0, stream>>>(Qp, Kp, Vt, pO, pL, HW, HW);
    attn_combine<<<5120, 256, 0, stream>>>(pO, pL, o_bf, 4);
    // 6) t += o @ wo1 + bo1
    gemm4<2, 320><<<dim3(5, 128), 256, 0, stream>>>(o_bf, wo1T, bo1, t_, t_, nullptr, CCH, 0, 1.f);
    // 7) ln2 -> a_bf
    ln_kernel<<<1024, 256, 0, stream>>>(t_, ln2_w, ln2_b, a_bf);
    // 8) cross q -> Qp; ctx K/V packed directly
    gemm4<2, 320><<<dim3(5, 128), 256, 0, stream>>>(a_bf, wq2T, nullptr, nullptr, Qp, nullptr, CCH, 2, qscale);
    ctx_kv<<<dim3(5, 2, 2), 256, 0, stream>>>(ctx, wk2, wv2, Kc, Vc);
    // 9) cross-attention (Lk=77, 1 seg of 2 tiles, masked)
    attn6<2, true><<<512, 256, 0, stream>>>(Qp, Kc, Vc, pO, pL, 77, 128);
    attn_combine<<<5120, 256, 0, stream>>>(pO, pL, o_bf, 1);
    // 10) t += o @ wo2 + bo2
    gemm4<2, 320><<<dim3(5, 128), 256, 0, stream>>>(o_bf, wo2T, bo2, t_, t_, nullptr, CCH, 0, 1.f);
    // 11) ln3 -> a_bf
    ln_kernel<<<1024, 256, 0, stream>>>(t_, ln3_w, ln3_b, a_bf);
    // 12+13) FF1 with fused GEGLU -> g_bf
    gemm4<2, 320><<<dim3(40, 128), 256, 0, stream>>>(a_bf, wff1T, bff1, nullptr, g_bf, nullptr, 2 * FFI, 5, 1.f);
    // 14) t_bf = bf16(t + g @ wff2 + bff2)  (K=1280: 20 chunks)
    gemm4<2, 1280><<<dim3(5, 128), 256, 0, stream>>>(g_bf, wff2T, bff2, t_, t_bf, nullptr, CCH, 4, 1.f);
    // 15) y = t_bf @ w_out + b_out (fp32)
    gemm4<2, 320><<<dim3(5, 128), 256, 0, stream>>>(t_bf, w_outT, b_out, nullptr, y_, nullptr, CCH, 0, 1.f);
    // 16) out = y^T + x
    final_kernel<<<5120, 256, 0, stream>>>(y_, x, out);
}

// Round 11
// 408.404 us; speedup vs baseline: 5.7915x; 1.1177x over previous
//
#include <hip/hip_runtime.h>
#include <hip/hip_bf16.h>
#include <math.h>

#define CCH 320
#define NHEADS 8
#define DH 40
#define HW 4096
#define FFI 1280

typedef __bf16 bf16x8 __attribute__((ext_vector_type(8)));
typedef unsigned short u16x8 __attribute__((ext_vector_type(8)));
typedef float f32x4 __attribute__((ext_vector_type(4)));
typedef unsigned int u32x4 __attribute__((ext_vector_type(4)));

__device__ inline unsigned short f2bf(float f) {
    __hip_bfloat16 h = __float2bfloat16(f);
    return __builtin_bit_cast(unsigned short, h);
}
__device__ inline float bf2f(unsigned short u) {
    return __builtin_bit_cast(float, ((unsigned)u) << 16);
}
__device__ inline bf16x8 ldfrag(const unsigned short* p) {
    u16x8 raw = *reinterpret_cast<const u16x8*>(p);
    return __builtin_bit_cast(bf16x8, raw);
}

// ---------------------------------------------------------------------------
// Coalesced weight transpose via LDS 64x65 tiles.
__global__ __launch_bounds__(256) void prep_w2(
    const float* __restrict__ w_in, const float* __restrict__ wq1,
    const float* __restrict__ wk1, const float* __restrict__ wv1,
    const float* __restrict__ wo1, const float* __restrict__ wq2,
    const float* __restrict__ wo2, const float* __restrict__ w_out,
    const float* __restrict__ wff1, const float* __restrict__ wff2,
    unsigned short* __restrict__ Wt) {
    __shared__ float tile[64][65];
    const int b = blockIdx.x, tid = threadIdx.x;
    const float* src;
    int K, stride, dstoff, k0, n0;
    bool glu = false;
    if (b < 200) {
        int m = b / 25, t = b % 25;
        k0 = (t / 5) * 64; n0 = (t % 5) * 64;
        K = 320; stride = 320; dstoff = m * 102400;
        src = (m == 0) ? w_in : (m == 1) ? wq1 : (m == 2) ? wk1 :
              (m == 3) ? wv1 : (m == 4) ? wo1 : (m == 5) ? wq2 :
              (m == 6) ? wo2 : w_out;
    } else if (b < 300) {
        int t = b - 200;
        k0 = (t / 5) * 64; n0 = (t % 5) * 64;
        K = 1280; stride = 320; dstoff = 1638400; src = wff2;
    } else {
        int t = b - 300;
        k0 = (t / 40) * 64; n0 = (t % 40) * 64;
        K = 320; stride = 2560; dstoff = 819200; src = wff1; glu = true;
    }
#pragma unroll
    for (int i = 0; i < 16; ++i) {
        int idx = tid + i * 256;
        int r = idx >> 6, cn = idx & 63;
        int scol = glu ? ((n0 >> 1) + (cn >> 1) + (cn & 1) * FFI) : (n0 + cn);
        tile[r][cn] = src[(size_t)(k0 + r) * stride + scol];
    }
    __syncthreads();
#pragma unroll
    for (int i = 0; i < 16; ++i) {
        int idx = tid + i * 256;
        int cl = idx >> 6, cr = idx & 63;
        Wt[dstoff + (size_t)(n0 + cl) * K + k0 + cr] = f2bf(tile[cr][cl]);
    }
}

// ---------------------------------------------------------------------------
__global__ __launch_bounds__(256) void gn_stats(const float* __restrict__ X,
                                                float2* __restrict__ part) {
    __shared__ float s1[256], s2[256];
    const int b = blockIdx.x, tid = threadIdx.x;
    const float* xg = X + b * 5120;
    float s = 0.f, sq = 0.f;
#pragma unroll
    for (int i = 0; i < 20; ++i) { float v = xg[tid + i * 256]; s += v; sq += v * v; }
    s1[tid] = s; s2[tid] = sq; __syncthreads();
    for (int off = 128; off > 0; off >>= 1) {
        if (tid < off) { s1[tid] += s1[tid + off]; s2[tid] += s2[tid + off]; }
        __syncthreads();
    }
    if (tid == 0) part[b] = make_float2(s1[0], s2[0]);
}

__global__ __launch_bounds__(256) void gn_apply(const float* __restrict__ X,
                                                const float2* __restrict__ part,
                                                const float* __restrict__ w,
                                                const float* __restrict__ b,
                                                unsigned short* __restrict__ Y) {
    __shared__ float tile[64][65];
    __shared__ float gm[32], gr[32];
    const int tid = threadIdx.x;
    const int hw0 = blockIdx.x * 64, c0 = blockIdx.y * 64;
    if (tid < 32) {
        float s = 0.f, sq = 0.f;
#pragma unroll
        for (int i = 0; i < 8; ++i) { float2 p = part[tid * 8 + i]; s += p.x; sq += p.y; }
        float mean = s * (1.f / 40960.f);
        float var  = sq * (1.f / 40960.f) - mean * mean;
        gm[tid] = mean; gr[tid] = rsqrtf(var + 1e-6f);
    }
#pragma unroll
    for (int i = 0; i < 16; ++i) {
        int idx = tid + i * 256;
        int r = idx >> 6, col = idx & 63;
        tile[r][col] = X[(size_t)(c0 + r) * HW + hw0 + col];
    }
    __syncthreads();
#pragma unroll
    for (int i = 0; i < 16; ++i) {
        int idx = tid + i * 256;
        int hwl = idx >> 6, cl = idx & 63;
        int c = c0 + cl, g = c / 10;
        float v = (tile[cl][hwl] - gm[g]) * gr[g] * w[c] + b[c];
        Y[(size_t)(hw0 + hwl) * CCH + c] = f2bf(v);
    }
}

// ---------------------------------------------------------------------------
__global__ __launch_bounds__(256) void ln_kernel(const float* __restrict__ X,
                                                 const float* __restrict__ w,
                                                 const float* __restrict__ b,
                                                 unsigned short* __restrict__ Y) {
    const int row  = blockIdx.x * 4 + (threadIdx.x >> 6);
    const int lane = threadIdx.x & 63;
    const float* xr = X + row * CCH;
    float v[5];
    float s = 0.f, sq = 0.f;
#pragma unroll
    for (int i = 0; i < 5; ++i) { v[i] = xr[lane + 64 * i]; s += v[i]; sq += v[i] * v[i]; }
#pragma unroll
    for (int off = 32; off > 0; off >>= 1) {
        s  += __shfl_xor(s, off, 64);
        sq += __shfl_xor(sq, off, 64);
    }
    const float mean = s * (1.f / 320.f);
    const float var  = sq * (1.f / 320.f) - mean * mean;
    const float rstd = rsqrtf(var + 1e-5f);
    unsigned short* yr = Y + row * CCH;
#pragma unroll
    for (int i = 0; i < 5; ++i) {
        int c = lane + 64 * i;
        yr[c] = f2bf((v[i] - mean) * rstd * w[c] + b[c]);
    }
}

// ---------------------------------------------------------------------------
// gemm4 (round-9 proven double-buffer GEMM, unchanged).
template <int MT, int K>
__global__ __launch_bounds__(256) void gemm4(
    const unsigned short* __restrict__ A,
    const unsigned short* __restrict__ Bt,
    const float* __restrict__ bias,
    const float* __restrict__ res,
    void* __restrict__ Cout, void* __restrict__ Cout2,
    int N, int mode, float scale) {
    constexpr int NCH = K / 64;
    __shared__ __align__(16) unsigned short Ab[2][MT * 16 * 64];
    __shared__ __align__(16) unsigned short Bb[2][64 * 64];
    const int tid  = threadIdx.x;
    const int wave = tid >> 6, lane = tid & 63;
    const int quad = lane >> 4, c = lane & 15;
    const int m0 = blockIdx.y * (MT * 16);
    const int bn = blockIdx.x;

    f32x4 acc[MT];
#pragma unroll
    for (int i = 0; i < MT; ++i) acc[i] = (f32x4){0.f, 0.f, 0.f, 0.f};

    const unsigned short* aslab = A + (size_t)m0 * K;
    const unsigned short* bslab = Bt + (size_t)(bn * 64) * K;

    constexpr int ITA = MT * 16 * 8 / 256;
    int arow[ITA], aoff[ITA];
#pragma unroll
    for (int i = 0; i < ITA; ++i) {
        int idx = tid + i * 256;
        arow[i] = idx >> 3;
        int g = idx & 7;
        aoff[i] = arow[i] * 64 + ((g ^ (arow[i] & 7)) * 8);
    }
    int brow[2], boff[2];
#pragma unroll
    for (int i = 0; i < 2; ++i) {
        int idx = tid + i * 256;
        brow[i] = idx >> 3;
        int g = idx & 7;
        boff[i] = brow[i] * 64 + ((g ^ (brow[i] & 7)) * 8);
    }
    const int ag = (tid & 7) * 8;

    {
        u16x8 ra[ITA], rb[2];
#pragma unroll
        for (int i = 0; i < ITA; ++i)
            ra[i] = *(const u16x8*)(aslab + (size_t)arow[i] * K + ag);
#pragma unroll
        for (int i = 0; i < 2; ++i)
            rb[i] = *(const u16x8*)(bslab + (size_t)brow[i] * K + ag);
#pragma unroll
        for (int i = 0; i < ITA; ++i) *(u16x8*)&Ab[0][aoff[i]] = ra[i];
#pragma unroll
        for (int i = 0; i < 2; ++i) *(u16x8*)&Bb[0][boff[i]] = rb[i];
    }
    __syncthreads();

    const int swz0 = (quad ^ (c & 7)) * 8;
    const int swz1 = ((quad + 4) ^ (c & 7)) * 8;
#pragma unroll
    for (int ch = 0; ch < NCH; ++ch) {
        const int buf = ch & 1;
        u16x8 ra[ITA], rb[2];
        if (ch + 1 < NCH) {
            const int kb = (ch + 1) * 64;
#pragma unroll
            for (int i = 0; i < ITA; ++i)
                ra[i] = *(const u16x8*)(aslab + (size_t)arow[i] * K + kb + ag);
#pragma unroll
            for (int i = 0; i < 2; ++i)
                rb[i] = *(const u16x8*)(bslab + (size_t)brow[i] * K + kb + ag);
        }
        bf16x8 b0 = ldfrag(&Bb[buf][(wave * 16 + c) * 64 + swz0]);
        bf16x8 b1 = ldfrag(&Bb[buf][(wave * 16 + c) * 64 + swz1]);
#pragma unroll
        for (int mt = 0; mt < MT; ++mt) {
            bf16x8 a0 = ldfrag(&Ab[buf][(mt * 16 + c) * 64 + swz0]);
            bf16x8 a1 = ldfrag(&Ab[buf][(mt * 16 + c) * 64 + swz1]);
            acc[mt] = __builtin_amdgcn_mfma_f32_16x16x32_bf16(a0, b0, acc[mt], 0, 0, 0);
            acc[mt] = __builtin_amdgcn_mfma_f32_16x16x32_bf16(a1, b1, acc[mt], 0, 0, 0);
        }
        if (ch + 1 < NCH) {
            const int nb = buf ^ 1;
#pragma unroll
            for (int i = 0; i < ITA; ++i) *(u16x8*)&Ab[nb][aoff[i]] = ra[i];
#pragma unroll
            for (int i = 0; i < 2; ++i) *(u16x8*)&Bb[nb][boff[i]] = rb[i];
        }
        __syncthreads();
    }

    const int col = bn * 64 + wave * 16 + c;
    float bval = 0.f;
    if (bias) bval = (mode == 5) ? bias[(col >> 1) + (col & 1) * FFI] : bias[col];
#pragma unroll
    for (int mt = 0; mt < MT; ++mt) {
#pragma unroll
        for (int r = 0; r < 4; ++r) {
            const int row = m0 + mt * 16 + quad * 4 + r;
            float v = acc[mt][r];
            if (mode == 0) {
                v += bval;
                if (res) v += res[(size_t)row * N + col];
                ((float*)Cout)[(size_t)row * N + col] = v;
            } else if (mode == 2) {
                int h = col & 7, d = col >> 3;
                ((unsigned short*)Cout)[(((size_t)h << 12) + row) * 64 + d] = f2bf(v * scale);
            } else if (mode == 4) {
                ((unsigned short*)Cout)[(size_t)row * N + col] =
                    f2bf(v + bval + res[(size_t)row * N + col]);
            } else if (mode == 5) {
                v += bval;
                float other = __shfl_xor(v, 1, 64);
                if ((c & 1) == 0) {
                    float g = 0.5f * other * (1.f + erff(other * 0.70710678118654752f));
                    ((unsigned short*)Cout)[(size_t)row * FFI + (col >> 1)] = f2bf(v * g);
                }
            } else if (mode == 6) {
                ((unsigned short*)Cout)[(size_t)row * N + col] = f2bf(v);
                int h = col & 7, d = col >> 3;
                ((unsigned short*)Cout2)[(((size_t)h << 12) + row) * 64 + d] = f2bf(v * scale);
            } else {  // 7
                if (col < 320) {
                    int h = col & 7, d = col >> 3;
                    ((unsigned short*)Cout)[(((size_t)h << 12) + row) * 64 + d] = f2bf(v);
                } else {
                    int c2 = col - 320;
                    int h = c2 & 7, d = c2 >> 3;
                    ((unsigned short*)Cout2)[(((size_t)(h * 48 + d)) << 12) + row] = f2bf(v);
                }
            }
        }
    }
}

// ---------------------------------------------------------------------------
// Context K/V (77 rows) -> packed Kc [h][128][64], Vc [h*48+d][128].
__global__ __launch_bounds__(256) void ctx_kv(
    const float* __restrict__ ctx, const float* __restrict__ wk2,
    const float* __restrict__ wv2, unsigned short* __restrict__ Kc,
    unsigned short* __restrict__ Vc) {
    __shared__ __align__(16) float As[16][68];
    __shared__ __align__(16) float Bs[16][68];
    const int tid = threadIdx.x;
    const int tx = tid & 15, ty = tid >> 4;
    const int bn = blockIdx.x, bm = blockIdx.y;
    const float* B = (blockIdx.z == 0) ? wk2 : wv2;
    float acc[4][4] = {};
    for (int k0 = 0; k0 < 768; k0 += 16) {
#pragma unroll
        for (int i = 0; i < 4; ++i) {
            int idx = tid + i * 256;
            int r = idx >> 4, cc = idx & 15;
            int gm = bm * 64 + r;
            As[cc][r] = (gm < 77) ? ctx[gm * 768 + k0 + cc] : 0.f;
        }
#pragma unroll
        for (int i = 0; i < 4; ++i) {
            int idx = tid + i * 256;
            int r = idx >> 6, cc = idx & 63;
            Bs[r][cc] = B[(k0 + r) * CCH + bn * 64 + cc];
        }
        __syncthreads();
#pragma unroll
        for (int kk = 0; kk < 16; ++kk) {
            float4 a4 = *(const float4*)&As[kk][ty * 4];
            float4 b4 = *(const float4*)&Bs[kk][tx * 4];
            float av[4] = {a4.x, a4.y, a4.z, a4.w};
            float bv[4] = {b4.x, b4.y, b4.z, b4.w};
#pragma unroll
            for (int i = 0; i < 4; ++i)
#pragma unroll
                for (int j = 0; j < 4; ++j) acc[i][j] += av[i] * bv[j];
        }
        __syncthreads();
    }
#pragma unroll
    for (int i = 0; i < 4; ++i) {
        int row = bm * 64 + ty * 4 + i;
#pragma unroll
        for (int j = 0; j < 4; ++j) {
            int col = bn * 64 + tx * 4 + j;
            int h = col & 7, d = col >> 3;
            float v = (row < 77) ? acc[i][j] : 0.f;
            if (blockIdx.z == 0)
                Kc[(((size_t)h << 7) + row) * 64 + d] = f2bf(v);
            else
                Vc[(size_t)(h * 48 + d) * 128 + row] = f2bf(v);
        }
    }
}

// ---------------------------------------------------------------------------
// Set V^T padded dim-40 row to 1.0 so sum(p) materializes in the PV MFMA.
__global__ void set_ones(unsigned short* __restrict__ Vt,
                         unsigned short* __restrict__ Vc) {
    int idx = blockIdx.x * 256 + threadIdx.x;  // grid 132 -> 33792 exact
    if (idx < 32768) {
        int h = idx >> 12, r = idx & 4095;
        Vt[((size_t)(h * 48 + 40) << 12) + r] = 0x3F80;  // bf16(1.0)
    } else {
        int j = idx - 32768;
        int h = j >> 7, r = j & 127;
        Vc[(h * 48 + 40) * 128 + r] = 0x3F80;
    }
}

// ---------------------------------------------------------------------------
// attn7: LDS-staged flash attention, 128 queries/block (32/wave, two
// B-operand Q groups A,B). Same staging/double-buffer as round-8 attn6 —
// but 2x compute per staged tile, so per-tile compute (~28 MFMA + VALU)
// exceeds staging latency. l comes free from V dim-40 == 1 (PV row 40).
template <int TILES, bool MASK>
__global__ __launch_bounds__(256) void attn7(
    const unsigned short* __restrict__ Qp,
    const unsigned short* __restrict__ Kp,
    const unsigned short* __restrict__ Vt,
    float* __restrict__ pO, float* __restrict__ pL,
    int Lk, int Lkp) {
    __shared__ __align__(16) unsigned short Kb[2][64 * 64];
    __shared__ __align__(16) unsigned short Vb[2][48 * 64];
    const int tid  = threadIdx.x;
    const int wave = tid >> 6, lane = tid & 63;
    const int quad = lane >> 4, c = lane & 15;
    const int id  = blockIdx.x;
    const int h   = id & 7;
    const int qt  = (id >> 3) & 31;
    const int seg = id >> 8;
    const int q0  = qt * 128 + wave * 32;

    const unsigned short* qbaseA = Qp + ((((size_t)h << 12) + q0 + c) << 6) + quad * 8;
    const bf16x8 bQA0 = ldfrag(qbaseA);
    const bf16x8 bQA1 = ldfrag(qbaseA + 32);
    const bf16x8 bQB0 = ldfrag(qbaseA + 1024);        // +16 rows * 64
    const bf16x8 bQB1 = ldfrag(qbaseA + 1024 + 32);

    f32x4 oA0 = {0.f, 0.f, 0.f, 0.f}, oA1 = oA0, oA2 = oA0;
    f32x4 oB0 = oA0, oB1 = oA0, oB2 = oA0;
    const int idx0 = ((((quad & 1) * 2 + 0) * 16 + c) << 2);
    const int idx1 = ((((quad & 1) * 2 + 1) * 16 + c) << 2);
    const bool hiQuad = (quad >> 1) != 0;

    const int kt0 = seg * TILES;
    const unsigned short* kglob = Kp + (((size_t)h * Lkp + kt0 * 64) << 6);
    const unsigned short* vglob = Vt + ((size_t)h * 48) * Lkp + kt0 * 64;

    const int r0 = lane >> 3;
    const int g  = lane & 7;
    int ldsoff[4];
    const unsigned short* gptr0[4];
#pragma unroll
    for (int i = 0; i < 4; ++i) {
        int s = wave + 4 * i;
        if (s < 8) {
            int row = s * 8 + r0;
            ldsoff[i] = row * 64 + (g ^ (row & 7)) * 8;
            gptr0[i]  = kglob + (size_t)row * 64 + g * 8;
        } else if (s < 14) {
            int d = (s - 8) * 8 + r0;
            ldsoff[i] = d * 64 + (g ^ (d & 7)) * 8;
            gptr0[i]  = vglob + (size_t)d * Lkp + g * 8;
        } else {
            ldsoff[i] = 0; gptr0[i] = nullptr;
        }
    }
    const bool isK[4] = {(wave + 0) < 8, (wave + 4) < 8, (wave + 8) < 8, (wave + 12) < 8};
    const bool act[4] = {true, true, true, (wave + 12) < 14};

    {
        u16x8 st[4];
#pragma unroll
        for (int i = 0; i < 4; ++i)
            if (act[i]) st[i] = *(const u16x8*)(gptr0[i]);
#pragma unroll
        for (int i = 0; i < 4; ++i)
            if (act[i]) {
                unsigned short* lp = isK[i] ? &Kb[0][ldsoff[i]] : &Vb[0][ldsoff[i]];
                *(u16x8*)lp = st[i];
            }
    }
    __syncthreads();

#pragma unroll
    for (int t = 0; t < TILES; ++t) {
        const int b = t & 1;
        u16x8 st[4];
        if (t + 1 < TILES) {
            const int kb = (t + 1) * 64;
#pragma unroll
            for (int i = 0; i < 4; ++i)
                if (act[i]) {
                    const unsigned short* gp =
                        isK[i] ? (gptr0[i] + (size_t)kb * 64) : (gptr0[i] + kb);
                    st[i] = *(const u16x8*)gp;
                }
        }
        const unsigned short* Kl = &Kb[b][0];
        const unsigned short* Vl = &Vb[b][0];
        const int sw0 = (quad ^ (c & 7)) * 8;
        const int sw1 = ((quad + 4) ^ (c & 7)) * 8;
        // ---- S^T for both query groups ----
        f32x4 sA[4], sB[4];
#pragma unroll
        for (int blk = 0; blk < 4; ++blk) {
            const int row = (blk * 16 + c) * 64;
            bf16x8 k0 = ldfrag(Kl + row + sw0);
            bf16x8 k1 = ldfrag(Kl + row + sw1);
            f32x4 zA = {0.f, 0.f, 0.f, 0.f};
            zA = __builtin_amdgcn_mfma_f32_16x16x32_bf16(k0, bQA0, zA, 0, 0, 0);
            zA = __builtin_amdgcn_mfma_f32_16x16x32_bf16(k1, bQA1, zA, 0, 0, 0);
            sA[blk] = zA;
            f32x4 zB = {0.f, 0.f, 0.f, 0.f};
            zB = __builtin_amdgcn_mfma_f32_16x16x32_bf16(k0, bQB0, zB, 0, 0, 0);
            zB = __builtin_amdgcn_mfma_f32_16x16x32_bf16(k1, bQB1, zB, 0, 0, 0);
            sB[blk] = zB;
        }
        if (MASK) {
            const int abs_kb = kt0 * 64 + t * 64;
#pragma unroll
            for (int blk = 0; blk < 4; ++blk)
#pragma unroll
                for (int r = 0; r < 4; ++r) {
                    bool inv = (abs_kb + blk * 16 + quad * 4 + r >= Lk);
                    sA[blk][r] = inv ? -30000.f : sA[blk][r];
                    sB[blk][r] = inv ? -30000.f : sB[blk][r];
                }
        }
        // ---- p = exp2(s); pack ----
        unsigned pkA[4][2], pkB[4][2];
#pragma unroll
        for (int blk = 0; blk < 4; ++blk) {
            pkA[blk][0] = (unsigned)f2bf(exp2f(sA[blk][0])) |
                          ((unsigned)f2bf(exp2f(sA[blk][1])) << 16);
            pkA[blk][1] = (unsigned)f2bf(exp2f(sA[blk][2])) |
                          ((unsigned)f2bf(exp2f(sA[blk][3])) << 16);
            pkB[blk][0] = (unsigned)f2bf(exp2f(sB[blk][0])) |
                          ((unsigned)f2bf(exp2f(sB[blk][1])) << 16);
            pkB[blk][1] = (unsigned)f2bf(exp2f(sB[blk][2])) |
                          ((unsigned)f2bf(exp2f(sB[blk][3])) << 16);
        }
        // ---- C-layout -> B-layout permutation (both groups) ----
        u32x4 BwA[2], BwB[2];
#pragma unroll
        for (int m = 0; m < 2; ++m) {
            int lo, hi;
            lo = __builtin_amdgcn_ds_bpermute(idx0, (int)pkA[2 * m][0]);
            hi = __builtin_amdgcn_ds_bpermute(idx0, (int)pkA[2 * m + 1][0]);
            BwA[m][0] = (unsigned)(hiQuad ? hi : lo);
            lo = __builtin_amdgcn_ds_bpermute(idx0, (int)pkA[2 * m][1]);
            hi = __builtin_amdgcn_ds_bpermute(idx0, (int)pkA[2 * m + 1][1]);
            BwA[m][1] = (unsigned)(hiQuad ? hi : lo);
            lo = __builtin_amdgcn_ds_bpermute(idx1, (int)pkA[2 * m][0]);
            hi = __builtin_amdgcn_ds_bpermute(idx1, (int)pkA[2 * m + 1][0]);
            BwA[m][2] = (unsigned)(hiQuad ? hi : lo);
            lo = __builtin_amdgcn_ds_bpermute(idx1, (int)pkA[2 * m][1]);
            hi = __builtin_amdgcn_ds_bpermute(idx1, (int)pkA[2 * m + 1][1]);
            BwA[m][3] = (unsigned)(hiQuad ? hi : lo);
            lo = __builtin_amdgcn_ds_bpermute(idx0, (int)pkB[2 * m][0]);
            hi = __builtin_amdgcn_ds_bpermute(idx0, (int)pkB[2 * m + 1][0]);
            BwB[m][0] = (unsigned)(hiQuad ? hi : lo);
            lo = __builtin_amdgcn_ds_bpermute(idx0, (int)pkB[2 * m][1]);
            hi = __builtin_amdgcn_ds_bpermute(idx0, (int)pkB[2 * m + 1][1]);
            BwB[m][1] = (unsigned)(hiQuad ? hi : lo);
            lo = __builtin_amdgcn_ds_bpermute(idx1, (int)pkB[2 * m][0]);
            hi = __builtin_amdgcn_ds_bpermute(idx1, (int)pkB[2 * m + 1][0]);
            BwB[m][2] = (unsigned)(hiQuad ? hi : lo);
            lo = __builtin_amdgcn_ds_bpermute(idx1, (int)pkB[2 * m][1]);
            hi = __builtin_amdgcn_ds_bpermute(idx1, (int)pkB[2 * m + 1][1]);
            BwB[m][3] = (unsigned)(hiQuad ? hi : lo);
        }
        bf16x8 PA0 = __builtin_bit_cast(bf16x8, BwA[0]);
        bf16x8 PA1 = __builtin_bit_cast(bf16x8, BwA[1]);
        bf16x8 PB0 = __builtin_bit_cast(bf16x8, BwB[0]);
        bf16x8 PB1 = __builtin_bit_cast(bf16x8, BwB[1]);
        // ---- O^T += V^T · P^T (both groups; V frags loaded just-in-time) ----
        {
            bf16x8 v0 = ldfrag(Vl + (0 * 16 + c) * 64 + sw0);
            bf16x8 v1 = ldfrag(Vl + (0 * 16 + c) * 64 + sw1);
            oA0 = __builtin_amdgcn_mfma_f32_16x16x32_bf16(v0, PA0, oA0, 0, 0, 0);
            oA0 = __builtin_amdgcn_mfma_f32_16x16x32_bf16(v1, PA1, oA0, 0, 0, 0);
            oB0 = __builtin_amdgcn_mfma_f32_16x16x32_bf16(v0, PB0, oB0, 0, 0, 0);
            oB0 = __builtin_amdgcn_mfma_f32_16x16x32_bf16(v1, PB1, oB0, 0, 0, 0);
        }
        {
            bf16x8 v0 = ldfrag(Vl + (1 * 16 + c) * 64 + sw0);
            bf16x8 v1 = ldfrag(Vl + (1 * 16 + c) * 64 + sw1);
            oA1 = __builtin_amdgcn_mfma_f32_16x16x32_bf16(v0, PA0, oA1, 0, 0, 0);
            oA1 = __builtin_amdgcn_mfma_f32_16x16x32_bf16(v1, PA1, oA1, 0, 0, 0);
            oB1 = __builtin_amdgcn_mfma_f32_16x16x32_bf16(v0, PB0, oB1, 0, 0, 0);
            oB1 = __builtin_amdgcn_mfma_f32_16x16x32_bf16(v1, PB1, oB1, 0, 0, 0);
        }
        {
            bf16x8 v0 = ldfrag(Vl + (2 * 16 + c) * 64 + sw0);
            bf16x8 v1 = ldfrag(Vl + (2 * 16 + c) * 64 + sw1);
            oA2 = __builtin_amdgcn_mfma_f32_16x16x32_bf16(v0, PA0, oA2, 0, 0, 0);
            oA2 = __builtin_amdgcn_mfma_f32_16x16x32_bf16(v1, PA1, oA2, 0, 0, 0);
            oB2 = __builtin_amdgcn_mfma_f32_16x16x32_bf16(v0, PB0, oB2, 0, 0, 0);
            oB2 = __builtin_amdgcn_mfma_f32_16x16x32_bf16(v1, PB1, oB2, 0, 0, 0);
        }
        if (t + 1 < TILES) {
            const int nb = b ^ 1;
#pragma unroll
            for (int i = 0; i < 4; ++i)
                if (act[i]) {
                    unsigned short* lp = isK[i] ? &Kb[nb][ldsoff[i]] : &Vb[nb][ldsoff[i]];
                    *(u16x8*)lp = st[i];
                }
        }
        __syncthreads();
    }
    // epilogue: dims 0..39 per query; l = PV row 40 = oX2[0] at quad==2
    const size_t base = ((size_t)(seg * 8 + h)) << 12;
    float* obA = pO + (base + q0 + c) * 40;
    *(float4*)(obA + quad * 4)      = make_float4(oA0[0], oA0[1], oA0[2], oA0[3]);
    *(float4*)(obA + 16 + quad * 4) = make_float4(oA1[0], oA1[1], oA1[2], oA1[3]);
    if (quad < 2)
        *(float4*)(obA + 32 + quad * 4) = make_float4(oA2[0], oA2[1], oA2[2], oA2[3]);
    float* obB = pO + (base + q0 + 16 + c) * 40;
    *(float4*)(obB + quad * 4)      = make_float4(oB0[0], oB0[1], oB0[2], oB0[3]);
    *(float4*)(obB + 16 + quad * 4) = make_float4(oB1[0], oB1[1], oB1[2], oB1[3]);
    if (quad < 2)
        *(float4*)(obB + 32 + quad * 4) = make_float4(oB2[0], oB2[1], oB2[2], oB2[3]);
    if (quad == 2) {
        pL[base + q0 + c]      = oA2[0];   // dim 40 = sum(p)
        pL[base + q0 + 16 + c] = oB2[0];
    }
}

// Combine partials across S segments -> bf16 O (HW,320), col = h*40+d.
__global__ __launch_bounds__(256) void attn_combine(
    const float* __restrict__ pO, const float* __restrict__ pL,
    unsigned short* __restrict__ O, int S) {
    int idx = blockIdx.x * 256 + threadIdx.x;  // < 8*4096*40, grid 5120
    int h = idx / (HW * 40);
    int rem = idx - h * (HW * 40);
    int row = rem / 40, d = rem - row * 40;
    float num = 0.f, den = 0.f;
    for (int s = 0; s < S; ++s) {
        size_t base = ((size_t)(s * 8 + h)) << 12;
        num += pO[(base + row) * 40 + d];
        den += pL[base + row];
    }
    O[(size_t)row * CCH + h * DH + d] = f2bf(num / den);
}

// ---------------------------------------------------------------------------
__global__ void final_kernel(const float* __restrict__ Yv,
                             const float* __restrict__ X,
                             float* __restrict__ Out) {
    int idx = blockIdx.x * 256 + threadIdx.x;
    int o = idx >> 12, hw = idx & 4095;
    Out[idx] = Yv[hw * CCH + o] + X[idx];
}

// ---------------------------------------------------------------------------
extern "C" void kernel_launch(void* const* d_in, const int* in_sizes, int n_in,
                              void* d_out, int out_size, void* d_ws, size_t ws_size,
                              hipStream_t stream) {
    const float* x     = (const float*)d_in[0];
    const float* ctx   = (const float*)d_in[1];
    const float* gn_w  = (const float*)d_in[2];
    const float* gn_b  = (const float*)d_in[3];
    const float* w_in  = (const float*)d_in[4];
    const float* b_in  = (const float*)d_in[5];
    const float* ln1_w = (const float*)d_in[6];
    const float* ln1_b = (const float*)d_in[7];
    const float* wq1   = (const float*)d_in[8];
    const float* wk1   = (const float*)d_in[9];
    const float* wv1   = (const float*)d_in[10];
    const float* wo1   = (const float*)d_in[11];
    const float* bo1   = (const float*)d_in[12];
    const float* ln2_w = (const float*)d_in[13];
    const float* ln2_b = (const float*)d_in[14];
    const float* wq2   = (const float*)d_in[15];
    const float* wk2   = (const float*)d_in[16];
    const float* wv2   = (const float*)d_in[17];
    const float* wo2   = (const float*)d_in[18];
    const float* bo2   = (const float*)d_in[19];
    const float* ln3_w = (const float*)d_in[20];
    const float* ln3_b = (const float*)d_in[21];
    const float* wff1  = (const float*)d_in[22];
    const float* bff1  = (const float*)d_in[23];
    const float* wff2  = (const float*)d_in[24];
    const float* bff2  = (const float*)d_in[25];
    const float* w_out = (const float*)d_in[26];
    const float* b_out = (const float*)d_in[27];
    float* out = (float*)d_out;

    const int NT = HW * CCH;  // 1,310,720
    float* ws = (float*)d_ws;
    float* t_   = ws;
    float* y_   = t_ + NT;
    float* pO   = y_ + NT;
    float* pL   = pO + 4 * 8 * 4096 * 40;
    float2* gnp = (float2*)(pL + 4 * 8 * 4096);
    unsigned short* u = (unsigned short*)(gnp + 256);
    unsigned short* a_bf = u;                  u += NT;
    unsigned short* q_bf = u;                  u += NT;
    unsigned short* o_bf = u;                  u += NT;
    unsigned short* t_bf = u;                  u += NT;
    unsigned short* g_bf = u;                  u += HW * FFI;
    unsigned short* Qp   = u;                  u += 8 * 4096 * 64;
    unsigned short* Kp   = u;                  u += 8 * 4096 * 64;
    unsigned short* Vt   = u;                  u += 8 * 48 * 4096;
    unsigned short* Kc   = u;                  u += 8 * 128 * 64;
    unsigned short* Vc   = u;                  u += 8 * 48 * 128;
    unsigned short* Wt   = u;                  u += 2048000;

    const unsigned short* w_inT  = Wt;
    const unsigned short* wq1T   = Wt + 102400;
    const unsigned short* wk1T   = Wt + 204800;  // wv1T contiguous at +307200
    const unsigned short* wo1T   = Wt + 409600;
    const unsigned short* wq2T   = Wt + 512000;
    const unsigned short* wo2T   = Wt + 614400;
    const unsigned short* w_outT = Wt + 716800;
    const unsigned short* wff1T  = Wt + 819200;
    const unsigned short* wff2T  = Wt + 1638400;

    const float qscale = 0.15811388300841897f * 1.4426950408889634f;  // 40^-.5 * log2e

    prep_w2<<<500, 256, 0, stream>>>(w_in, wq1, wk1, wv1, wo1, wq2, wo2, w_out,
                                     wff1, wff2, Wt);
    hipMemsetAsync(Qp, 0,
                   (size_t)(8 * 4096 * 64 * 2 + 8 * 48 * 4096 + 8 * 128 * 64 + 8 * 48 * 128) * 2,
                   stream);
    set_ones<<<132, 256, 0, stream>>>(Vt, Vc);

    // 1) GroupNorm -> a_bf (HW,C)
    gn_stats<<<256, 256, 0, stream>>>(x, gnp);
    gn_apply<<<dim3(64, 5), 256, 0, stream>>>(x, gnp, gn_w, gn_b, a_bf);
    // 2) proj_in: t = a @ w_in + b_in (fp32)
    gemm4<2, 320><<<dim3(5, 128), 256, 0, stream>>>(a_bf, w_inT, b_in, nullptr, t_, nullptr, CCH, 0, 1.f);
    // 3) ln1 -> a_bf
    ln_kernel<<<1024, 256, 0, stream>>>(t_, ln1_w, ln1_b, a_bf);
    // 4) q (dual); k&v in one N=640 dispatch
    gemm4<2, 320><<<dim3(5, 128), 256, 0, stream>>>(a_bf, wq1T, nullptr, nullptr, q_bf, Qp, CCH, 6, qscale);
    gemm4<2, 320><<<dim3(10, 128), 256, 0, stream>>>(q_bf, wk1T, nullptr, nullptr, Kp, Vt, 640, 7, 1.f);
    // 5) self-attention: 128 queries/block, 4 segs, XCD swizzle
    attn7<16, false><<<1024, 256, 0, stream>>>(Qp, Kp, Vt, pO, pL, HW, HW);
    attn_combine<<<5120, 256, 0, stream>>>(pO, pL, o_bf, 4);
    // 6) t += o @ wo1 + bo1
    gemm4<2, 320><<<dim3(5, 128), 256, 0, stream>>>(o_bf, wo1T, bo1, t_, t_, nullptr, CCH, 0, 1.f);
    // 7) ln2 -> a_bf
    ln_kernel<<<1024, 256, 0, stream>>>(t_, ln2_w, ln2_b, a_bf);
    // 8) cross q -> Qp; ctx K/V packed directly
    gemm4<2, 320><<<dim3(5, 128), 256, 0, stream>>>(a_bf, wq2T, nullptr, nullptr, Qp, nullptr, CCH, 2, qscale);
    ctx_kv<<<dim3(5, 2, 2), 256, 0, stream>>>(ctx, wk2, wv2, Kc, Vc);
    // 9) cross-attention (Lk=77, 1 seg of 2 tiles, masked)
    attn7<2, true><<<256, 256, 0, stream>>>(Qp, Kc, Vc, pO, pL, 77, 128);
    attn_combine<<<5120, 256, 0, stream>>>(pO, pL, o_bf, 1);
    // 10) t += o @ wo2 + bo2
    gemm4<2, 320><<<dim3(5, 128), 256, 0, stream>>>(o_bf, wo2T, bo2, t_, t_, nullptr, CCH, 0, 1.f);
    // 11) ln3 -> a_bf
    ln_kernel<<<1024, 256, 0, stream>>>(t_, ln3_w, ln3_b, a_bf);
    // 12+13) FF1 with fused GEGLU -> g_bf
    gemm4<2, 320><<<dim3(40, 128), 256, 0, stream>>>(a_bf, wff1T, bff1, nullptr, g_bf, nullptr, 2 * FFI, 5, 1.f);
    // 14) t_bf = bf16(t + g @ wff2 + bff2)
    gemm4<2, 1280><<<dim3(5, 128), 256, 0, stream>>>(g_bf, wff2T, bff2, t_, t_bf, nullptr, CCH, 4, 1.f);
    // 15) y = t_bf @ w_out + b_out (fp32)
    gemm4<2, 320><<<dim3(5, 128), 256, 0, stream>>>(t_bf, w_outT, b_out, nullptr, y_, nullptr, CCH, 0, 1.f);
    // 16) out = y^T + x
    final_kernel<<<5120, 256, 0, stream>>>(y_, x, out);
}

// Round 12
// 345.912 us; speedup vs baseline: 6.8377x; 1.1807x over previous
//
#include <hip/hip_runtime.h>
#include <hip/hip_bf16.h>
#include <math.h>

#define CCH 320
#define NHEADS 8
#define DH 40
#define HW 4096
#define FFI 1280

typedef __bf16 bf16x8 __attribute__((ext_vector_type(8)));
typedef unsigned short u16x8 __attribute__((ext_vector_type(8)));
typedef float f32x4 __attribute__((ext_vector_type(4)));
typedef unsigned int u32x4 __attribute__((ext_vector_type(4)));

__device__ inline unsigned short f2bf(float f) {
    __hip_bfloat16 h = __float2bfloat16(f);
    return __builtin_bit_cast(unsigned short, h);
}
__device__ inline float bf2f(unsigned short u) {
    return __builtin_bit_cast(float, ((unsigned)u) << 16);
}
__device__ inline bf16x8 ldfrag(const unsigned short* p) {
    u16x8 raw = *reinterpret_cast<const u16x8*>(p);
    return __builtin_bit_cast(bf16x8, raw);
}

// ---------------------------------------------------------------------------
// Coalesced weight transpose via LDS 64x65 tiles. 620 tiles:
// 8 squares (200), wff2 (100), wff1-GLU (200), wk2T (60), wv2T (60).
__global__ __launch_bounds__(256) void prep_w2(
    const float* __restrict__ w_in, const float* __restrict__ wq1,
    const float* __restrict__ wk1, const float* __restrict__ wv1,
    const float* __restrict__ wo1, const float* __restrict__ wq2,
    const float* __restrict__ wo2, const float* __restrict__ w_out,
    const float* __restrict__ wff1, const float* __restrict__ wff2,
    const float* __restrict__ wk2, const float* __restrict__ wv2,
    unsigned short* __restrict__ Wt) {
    __shared__ float tile[64][65];
    const int b = blockIdx.x, tid = threadIdx.x;
    const float* src;
    int K, stride, dstoff, k0, n0;
    bool glu = false;
    if (b < 200) {
        int m = b / 25, t = b % 25;
        k0 = (t / 5) * 64; n0 = (t % 5) * 64;
        K = 320; stride = 320; dstoff = m * 102400;
        src = (m == 0) ? w_in : (m == 1) ? wq1 : (m == 2) ? wk1 :
              (m == 3) ? wv1 : (m == 4) ? wo1 : (m == 5) ? wq2 :
              (m == 6) ? wo2 : w_out;
    } else if (b < 300) {
        int t = b - 200;
        k0 = (t / 5) * 64; n0 = (t % 5) * 64;
        K = 1280; stride = 320; dstoff = 1638400; src = wff2;
    } else if (b < 500) {
        int t = b - 300;
        k0 = (t / 40) * 64; n0 = (t % 40) * 64;
        K = 320; stride = 2560; dstoff = 819200; src = wff1; glu = true;
    } else if (b < 560) {
        int t = b - 500;
        k0 = (t / 5) * 64; n0 = (t % 5) * 64;
        K = 768; stride = 320; dstoff = 2048000; src = wk2;
    } else {
        int t = b - 560;
        k0 = (t / 5) * 64; n0 = (t % 5) * 64;
        K = 768; stride = 320; dstoff = 2048000 + 245760; src = wv2;
    }
#pragma unroll
    for (int i = 0; i < 16; ++i) {
        int idx = tid + i * 256;
        int r = idx >> 6, cn = idx & 63;
        int scol = glu ? ((n0 >> 1) + (cn >> 1) + (cn & 1) * FFI) : (n0 + cn);
        tile[r][cn] = src[(size_t)(k0 + r) * stride + scol];
    }
    __syncthreads();
#pragma unroll
    for (int i = 0; i < 16; ++i) {
        int idx = tid + i * 256;
        int cl = idx >> 6, cr = idx & 63;
        Wt[dstoff + (size_t)(n0 + cl) * K + k0 + cr] = f2bf(tile[cr][cl]);
    }
}

// ---------------------------------------------------------------------------
// ctx (77x768 fp32) -> bf16 (128x768), rows >= 77 zeroed.
__global__ void pack_ctx(const float* __restrict__ ctx,
                         unsigned short* __restrict__ D) {
    int idx = blockIdx.x * 256 + threadIdx.x;  // grid 384 -> 98304 exact
    int row = idx / 768, col = idx - row * 768;
    float v = (row < 77) ? ctx[row * 768 + col] : 0.f;
    D[idx] = f2bf(v);
}

// ---------------------------------------------------------------------------
__global__ __launch_bounds__(256) void gn_stats(const float* __restrict__ X,
                                                float2* __restrict__ part) {
    __shared__ float s1[256], s2[256];
    const int b = blockIdx.x, tid = threadIdx.x;
    const float* xg = X + b * 5120;
    float s = 0.f, sq = 0.f;
#pragma unroll
    for (int i = 0; i < 20; ++i) { float v = xg[tid + i * 256]; s += v; sq += v * v; }
    s1[tid] = s; s2[tid] = sq; __syncthreads();
    for (int off = 128; off > 0; off >>= 1) {
        if (tid < off) { s1[tid] += s1[tid + off]; s2[tid] += s2[tid + off]; }
        __syncthreads();
    }
    if (tid == 0) part[b] = make_float2(s1[0], s2[0]);
}

__global__ __launch_bounds__(256) void gn_apply(const float* __restrict__ X,
                                                const float2* __restrict__ part,
                                                const float* __restrict__ w,
                                                const float* __restrict__ b,
                                                unsigned short* __restrict__ Y) {
    __shared__ float tile[64][65];
    __shared__ float gm[32], gr[32];
    const int tid = threadIdx.x;
    const int hw0 = blockIdx.x * 64, c0 = blockIdx.y * 64;
    if (tid < 32) {
        float s = 0.f, sq = 0.f;
#pragma unroll
        for (int i = 0; i < 8; ++i) { float2 p = part[tid * 8 + i]; s += p.x; sq += p.y; }
        float mean = s * (1.f / 40960.f);
        float var  = sq * (1.f / 40960.f) - mean * mean;
        gm[tid] = mean; gr[tid] = rsqrtf(var + 1e-6f);
    }
#pragma unroll
    for (int i = 0; i < 16; ++i) {
        int idx = tid + i * 256;
        int r = idx >> 6, col = idx & 63;
        tile[r][col] = X[(size_t)(c0 + r) * HW + hw0 + col];
    }
    __syncthreads();
#pragma unroll
    for (int i = 0; i < 16; ++i) {
        int idx = tid + i * 256;
        int hwl = idx >> 6, cl = idx & 63;
        int c = c0 + cl, g = c / 10;
        float v = (tile[cl][hwl] - gm[g]) * gr[g] * w[c] + b[c];
        Y[(size_t)(hw0 + hwl) * CCH + c] = f2bf(v);
    }
}

// ---------------------------------------------------------------------------
__global__ __launch_bounds__(256) void ln_kernel(const float* __restrict__ X,
                                                 const float* __restrict__ w,
                                                 const float* __restrict__ b,
                                                 unsigned short* __restrict__ Y) {
    const int row  = blockIdx.x * 4 + (threadIdx.x >> 6);
    const int lane = threadIdx.x & 63;
    const float* xr = X + row * CCH;
    float v[5];
    float s = 0.f, sq = 0.f;
#pragma unroll
    for (int i = 0; i < 5; ++i) { v[i] = xr[lane + 64 * i]; s += v[i]; sq += v[i] * v[i]; }
#pragma unroll
    for (int off = 32; off > 0; off >>= 1) {
        s  += __shfl_xor(s, off, 64);
        sq += __shfl_xor(sq, off, 64);
    }
    const float mean = s * (1.f / 320.f);
    const float var  = sq * (1.f / 320.f) - mean * mean;
    const float rstd = rsqrtf(var + 1e-5f);
    unsigned short* yr = Y + row * CCH;
#pragma unroll
    for (int i = 0; i < 5; ++i) {
        int c = lane + 64 * i;
        yr[c] = f2bf((v[i] - mean) * rstd * w[c] + b[c]);
    }
}

// ---------------------------------------------------------------------------
// gemm4 (round-9 proven double-buffer GEMM).
// Modes: 0 fp32+bias(+res) | 2 QK-pack*scale | 4 bf16+bias+res |
//        5 GLU-interleaved | 6 dual bf16+QK-pack | 7 kv-merged (Lkp=4096) |
//        8 ctx kv-merged (Lkp=128)
template <int MT, int K>
__global__ __launch_bounds__(256) void gemm4(
    const unsigned short* __restrict__ A,
    const unsigned short* __restrict__ Bt,
    const float* __restrict__ bias,
    const float* __restrict__ res,
    void* __restrict__ Cout, void* __restrict__ Cout2,
    int N, int mode, float scale) {
    constexpr int NCH = K / 64;
    __shared__ __align__(16) unsigned short Ab[2][MT * 16 * 64];
    __shared__ __align__(16) unsigned short Bb[2][64 * 64];
    const int tid  = threadIdx.x;
    const int wave = tid >> 6, lane = tid & 63;
    const int quad = lane >> 4, c = lane & 15;
    const int m0 = blockIdx.y * (MT * 16);
    const int bn = blockIdx.x;

    f32x4 acc[MT];
#pragma unroll
    for (int i = 0; i < MT; ++i) acc[i] = (f32x4){0.f, 0.f, 0.f, 0.f};

    const unsigned short* aslab = A + (size_t)m0 * K;
    const unsigned short* bslab = Bt + (size_t)(bn * 64) * K;

    constexpr int ITA = MT * 16 * 8 / 256;
    int arow[ITA], aoff[ITA];
#pragma unroll
    for (int i = 0; i < ITA; ++i) {
        int idx = tid + i * 256;
        arow[i] = idx >> 3;
        int g = idx & 7;
        aoff[i] = arow[i] * 64 + ((g ^ (arow[i] & 7)) * 8);
    }
    int brow[2], boff[2];
#pragma unroll
    for (int i = 0; i < 2; ++i) {
        int idx = tid + i * 256;
        brow[i] = idx >> 3;
        int g = idx & 7;
        boff[i] = brow[i] * 64 + ((g ^ (brow[i] & 7)) * 8);
    }
    const int ag = (tid & 7) * 8;

    {
        u16x8 ra[ITA], rb[2];
#pragma unroll
        for (int i = 0; i < ITA; ++i)
            ra[i] = *(const u16x8*)(aslab + (size_t)arow[i] * K + ag);
#pragma unroll
        for (int i = 0; i < 2; ++i)
            rb[i] = *(const u16x8*)(bslab + (size_t)brow[i] * K + ag);
#pragma unroll
        for (int i = 0; i < ITA; ++i) *(u16x8*)&Ab[0][aoff[i]] = ra[i];
#pragma unroll
        for (int i = 0; i < 2; ++i) *(u16x8*)&Bb[0][boff[i]] = rb[i];
    }
    __syncthreads();

    const int swz0 = (quad ^ (c & 7)) * 8;
    const int swz1 = ((quad + 4) ^ (c & 7)) * 8;
#pragma unroll
    for (int ch = 0; ch < NCH; ++ch) {
        const int buf = ch & 1;
        u16x8 ra[ITA], rb[2];
        if (ch + 1 < NCH) {
            const int kb = (ch + 1) * 64;
#pragma unroll
            for (int i = 0; i < ITA; ++i)
                ra[i] = *(const u16x8*)(aslab + (size_t)arow[i] * K + kb + ag);
#pragma unroll
            for (int i = 0; i < 2; ++i)
                rb[i] = *(const u16x8*)(bslab + (size_t)brow[i] * K + kb + ag);
        }
        bf16x8 b0 = ldfrag(&Bb[buf][(wave * 16 + c) * 64 + swz0]);
        bf16x8 b1 = ldfrag(&Bb[buf][(wave * 16 + c) * 64 + swz1]);
#pragma unroll
        for (int mt = 0; mt < MT; ++mt) {
            bf16x8 a0 = ldfrag(&Ab[buf][(mt * 16 + c) * 64 + swz0]);
            bf16x8 a1 = ldfrag(&Ab[buf][(mt * 16 + c) * 64 + swz1]);
            acc[mt] = __builtin_amdgcn_mfma_f32_16x16x32_bf16(a0, b0, acc[mt], 0, 0, 0);
            acc[mt] = __builtin_amdgcn_mfma_f32_16x16x32_bf16(a1, b1, acc[mt], 0, 0, 0);
        }
        if (ch + 1 < NCH) {
            const int nb = buf ^ 1;
#pragma unroll
            for (int i = 0; i < ITA; ++i) *(u16x8*)&Ab[nb][aoff[i]] = ra[i];
#pragma unroll
            for (int i = 0; i < 2; ++i) *(u16x8*)&Bb[nb][boff[i]] = rb[i];
        }
        __syncthreads();
    }

    const int col = bn * 64 + wave * 16 + c;
    float bval = 0.f;
    if (bias) bval = (mode == 5) ? bias[(col >> 1) + (col & 1) * FFI] : bias[col];
#pragma unroll
    for (int mt = 0; mt < MT; ++mt) {
#pragma unroll
        for (int r = 0; r < 4; ++r) {
            const int row = m0 + mt * 16 + quad * 4 + r;
            float v = acc[mt][r];
            if (mode == 0) {
                v += bval;
                if (res) v += res[(size_t)row * N + col];
                ((float*)Cout)[(size_t)row * N + col] = v;
            } else if (mode == 2) {
                int h = col & 7, d = col >> 3;
                ((unsigned short*)Cout)[(((size_t)h << 12) + row) * 64 + d] = f2bf(v * scale);
            } else if (mode == 4) {
                ((unsigned short*)Cout)[(size_t)row * N + col] =
                    f2bf(v + bval + res[(size_t)row * N + col]);
            } else if (mode == 5) {
                v += bval;
                float other = __shfl_xor(v, 1, 64);
                if ((c & 1) == 0) {
                    float g = 0.5f * other * (1.f + erff(other * 0.70710678118654752f));
                    ((unsigned short*)Cout)[(size_t)row * FFI + (col >> 1)] = f2bf(v * g);
                }
            } else if (mode == 6) {
                ((unsigned short*)Cout)[(size_t)row * N + col] = f2bf(v);
                int h = col & 7, d = col >> 3;
                ((unsigned short*)Cout2)[(((size_t)h << 12) + row) * 64 + d] = f2bf(v * scale);
            } else if (mode == 7) {
                if (col < 320) {
                    int h = col & 7, d = col >> 3;
                    ((unsigned short*)Cout)[(((size_t)h << 12) + row) * 64 + d] = f2bf(v);
                } else {
                    int c2 = col - 320;
                    int h = c2 & 7, d = c2 >> 3;
                    ((unsigned short*)Cout2)[(((size_t)(h * 48 + d)) << 12) + row] = f2bf(v);
                }
            } else {  // 8: ctx kv-merged, Lkp = 128
                if (col < 320) {
                    int h = col & 7, d = col >> 3;
                    ((unsigned short*)Cout)[(((size_t)h << 7) + row) * 64 + d] = f2bf(v);
                } else {
                    int c2 = col - 320;
                    int h = c2 & 7, d = c2 >> 3;
                    ((unsigned short*)Cout2)[(size_t)(h * 48 + d) * 128 + row] = f2bf(v);
                }
            }
        }
    }
}

// ---------------------------------------------------------------------------
// Set V^T padded dim-40 row to 1.0 so sum(p) materializes in the PV MFMA.
__global__ void set_ones(unsigned short* __restrict__ Vt,
                         unsigned short* __restrict__ Vc) {
    int idx = blockIdx.x * 256 + threadIdx.x;  // grid 132 -> 33792 exact
    if (idx < 32768) {
        int h = idx >> 12, r = idx & 4095;
        Vt[((size_t)(h * 48 + 40) << 12) + r] = 0x3F80;  // bf16(1.0)
    } else {
        int j = idx - 32768;
        int h = j >> 7, r = j & 127;
        Vc[(h * 48 + 40) * 128 + r] = 0x3F80;
    }
}

// ---------------------------------------------------------------------------
// attn7: LDS-staged flash attention, 128 queries/block (round-10 version).
template <int TILES, bool MASK>
__global__ __launch_bounds__(256) void attn7(
    const unsigned short* __restrict__ Qp,
    const unsigned short* __restrict__ Kp,
    const unsigned short* __restrict__ Vt,
    float* __restrict__ pO, float* __restrict__ pL,
    int Lk, int Lkp) {
    __shared__ __align__(16) unsigned short Kb[2][64 * 64];
    __shared__ __align__(16) unsigned short Vb[2][48 * 64];
    const int tid  = threadIdx.x;
    const int wave = tid >> 6, lane = tid & 63;
    const int quad = lane >> 4, c = lane & 15;
    const int id  = blockIdx.x;
    const int h   = id & 7;
    const int qt  = (id >> 3) & 31;
    const int seg = id >> 8;
    const int q0  = qt * 128 + wave * 32;

    const unsigned short* qbaseA = Qp + ((((size_t)h << 12) + q0 + c) << 6) + quad * 8;
    const bf16x8 bQA0 = ldfrag(qbaseA);
    const bf16x8 bQA1 = ldfrag(qbaseA + 32);
    const bf16x8 bQB0 = ldfrag(qbaseA + 1024);
    const bf16x8 bQB1 = ldfrag(qbaseA + 1024 + 32);

    f32x4 oA0 = {0.f, 0.f, 0.f, 0.f}, oA1 = oA0, oA2 = oA0;
    f32x4 oB0 = oA0, oB1 = oA0, oB2 = oA0;
    const int idx0 = ((((quad & 1) * 2 + 0) * 16 + c) << 2);
    const int idx1 = ((((quad & 1) * 2 + 1) * 16 + c) << 2);
    const bool hiQuad = (quad >> 1) != 0;

    const int kt0 = seg * TILES;
    const unsigned short* kglob = Kp + (((size_t)h * Lkp + kt0 * 64) << 6);
    const unsigned short* vglob = Vt + ((size_t)h * 48) * Lkp + kt0 * 64;

    const int r0 = lane >> 3;
    const int g  = lane & 7;
    int ldsoff[4];
    const unsigned short* gptr0[4];
#pragma unroll
    for (int i = 0; i < 4; ++i) {
        int s = wave + 4 * i;
        if (s < 8) {
            int row = s * 8 + r0;
            ldsoff[i] = row * 64 + (g ^ (row & 7)) * 8;
            gptr0[i]  = kglob + (size_t)row * 64 + g * 8;
        } else if (s < 14) {
            int d = (s - 8) * 8 + r0;
            ldsoff[i] = d * 64 + (g ^ (d & 7)) * 8;
            gptr0[i]  = vglob + (size_t)d * Lkp + g * 8;
        } else {
            ldsoff[i] = 0; gptr0[i] = nullptr;
        }
    }
    const bool isK[4] = {(wave + 0) < 8, (wave + 4) < 8, (wave + 8) < 8, (wave + 12) < 8};
    const bool act[4] = {true, true, true, (wave + 12) < 14};

    {
        u16x8 st[4];
#pragma unroll
        for (int i = 0; i < 4; ++i)
            if (act[i]) st[i] = *(const u16x8*)(gptr0[i]);
#pragma unroll
        for (int i = 0; i < 4; ++i)
            if (act[i]) {
                unsigned short* lp = isK[i] ? &Kb[0][ldsoff[i]] : &Vb[0][ldsoff[i]];
                *(u16x8*)lp = st[i];
            }
    }
    __syncthreads();

#pragma unroll
    for (int t = 0; t < TILES; ++t) {
        const int b = t & 1;
        u16x8 st[4];
        if (t + 1 < TILES) {
            const int kb = (t + 1) * 64;
#pragma unroll
            for (int i = 0; i < 4; ++i)
                if (act[i]) {
                    const unsigned short* gp =
                        isK[i] ? (gptr0[i] + (size_t)kb * 64) : (gptr0[i] + kb);
                    st[i] = *(const u16x8*)gp;
                }
        }
        const unsigned short* Kl = &Kb[b][0];
        const unsigned short* Vl = &Vb[b][0];
        const int sw0 = (quad ^ (c & 7)) * 8;
        const int sw1 = ((quad + 4) ^ (c & 7)) * 8;
        f32x4 sA[4], sB[4];
#pragma unroll
        for (int blk = 0; blk < 4; ++blk) {
            const int row = (blk * 16 + c) * 64;
            bf16x8 k0 = ldfrag(Kl + row + sw0);
            bf16x8 k1 = ldfrag(Kl + row + sw1);
            f32x4 zA = {0.f, 0.f, 0.f, 0.f};
            zA = __builtin_amdgcn_mfma_f32_16x16x32_bf16(k0, bQA0, zA, 0, 0, 0);
            zA = __builtin_amdgcn_mfma_f32_16x16x32_bf16(k1, bQA1, zA, 0, 0, 0);
            sA[blk] = zA;
            f32x4 zB = {0.f, 0.f, 0.f, 0.f};
            zB = __builtin_amdgcn_mfma_f32_16x16x32_bf16(k0, bQB0, zB, 0, 0, 0);
            zB = __builtin_amdgcn_mfma_f32_16x16x32_bf16(k1, bQB1, zB, 0, 0, 0);
            sB[blk] = zB;
        }
        if (MASK) {
            const int abs_kb = kt0 * 64 + t * 64;
#pragma unroll
            for (int blk = 0; blk < 4; ++blk)
#pragma unroll
                for (int r = 0; r < 4; ++r) {
                    bool inv = (abs_kb + blk * 16 + quad * 4 + r >= Lk);
                    sA[blk][r] = inv ? -30000.f : sA[blk][r];
                    sB[blk][r] = inv ? -30000.f : sB[blk][r];
                }
        }
        unsigned pkA[4][2], pkB[4][2];
#pragma unroll
        for (int blk = 0; blk < 4; ++blk) {
            pkA[blk][0] = (unsigned)f2bf(exp2f(sA[blk][0])) |
                          ((unsigned)f2bf(exp2f(sA[blk][1])) << 16);
            pkA[blk][1] = (unsigned)f2bf(exp2f(sA[blk][2])) |
                          ((unsigned)f2bf(exp2f(sA[blk][3])) << 16);
            pkB[blk][0] = (unsigned)f2bf(exp2f(sB[blk][0])) |
                          ((unsigned)f2bf(exp2f(sB[blk][1])) << 16);
            pkB[blk][1] = (unsigned)f2bf(exp2f(sB[blk][2])) |
                          ((unsigned)f2bf(exp2f(sB[blk][3])) << 16);
        }
        u32x4 BwA[2], BwB[2];
#pragma unroll
        for (int m = 0; m < 2; ++m) {
            int lo, hi;
            lo = __builtin_amdgcn_ds_bpermute(idx0, (int)pkA[2 * m][0]);
            hi = __builtin_amdgcn_ds_bpermute(idx0, (int)pkA[2 * m + 1][0]);
            BwA[m][0] = (unsigned)(hiQuad ? hi : lo);
            lo = __builtin_amdgcn_ds_bpermute(idx0, (int)pkA[2 * m][1]);
            hi = __builtin_amdgcn_ds_bpermute(idx0, (int)pkA[2 * m + 1][1]);
            BwA[m][1] = (unsigned)(hiQuad ? hi : lo);
            lo = __builtin_amdgcn_ds_bpermute(idx1, (int)pkA[2 * m][0]);
            hi = __builtin_amdgcn_ds_bpermute(idx1, (int)pkA[2 * m + 1][0]);
            BwA[m][2] = (unsigned)(hiQuad ? hi : lo);
            lo = __builtin_amdgcn_ds_bpermute(idx1, (int)pkA[2 * m][1]);
            hi = __builtin_amdgcn_ds_bpermute(idx1, (int)pkA[2 * m + 1][1]);
            BwA[m][3] = (unsigned)(hiQuad ? hi : lo);
            lo = __builtin_amdgcn_ds_bpermute(idx0, (int)pkB[2 * m][0]);
            hi = __builtin_amdgcn_ds_bpermute(idx0, (int)pkB[2 * m + 1][0]);
            BwB[m][0] = (unsigned)(hiQuad ? hi : lo);
            lo = __builtin_amdgcn_ds_bpermute(idx0, (int)pkB[2 * m][1]);
            hi = __builtin_amdgcn_ds_bpermute(idx0, (int)pkB[2 * m + 1][1]);
            BwB[m][1] = (unsigned)(hiQuad ? hi : lo);
            lo = __builtin_amdgcn_ds_bpermute(idx1, (int)pkB[2 * m][0]);
            hi = __builtin_amdgcn_ds_bpermute(idx1, (int)pkB[2 * m + 1][0]);
            BwB[m][2] = (unsigned)(hiQuad ? hi : lo);
            lo = __builtin_amdgcn_ds_bpermute(idx1, (int)pkB[2 * m][1]);
            hi = __builtin_amdgcn_ds_bpermute(idx1, (int)pkB[2 * m + 1][1]);
            BwB[m][3] = (unsigned)(hiQuad ? hi : lo);
        }
        bf16x8 PA0 = __builtin_bit_cast(bf16x8, BwA[0]);
        bf16x8 PA1 = __builtin_bit_cast(bf16x8, BwA[1]);
        bf16x8 PB0 = __builtin_bit_cast(bf16x8, BwB[0]);
        bf16x8 PB1 = __builtin_bit_cast(bf16x8, BwB[1]);
        {
            bf16x8 v0 = ldfrag(Vl + (0 * 16 + c) * 64 + sw0);
            bf16x8 v1 = ldfrag(Vl + (0 * 16 + c) * 64 + sw1);
            oA0 = __builtin_amdgcn_mfma_f32_16x16x32_bf16(v0, PA0, oA0, 0, 0, 0);
            oA0 = __builtin_amdgcn_mfma_f32_16x16x32_bf16(v1, PA1, oA0, 0, 0, 0);
            oB0 = __builtin_amdgcn_mfma_f32_16x16x32_bf16(v0, PB0, oB0, 0, 0, 0);
            oB0 = __builtin_amdgcn_mfma_f32_16x16x32_bf16(v1, PB1, oB0, 0, 0, 0);
        }
        {
            bf16x8 v0 = ldfrag(Vl + (1 * 16 + c) * 64 + sw0);
            bf16x8 v1 = ldfrag(Vl + (1 * 16 + c) * 64 + sw1);
            oA1 = __builtin_amdgcn_mfma_f32_16x16x32_bf16(v0, PA0, oA1, 0, 0, 0);
            oA1 = __builtin_amdgcn_mfma_f32_16x16x32_bf16(v1, PA1, oA1, 0, 0, 0);
            oB1 = __builtin_amdgcn_mfma_f32_16x16x32_bf16(v0, PB0, oB1, 0, 0, 0);
            oB1 = __builtin_amdgcn_mfma_f32_16x16x32_bf16(v1, PB1, oB1, 0, 0, 0);
        }
        {
            bf16x8 v0 = ldfrag(Vl + (2 * 16 + c) * 64 + sw0);
            bf16x8 v1 = ldfrag(Vl + (2 * 16 + c) * 64 + sw1);
            oA2 = __builtin_amdgcn_mfma_f32_16x16x32_bf16(v0, PA0, oA2, 0, 0, 0);
            oA2 = __builtin_amdgcn_mfma_f32_16x16x32_bf16(v1, PA1, oA2, 0, 0, 0);
            oB2 = __builtin_amdgcn_mfma_f32_16x16x32_bf16(v0, PB0, oB2, 0, 0, 0);
            oB2 = __builtin_amdgcn_mfma_f32_16x16x32_bf16(v1, PB1, oB2, 0, 0, 0);
        }
        if (t + 1 < TILES) {
            const int nb = b ^ 1;
#pragma unroll
            for (int i = 0; i < 4; ++i)
                if (act[i]) {
                    unsigned short* lp = isK[i] ? &Kb[nb][ldsoff[i]] : &Vb[nb][ldsoff[i]];
                    *(u16x8*)lp = st[i];
                }
        }
        __syncthreads();
    }
    const size_t base = ((size_t)(seg * 8 + h)) << 12;
    float* obA = pO + (base + q0 + c) * 40;
    *(float4*)(obA + quad * 4)      = make_float4(oA0[0], oA0[1], oA0[2], oA0[3]);
    *(float4*)(obA + 16 + quad * 4) = make_float4(oA1[0], oA1[1], oA1[2], oA1[3]);
    if (quad < 2)
        *(float4*)(obA + 32 + quad * 4) = make_float4(oA2[0], oA2[1], oA2[2], oA2[3]);
    float* obB = pO + (base + q0 + 16 + c) * 40;
    *(float4*)(obB + quad * 4)      = make_float4(oB0[0], oB0[1], oB0[2], oB0[3]);
    *(float4*)(obB + 16 + quad * 4) = make_float4(oB1[0], oB1[1], oB1[2], oB1[3]);
    if (quad < 2)
        *(float4*)(obB + 32 + quad * 4) = make_float4(oB2[0], oB2[1], oB2[2], oB2[3]);
    if (quad == 2) {
        pL[base + q0 + c]      = oA2[0];
        pL[base + q0 + 16 + c] = oB2[0];
    }
}

// Combine partials across S segments -> bf16 O (HW,320), col = h*40+d.
__global__ __launch_bounds__(256) void attn_combine(
    const float* __restrict__ pO, const float* __restrict__ pL,
    unsigned short* __restrict__ O, int S) {
    int idx = blockIdx.x * 256 + threadIdx.x;  // < 8*4096*40, grid 5120
    int h = idx / (HW * 40);
    int rem = idx - h * (HW * 40);
    int row = rem / 40, d = rem - row * 40;
    float num = 0.f, den = 0.f;
    for (int s = 0; s < S; ++s) {
        size_t base = ((size_t)(s * 8 + h)) << 12;
        num += pO[(base + row) * 40 + d];
        den += pL[base + row];
    }
    O[(size_t)row * CCH + h * DH + d] = f2bf(num / den);
}

// ---------------------------------------------------------------------------
__global__ void final_kernel(const float* __restrict__ Yv,
                             const float* __restrict__ X,
                             float* __restrict__ Out) {
    int idx = blockIdx.x * 256 + threadIdx.x;
    int o = idx >> 12, hw = idx & 4095;
    Out[idx] = Yv[hw * CCH + o] + X[idx];
}

// ---------------------------------------------------------------------------
extern "C" void kernel_launch(void* const* d_in, const int* in_sizes, int n_in,
                              void* d_out, int out_size, void* d_ws, size_t ws_size,
                              hipStream_t stream) {
    const float* x     = (const float*)d_in[0];
    const float* ctx   = (const float*)d_in[1];
    const float* gn_w  = (const float*)d_in[2];
    const float* gn_b  = (const float*)d_in[3];
    const float* w_in  = (const float*)d_in[4];
    const float* b_in  = (const float*)d_in[5];
    const float* ln1_w = (const float*)d_in[6];
    const float* ln1_b = (const float*)d_in[7];
    const float* wq1   = (const float*)d_in[8];
    const float* wk1   = (const float*)d_in[9];
    const float* wv1   = (const float*)d_in[10];
    const float* wo1   = (const float*)d_in[11];
    const float* bo1   = (const float*)d_in[12];
    const float* ln2_w = (const float*)d_in[13];
    const float* ln2_b = (const float*)d_in[14];
    const float* wq2   = (const float*)d_in[15];
    const float* wk2   = (const float*)d_in[16];
    const float* wv2   = (const float*)d_in[17];
    const float* wo2   = (const float*)d_in[18];
    const float* bo2   = (const float*)d_in[19];
    const float* ln3_w = (const float*)d_in[20];
    const float* ln3_b = (const float*)d_in[21];
    const float* wff1  = (const float*)d_in[22];
    const float* bff1  = (const float*)d_in[23];
    const float* wff2  = (const float*)d_in[24];
    const float* bff2  = (const float*)d_in[25];
    const float* w_out = (const float*)d_in[26];
    const float* b_out = (const float*)d_in[27];
    float* out = (float*)d_out;

    const int NT = HW * CCH;  // 1,310,720
    float* ws = (float*)d_ws;
    float* t_   = ws;
    float* y_   = t_ + NT;
    float* pO   = y_ + NT;
    float* pL   = pO + 4 * 8 * 4096 * 40;
    float2* gnp = (float2*)(pL + 4 * 8 * 4096);
    unsigned short* u = (unsigned short*)(gnp + 256);
    unsigned short* a_bf = u;                  u += NT;
    unsigned short* q_bf = u;                  u += NT;
    unsigned short* o_bf = u;                  u += NT;
    unsigned short* t_bf = u;                  u += NT;
    unsigned short* g_bf = u;                  u += HW * FFI;
    unsigned short* Qp   = u;                  u += 8 * 4096 * 64;
    unsigned short* Kp   = u;                  u += 8 * 4096 * 64;
    unsigned short* Vt   = u;                  u += 8 * 48 * 4096;
    unsigned short* Kc   = u;                  u += 8 * 128 * 64;
    unsigned short* Vc   = u;                  u += 8 * 48 * 128;
    unsigned short* Wt   = u;                  u += 2048000 + 2 * 245760;
    unsigned short* ctx_bf = u;                u += 128 * 768;

    const unsigned short* w_inT  = Wt;
    const unsigned short* wq1T   = Wt + 102400;
    const unsigned short* wk1T   = Wt + 204800;  // wv1T contiguous at +307200
    const unsigned short* wo1T   = Wt + 409600;
    const unsigned short* wq2T   = Wt + 512000;
    const unsigned short* wo2T   = Wt + 614400;
    const unsigned short* w_outT = Wt + 716800;
    const unsigned short* wff1T  = Wt + 819200;
    const unsigned short* wff2T  = Wt + 1638400;
    const unsigned short* wk2T   = Wt + 2048000;  // wv2T contiguous (N=640 merged)

    const float qscale = 0.15811388300841897f * 1.4426950408889634f;  // 40^-.5 * log2e

    prep_w2<<<620, 256, 0, stream>>>(w_in, wq1, wk1, wv1, wo1, wq2, wo2, w_out,
                                     wff1, wff2, wk2, wv2, Wt);
    hipMemsetAsync(Qp, 0,
                   (size_t)(8 * 4096 * 64 * 2 + 8 * 48 * 4096 + 8 * 128 * 64 + 8 * 48 * 128) * 2,
                   stream);
    set_ones<<<132, 256, 0, stream>>>(Vt, Vc);
    pack_ctx<<<384, 256, 0, stream>>>(ctx, ctx_bf);

    // 1) GroupNorm -> a_bf (HW,C)
    gn_stats<<<256, 256, 0, stream>>>(x, gnp);
    gn_apply<<<dim3(64, 5), 256, 0, stream>>>(x, gnp, gn_w, gn_b, a_bf);
    // 2) proj_in: t = a @ w_in + b_in (fp32)
    gemm4<2, 320><<<dim3(5, 128), 256, 0, stream>>>(a_bf, w_inT, b_in, nullptr, t_, nullptr, CCH, 0, 1.f);
    // 3) ln1 -> a_bf
    ln_kernel<<<1024, 256, 0, stream>>>(t_, ln1_w, ln1_b, a_bf);
    // 4) q (dual); k&v in one N=640 dispatch
    gemm4<2, 320><<<dim3(5, 128), 256, 0, stream>>>(a_bf, wq1T, nullptr, nullptr, q_bf, Qp, CCH, 6, qscale);
    gemm4<2, 320><<<dim3(10, 128), 256, 0, stream>>>(q_bf, wk1T, nullptr, nullptr, Kp, Vt, 640, 7, 1.f);
    // 5) self-attention: 128 queries/block, 4 segs, XCD swizzle
    attn7<16, false><<<1024, 256, 0, stream>>>(Qp, Kp, Vt, pO, pL, HW, HW);
    attn_combine<<<5120, 256, 0, stream>>>(pO, pL, o_bf, 4);
    // 6) t += o @ wo1 + bo1
    gemm4<2, 320><<<dim3(5, 128), 256, 0, stream>>>(o_bf, wo1T, bo1, t_, t_, nullptr, CCH, 0, 1.f);
    // 7) ln2 -> a_bf
    ln_kernel<<<1024, 256, 0, stream>>>(t_, ln2_w, ln2_b, a_bf);
    // 8) cross q -> Qp; ctx K/V via MFMA gemm (mode 8, Lkp=128)
    gemm4<2, 320><<<dim3(5, 128), 256, 0, stream>>>(a_bf, wq2T, nullptr, nullptr, Qp, nullptr, CCH, 2, qscale);
    gemm4<2, 768><<<dim3(10, 4), 256, 0, stream>>>(ctx_bf, wk2T, nullptr, nullptr, Kc, Vc, 640, 8, 1.f);
    // 9) cross-attention (Lk=77, 1 seg of 2 tiles, masked)
    attn7<2, true><<<256, 256, 0, stream>>>(Qp, Kc, Vc, pO, pL, 77, 128);
    attn_combine<<<5120, 256, 0, stream>>>(pO, pL, o_bf, 1);
    // 10) t += o @ wo2 + bo2
    gemm4<2, 320><<<dim3(5, 128), 256, 0, stream>>>(o_bf, wo2T, bo2, t_, t_, nullptr, CCH, 0, 1.f);
    // 11) ln3 -> a_bf
    ln_kernel<<<1024, 256, 0, stream>>>(t_, ln3_w, ln3_b, a_bf);
    // 12+13) FF1 with fused GEGLU -> g_bf
    gemm4<2, 320><<<dim3(40, 128), 256, 0, stream>>>(a_bf, wff1T, bff1, nullptr, g_bf, nullptr, 2 * FFI, 5, 1.f);
    // 14) t_bf = bf16(t + g @ wff2 + bff2)
    gemm4<2, 1280><<<dim3(5, 128), 256, 0, stream>>>(g_bf, wff2T, bff2, t_, t_bf, nullptr, CCH, 4, 1.f);
    // 15) y = t_bf @ w_out + b_out (fp32)
    gemm4<2, 320><<<dim3(5, 128), 256, 0, stream>>>(t_bf, w_outT, b_out, nullptr, y_, nullptr, CCH, 0, 1.f);
    // 16) out = y^T + x
    final_kernel<<<5120, 256, 0, stream>>>(y_, x, out);
}

// Round 13
// 330.025 us; speedup vs baseline: 7.1669x; 1.0481x over previous
//
#include <hip/hip_runtime.h>
#include <hip/hip_bf16.h>
#include <math.h>

#define CCH 320
#define NHEADS 8
#define DH 40
#define HW 4096
#define FFI 1280

typedef __bf16 bf16x8 __attribute__((ext_vector_type(8)));
typedef unsigned short u16x8 __attribute__((ext_vector_type(8)));
typedef float f32x4 __attribute__((ext_vector_type(4)));
typedef unsigned int u32x4 __attribute__((ext_vector_type(4)));

__device__ inline unsigned short f2bf(float f) {
    __hip_bfloat16 h = __float2bfloat16(f);
    return __builtin_bit_cast(unsigned short, h);
}
// HW packed f32x2 -> bf16x2 convert (gfx950 v_cvt_pk_bf16_f32); 1 op vs ~10.
__device__ inline unsigned pk2bf(float a, float b) {
#if __has_builtin(__builtin_amdgcn_cvt_pk_bf16_f32)
    typedef __bf16 bf16x2 __attribute__((ext_vector_type(2)));
    bf16x2 r = __builtin_amdgcn_cvt_pk_bf16_f32(a, b);
    return __builtin_bit_cast(unsigned, r);
#else
    return (unsigned)f2bf(a) | ((unsigned)f2bf(b) << 16);
#endif
}
__device__ inline float bf2f(unsigned short u) {
    return __builtin_bit_cast(float, ((unsigned)u) << 16);
}
__device__ inline bf16x8 ldfrag(const unsigned short* p) {
    u16x8 raw = *reinterpret_cast<const u16x8*>(p);
    return __builtin_bit_cast(bf16x8, raw);
}

// ---------------------------------------------------------------------------
// Coalesced weight transpose via LDS 64x65 tiles. 620 tiles.
__global__ __launch_bounds__(256) void prep_w2(
    const float* __restrict__ w_in, const float* __restrict__ wq1,
    const float* __restrict__ wk1, const float* __restrict__ wv1,
    const float* __restrict__ wo1, const float* __restrict__ wq2,
    const float* __restrict__ wo2, const float* __restrict__ w_out,
    const float* __restrict__ wff1, const float* __restrict__ wff2,
    const float* __restrict__ wk2, const float* __restrict__ wv2,
    unsigned short* __restrict__ Wt) {
    __shared__ float tile[64][65];
    const int b = blockIdx.x, tid = threadIdx.x;
    const float* src;
    int K, stride, dstoff, k0, n0;
    bool glu = false;
    if (b < 200) {
        int m = b / 25, t = b % 25;
        k0 = (t / 5) * 64; n0 = (t % 5) * 64;
        K = 320; stride = 320; dstoff = m * 102400;
        src = (m == 0) ? w_in : (m == 1) ? wq1 : (m == 2) ? wk1 :
              (m == 3) ? wv1 : (m == 4) ? wo1 : (m == 5) ? wq2 :
              (m == 6) ? wo2 : w_out;
    } else if (b < 300) {
        int t = b - 200;
        k0 = (t / 5) * 64; n0 = (t % 5) * 64;
        K = 1280; stride = 320; dstoff = 1638400; src = wff2;
    } else if (b < 500) {
        int t = b - 300;
        k0 = (t / 40) * 64; n0 = (t % 40) * 64;
        K = 320; stride = 2560; dstoff = 819200; src = wff1; glu = true;
    } else if (b < 560) {
        int t = b - 500;
        k0 = (t / 5) * 64; n0 = (t % 5) * 64;
        K = 768; stride = 320; dstoff = 2048000; src = wk2;
    } else {
        int t = b - 560;
        k0 = (t / 5) * 64; n0 = (t % 5) * 64;
        K = 768; stride = 320; dstoff = 2048000 + 245760; src = wv2;
    }
#pragma unroll
    for (int i = 0; i < 16; ++i) {
        int idx = tid + i * 256;
        int r = idx >> 6, cn = idx & 63;
        int scol = glu ? ((n0 >> 1) + (cn >> 1) + (cn & 1) * FFI) : (n0 + cn);
        tile[r][cn] = src[(size_t)(k0 + r) * stride + scol];
    }
    __syncthreads();
#pragma unroll
    for (int i = 0; i < 16; ++i) {
        int idx = tid + i * 256;
        int cl = idx >> 6, cr = idx & 63;
        Wt[dstoff + (size_t)(n0 + cl) * K + k0 + cr] = f2bf(tile[cr][cl]);
    }
}

// ---------------------------------------------------------------------------
// ctx (77x768 fp32) -> bf16 (128x768), rows >= 77 zeroed.
__global__ void pack_ctx(const float* __restrict__ ctx,
                         unsigned short* __restrict__ D) {
    int idx = blockIdx.x * 256 + threadIdx.x;  // grid 384 -> 98304 exact
    int row = idx / 768, col = idx - row * 768;
    float v = (row < 77) ? ctx[row * 768 + col] : 0.f;
    D[idx] = f2bf(v);
}

// ---------------------------------------------------------------------------
__global__ __launch_bounds__(256) void gn_stats(const float* __restrict__ X,
                                                float2* __restrict__ part) {
    __shared__ float s1[256], s2[256];
    const int b = blockIdx.x, tid = threadIdx.x;
    const float* xg = X + b * 5120;
    float s = 0.f, sq = 0.f;
#pragma unroll
    for (int i = 0; i < 20; ++i) { float v = xg[tid + i * 256]; s += v; sq += v * v; }
    s1[tid] = s; s2[tid] = sq; __syncthreads();
    for (int off = 128; off > 0; off >>= 1) {
        if (tid < off) { s1[tid] += s1[tid + off]; s2[tid] += s2[tid + off]; }
        __syncthreads();
    }
    if (tid == 0) part[b] = make_float2(s1[0], s2[0]);
}

__global__ __launch_bounds__(256) void gn_apply(const float* __restrict__ X,
                                                const float2* __restrict__ part,
                                                const float* __restrict__ w,
                                                const float* __restrict__ b,
                                                unsigned short* __restrict__ Y) {
    __shared__ float tile[64][65];
    __shared__ float gm[32], gr[32];
    const int tid = threadIdx.x;
    const int hw0 = blockIdx.x * 64, c0 = blockIdx.y * 64;
    if (tid < 32) {
        float s = 0.f, sq = 0.f;
#pragma unroll
        for (int i = 0; i < 8; ++i) { float2 p = part[tid * 8 + i]; s += p.x; sq += p.y; }
        float mean = s * (1.f / 40960.f);
        float var  = sq * (1.f / 40960.f) - mean * mean;
        gm[tid] = mean; gr[tid] = rsqrtf(var + 1e-6f);
    }
#pragma unroll
    for (int i = 0; i < 16; ++i) {
        int idx = tid + i * 256;
        int r = idx >> 6, col = idx & 63;
        tile[r][col] = X[(size_t)(c0 + r) * HW + hw0 + col];
    }
    __syncthreads();
#pragma unroll
    for (int i = 0; i < 16; ++i) {
        int idx = tid + i * 256;
        int hwl = idx >> 6, cl = idx & 63;
        int c = c0 + cl, g = c / 10;
        float v = (tile[cl][hwl] - gm[g]) * gr[g] * w[c] + b[c];
        Y[(size_t)(hw0 + hwl) * CCH + c] = f2bf(v);
    }
}

// ---------------------------------------------------------------------------
__global__ __launch_bounds__(256) void ln_kernel(const float* __restrict__ X,
                                                 const float* __restrict__ w,
                                                 const float* __restrict__ b,
                                                 unsigned short* __restrict__ Y) {
    const int row  = blockIdx.x * 4 + (threadIdx.x >> 6);
    const int lane = threadIdx.x & 63;
    const float* xr = X + row * CCH;
    float v[5];
    float s = 0.f, sq = 0.f;
#pragma unroll
    for (int i = 0; i < 5; ++i) { v[i] = xr[lane + 64 * i]; s += v[i]; sq += v[i] * v[i]; }
#pragma unroll
    for (int off = 32; off > 0; off >>= 1) {
        s  += __shfl_xor(s, off, 64);
        sq += __shfl_xor(sq, off, 64);
    }
    const float mean = s * (1.f / 320.f);
    const float var  = sq * (1.f / 320.f) - mean * mean;
    const float rstd = rsqrtf(var + 1e-5f);
    unsigned short* yr = Y + row * CCH;
#pragma unroll
    for (int i = 0; i < 5; ++i) {
        int c = lane + 64 * i;
        yr[c] = f2bf((v[i] - mean) * rstd * w[c] + b[c]);
    }
}

// ---------------------------------------------------------------------------
// gemm4 (proven double-buffer GEMM).
// Modes: 0 fp32+bias(+res) | 2 QK-pack*scale | 4 bf16+bias+res |
//        5 GLU-interleaved | 6 dual bf16+QK-pack | 7 kv-merged (Lkp=4096) |
//        8 ctx kv-merged (Lkp=128) | 9 transposed fp32 out + x (final fused)
template <int MT, int K>
__global__ __launch_bounds__(256) void gemm4(
    const unsigned short* __restrict__ A,
    const unsigned short* __restrict__ Bt,
    const float* __restrict__ bias,
    const float* __restrict__ res,
    void* __restrict__ Cout, void* __restrict__ Cout2,
    int N, int mode, float scale) {
    constexpr int NCH = K / 64;
    __shared__ __align__(16) unsigned short Ab[2][MT * 16 * 64];
    __shared__ __align__(16) unsigned short Bb[2][64 * 64];
    const int tid  = threadIdx.x;
    const int wave = tid >> 6, lane = tid & 63;
    const int quad = lane >> 4, c = lane & 15;
    const int m0 = blockIdx.y * (MT * 16);
    const int bn = blockIdx.x;

    f32x4 acc[MT];
#pragma unroll
    for (int i = 0; i < MT; ++i) acc[i] = (f32x4){0.f, 0.f, 0.f, 0.f};

    const unsigned short* aslab = A + (size_t)m0 * K;
    const unsigned short* bslab = Bt + (size_t)(bn * 64) * K;

    constexpr int ITA = MT * 16 * 8 / 256;
    int arow[ITA], aoff[ITA];
#pragma unroll
    for (int i = 0; i < ITA; ++i) {
        int idx = tid + i * 256;
        arow[i] = idx >> 3;
        int g = idx & 7;
        aoff[i] = arow[i] * 64 + ((g ^ (arow[i] & 7)) * 8);
    }
    int brow[2], boff[2];
#pragma unroll
    for (int i = 0; i < 2; ++i) {
        int idx = tid + i * 256;
        brow[i] = idx >> 3;
        int g = idx & 7;
        boff[i] = brow[i] * 64 + ((g ^ (brow[i] & 7)) * 8);
    }
    const int ag = (tid & 7) * 8;

    {
        u16x8 ra[ITA], rb[2];
#pragma unroll
        for (int i = 0; i < ITA; ++i)
            ra[i] = *(const u16x8*)(aslab + (size_t)arow[i] * K + ag);
#pragma unroll
        for (int i = 0; i < 2; ++i)
            rb[i] = *(const u16x8*)(bslab + (size_t)brow[i] * K + ag);
#pragma unroll
        for (int i = 0; i < ITA; ++i) *(u16x8*)&Ab[0][aoff[i]] = ra[i];
#pragma unroll
        for (int i = 0; i < 2; ++i) *(u16x8*)&Bb[0][boff[i]] = rb[i];
    }
    __syncthreads();

    const int swz0 = (quad ^ (c & 7)) * 8;
    const int swz1 = ((quad + 4) ^ (c & 7)) * 8;
#pragma unroll
    for (int ch = 0; ch < NCH; ++ch) {
        const int buf = ch & 1;
        u16x8 ra[ITA], rb[2];
        if (ch + 1 < NCH) {
            const int kb = (ch + 1) * 64;
#pragma unroll
            for (int i = 0; i < ITA; ++i)
                ra[i] = *(const u16x8*)(aslab + (size_t)arow[i] * K + kb + ag);
#pragma unroll
            for (int i = 0; i < 2; ++i)
                rb[i] = *(const u16x8*)(bslab + (size_t)brow[i] * K + kb + ag);
        }
        bf16x8 b0 = ldfrag(&Bb[buf][(wave * 16 + c) * 64 + swz0]);
        bf16x8 b1 = ldfrag(&Bb[buf][(wave * 16 + c) * 64 + swz1]);
#pragma unroll
        for (int mt = 0; mt < MT; ++mt) {
            bf16x8 a0 = ldfrag(&Ab[buf][(mt * 16 + c) * 64 + swz0]);
            bf16x8 a1 = ldfrag(&Ab[buf][(mt * 16 + c) * 64 + swz1]);
            acc[mt] = __builtin_amdgcn_mfma_f32_16x16x32_bf16(a0, b0, acc[mt], 0, 0, 0);
            acc[mt] = __builtin_amdgcn_mfma_f32_16x16x32_bf16(a1, b1, acc[mt], 0, 0, 0);
        }
        if (ch + 1 < NCH) {
            const int nb = buf ^ 1;
#pragma unroll
            for (int i = 0; i < ITA; ++i) *(u16x8*)&Ab[nb][aoff[i]] = ra[i];
#pragma unroll
            for (int i = 0; i < 2; ++i) *(u16x8*)&Bb[nb][boff[i]] = rb[i];
        }
        __syncthreads();
    }

    const int col = bn * 64 + wave * 16 + c;
    float bval = 0.f;
    if (bias) bval = (mode == 5) ? bias[(col >> 1) + (col & 1) * FFI] : bias[col];

    if (mode == 9) {  // transposed fp32 out + x residual (final fused), float4
#pragma unroll
        for (int mt = 0; mt < MT; ++mt) {
            const int row0 = m0 + mt * 16 + quad * 4;
            float4 xv = *(const float4*)(res + (size_t)col * HW + row0);
            float4 ov;
            ov.x = acc[mt][0] + bval + xv.x;
            ov.y = acc[mt][1] + bval + xv.y;
            ov.z = acc[mt][2] + bval + xv.z;
            ov.w = acc[mt][3] + bval + xv.w;
            *(float4*)((float*)Cout + (size_t)col * HW + row0) = ov;
        }
        return;
    }
#pragma unroll
    for (int mt = 0; mt < MT; ++mt) {
#pragma unroll
        for (int r = 0; r < 4; ++r) {
            const int row = m0 + mt * 16 + quad * 4 + r;
            float v = acc[mt][r];
            if (mode == 0) {
                v += bval;
                if (res) v += res[(size_t)row * N + col];
                ((float*)Cout)[(size_t)row * N + col] = v;
            } else if (mode == 2) {
                int h = col & 7, d = col >> 3;
                ((unsigned short*)Cout)[(((size_t)h << 12) + row) * 64 + d] = f2bf(v * scale);
            } else if (mode == 4) {
                ((unsigned short*)Cout)[(size_t)row * N + col] =
                    f2bf(v + bval + res[(size_t)row * N + col]);
            } else if (mode == 5) {
                v += bval;
                float other = __shfl_xor(v, 1, 64);
                if ((c & 1) == 0) {
                    float g = 0.5f * other * (1.f + erff(other * 0.70710678118654752f));
                    ((unsigned short*)Cout)[(size_t)row * FFI + (col >> 1)] = f2bf(v * g);
                }
            } else if (mode == 6) {
                ((unsigned short*)Cout)[(size_t)row * N + col] = f2bf(v);
                int h = col & 7, d = col >> 3;
                ((unsigned short*)Cout2)[(((size_t)h << 12) + row) * 64 + d] = f2bf(v * scale);
            } else if (mode == 7) {
                if (col < 320) {
                    int h = col & 7, d = col >> 3;
                    ((unsigned short*)Cout)[(((size_t)h << 12) + row) * 64 + d] = f2bf(v);
                } else {
                    int c2 = col - 320;
                    int h = c2 & 7, d = c2 >> 3;
                    ((unsigned short*)Cout2)[(((size_t)(h * 48 + d)) << 12) + row] = f2bf(v);
                }
            } else {  // 8: ctx kv-merged, Lkp = 128
                if (col < 320) {
                    int h = col & 7, d = col >> 3;
                    ((unsigned short*)Cout)[(((size_t)h << 7) + row) * 64 + d] = f2bf(v);
                } else {
                    int c2 = col - 320;
                    int h = c2 & 7, d = c2 >> 3;
                    ((unsigned short*)Cout2)[(size_t)(h * 48 + d) * 128 + row] = f2bf(v);
                }
            }
        }
    }
}

// ---------------------------------------------------------------------------
// Set V^T padded dim-40 row to 1.0 so sum(p) materializes in the PV MFMA.
__global__ void set_ones(unsigned short* __restrict__ Vt,
                         unsigned short* __restrict__ Vc) {
    int idx = blockIdx.x * 256 + threadIdx.x;  // grid 132 -> 33792 exact
    if (idx < 32768) {
        int h = idx >> 12, r = idx & 4095;
        Vt[((size_t)(h * 48 + 40) << 12) + r] = 0x3F80;  // bf16(1.0)
    } else {
        int j = idx - 32768;
        int h = j >> 7, r = j & 127;
        Vc[(h * 48 + 40) * 128 + r] = 0x3F80;
    }
}

// ---------------------------------------------------------------------------
// attn7: LDS-staged flash attention, 128 queries/block; packed bf16 converts.
template <int TILES, bool MASK>
__global__ __launch_bounds__(256) void attn7(
    const unsigned short* __restrict__ Qp,
    const unsigned short* __restrict__ Kp,
    const unsigned short* __restrict__ Vt,
    float* __restrict__ pO, float* __restrict__ pL,
    int Lk, int Lkp) {
    __shared__ __align__(16) unsigned short Kb[2][64 * 64];
    __shared__ __align__(16) unsigned short Vb[2][48 * 64];
    const int tid  = threadIdx.x;
    const int wave = tid >> 6, lane = tid & 63;
    const int quad = lane >> 4, c = lane & 15;
    const int id  = blockIdx.x;
    const int h   = id & 7;
    const int qt  = (id >> 3) & 31;
    const int seg = id >> 8;
    const int q0  = qt * 128 + wave * 32;

    const unsigned short* qbaseA = Qp + ((((size_t)h << 12) + q0 + c) << 6) + quad * 8;
    const bf16x8 bQA0 = ldfrag(qbaseA);
    const bf16x8 bQA1 = ldfrag(qbaseA + 32);
    const bf16x8 bQB0 = ldfrag(qbaseA + 1024);
    const bf16x8 bQB1 = ldfrag(qbaseA + 1024 + 32);

    f32x4 oA0 = {0.f, 0.f, 0.f, 0.f}, oA1 = oA0, oA2 = oA0;
    f32x4 oB0 = oA0, oB1 = oA0, oB2 = oA0;
    const int idx0 = ((((quad & 1) * 2 + 0) * 16 + c) << 2);
    const int idx1 = ((((quad & 1) * 2 + 1) * 16 + c) << 2);
    const bool hiQuad = (quad >> 1) != 0;

    const int kt0 = seg * TILES;
    const unsigned short* kglob = Kp + (((size_t)h * Lkp + kt0 * 64) << 6);
    const unsigned short* vglob = Vt + ((size_t)h * 48) * Lkp + kt0 * 64;

    const int r0 = lane >> 3;
    const int g  = lane & 7;
    int ldsoff[4];
    const unsigned short* gptr0[4];
#pragma unroll
    for (int i = 0; i < 4; ++i) {
        int s = wave + 4 * i;
        if (s < 8) {
            int row = s * 8 + r0;
            ldsoff[i] = row * 64 + (g ^ (row & 7)) * 8;
            gptr0[i]  = kglob + (size_t)row * 64 + g * 8;
        } else if (s < 14) {
            int d = (s - 8) * 8 + r0;
            ldsoff[i] = d * 64 + (g ^ (d & 7)) * 8;
            gptr0[i]  = vglob + (size_t)d * Lkp + g * 8;
        } else {
            ldsoff[i] = 0; gptr0[i] = nullptr;
        }
    }
    const bool isK[4] = {(wave + 0) < 8, (wave + 4) < 8, (wave + 8) < 8, (wave + 12) < 8};
    const bool act[4] = {true, true, true, (wave + 12) < 14};

    {
        u16x8 st[4];
#pragma unroll
        for (int i = 0; i < 4; ++i)
            if (act[i]) st[i] = *(const u16x8*)(gptr0[i]);
#pragma unroll
        for (int i = 0; i < 4; ++i)
            if (act[i]) {
                unsigned short* lp = isK[i] ? &Kb[0][ldsoff[i]] : &Vb[0][ldsoff[i]];
                *(u16x8*)lp = st[i];
            }
    }
    __syncthreads();

#pragma unroll
    for (int t = 0; t < TILES; ++t) {
        const int b = t & 1;
        u16x8 st[4];
        if (t + 1 < TILES) {
            const int kb = (t + 1) * 64;
#pragma unroll
            for (int i = 0; i < 4; ++i)
                if (act[i]) {
                    const unsigned short* gp =
                        isK[i] ? (gptr0[i] + (size_t)kb * 64) : (gptr0[i] + kb);
                    st[i] = *(const u16x8*)gp;
                }
        }
        const unsigned short* Kl = &Kb[b][0];
        const unsigned short* Vl = &Vb[b][0];
        const int sw0 = (quad ^ (c & 7)) * 8;
        const int sw1 = ((quad + 4) ^ (c & 7)) * 8;
        f32x4 sA[4], sB[4];
#pragma unroll
        for (int blk = 0; blk < 4; ++blk) {
            const int row = (blk * 16 + c) * 64;
            bf16x8 k0 = ldfrag(Kl + row + sw0);
            bf16x8 k1 = ldfrag(Kl + row + sw1);
            f32x4 zA = {0.f, 0.f, 0.f, 0.f};
            zA = __builtin_amdgcn_mfma_f32_16x16x32_bf16(k0, bQA0, zA, 0, 0, 0);
            zA = __builtin_amdgcn_mfma_f32_16x16x32_bf16(k1, bQA1, zA, 0, 0, 0);
            sA[blk] = zA;
            f32x4 zB = {0.f, 0.f, 0.f, 0.f};
            zB = __builtin_amdgcn_mfma_f32_16x16x32_bf16(k0, bQB0, zB, 0, 0, 0);
            zB = __builtin_amdgcn_mfma_f32_16x16x32_bf16(k1, bQB1, zB, 0, 0, 0);
            sB[blk] = zB;
        }
        if (MASK) {
            const int abs_kb = kt0 * 64 + t * 64;
#pragma unroll
            for (int blk = 0; blk < 4; ++blk)
#pragma unroll
                for (int r = 0; r < 4; ++r) {
                    bool inv = (abs_kb + blk * 16 + quad * 4 + r >= Lk);
                    sA[blk][r] = inv ? -30000.f : sA[blk][r];
                    sB[blk][r] = inv ? -30000.f : sB[blk][r];
                }
        }
        unsigned pkA[4][2], pkB[4][2];
#pragma unroll
        for (int blk = 0; blk < 4; ++blk) {
            pkA[blk][0] = pk2bf(exp2f(sA[blk][0]), exp2f(sA[blk][1]));
            pkA[blk][1] = pk2bf(exp2f(sA[blk][2]), exp2f(sA[blk][3]));
            pkB[blk][0] = pk2bf(exp2f(sB[blk][0]), exp2f(sB[blk][1]));
            pkB[blk][1] = pk2bf(exp2f(sB[blk][2]), exp2f(sB[blk][3]));
        }
        u32x4 BwA[2], BwB[2];
#pragma unroll
        for (int m = 0; m < 2; ++m) {
            int lo, hi;
            lo = __builtin_amdgcn_ds_bpermute(idx0, (int)pkA[2 * m][0]);
            hi = __builtin_amdgcn_ds_bpermute(idx0, (int)pkA[2 * m + 1][0]);
            BwA[m][0] = (unsigned)(hiQuad ? hi : lo);
            lo = __builtin_amdgcn_ds_bpermute(idx0, (int)pkA[2 * m][1]);
            hi = __builtin_amdgcn_ds_bpermute(idx0, (int)pkA[2 * m + 1][1]);
            BwA[m][1] = (unsigned)(hiQuad ? hi : lo);
            lo = __builtin_amdgcn_ds_bpermute(idx1, (int)pkA[2 * m][0]);
            hi = __builtin_amdgcn_ds_bpermute(idx1, (int)pkA[2 * m + 1][0]);
            BwA[m][2] = (unsigned)(hiQuad ? hi : lo);
            lo = __builtin_amdgcn_ds_bpermute(idx1, (int)pkA[2 * m][1]);
            hi = __builtin_amdgcn_ds_bpermute(idx1, (int)pkA[2 * m + 1][1]);
            BwA[m][3] = (unsigned)(hiQuad ? hi : lo);
            lo = __builtin_amdgcn_ds_bpermute(idx0, (int)pkB[2 * m][0]);
            hi = __builtin_amdgcn_ds_bpermute(idx0, (int)pkB[2 * m + 1][0]);
            BwB[m][0] = (unsigned)(hiQuad ? hi : lo);
            lo = __builtin_amdgcn_ds_bpermute(idx0, (int)pkB[2 * m][1]);
            hi = __builtin_amdgcn_ds_bpermute(idx0, (int)pkB[2 * m + 1][1]);
            BwB[m][1] = (unsigned)(hiQuad ? hi : lo);
            lo = __builtin_amdgcn_ds_bpermute(idx1, (int)pkB[2 * m][0]);
            hi = __builtin_amdgcn_ds_bpermute(idx1, (int)pkB[2 * m + 1][0]);
            BwB[m][2] = (unsigned)(hiQuad ? hi : lo);
            lo = __builtin_amdgcn_ds_bpermute(idx1, (int)pkB[2 * m][1]);
            hi = __builtin_amdgcn_ds_bpermute(idx1, (int)pkB[2 * m + 1][1]);
            BwB[m][3] = (unsigned)(hiQuad ? hi : lo);
        }
        bf16x8 PA0 = __builtin_bit_cast(bf16x8, BwA[0]);
        bf16x8 PA1 = __builtin_bit_cast(bf16x8, BwA[1]);
        bf16x8 PB0 = __builtin_bit_cast(bf16x8, BwB[0]);
        bf16x8 PB1 = __builtin_bit_cast(bf16x8, BwB[1]);
        {
            bf16x8 v0 = ldfrag(Vl + (0 * 16 + c) * 64 + sw0);
            bf16x8 v1 = ldfrag(Vl + (0 * 16 + c) * 64 + sw1);
            oA0 = __builtin_amdgcn_mfma_f32_16x16x32_bf16(v0, PA0, oA0, 0, 0, 0);
            oA0 = __builtin_amdgcn_mfma_f32_16x16x32_bf16(v1, PA1, oA0, 0, 0, 0);
            oB0 = __builtin_amdgcn_mfma_f32_16x16x32_bf16(v0, PB0, oB0, 0, 0, 0);
            oB0 = __builtin_amdgcn_mfma_f32_16x16x32_bf16(v1, PB1, oB0, 0, 0, 0);
        }
        {
            bf16x8 v0 = ldfrag(Vl + (1 * 16 + c) * 64 + sw0);
            bf16x8 v1 = ldfrag(Vl + (1 * 16 + c) * 64 + sw1);
            oA1 = __builtin_amdgcn_mfma_f32_16x16x32_bf16(v0, PA0, oA1, 0, 0, 0);
            oA1 = __builtin_amdgcn_mfma_f32_16x16x32_bf16(v1, PA1, oA1, 0, 0, 0);
            oB1 = __builtin_amdgcn_mfma_f32_16x16x32_bf16(v0, PB0, oB1, 0, 0, 0);
            oB1 = __builtin_amdgcn_mfma_f32_16x16x32_bf16(v1, PB1, oB1, 0, 0, 0);
        }
        {
            bf16x8 v0 = ldfrag(Vl + (2 * 16 + c) * 64 + sw0);
            bf16x8 v1 = ldfrag(Vl + (2 * 16 + c) * 64 + sw1);
            oA2 = __builtin_amdgcn_mfma_f32_16x16x32_bf16(v0, PA0, oA2, 0, 0, 0);
            oA2 = __builtin_amdgcn_mfma_f32_16x16x32_bf16(v1, PA1, oA2, 0, 0, 0);
            oB2 = __builtin_amdgcn_mfma_f32_16x16x32_bf16(v0, PB0, oB2, 0, 0, 0);
            oB2 = __builtin_amdgcn_mfma_f32_16x16x32_bf16(v1, PB1, oB2, 0, 0, 0);
        }
        if (t + 1 < TILES) {
            const int nb = b ^ 1;
#pragma unroll
            for (int i = 0; i < 4; ++i)
                if (act[i]) {
                    unsigned short* lp = isK[i] ? &Kb[nb][ldsoff[i]] : &Vb[nb][ldsoff[i]];
                    *(u16x8*)lp = st[i];
                }
        }
        __syncthreads();
    }
    const size_t base = ((size_t)(seg * 8 + h)) << 12;
    float* obA = pO + (base + q0 + c) * 40;
    *(float4*)(obA + quad * 4)      = make_float4(oA0[0], oA0[1], oA0[2], oA0[3]);
    *(float4*)(obA + 16 + quad * 4) = make_float4(oA1[0], oA1[1], oA1[2], oA1[3]);
    if (quad < 2)
        *(float4*)(obA + 32 + quad * 4) = make_float4(oA2[0], oA2[1], oA2[2], oA2[3]);
    float* obB = pO + (base + q0 + 16 + c) * 40;
    *(float4*)(obB + quad * 4)      = make_float4(oB0[0], oB0[1], oB0[2], oB0[3]);
    *(float4*)(obB + 16 + quad * 4) = make_float4(oB1[0], oB1[1], oB1[2], oB1[3]);
    if (quad < 2)
        *(float4*)(obB + 32 + quad * 4) = make_float4(oB2[0], oB2[1], oB2[2], oB2[3]);
    if (quad == 2) {
        pL[base + q0 + c]      = oA2[0];
        pL[base + q0 + 16 + c] = oB2[0];
    }
}

// Combine partials (vectorized): float4 loads, packed bf16 stores.
__global__ __launch_bounds__(256) void attn_combine2(
    const float* __restrict__ pO, const float* __restrict__ pL,
    unsigned short* __restrict__ O, int S) {
    int idx = blockIdx.x * 256 + threadIdx.x;  // < 8*4096*10, grid 1280
    int h = idx / (HW * 10);
    int rem = idx - h * (HW * 10);
    int row = rem / 10, dg = rem - row * 10;
    float4 num = make_float4(0.f, 0.f, 0.f, 0.f);
    float den = 0.f;
    for (int s = 0; s < S; ++s) {
        size_t base = ((size_t)(s * 8 + h)) << 12;
        float4 p = *(const float4*)(pO + (base + row) * 40 + dg * 4);
        num.x += p.x; num.y += p.y; num.z += p.z; num.w += p.w;
        den += pL[base + row];
    }
    float inv = 1.f / den;
    unsigned short* ob = O + (size_t)row * CCH + h * DH + dg * 4;
    unsigned lo = pk2bf(num.x * inv, num.y * inv);
    unsigned hi = pk2bf(num.z * inv, num.w * inv);
    *(uint2*)ob = make_uint2(lo, hi);
}

// ---------------------------------------------------------------------------
extern "C" void kernel_launch(void* const* d_in, const int* in_sizes, int n_in,
                              void* d_out, int out_size, void* d_ws, size_t ws_size,
                              hipStream_t stream) {
    const float* x     = (const float*)d_in[0];
    const float* ctx   = (const float*)d_in[1];
    const float* gn_w  = (const float*)d_in[2];
    const float* gn_b  = (const float*)d_in[3];
    const float* w_in  = (const float*)d_in[4];
    const float* b_in  = (const float*)d_in[5];
    const float* ln1_w = (const float*)d_in[6];
    const float* ln1_b = (const float*)d_in[7];
    const float* wq1   = (const float*)d_in[8];
    const float* wk1   = (const float*)d_in[9];
    const float* wv1   = (const float*)d_in[10];
    const float* wo1   = (const float*)d_in[11];
    const float* bo1   = (const float*)d_in[12];
    const float* ln2_w = (const float*)d_in[13];
    const float* ln2_b = (const float*)d_in[14];
    const float* wq2   = (const float*)d_in[15];
    const float* wk2   = (const float*)d_in[16];
    const float* wv2   = (const float*)d_in[17];
    const float* wo2   = (const float*)d_in[18];
    const float* bo2   = (const float*)d_in[19];
    const float* ln3_w = (const float*)d_in[20];
    const float* ln3_b = (const float*)d_in[21];
    const float* wff1  = (const float*)d_in[22];
    const float* bff1  = (const float*)d_in[23];
    const float* wff2  = (const float*)d_in[24];
    const float* bff2  = (const float*)d_in[25];
    const float* w_out = (const float*)d_in[26];
    const float* b_out = (const float*)d_in[27];
    float* out = (float*)d_out;

    const int NT = HW * CCH;  // 1,310,720
    float* ws = (float*)d_ws;
    float* t_   = ws;
    float* y_   = t_ + NT;   // (unused, kept for layout stability)
    float* pO   = y_ + NT;
    float* pL   = pO + 4 * 8 * 4096 * 40;
    float2* gnp = (float2*)(pL + 4 * 8 * 4096);
    unsigned short* u = (unsigned short*)(gnp + 256);
    unsigned short* a_bf = u;                  u += NT;
    unsigned short* q_bf = u;                  u += NT;
    unsigned short* o_bf = u;                  u += NT;
    unsigned short* t_bf = u;                  u += NT;
    unsigned short* g_bf = u;                  u += HW * FFI;
    unsigned short* Qp   = u;                  u += 8 * 4096 * 64;
    unsigned short* Kp   = u;                  u += 8 * 4096 * 64;
    unsigned short* Vt   = u;                  u += 8 * 48 * 4096;
    unsigned short* Kc   = u;                  u += 8 * 128 * 64;
    unsigned short* Vc   = u;                  u += 8 * 48 * 128;
    unsigned short* Wt   = u;                  u += 2048000 + 2 * 245760;
    unsigned short* ctx_bf = u;                u += 128 * 768;

    const unsigned short* w_inT  = Wt;
    const unsigned short* wq1T   = Wt + 102400;
    const unsigned short* wk1T   = Wt + 204800;  // wv1T contiguous at +307200
    const unsigned short* wo1T   = Wt + 409600;
    const unsigned short* wq2T   = Wt + 512000;
    const unsigned short* wo2T   = Wt + 614400;
    const unsigned short* w_outT = Wt + 716800;
    const unsigned short* wff1T  = Wt + 819200;
    const unsigned short* wff2T  = Wt + 1638400;
    const unsigned short* wk2T   = Wt + 2048000;  // wv2T contiguous (N=640)

    const float qscale = 0.15811388300841897f * 1.4426950408889634f;  // 40^-.5 * log2e

    prep_w2<<<620, 256, 0, stream>>>(w_in, wq1, wk1, wv1, wo1, wq2, wo2, w_out,
                                     wff1, wff2, wk2, wv2, Wt);
    hipMemsetAsync(Qp, 0,
                   (size_t)(8 * 4096 * 64 * 2 + 8 * 48 * 4096 + 8 * 128 * 64 + 8 * 48 * 128) * 2,
                   stream);
    set_ones<<<132, 256, 0, stream>>>(Vt, Vc);
    pack_ctx<<<384, 256, 0, stream>>>(ctx, ctx_bf);

    // 1) GroupNorm -> a_bf (HW,C)
    gn_stats<<<256, 256, 0, stream>>>(x, gnp);
    gn_apply<<<dim3(64, 5), 256, 0, stream>>>(x, gnp, gn_w, gn_b, a_bf);
    // 2) proj_in: t = a @ w_in + b_in (fp32)
    gemm4<2, 320><<<dim3(5, 128), 256, 0, stream>>>(a_bf, w_inT, b_in, nullptr, t_, nullptr, CCH, 0, 1.f);
    // 3) ln1 -> a_bf
    ln_kernel<<<1024, 256, 0, stream>>>(t_, ln1_w, ln1_b, a_bf);
    // 4) q (dual); k&v in one N=640 dispatch
    gemm4<2, 320><<<dim3(5, 128), 256, 0, stream>>>(a_bf, wq1T, nullptr, nullptr, q_bf, Qp, CCH, 6, qscale);
    gemm4<2, 320><<<dim3(10, 128), 256, 0, stream>>>(q_bf, wk1T, nullptr, nullptr, Kp, Vt, 640, 7, 1.f);
    // 5) self-attention: 128 queries/block, 4 segs, XCD swizzle
    attn7<16, false><<<1024, 256, 0, stream>>>(Qp, Kp, Vt, pO, pL, HW, HW);
    attn_combine2<<<1280, 256, 0, stream>>>(pO, pL, o_bf, 4);
    // 6) t += o @ wo1 + bo1
    gemm4<2, 320><<<dim3(5, 128), 256, 0, stream>>>(o_bf, wo1T, bo1, t_, t_, nullptr, CCH, 0, 1.f);
    // 7) ln2 -> a_bf
    ln_kernel<<<1024, 256, 0, stream>>>(t_, ln2_w, ln2_b, a_bf);
    // 8) cross q -> Qp; ctx K/V via MFMA gemm (mode 8)
    gemm4<2, 320><<<dim3(5, 128), 256, 0, stream>>>(a_bf, wq2T, nullptr, nullptr, Qp, nullptr, CCH, 2, qscale);
    gemm4<2, 768><<<dim3(10, 4), 256, 0, stream>>>(ctx_bf, wk2T, nullptr, nullptr, Kc, Vc, 640, 8, 1.f);
    // 9) cross-attention (Lk=77, masked)
    attn7<2, true><<<256, 256, 0, stream>>>(Qp, Kc, Vc, pO, pL, 77, 128);
    attn_combine2<<<1280, 256, 0, stream>>>(pO, pL, o_bf, 1);
    // 10) t += o @ wo2 + bo2
    gemm4<2, 320><<<dim3(5, 128), 256, 0, stream>>>(o_bf, wo2T, bo2, t_, t_, nullptr, CCH, 0, 1.f);
    // 11) ln3 -> a_bf
    ln_kernel<<<1024, 256, 0, stream>>>(t_, ln3_w, ln3_b, a_bf);
    // 12+13) FF1 with fused GEGLU -> g_bf
    gemm4<2, 320><<<dim3(40, 128), 256, 0, stream>>>(a_bf, wff1T, bff1, nullptr, g_bf, nullptr, 2 * FFI, 5, 1.f);
    // 14) t_bf = bf16(t + g @ wff2 + bff2)
    gemm4<2, 1280><<<dim3(5, 128), 256, 0, stream>>>(g_bf, wff2T, bff2, t_, t_bf, nullptr, CCH, 4, 1.f);
    // 15+16) out = (t_bf @ w_out + b_out)^T + x  (final fused, mode 9)
    gemm4<2, 320><<<dim3(5, 128), 256, 0, stream>>>(t_bf, w_outT, b_out, x, out, nullptr, CCH, 9, 1.f);
}

// Round 14
// 315.490 us; speedup vs baseline: 7.4971x; 1.0461x over previous
//
#include <hip/hip_runtime.h>
#include <hip/hip_bf16.h>
#include <math.h>

#define CCH 320
#define NHEADS 8
#define DH 40
#define HW 4096
#define FFI 1280

typedef __bf16 bf16x8 __attribute__((ext_vector_type(8)));
typedef unsigned short u16x8 __attribute__((ext_vector_type(8)));
typedef short s16x4 __attribute__((ext_vector_type(4)));
typedef float f32x4 __attribute__((ext_vector_type(4)));
typedef unsigned int u32x4 __attribute__((ext_vector_type(4)));

__device__ inline unsigned short f2bf(float f) {
    __hip_bfloat16 h = __float2bfloat16(f);
    return __builtin_bit_cast(unsigned short, h);
}
// HW packed f32x2 -> bf16x2 convert where available.
__device__ inline unsigned pk2bf(float a, float b) {
#if __has_builtin(__builtin_amdgcn_cvt_pk_bf16_f32)
    typedef __bf16 bf16x2 __attribute__((ext_vector_type(2)));
    bf16x2 r = __builtin_amdgcn_cvt_pk_bf16_f32(a, b);
    return __builtin_bit_cast(unsigned, r);
#else
    return (unsigned)f2bf(a) | ((unsigned)f2bf(b) << 16);
#endif
}
__device__ inline float bf2f(unsigned short u) {
    return __builtin_bit_cast(float, ((unsigned)u) << 16);
}
__device__ inline bf16x8 ldfrag(const unsigned short* p) {
    u16x8 raw = *reinterpret_cast<const u16x8*>(p);
    return __builtin_bit_cast(bf16x8, raw);
}
// Build a k=16 B-operand fragment from two packed bf16 dwords (no shuffle!).
__device__ inline s16x4 pk2frag(unsigned a, unsigned b) {
    unsigned long long v = (unsigned long long)a | ((unsigned long long)b << 32);
    return __builtin_bit_cast(s16x4, v);
}

// ---------------------------------------------------------------------------
// Coalesced weight transpose via LDS 64x65 tiles. 620 tiles.
__global__ __launch_bounds__(256) void prep_w2(
    const float* __restrict__ w_in, const float* __restrict__ wq1,
    const float* __restrict__ wk1, const float* __restrict__ wv1,
    const float* __restrict__ wo1, const float* __restrict__ wq2,
    const float* __restrict__ wo2, const float* __restrict__ w_out,
    const float* __restrict__ wff1, const float* __restrict__ wff2,
    const float* __restrict__ wk2, const float* __restrict__ wv2,
    unsigned short* __restrict__ Wt) {
    __shared__ float tile[64][65];
    const int b = blockIdx.x, tid = threadIdx.x;
    const float* src;
    int K, stride, dstoff, k0, n0;
    bool glu = false;
    if (b < 200) {
        int m = b / 25, t = b % 25;
        k0 = (t / 5) * 64; n0 = (t % 5) * 64;
        K = 320; stride = 320; dstoff = m * 102400;
        src = (m == 0) ? w_in : (m == 1) ? wq1 : (m == 2) ? wk1 :
              (m == 3) ? wv1 : (m == 4) ? wo1 : (m == 5) ? wq2 :
              (m == 6) ? wo2 : w_out;
    } else if (b < 300) {
        int t = b - 200;
        k0 = (t / 5) * 64; n0 = (t % 5) * 64;
        K = 1280; stride = 320; dstoff = 1638400; src = wff2;
    } else if (b < 500) {
        int t = b - 300;
        k0 = (t / 40) * 64; n0 = (t % 40) * 64;
        K = 320; stride = 2560; dstoff = 819200; src = wff1; glu = true;
    } else if (b < 560) {
        int t = b - 500;
        k0 = (t / 5) * 64; n0 = (t % 5) * 64;
        K = 768; stride = 320; dstoff = 2048000; src = wk2;
    } else {
        int t = b - 560;
        k0 = (t / 5) * 64; n0 = (t % 5) * 64;
        K = 768; stride = 320; dstoff = 2048000 + 245760; src = wv2;
    }
#pragma unroll
    for (int i = 0; i < 16; ++i) {
        int idx = tid + i * 256;
        int r = idx >> 6, cn = idx & 63;
        int scol = glu ? ((n0 >> 1) + (cn >> 1) + (cn & 1) * FFI) : (n0 + cn);
        tile[r][cn] = src[(size_t)(k0 + r) * stride + scol];
    }
    __syncthreads();
#pragma unroll
    for (int i = 0; i < 16; ++i) {
        int idx = tid + i * 256;
        int cl = idx >> 6, cr = idx & 63;
        Wt[dstoff + (size_t)(n0 + cl) * K + k0 + cr] = f2bf(tile[cr][cl]);
    }
}

// ---------------------------------------------------------------------------
// ctx (77x768 fp32) -> bf16 (128x768), rows >= 77 zeroed.
__global__ void pack_ctx(const float* __restrict__ ctx,
                         unsigned short* __restrict__ D) {
    int idx = blockIdx.x * 256 + threadIdx.x;  // grid 384 -> 98304 exact
    int row = idx / 768, col = idx - row * 768;
    float v = (row < 77) ? ctx[row * 768 + col] : 0.f;
    D[idx] = f2bf(v);
}

// ---------------------------------------------------------------------------
__global__ __launch_bounds__(256) void gn_stats(const float* __restrict__ X,
                                                float2* __restrict__ part) {
    __shared__ float s1[256], s2[256];
    const int b = blockIdx.x, tid = threadIdx.x;
    const float* xg = X + b * 5120;
    float s = 0.f, sq = 0.f;
#pragma unroll
    for (int i = 0; i < 20; ++i) { float v = xg[tid + i * 256]; s += v; sq += v * v; }
    s1[tid] = s; s2[tid] = sq; __syncthreads();
    for (int off = 128; off > 0; off >>= 1) {
        if (tid < off) { s1[tid] += s1[tid + off]; s2[tid] += s2[tid + off]; }
        __syncthreads();
    }
    if (tid == 0) part[b] = make_float2(s1[0], s2[0]);
}

__global__ __launch_bounds__(256) void gn_apply(const float* __restrict__ X,
                                                const float2* __restrict__ part,
                                                const float* __restrict__ w,
                                                const float* __restrict__ b,
                                                unsigned short* __restrict__ Y) {
    __shared__ float tile[64][65];
    __shared__ float gm[32], gr[32];
    const int tid = threadIdx.x;
    const int hw0 = blockIdx.x * 64, c0 = blockIdx.y * 64;
    if (tid < 32) {
        float s = 0.f, sq = 0.f;
#pragma unroll
        for (int i = 0; i < 8; ++i) { float2 p = part[tid * 8 + i]; s += p.x; sq += p.y; }
        float mean = s * (1.f / 40960.f);
        float var  = sq * (1.f / 40960.f) - mean * mean;
        gm[tid] = mean; gr[tid] = rsqrtf(var + 1e-6f);
    }
#pragma unroll
    for (int i = 0; i < 16; ++i) {
        int idx = tid + i * 256;
        int r = idx >> 6, col = idx & 63;
        tile[r][col] = X[(size_t)(c0 + r) * HW + hw0 + col];
    }
    __syncthreads();
#pragma unroll
    for (int i = 0; i < 16; ++i) {
        int idx = tid + i * 256;
        int hwl = idx >> 6, cl = idx & 63;
        int c = c0 + cl, g = c / 10;
        float v = (tile[cl][hwl] - gm[g]) * gr[g] * w[c] + b[c];
        Y[(size_t)(hw0 + hwl) * CCH + c] = f2bf(v);
    }
}

// ---------------------------------------------------------------------------
__global__ __launch_bounds__(256) void ln_kernel(const float* __restrict__ X,
                                                 const float* __restrict__ w,
                                                 const float* __restrict__ b,
                                                 unsigned short* __restrict__ Y) {
    const int row  = blockIdx.x * 4 + (threadIdx.x >> 6);
    const int lane = threadIdx.x & 63;
    const float* xr = X + row * CCH;
    float v[5];
    float s = 0.f, sq = 0.f;
#pragma unroll
    for (int i = 0; i < 5; ++i) { v[i] = xr[lane + 64 * i]; s += v[i]; sq += v[i] * v[i]; }
#pragma unroll
    for (int off = 32; off > 0; off >>= 1) {
        s  += __shfl_xor(s, off, 64);
        sq += __shfl_xor(sq, off, 64);
    }
    const float mean = s * (1.f / 320.f);
    const float var  = sq * (1.f / 320.f) - mean * mean;
    const float rstd = rsqrtf(var + 1e-5f);
    unsigned short* yr = Y + row * CCH;
#pragma unroll
    for (int i = 0; i < 5; ++i) {
        int c = lane + 64 * i;
        yr[c] = f2bf((v[i] - mean) * rstd * w[c] + b[c]);
    }
}

// ---------------------------------------------------------------------------
// gemm4 (proven double-buffer GEMM).
// Modes: 0 fp32+bias(+res) | 2 QK-pack*scale | 4 bf16+bias+res |
//        5 GLU-interleaved | 6 dual bf16+QK-pack | 7 kv-merged (Lkp=4096) |
//        8 ctx kv-merged (Lkp=128) | 9 transposed fp32 out + x (final fused)
template <int MT, int K>
__global__ __launch_bounds__(256) void gemm4(
    const unsigned short* __restrict__ A,
    const unsigned short* __restrict__ Bt,
    const float* __restrict__ bias,
    const float* __restrict__ res,
    void* __restrict__ Cout, void* __restrict__ Cout2,
    int N, int mode, float scale) {
    constexpr int NCH = K / 64;
    __shared__ __align__(16) unsigned short Ab[2][MT * 16 * 64];
    __shared__ __align__(16) unsigned short Bb[2][64 * 64];
    const int tid  = threadIdx.x;
    const int wave = tid >> 6, lane = tid & 63;
    const int quad = lane >> 4, c = lane & 15;
    const int m0 = blockIdx.y * (MT * 16);
    const int bn = blockIdx.x;

    f32x4 acc[MT];
#pragma unroll
    for (int i = 0; i < MT; ++i) acc[i] = (f32x4){0.f, 0.f, 0.f, 0.f};

    const unsigned short* aslab = A + (size_t)m0 * K;
    const unsigned short* bslab = Bt + (size_t)(bn * 64) * K;

    constexpr int ITA = MT * 16 * 8 / 256;
    int arow[ITA], aoff[ITA];
#pragma unroll
    for (int i = 0; i < ITA; ++i) {
        int idx = tid + i * 256;
        arow[i] = idx >> 3;
        int g = idx & 7;
        aoff[i] = arow[i] * 64 + ((g ^ (arow[i] & 7)) * 8);
    }
    int brow[2], boff[2];
#pragma unroll
    for (int i = 0; i < 2; ++i) {
        int idx = tid + i * 256;
        brow[i] = idx >> 3;
        int g = idx & 7;
        boff[i] = brow[i] * 64 + ((g ^ (brow[i] & 7)) * 8);
    }
    const int ag = (tid & 7) * 8;

    {
        u16x8 ra[ITA], rb[2];
#pragma unroll
        for (int i = 0; i < ITA; ++i)
            ra[i] = *(const u16x8*)(aslab + (size_t)arow[i] * K + ag);
#pragma unroll
        for (int i = 0; i < 2; ++i)
            rb[i] = *(const u16x8*)(bslab + (size_t)brow[i] * K + ag);
#pragma unroll
        for (int i = 0; i < ITA; ++i) *(u16x8*)&Ab[0][aoff[i]] = ra[i];
#pragma unroll
        for (int i = 0; i < 2; ++i) *(u16x8*)&Bb[0][boff[i]] = rb[i];
    }
    __syncthreads();

    const int swz0 = (quad ^ (c & 7)) * 8;
    const int swz1 = ((quad + 4) ^ (c & 7)) * 8;
#pragma unroll
    for (int ch = 0; ch < NCH; ++ch) {
        const int buf = ch & 1;
        u16x8 ra[ITA], rb[2];
        if (ch + 1 < NCH) {
            const int kb = (ch + 1) * 64;
#pragma unroll
            for (int i = 0; i < ITA; ++i)
                ra[i] = *(const u16x8*)(aslab + (size_t)arow[i] * K + kb + ag);
#pragma unroll
            for (int i = 0; i < 2; ++i)
                rb[i] = *(const u16x8*)(bslab + (size_t)brow[i] * K + kb + ag);
        }
        bf16x8 b0 = ldfrag(&Bb[buf][(wave * 16 + c) * 64 + swz0]);
        bf16x8 b1 = ldfrag(&Bb[buf][(wave * 16 + c) * 64 + swz1]);
#pragma unroll
        for (int mt = 0; mt < MT; ++mt) {
            bf16x8 a0 = ldfrag(&Ab[buf][(mt * 16 + c) * 64 + swz0]);
            bf16x8 a1 = ldfrag(&Ab[buf][(mt * 16 + c) * 64 + swz1]);
            acc[mt] = __builtin_amdgcn_mfma_f32_16x16x32_bf16(a0, b0, acc[mt], 0, 0, 0);
            acc[mt] = __builtin_amdgcn_mfma_f32_16x16x32_bf16(a1, b1, acc[mt], 0, 0, 0);
        }
        if (ch + 1 < NCH) {
            const int nb = buf ^ 1;
#pragma unroll
            for (int i = 0; i < ITA; ++i) *(u16x8*)&Ab[nb][aoff[i]] = ra[i];
#pragma unroll
            for (int i = 0; i < 2; ++i) *(u16x8*)&Bb[nb][boff[i]] = rb[i];
        }
        __syncthreads();
    }

    const int col = bn * 64 + wave * 16 + c;
    float bval = 0.f;
    if (bias) bval = (mode == 5) ? bias[(col >> 1) + (col & 1) * FFI] : bias[col];

    if (mode == 9) {  // transposed fp32 out + x residual (final fused), float4
#pragma unroll
        for (int mt = 0; mt < MT; ++mt) {
            const int row0 = m0 + mt * 16 + quad * 4;
            float4 xv = *(const float4*)(res + (size_t)col * HW + row0);
            float4 ov;
            ov.x = acc[mt][0] + bval + xv.x;
            ov.y = acc[mt][1] + bval + xv.y;
            ov.z = acc[mt][2] + bval + xv.z;
            ov.w = acc[mt][3] + bval + xv.w;
            *(float4*)((float*)Cout + (size_t)col * HW + row0) = ov;
        }
        return;
    }
#pragma unroll
    for (int mt = 0; mt < MT; ++mt) {
#pragma unroll
        for (int r = 0; r < 4; ++r) {
            const int row = m0 + mt * 16 + quad * 4 + r;
            float v = acc[mt][r];
            if (mode == 0) {
                v += bval;
                if (res) v += res[(size_t)row * N + col];
                ((float*)Cout)[(size_t)row * N + col] = v;
            } else if (mode == 2) {
                int h = col & 7, d = col >> 3;
                ((unsigned short*)Cout)[(((size_t)h << 12) + row) * 64 + d] = f2bf(v * scale);
            } else if (mode == 4) {
                ((unsigned short*)Cout)[(size_t)row * N + col] =
                    f2bf(v + bval + res[(size_t)row * N + col]);
            } else if (mode == 5) {
                v += bval;
                float other = __shfl_xor(v, 1, 64);
                if ((c & 1) == 0) {
                    float g = 0.5f * other * (1.f + erff(other * 0.70710678118654752f));
                    ((unsigned short*)Cout)[(size_t)row * FFI + (col >> 1)] = f2bf(v * g);
                }
            } else if (mode == 6) {
                ((unsigned short*)Cout)[(size_t)row * N + col] = f2bf(v);
                int h = col & 7, d = col >> 3;
                ((unsigned short*)Cout2)[(((size_t)h << 12) + row) * 64 + d] = f2bf(v * scale);
            } else if (mode == 7) {
                if (col < 320) {
                    int h = col & 7, d = col >> 3;
                    ((unsigned short*)Cout)[(((size_t)h << 12) + row) * 64 + d] = f2bf(v);
                } else {
                    int c2 = col - 320;
                    int h = c2 & 7, d = c2 >> 3;
                    ((unsigned short*)Cout2)[(((size_t)(h * 48 + d)) << 12) + row] = f2bf(v);
                }
            } else {  // 8: ctx kv-merged, Lkp = 128
                if (col < 320) {
                    int h = col & 7, d = col >> 3;
                    ((unsigned short*)Cout)[(((size_t)h << 7) + row) * 64 + d] = f2bf(v);
                } else {
                    int c2 = col - 320;
                    int h = c2 & 7, d = c2 >> 3;
                    ((unsigned short*)Cout2)[(size_t)(h * 48 + d) * 128 + row] = f2bf(v);
                }
            }
        }
    }
}

// ---------------------------------------------------------------------------
// Set V^T padded dim-40 row to 1.0 so sum(p) materializes in the PV MFMA.
__global__ void set_ones(unsigned short* __restrict__ Vt,
                         unsigned short* __restrict__ Vc) {
    int idx = blockIdx.x * 256 + threadIdx.x;  // grid 132 -> 33792 exact
    if (idx < 32768) {
        int h = idx >> 12, r = idx & 4095;
        Vt[((size_t)(h * 48 + 40) << 12) + r] = 0x3F80;  // bf16(1.0)
    } else {
        int j = idx - 32768;
        int h = j >> 7, r = j & 127;
        Vc[(h * 48 + 40) * 128 + r] = 0x3F80;
    }
}

// ---------------------------------------------------------------------------
// attn8: LDS-staged flash attention, 128 queries/block. PV uses k=16 MFMAs
// (mfma_f32_16x16x16bf16_1k) whose B-operand layout EQUALS the S^T C-layout,
// so the packed exp2 dwords feed PV directly — zero bpermutes/selects.
// V A-frags are 8B ds_read_b64 per (dim-block, key-block).
template <int TILES, bool MASK>
__global__ __launch_bounds__(256) void attn8(
    const unsigned short* __restrict__ Qp,
    const unsigned short* __restrict__ Kp,
    const unsigned short* __restrict__ Vt,
    float* __restrict__ pO, float* __restrict__ pL,
    int Lk, int Lkp) {
    __shared__ __align__(16) unsigned short Kb[2][64 * 64];
    __shared__ __align__(16) unsigned short Vb[2][48 * 64];
    const int tid  = threadIdx.x;
    const int wave = tid >> 6, lane = tid & 63;
    const int quad = lane >> 4, c = lane & 15;
    const int id  = blockIdx.x;
    const int h   = id & 7;
    const int qt  = (id >> 3) & 31;
    const int seg = id >> 8;
    const int q0  = qt * 128 + wave * 32;

    const unsigned short* qbaseA = Qp + ((((size_t)h << 12) + q0 + c) << 6) + quad * 8;
    const bf16x8 bQA0 = ldfrag(qbaseA);
    const bf16x8 bQA1 = ldfrag(qbaseA + 32);
    const bf16x8 bQB0 = ldfrag(qbaseA + 1024);
    const bf16x8 bQB1 = ldfrag(qbaseA + 1024 + 32);

    f32x4 oA[3], oB[3];
#pragma unroll
    for (int i = 0; i < 3; ++i) {
        oA[i] = (f32x4){0.f, 0.f, 0.f, 0.f};
        oB[i] = (f32x4){0.f, 0.f, 0.f, 0.f};
    }

    const int kt0 = seg * TILES;
    const unsigned short* kglob = Kp + (((size_t)h * Lkp + kt0 * 64) << 6);
    const unsigned short* vglob = Vt + ((size_t)h * 48) * Lkp + kt0 * 64;

    const int r0 = lane >> 3;
    const int g  = lane & 7;
    int ldsoff[4];
    const unsigned short* gptr0[4];
#pragma unroll
    for (int i = 0; i < 4; ++i) {
        int s = wave + 4 * i;
        if (s < 8) {
            int row = s * 8 + r0;
            ldsoff[i] = row * 64 + (g ^ (row & 7)) * 8;
            gptr0[i]  = kglob + (size_t)row * 64 + g * 8;
        } else if (s < 14) {
            int d = (s - 8) * 8 + r0;
            ldsoff[i] = d * 64 + (g ^ (d & 7)) * 8;
            gptr0[i]  = vglob + (size_t)d * Lkp + g * 8;
        } else {
            ldsoff[i] = 0; gptr0[i] = nullptr;
        }
    }
    const bool isK[4] = {(wave + 0) < 8, (wave + 4) < 8, (wave + 8) < 8, (wave + 12) < 8};
    const bool act[4] = {true, true, true, (wave + 12) < 14};

    {
        u16x8 st[4];
#pragma unroll
        for (int i = 0; i < 4; ++i)
            if (act[i]) st[i] = *(const u16x8*)(gptr0[i]);
#pragma unroll
        for (int i = 0; i < 4; ++i)
            if (act[i]) {
                unsigned short* lp = isK[i] ? &Kb[0][ldsoff[i]] : &Vb[0][ldsoff[i]];
                *(u16x8*)lp = st[i];
            }
    }
    __syncthreads();

#pragma unroll
    for (int t = 0; t < TILES; ++t) {
        const int b = t & 1;
        u16x8 st[4];
        if (t + 1 < TILES) {
            const int kb = (t + 1) * 64;
#pragma unroll
            for (int i = 0; i < 4; ++i)
                if (act[i]) {
                    const unsigned short* gp =
                        isK[i] ? (gptr0[i] + (size_t)kb * 64) : (gptr0[i] + kb);
                    st[i] = *(const u16x8*)gp;
                }
        }
        const unsigned short* Kl = &Kb[b][0];
        const unsigned short* Vl = &Vb[b][0];
        const int sw0 = (quad ^ (c & 7)) * 8;
        const int sw1 = ((quad + 4) ^ (c & 7)) * 8;
        // ---- S^T for both query groups ----
        f32x4 sA[4], sB[4];
#pragma unroll
        for (int blk = 0; blk < 4; ++blk) {
            const int row = (blk * 16 + c) * 64;
            bf16x8 k0 = ldfrag(Kl + row + sw0);
            bf16x8 k1 = ldfrag(Kl + row + sw1);
            f32x4 zA = {0.f, 0.f, 0.f, 0.f};
            zA = __builtin_amdgcn_mfma_f32_16x16x32_bf16(k0, bQA0, zA, 0, 0, 0);
            zA = __builtin_amdgcn_mfma_f32_16x16x32_bf16(k1, bQA1, zA, 0, 0, 0);
            sA[blk] = zA;
            f32x4 zB = {0.f, 0.f, 0.f, 0.f};
            zB = __builtin_amdgcn_mfma_f32_16x16x32_bf16(k0, bQB0, zB, 0, 0, 0);
            zB = __builtin_amdgcn_mfma_f32_16x16x32_bf16(k1, bQB1, zB, 0, 0, 0);
            sB[blk] = zB;
        }
        if (MASK) {
            const int abs_kb = kt0 * 64 + t * 64;
#pragma unroll
            for (int blk = 0; blk < 4; ++blk)
#pragma unroll
                for (int r = 0; r < 4; ++r) {
                    bool inv = (abs_kb + blk * 16 + quad * 4 + r >= Lk);
                    sA[blk][r] = inv ? -30000.f : sA[blk][r];
                    sB[blk][r] = inv ? -30000.f : sB[blk][r];
                }
        }
        // ---- p = exp2(s); pack as B-fragments (identity layout) ----
        s16x4 PA[4], PB[4];
#pragma unroll
        for (int blk = 0; blk < 4; ++blk) {
            PA[blk] = pk2frag(pk2bf(exp2f(sA[blk][0]), exp2f(sA[blk][1])),
                              pk2bf(exp2f(sA[blk][2]), exp2f(sA[blk][3])));
            PB[blk] = pk2frag(pk2bf(exp2f(sB[blk][0]), exp2f(sB[blk][1])),
                              pk2bf(exp2f(sB[blk][2]), exp2f(sB[blk][3])));
        }
        // ---- O^T += V^T · P^T via k=16 MFMAs (B = P directly) ----
#pragma unroll
        for (int db = 0; db < 3; ++db) {
            const int dim = db * 16 + c;
            const unsigned short* vrow = Vl + dim * 64;
            const int dswz = dim & 7;
#pragma unroll
            for (int kb = 0; kb < 4; ++kb) {
                const int off = (((kb * 2 + (quad >> 1)) ^ dswz) * 8) + (quad & 1) * 4;
                s16x4 vf = *(const s16x4*)(vrow + off);
                oA[db] = __builtin_amdgcn_mfma_f32_16x16x16bf16_1k(vf, PA[kb], oA[db], 0, 0, 0);
                oB[db] = __builtin_amdgcn_mfma_f32_16x16x16bf16_1k(vf, PB[kb], oB[db], 0, 0, 0);
            }
        }
        if (t + 1 < TILES) {
            const int nb = b ^ 1;
#pragma unroll
            for (int i = 0; i < 4; ++i)
                if (act[i]) {
                    unsigned short* lp = isK[i] ? &Kb[nb][ldsoff[i]] : &Vb[nb][ldsoff[i]];
                    *(u16x8*)lp = st[i];
                }
        }
        __syncthreads();
    }
    // epilogue: dims 0..39 per query; l = PV row 40 = oX[2][0] at quad==2
    const size_t base = ((size_t)(seg * 8 + h)) << 12;
    float* obA = pO + (base + q0 + c) * 40;
    *(float4*)(obA + quad * 4)      = make_float4(oA[0][0], oA[0][1], oA[0][2], oA[0][3]);
    *(float4*)(obA + 16 + quad * 4) = make_float4(oA[1][0], oA[1][1], oA[1][2], oA[1][3]);
    if (quad < 2)
        *(float4*)(obA + 32 + quad * 4) = make_float4(oA[2][0], oA[2][1], oA[2][2], oA[2][3]);
    float* obB = pO + (base + q0 + 16 + c) * 40;
    *(float4*)(obB + quad * 4)      = make_float4(oB[0][0], oB[0][1], oB[0][2], oB[0][3]);
    *(float4*)(obB + 16 + quad * 4) = make_float4(oB[1][0], oB[1][1], oB[1][2], oB[1][3]);
    if (quad < 2)
        *(float4*)(obB + 32 + quad * 4) = make_float4(oB[2][0], oB[2][1], oB[2][2], oB[2][3]);
    if (quad == 2) {
        pL[base + q0 + c]      = oA[2][0];
        pL[base + q0 + 16 + c] = oB[2][0];
    }
}

// Combine partials (vectorized): float4 loads, packed bf16 stores.
__global__ __launch_bounds__(256) void attn_combine2(
    const float* __restrict__ pO, const float* __restrict__ pL,
    unsigned short* __restrict__ O, int S) {
    int idx = blockIdx.x * 256 + threadIdx.x;  // < 8*4096*10, grid 1280
    int h = idx / (HW * 10);
    int rem = idx - h * (HW * 10);
    int row = rem / 10, dg = rem - row * 10;
    float4 num = make_float4(0.f, 0.f, 0.f, 0.f);
    float den = 0.f;
    for (int s = 0; s < S; ++s) {
        size_t base = ((size_t)(s * 8 + h)) << 12;
        float4 p = *(const float4*)(pO + (base + row) * 40 + dg * 4);
        num.x += p.x; num.y += p.y; num.z += p.z; num.w += p.w;
        den += pL[base + row];
    }
    float inv = 1.f / den;
    unsigned short* ob = O + (size_t)row * CCH + h * DH + dg * 4;
    unsigned lo = pk2bf(num.x * inv, num.y * inv);
    unsigned hi = pk2bf(num.z * inv, num.w * inv);
    *(uint2*)ob = make_uint2(lo, hi);
}

// ---------------------------------------------------------------------------
extern "C" void kernel_launch(void* const* d_in, const int* in_sizes, int n_in,
                              void* d_out, int out_size, void* d_ws, size_t ws_size,
                              hipStream_t stream) {
    const float* x     = (const float*)d_in[0];
    const float* ctx   = (const float*)d_in[1];
    const float* gn_w  = (const float*)d_in[2];
    const float* gn_b  = (const float*)d_in[3];
    const float* w_in  = (const float*)d_in[4];
    const float* b_in  = (const float*)d_in[5];
    const float* ln1_w = (const float*)d_in[6];
    const float* ln1_b = (const float*)d_in[7];
    const float* wq1   = (const float*)d_in[8];
    const float* wk1   = (const float*)d_in[9];
    const float* wv1   = (const float*)d_in[10];
    const float* wo1   = (const float*)d_in[11];
    const float* bo1   = (const float*)d_in[12];
    const float* ln2_w = (const float*)d_in[13];
    const float* ln2_b = (const float*)d_in[14];
    const float* wq2   = (const float*)d_in[15];
    const float* wk2   = (const float*)d_in[16];
    const float* wv2   = (const float*)d_in[17];
    const float* wo2   = (const float*)d_in[18];
    const float* bo2   = (const float*)d_in[19];
    const float* ln3_w = (const float*)d_in[20];
    const float* ln3_b = (const float*)d_in[21];
    const float* wff1  = (const float*)d_in[22];
    const float* bff1  = (const float*)d_in[23];
    const float* wff2  = (const float*)d_in[24];
    const float* bff2  = (const float*)d_in[25];
    const float* w_out = (const float*)d_in[26];
    const float* b_out = (const float*)d_in[27];
    float* out = (float*)d_out;

    const int NT = HW * CCH;  // 1,310,720
    float* ws = (float*)d_ws;
    float* t_   = ws;
    float* y_   = t_ + NT;   // (unused, layout stability)
    float* pO   = y_ + NT;
    float* pL   = pO + 4 * 8 * 4096 * 40;
    float2* gnp = (float2*)(pL + 4 * 8 * 4096);
    unsigned short* u = (unsigned short*)(gnp + 256);
    unsigned short* a_bf = u;                  u += NT;
    unsigned short* q_bf = u;                  u += NT;
    unsigned short* o_bf = u;                  u += NT;
    unsigned short* t_bf = u;                  u += NT;
    unsigned short* g_bf = u;                  u += HW * FFI;
    unsigned short* Qp   = u;                  u += 8 * 4096 * 64;
    unsigned short* Kp   = u;                  u += 8 * 4096 * 64;
    unsigned short* Vt   = u;                  u += 8 * 48 * 4096;
    unsigned short* Kc   = u;                  u += 8 * 128 * 64;
    unsigned short* Vc   = u;                  u += 8 * 48 * 128;
    unsigned short* Wt   = u;                  u += 2048000 + 2 * 245760;
    unsigned short* ctx_bf = u;                u += 128 * 768;

    const unsigned short* w_inT  = Wt;
    const unsigned short* wq1T   = Wt + 102400;
    const unsigned short* wk1T   = Wt + 204800;  // wv1T contiguous at +307200
    const unsigned short* wo1T   = Wt + 409600;
    const unsigned short* wq2T   = Wt + 512000;
    const unsigned short* wo2T   = Wt + 614400;
    const unsigned short* w_outT = Wt + 716800;
    const unsigned short* wff1T  = Wt + 819200;
    const unsigned short* wff2T  = Wt + 1638400;
    const unsigned short* wk2T   = Wt + 2048000;  // wv2T contiguous (N=640)

    const float qscale = 0.15811388300841897f * 1.4426950408889634f;  // 40^-.5 * log2e

    prep_w2<<<620, 256, 0, stream>>>(w_in, wq1, wk1, wv1, wo1, wq2, wo2, w_out,
                                     wff1, wff2, wk2, wv2, Wt);
    hipMemsetAsync(Qp, 0,
                   (size_t)(8 * 4096 * 64 * 2 + 8 * 48 * 4096 + 8 * 128 * 64 + 8 * 48 * 128) * 2,
                   stream);
    set_ones<<<132, 256, 0, stream>>>(Vt, Vc);
    pack_ctx<<<384, 256, 0, stream>>>(ctx, ctx_bf);

    // 1) GroupNorm -> a_bf (HW,C)
    gn_stats<<<256, 256, 0, stream>>>(x, gnp);
    gn_apply<<<dim3(64, 5), 256, 0, stream>>>(x, gnp, gn_w, gn_b, a_bf);
    // 2) proj_in: t = a @ w_in + b_in (fp32)
    gemm4<2, 320><<<dim3(5, 128), 256, 0, stream>>>(a_bf, w_inT, b_in, nullptr, t_, nullptr, CCH, 0, 1.f);
    // 3) ln1 -> a_bf
    ln_kernel<<<1024, 256, 0, stream>>>(t_, ln1_w, ln1_b, a_bf);
    // 4) q (dual); k&v in one N=640 dispatch
    gemm4<2, 320><<<dim3(5, 128), 256, 0, stream>>>(a_bf, wq1T, nullptr, nullptr, q_bf, Qp, CCH, 6, qscale);
    gemm4<2, 320><<<dim3(10, 128), 256, 0, stream>>>(q_bf, wk1T, nullptr, nullptr, Kp, Vt, 640, 7, 1.f);
    // 5) self-attention: 128 queries/block, 4 segs, XCD swizzle
    attn8<16, false><<<1024, 256, 0, stream>>>(Qp, Kp, Vt, pO, pL, HW, HW);
    attn_combine2<<<1280, 256, 0, stream>>>(pO, pL, o_bf, 4);
    // 6) t += o @ wo1 + bo1
    gemm4<2, 320><<<dim3(5, 128), 256, 0, stream>>>(o_bf, wo1T, bo1, t_, t_, nullptr, CCH, 0, 1.f);
    // 7) ln2 -> a_bf
    ln_kernel<<<1024, 256, 0, stream>>>(t_, ln2_w, ln2_b, a_bf);
    // 8) cross q -> Qp; ctx K/V via MFMA gemm (mode 8)
    gemm4<2, 320><<<dim3(5, 128), 256, 0, stream>>>(a_bf, wq2T, nullptr, nullptr, Qp, nullptr, CCH, 2, qscale);
    gemm4<2, 768><<<dim3(10, 4), 256, 0, stream>>>(ctx_bf, wk2T, nullptr, nullptr, Kc, Vc, 640, 8, 1.f);
    // 9) cross-attention (Lk=77, masked)
    attn8<2, true><<<256, 256, 0, stream>>>(Qp, Kc, Vc, pO, pL, 77, 128);
    attn_combine2<<<1280, 256, 0, stream>>>(pO, pL, o_bf, 1);
    // 10) t += o @ wo2 + bo2
    gemm4<2, 320><<<dim3(5, 128), 256, 0, stream>>>(o_bf, wo2T, bo2, t_, t_, nullptr, CCH, 0, 1.f);
    // 11) ln3 -> a_bf
    ln_kernel<<<1024, 256, 0, stream>>>(t_, ln3_w, ln3_b, a_bf);
    // 12+13) FF1 with fused GEGLU -> g_bf
    gemm4<2, 320><<<dim3(40, 128), 256, 0, stream>>>(a_bf, wff1T, bff1, nullptr, g_bf, nullptr, 2 * FFI, 5, 1.f);
    // 14) t_bf = bf16(t + g @ wff2 + bff2)
    gemm4<2, 1280><<<dim3(5, 128), 256, 0, stream>>>(g_bf, wff2T, bff2, t_, t_bf, nullptr, CCH, 4, 1.f);
    // 15+16) out = (t_bf @ w_out + b_out)^T + x  (final fused, mode 9)
    gemm4<2, 320><<<dim3(5, 128), 256, 0, stream>>>(t_bf, w_outT, b_out, x, out, nullptr, CCH, 9, 1.f);
}